// Round 1
// baseline (4635.291 us; speedup 1.0000x reference)
//
#include <hip/hip_runtime.h>
#include <cstdint>
#include <cstddef>

#define H_DIM 128
#define N_HEADS 4
#define D_K 32
#define W_INP 300
#define N_DOC 32000
#define N_TOPIC 800
#define N_WORD 80000
#define BATCH 16

static __device__ __forceinline__ unsigned fenc(float f) {
  unsigned u = __float_as_uint(f);
  return (u & 0x80000000u) ? ~u : (u | 0x80000000u);
}
static __device__ __forceinline__ float fdec(unsigned k) {
  return (k & 0x80000000u) ? __uint_as_float(k ^ 0x80000000u) : __uint_as_float(~k);
}

// ---------------- generic projection kernel ----------------
// ACT: 0 plain (out = h@W+b), 1 tanh, 2 comb (out = proj*a + blend*(1-a)),
//      3 rel   (out = qt where qt[h,d] = sum_f (h@W+b)[h,f] * R[h,d,f])
template<int ACT>
__global__ __launch_bounds__(256) void proj_kernel(
    const float* __restrict__ src, const int* __restrict__ idx,
    const float* __restrict__ W, const float* __restrict__ bias,
    float* out, const float* blend, const float* __restrict__ skipp,
    const float* __restrict__ rel, int n, int K)
{
  extern __shared__ float smem[];
  float* Ws   = smem;                 // [64][128]
  float* hs   = Ws + 64 * 128;        // [8][64]
  float* qrow = hs + 8 * 64;          // [8][128]   (ACT3 only)
  float* Rs   = qrow + 8 * 128;       // [4][32][32] (ACT3 only)

  const int tid = threadIdx.x;
  const int cg  = tid & 31;
  const int ln  = tid >> 5;
  const int c0  = cg * 4;
  const int nb  = blockIdx.x * 8;
  const int gn  = nb + ln;

  if (ACT == 3) {
    for (int i = tid; i < 4096; i += 256) Rs[i] = rel[i];
  }

  float a0 = 0.f, a1 = 0.f, a2 = 0.f, a3 = 0.f;
  for (int kt = 0; kt < K; kt += 64) {
    #pragma unroll
    for (int j = 0; j < 8; ++j) {
      int f4  = j * 256 + tid;
      int row = f4 >> 5, col = f4 & 31;
      float4 w = make_float4(0.f, 0.f, 0.f, 0.f);
      if (kt + row < K) w = reinterpret_cast<const float4*>(W)[(size_t)(kt + row) * 32 + col];
      reinterpret_cast<float4*>(Ws)[f4] = w;
    }
    #pragma unroll
    for (int j = 0; j < 2; ++j) {
      int fi = j * 256 + tid;
      int nd = fi >> 6, k = fi & 63;
      int g = nb + nd;
      float v = 0.f;
      if (g < n && (kt + k) < K) {
        int row = idx ? idx[g] : g;
        v = src[(size_t)row * K + kt + k];
      }
      hs[nd * 64 + k] = v;
    }
    __syncthreads();
    #pragma unroll
    for (int k = 0; k < 64; k += 4) {
      float4 hv = *reinterpret_cast<const float4*>(&hs[ln * 64 + k]);
      float4 w0 = reinterpret_cast<const float4*>(Ws)[(k + 0) * 32 + cg];
      float4 w1 = reinterpret_cast<const float4*>(Ws)[(k + 1) * 32 + cg];
      float4 w2 = reinterpret_cast<const float4*>(Ws)[(k + 2) * 32 + cg];
      float4 w3 = reinterpret_cast<const float4*>(Ws)[(k + 3) * 32 + cg];
      a0 += hv.x * w0.x + hv.y * w1.x + hv.z * w2.x + hv.w * w3.x;
      a1 += hv.x * w0.y + hv.y * w1.y + hv.z * w2.y + hv.w * w3.y;
      a2 += hv.x * w0.z + hv.y * w1.z + hv.z * w2.z + hv.w * w3.z;
      a3 += hv.x * w0.w + hv.y * w1.w + hv.z * w2.w + hv.w * w3.w;
    }
    __syncthreads();
  }

  if (ACT != 3) {
    if (gn < n) {
      float v0 = a0 + bias[c0 + 0];
      float v1 = a1 + bias[c0 + 1];
      float v2 = a2 + bias[c0 + 2];
      float v3 = a3 + bias[c0 + 3];
      if (ACT == 1) { v0 = tanhf(v0); v1 = tanhf(v1); v2 = tanhf(v2); v3 = tanhf(v3); }
      if (ACT == 2) {
        float a = 1.f / (1.f + expf(-skipp[0]));
        const float4 bl = *reinterpret_cast<const float4*>(blend + (size_t)gn * H_DIM + c0);
        v0 = v0 * a + bl.x * (1.f - a); v1 = v1 * a + bl.y * (1.f - a);
        v2 = v2 * a + bl.z * (1.f - a); v3 = v3 * a + bl.w * (1.f - a);
      }
      *reinterpret_cast<float4*>(out + (size_t)gn * H_DIM + c0) = make_float4(v0, v1, v2, v3);
    }
  } else {
    qrow[ln * 128 + c0 + 0] = a0 + bias[c0 + 0];
    qrow[ln * 128 + c0 + 1] = a1 + bias[c0 + 1];
    qrow[ln * 128 + c0 + 2] = a2 + bias[c0 + 2];
    qrow[ln * 128 + c0 + 3] = a3 + bias[c0 + 3];
    __syncthreads();
    if (gn < n) {
      int h  = c0 >> 5;
      int d0 = c0 & 31;
      const float* qh = &qrow[ln * 128 + h * 32];
      const float* Rh = &Rs[h * 32 * 32];
      float o0 = 0.f, o1 = 0.f, o2 = 0.f, o3 = 0.f;
      #pragma unroll
      for (int f = 0; f < 32; ++f) {
        float qv = qh[f];
        o0 += qv * Rh[(d0 + 0) * 32 + f];
        o1 += qv * Rh[(d0 + 1) * 32 + f];
        o2 += qv * Rh[(d0 + 2) * 32 + f];
        o3 += qv * Rh[(d0 + 3) * 32 + f];
      }
      *reinterpret_cast<float4*>(out + (size_t)gn * H_DIM + c0) = make_float4(o0, o1, o2, o3);
    }
  }
}

// ---------------- gather ht ----------------
__global__ void gather_kernel(const float* __restrict__ emb, const int* __restrict__ ids,
                              float* __restrict__ out, int n) {
  int i = blockIdx.x * 256 + threadIdx.x;
  if (i < n * H_DIM) {
    int node = i >> 7, c = i & 127;
    out[i] = emb[(size_t)ids[node] * H_DIM + c];
  }
}

// ---------------- CSR build ----------------
__global__ void count_kernel(const int* __restrict__ dst, int* cnt, int E) {
  int i = blockIdx.x * 256 + threadIdx.x;
  if (i < E) atomicAdd(&cnt[dst[i]], 1);
}

__global__ void scan_kernel(const int* __restrict__ cnt, int* off, int* cursor, int n) {
  __shared__ int tile[1024];
  __shared__ int carry_s;
  int tid = threadIdx.x;
  if (tid == 0) carry_s = 0;
  __syncthreads();
  for (int base = 0; base < n; base += 4096) {
    int i0 = base + tid * 4;
    int v[4]; int s = 0;
    #pragma unroll
    for (int j = 0; j < 4; ++j) { int i = i0 + j; v[j] = (i < n) ? cnt[i] : 0; s += v[j]; }
    tile[tid] = s; __syncthreads();
    for (int ofs = 1; ofs < 1024; ofs <<= 1) {
      int t = (tid >= ofs) ? tile[tid - ofs] : 0; __syncthreads();
      tile[tid] += t; __syncthreads();
    }
    int run = tile[tid] - s + carry_s;
    #pragma unroll
    for (int j = 0; j < 4; ++j) {
      int i = i0 + j;
      if (i < n) { off[i] = run; cursor[i] = run; }
      run += v[j];
    }
    __syncthreads();
    if (tid == 1023) carry_s += tile[1023];
    __syncthreads();
  }
  if (tid == 0) off[n] = carry_s;
}

__global__ void fill_kernel(const int* __restrict__ srcA, const int* __restrict__ dstA,
                            int* cursor, int* csrc, int E) {
  int i = blockIdx.x * 256 + threadIdx.x;
  if (i < E) {
    int p = atomicAdd(&cursor[dstA[i]], 1);
    csrc[p] = srcA[i];
  }
}

// ---------------- per-dst-node softmax aggregation ----------------
// one wave per dst node; acc[h,d] = sum_e softmax_w(e) * v_raw[src,h,d]; then out = acc @ M[h]
__global__ __launch_bounds__(256) void aggregate_kernel(
    const float* __restrict__ qt, const float* __restrict__ ksrc, const float* __restrict__ vsrc,
    const int* __restrict__ offs, const int* __restrict__ csrc,
    const float* __restrict__ Mrel, const float* __restrict__ pri,
    float* t, int n_dst, float scale)
{
  __shared__ float Ms[N_HEADS * D_K * D_K];
  for (int i = threadIdx.x; i < N_HEADS * D_K * D_K; i += 256) Ms[i] = Mrel[i];
  __syncthreads();
  const int lane = threadIdx.x & 63;
  const int wave = threadIdx.x >> 6;
  const int node = blockIdx.x * 4 + wave;
  if (node >= n_dst) return;
  const int e0 = offs[node], e1 = offs[node + 1];
  if (e0 == e1) return;
  const int c0 = lane * 2;
  const int h  = lane >> 4;
  const float prih = pri[h] * 0.17677669529663687f; // rel_pri[h] / sqrt(32)
  const float qt0 = qt[(size_t)node * H_DIM + c0];
  const float qt1 = qt[(size_t)node * H_DIM + c0 + 1];
  float acc0 = 0.f, acc1 = 0.f, ssum = 0.f;
  for (int e = e0; e < e1; ++e) {
    int s = csrc[e];
    const float2 kk = *reinterpret_cast<const float2*>(ksrc + (size_t)s * H_DIM + c0);
    float part = qt0 * kk.x + qt1 * kk.y;
    part += __shfl_xor(part, 1);
    part += __shfl_xor(part, 2);
    part += __shfl_xor(part, 4);
    part += __shfl_xor(part, 8);
    float w = __expf(part * prih);
    const float2 vv = *reinterpret_cast<const float2*>(vsrc + (size_t)s * H_DIM + c0);
    ssum += w;
    acc0 += w * vv.x;
    acc1 += w * vv.y;
  }
  float inv = 1.f / ssum;
  acc0 *= inv; acc1 *= inv;
  const int d0 = c0 & 31;
  const int gbase = lane & 48;
  const float* Mh = &Ms[h * D_K * D_K];
  float o0 = 0.f, o1 = 0.f;
  #pragma unroll
  for (int j = 0; j < 16; ++j) {
    float b0 = __shfl(acc0, gbase + j);
    float b1 = __shfl(acc1, gbase + j);
    o0 += b0 * Mh[(2 * j) * D_K + d0]     + b1 * Mh[(2 * j + 1) * D_K + d0];
    o1 += b0 * Mh[(2 * j) * D_K + d0 + 1] + b1 * Mh[(2 * j + 1) * D_K + d0 + 1];
  }
  float* tp = t + (size_t)node * H_DIM + c0;
  tp[0] += scale * o0;
  tp[1] += scale * o1;
}

// ---------------- readout ----------------
__global__ void ginit_kernel(unsigned* g) {
  int i = blockIdx.x * 256 + threadIdx.x;
  if (i < BATCH * H_DIM) g[i] = 0x007FFFFFu; // fenc(-inf)
}

__global__ void segmax_kernel(const float* __restrict__ hd, const int* __restrict__ gid,
                              unsigned* g) {
  int c = threadIdx.x;
  int d0 = blockIdx.x * 256;
  int dend = min(d0 + 256, N_DOC);
  int cur = -1; float m = 0.f;
  for (int d = d0; d < dend; ++d) {
    int gg = gid[d];
    float v = hd[(size_t)d * H_DIM + c];
    if (gg != cur) {
      if (cur >= 0) atomicMax(&g[cur * H_DIM + c], fenc(m));
      cur = gg; m = v;
    } else {
      m = fmaxf(m, v);
    }
  }
  if (cur >= 0) atomicMax(&g[cur * H_DIM + c], fenc(m));
}

__global__ void final_kernel(const unsigned* __restrict__ g, const float* __restrict__ out_w,
                             const float* __restrict__ out_b, const float* __restrict__ y,
                             float* out) {
  int tid = threadIdx.x;
  int b = tid >> 4, seg = tid & 15;
  float p = 0.f;
  #pragma unroll
  for (int j = 0; j < 8; ++j) {
    int c = seg * 8 + j;
    p += fdec(g[b * H_DIM + c]) * out_w[c];
  }
  p += __shfl_xor(p, 1);
  p += __shfl_xor(p, 2);
  p += __shfl_xor(p, 4);
  p += __shfl_xor(p, 8);
  __shared__ float logits[BATCH];
  __shared__ float losses[BATCH];
  if (seg == 0) logits[b] = p + out_b[0];
  __syncthreads();
  if (tid < BATCH) {
    float l = logits[tid];
    float sig = 1.f / (1.f + expf(-l));
    out[1 + tid] = sig;
    float ls_pos = (l > 0.f) ? -log1pf(expf(-l)) : l - log1pf(expf(l));   // log_sigmoid(l)
    float ls_neg = (l < 0.f) ? -log1pf(expf(l)) : -l - log1pf(expf(-l));  // log_sigmoid(-l)
    losses[tid] = -(y[tid] * ls_pos + (1.f - y[tid]) * ls_neg);
  }
  __syncthreads();
  if (tid == 0) {
    float s = 0.f;
    for (int j = 0; j < BATCH; ++j) s += losses[j];
    out[0] = s / (float)BATCH;
  }
}

extern "C" void kernel_launch(void* const* d_in, const int* in_sizes, int n_in,
                              void* d_out, int out_size, void* d_ws, size_t ws_size,
                              hipStream_t stream)
{
  const float* word_embeds  = (const float*)d_in[0];
  const float* topic_embeds = (const float*)d_in[1];
  const float* KW  = (const float*)d_in[2];
  const float* Kb  = (const float*)d_in[3];
  const float* QW  = (const float*)d_in[4];
  const float* Qb  = (const float*)d_in[5];
  const float* VW  = (const float*)d_in[6];
  const float* Vb  = (const float*)d_in[7];
  const float* AW  = (const float*)d_in[8];
  const float* Ab  = (const float*)d_in[9];
  const float* rel_att = (const float*)d_in[10];
  const float* rel_msg = (const float*)d_in[11];
  const float* rel_pri = (const float*)d_in[12];
  const float* skip    = (const float*)d_in[13];
  const float* adapt_w = (const float*)d_in[14];
  const float* adapt_b = (const float*)d_in[15];
  const float* out_w   = (const float*)d_in[16];
  const float* out_b   = (const float*)d_in[17];
  const float* y_data  = (const float*)d_in[18];
  const int* word_ids  = (const int*)d_in[19];
  const int* topic_ids = (const int*)d_in[20];
  const int* doc_gid   = (const int*)d_in[21];
  const int* td_src = (const int*)d_in[22];
  const int* td_dst = (const int*)d_in[23];
  const int* tt_src = (const int*)d_in[24];
  const int* tt_dst = (const int*)d_in[25];
  const int* wd_src = (const int*)d_in[26];
  const int* wd_dst = (const int*)d_in[27];
  const int* wt_src = (const int*)d_in[28];
  const int* wt_dst = (const int*)d_in[29];
  const int* ww_src = (const int*)d_in[30];
  const int* ww_dst = (const int*)d_in[31];

  char* base = (char*)d_ws;
  size_t off_b = 0;
  auto alloc = [&](size_t bytes) -> char* {
    char* p = base + off_b;
    off_b = (off_b + bytes + 255) & ~(size_t)255;
    return p;
  };

  float* hw  = (float*)alloc((size_t)N_WORD * H_DIM * 4);
  float* ht  = (float*)alloc((size_t)N_TOPIC * H_DIM * 4);
  float* hd  = (float*)alloc((size_t)N_DOC * H_DIM * 4);
  float* kw  = (float*)alloc((size_t)N_WORD * H_DIM * 4);
  float* vw  = (float*)alloc((size_t)N_WORD * H_DIM * 4);
  float* kt  = (float*)alloc((size_t)N_TOPIC * H_DIM * 4);
  float* vt  = (float*)alloc((size_t)N_TOPIC * H_DIM * 4);
  float* qt  = (float*)alloc((size_t)N_WORD * H_DIM * 4);
  float* t_d = (float*)alloc((size_t)N_DOC * H_DIM * 4);
  float* t_t = (float*)alloc((size_t)N_TOPIC * H_DIM * 4);
  float* t_w = (float*)alloc((size_t)N_WORD * H_DIM * 4);
  unsigned* g = (unsigned*)alloc((size_t)BATCH * H_DIM * 4);

  // relation order: 0=td 1=wd 2=tt 3=wt 4=ww   (rel param index: 0,2,1,3,4)
  const int Es[5] = {80000, 250000, 20000, 100000, 400000};
  const int Nd[5] = {N_DOC, N_DOC, N_TOPIC, N_TOPIC, N_WORD};
  const int* esrc[5] = {td_src, wd_src, tt_src, wt_src, ww_src};
  const int* edst[5] = {td_dst, wd_dst, tt_dst, wt_dst, ww_dst};
  int* cnt[5]; int* offs[5]; int* csrc[5];
  for (int i = 0; i < 5; ++i) {
    cnt[i]  = (int*)alloc((size_t)Nd[i] * 4);
    offs[i] = (int*)alloc(((size_t)Nd[i] + 1) * 4);
    csrc[i] = (int*)alloc((size_t)Es[i] * 4);
  }

  const size_t SH_PLAIN = (64 * 128 + 8 * 64) * 4;
  const size_t SH_REL   = (64 * 128 + 8 * 64 + 8 * 128 + 4096) * 4;

  // ---- CSR build (static graph; reused by both layers) ----
  for (int i = 0; i < 5; ++i) {
    hipMemsetAsync(cnt[i], 0, (size_t)Nd[i] * 4, stream);
    count_kernel<<<(Es[i] + 255) / 256, 256, 0, stream>>>(edst[i], cnt[i], Es[i]);
    scan_kernel<<<1, 1024, 0, stream>>>(cnt[i], offs[i], cnt[i], Nd[i]); // cnt becomes cursor
    fill_kernel<<<(Es[i] + 255) / 256, 256, 0, stream>>>(esrc[i], edst[i], cnt[i], csrc[i], Es[i]);
  }

  // ---- initial node features ----
  hipMemsetAsync(hd, 0, (size_t)N_DOC * H_DIM * 4, stream);
  gather_kernel<<<(N_TOPIC * H_DIM + 255) / 256, 256, 0, stream>>>(topic_embeds, topic_ids, ht, N_TOPIC);
  proj_kernel<1><<<(N_WORD + 7) / 8, 256, SH_PLAIN, stream>>>(
      word_embeds, word_ids, adapt_w, adapt_b, hw, nullptr, nullptr, nullptr, N_WORD, W_INP);

  for (int li = 0; li < 2; ++li) {
    const size_t WSTRIDE = (size_t)H_DIM * H_DIM;
    auto Wp = [&](const float* Wb, int nid) { return Wb + ((size_t)li * 3 + nid) * WSTRIDE; };
    auto bp = [&](const float* Bb, int nid) { return Bb + ((size_t)li * 3 + nid) * H_DIM; };
    auto Rp = [&](const float* Rb, int r)   { return Rb + ((size_t)li * 5 + r) * 4096; };
    auto Pp = [&](int r)                    { return rel_pri + ((size_t)li * 5 + r) * 4; };

    // K/V projections for source types (topic, word)
    proj_kernel<0><<<(N_TOPIC + 7) / 8, 256, SH_PLAIN, stream>>>(
        ht, nullptr, Wp(KW, 1), bp(Kb, 1), kt, nullptr, nullptr, nullptr, N_TOPIC, H_DIM);
    proj_kernel<0><<<(N_TOPIC + 7) / 8, 256, SH_PLAIN, stream>>>(
        ht, nullptr, Wp(VW, 1), bp(Vb, 1), vt, nullptr, nullptr, nullptr, N_TOPIC, H_DIM);
    proj_kernel<0><<<(N_WORD + 7) / 8, 256, SH_PLAIN, stream>>>(
        hw, nullptr, Wp(KW, 2), bp(Kb, 2), kw, nullptr, nullptr, nullptr, N_WORD, H_DIM);
    proj_kernel<0><<<(N_WORD + 7) / 8, 256, SH_PLAIN, stream>>>(
        hw, nullptr, Wp(VW, 2), bp(Vb, 2), vw, nullptr, nullptr, nullptr, N_WORD, H_DIM);

    hipMemsetAsync(t_d, 0, (size_t)N_DOC * H_DIM * 4, stream);
    hipMemsetAsync(t_t, 0, (size_t)N_TOPIC * H_DIM * 4, stream);
    hipMemsetAsync(t_w, 0, (size_t)N_WORD * H_DIM * 4, stream);

    // td (r=0): topic -> doc
    proj_kernel<3><<<(N_DOC + 7) / 8, 256, SH_REL, stream>>>(
        hd, nullptr, Wp(QW, 0), bp(Qb, 0), qt, nullptr, nullptr, Rp(rel_att, 0), N_DOC, H_DIM);
    aggregate_kernel<<<(N_DOC + 3) / 4, 256, 0, stream>>>(
        qt, kt, vt, offs[0], csrc[0], Rp(rel_msg, 0), Pp(0), t_d, N_DOC, 0.5f);
    // wd (r=2): word -> doc
    proj_kernel<3><<<(N_DOC + 7) / 8, 256, SH_REL, stream>>>(
        hd, nullptr, Wp(QW, 0), bp(Qb, 0), qt, nullptr, nullptr, Rp(rel_att, 2), N_DOC, H_DIM);
    aggregate_kernel<<<(N_DOC + 3) / 4, 256, 0, stream>>>(
        qt, kw, vw, offs[1], csrc[1], Rp(rel_msg, 2), Pp(2), t_d, N_DOC, 0.5f);
    // tt (r=1): topic -> topic
    proj_kernel<3><<<(N_TOPIC + 7) / 8, 256, SH_REL, stream>>>(
        ht, nullptr, Wp(QW, 1), bp(Qb, 1), qt, nullptr, nullptr, Rp(rel_att, 1), N_TOPIC, H_DIM);
    aggregate_kernel<<<(N_TOPIC + 3) / 4, 256, 0, stream>>>(
        qt, kt, vt, offs[2], csrc[2], Rp(rel_msg, 1), Pp(1), t_t, N_TOPIC, 0.5f);
    // wt (r=3): word -> topic
    proj_kernel<3><<<(N_TOPIC + 7) / 8, 256, SH_REL, stream>>>(
        ht, nullptr, Wp(QW, 1), bp(Qb, 1), qt, nullptr, nullptr, Rp(rel_att, 3), N_TOPIC, H_DIM);
    aggregate_kernel<<<(N_TOPIC + 3) / 4, 256, 0, stream>>>(
        qt, kw, vw, offs[3], csrc[3], Rp(rel_msg, 3), Pp(3), t_t, N_TOPIC, 0.5f);
    // ww (r=4): word -> word
    proj_kernel<3><<<(N_WORD + 7) / 8, 256, SH_REL, stream>>>(
        hw, nullptr, Wp(QW, 2), bp(Qb, 2), qt, nullptr, nullptr, Rp(rel_att, 4), N_WORD, H_DIM);
    aggregate_kernel<<<(N_WORD + 3) / 4, 256, 0, stream>>>(
        qt, kw, vw, offs[4], csrc[4], Rp(rel_msg, 4), Pp(4), t_w, N_WORD, 1.0f);

    // comb (skip-gated output projection), in-place h update
    proj_kernel<2><<<(N_DOC + 7) / 8, 256, SH_PLAIN, stream>>>(
        t_d, nullptr, Wp(AW, 0), bp(Ab, 0), hd, hd, skip + (size_t)li * 3 + 0, nullptr, N_DOC, H_DIM);
    proj_kernel<2><<<(N_TOPIC + 7) / 8, 256, SH_PLAIN, stream>>>(
        t_t, nullptr, Wp(AW, 1), bp(Ab, 1), ht, ht, skip + (size_t)li * 3 + 1, nullptr, N_TOPIC, H_DIM);
    proj_kernel<2><<<(N_WORD + 7) / 8, 256, SH_PLAIN, stream>>>(
        t_w, nullptr, Wp(AW, 2), bp(Ab, 2), hw, hw, skip + (size_t)li * 3 + 2, nullptr, N_WORD, H_DIM);
  }

  // ---- readout ----
  ginit_kernel<<<(BATCH * H_DIM + 255) / 256, 256, 0, stream>>>(g);
  segmax_kernel<<<(N_DOC + 255) / 256, 128, 0, stream>>>(hd, doc_gid, g);
  final_kernel<<<1, 256, 0, stream>>>(g, out_w, out_b, y_data, (float*)d_out);
}

// Round 2
// 1209.878 us; speedup vs baseline: 3.8312x; 3.8312x over previous
//
#include <hip/hip_runtime.h>
#include <cstdint>
#include <cstddef>

#define H_DIM 128
#define N_DOC 32000
#define N_TOPIC 800
#define N_WORD 80000
#define BATCH 16
#define VOCAB 15000
#define NODES_ALL (N_DOC + N_DOC + N_TOPIC + N_TOPIC + N_WORD)   // 145600
#define EDGES_ALL 850000

typedef short bf16x8 __attribute__((ext_vector_type(8)));
typedef float f32x4 __attribute__((ext_vector_type(4)));

static __device__ __forceinline__ unsigned short f2bf(float x) {
  unsigned u = __float_as_uint(x);
  u += 0x7fffu + ((u >> 16) & 1u);
  return (unsigned short)(u >> 16);
}
static __device__ __forceinline__ float b2f(unsigned h) {
  return __uint_as_float(h << 16);
}
static __device__ __forceinline__ unsigned fenc(float f) {
  unsigned u = __float_as_uint(f);
  return (u & 0x80000000u) ? ~u : (u | 0x80000000u);
}
static __device__ __forceinline__ float fdec(unsigned k) {
  return (k & 0x80000000u) ? __uint_as_float(k ^ 0x80000000u) : __uint_as_float(~k);
}

// ======================= weight prep =======================
// 31 weights. wid 0: adapt (K=300 pad 320). wid 1..30: wl=wid-1, li=wl/15, j=wl%15:
//   j 0..4 plain {KW[li,1],KW[li,2],AW[li,0],AW[li,1],AW[li,2]}
//   j 5..9 Qfold r=j-5 (qt[h,d]=sum_f q[h,f]R[h,d,f])
//   j 10..14 Vfold r=j-10 (v'[h,f]=sum_d v[h,d]M[h,d,f])
// BL layout: frag(t,s) at (t*KS+s)*512 + lane*8 + j, element = W'[s*32+(lane>>4)*8+j][t*16+(lane&15)]
__global__ __launch_bounds__(256) void prep_kernel(
    const float* __restrict__ KW, const float* __restrict__ Kb,
    const float* __restrict__ QW, const float* __restrict__ Qb,
    const float* __restrict__ VW, const float* __restrict__ Vb,
    const float* __restrict__ AW, const float* __restrict__ Ab,
    const float* __restrict__ rel_att, const float* __restrict__ rel_msg,
    const float* __restrict__ adapt_w, const float* __restrict__ adapt_b,
    unsigned short* __restrict__ bl_arena, float* __restrict__ bias_arena)
{
  const int wid = blockIdx.x >> 3, t = blockIdx.x & 7;
  int KS, Kreal, fold;
  const float *W, *b, *R = nullptr;
  if (wid == 0) { KS = 10; Kreal = 300; fold = 0; W = adapt_w; b = adapt_b; }
  else {
    KS = 4; Kreal = 128;
    const int wl = wid - 1, li = wl / 15, j = wl % 15;
    if (j < 5) {
      fold = 0;
      const float *Wb, *bb; int nid;
      if (j == 0)      { Wb = KW; bb = Kb; nid = 1; }
      else if (j == 1) { Wb = KW; bb = Kb; nid = 2; }
      else             { Wb = AW; bb = Ab; nid = j - 2; }
      W = Wb + ((size_t)li * 3 + nid) * 16384; b = bb + ((size_t)li * 3 + nid) * 128;
    } else if (j < 10) {
      fold = 1; const int r = j - 5;
      const int nid = (r == 0) ? 0 : (r == 1) ? 1 : (r == 2) ? 0 : (r == 3) ? 1 : 2;
      W = QW + ((size_t)li * 3 + nid) * 16384; b = Qb + ((size_t)li * 3 + nid) * 128;
      R = rel_att + ((size_t)li * 5 + r) * 4096;
    } else {
      fold = 2; const int r = j - 10;
      const int nid = (r <= 1) ? 1 : 2;
      W = VW + ((size_t)li * 3 + nid) * 16384; b = Vb + ((size_t)li * 3 + nid) * 128;
      R = rel_msg + ((size_t)li * 5 + r) * 4096;
    }
  }
  unsigned short* obl = (wid == 0) ? bl_arena : bl_arena + 40960 + (size_t)(wid - 1) * 16384;
  float* obias = bias_arena + wid * 128;

  const int nelem = KS * 512;
  for (int e = threadIdx.x; e < nelem; e += 256) {
    const int s = e >> 9, rem = e & 511, l = rem >> 3, jj = rem & 7;
    const int k = s * 32 + ((l >> 4) << 3) + jj;
    const int nn = t * 16 + (l & 15);
    float v = 0.f;
    if (k < Kreal) {
      if (fold == 0) v = W[(size_t)k * 128 + nn];
      else {
        const int h = nn >> 5, d = nn & 31;
        const float* Wr = W + (size_t)k * 128 + h * 32;
        const float* Rh = R + h * 1024;
        if (fold == 1) { for (int f = 0; f < 32; ++f) v += Wr[f] * Rh[d * 32 + f]; }
        else           { for (int f = 0; f < 32; ++f) v += Wr[f] * Rh[f * 32 + d]; }
      }
    }
    obl[(size_t)(t * KS + s) * 512 + rem] = f2bf(v);
  }
  if (t == 0 && threadIdx.x < 128) {
    const int nn = threadIdx.x;
    float v = 0.f;
    if (fold == 0) v = b[nn];
    else {
      const int h = nn >> 5, d = nn & 31;
      const float* Rh = R + h * 1024;
      if (fold == 1) { for (int f = 0; f < 32; ++f) v += b[h * 32 + f] * Rh[d * 32 + f]; }
      else           { for (int f = 0; f < 32; ++f) v += b[h * 32 + f] * Rh[f * 32 + d]; }
    }
    obias[nn] = v;
  }
}

// ======================= MFMA GEMM =======================
// C[n x 128](bf16) = act( A[n x KS*32](bf16, rows via idx) @ W + bias )
// VAR: 0 plain, 1 tanh, 2 comb(a*proj+(1-a)*blend)
template<int KS, int VAR>
__global__ __launch_bounds__(256) void gemm_kernel(
    const unsigned short* __restrict__ A, const int* __restrict__ idx,
    const unsigned short* __restrict__ BL, const float* __restrict__ bias,
    unsigned short* __restrict__ C, const unsigned short* __restrict__ blend,
    const float* __restrict__ skipp, int n)
{
  __shared__ float lds[64 * 132];
  const int tid = threadIdx.x;
  const int lane = tid & 63, w = tid >> 6;
  const int m0 = blockIdx.x * 64 + w * 16;
  int rl = m0 + (lane & 15);
  if (rl >= n) rl = n - 1;
  const int row = idx ? idx[rl] : rl;
  const int g = lane >> 4;

  bf16x8 a[KS];
  const unsigned short* Ap = A + (size_t)row * (KS * 32) + g * 8;
  #pragma unroll
  for (int s = 0; s < KS; ++s)
    a[s] = *reinterpret_cast<const bf16x8*>(Ap + s * 32);

  f32x4 acc[8];
  #pragma unroll
  for (int t = 0; t < 8; ++t) acc[t] = (f32x4)0.f;

  const unsigned short* Bp = BL + (size_t)lane * 8;
  #pragma unroll
  for (int s = 0; s < KS; ++s) {
    #pragma unroll
    for (int t = 0; t < 8; ++t) {
      bf16x8 bfr = *reinterpret_cast<const bf16x8*>(Bp + (size_t)(t * KS + s) * 512);
      acc[t] = __builtin_amdgcn_mfma_f32_16x16x32_bf16(a[s], bfr, acc[t], 0, 0, 0);
    }
  }
  #pragma unroll
  for (int t = 0; t < 8; ++t) {
    const int col = t * 16 + (lane & 15);
    const int mr = w * 16 + g * 4;
    lds[(mr + 0) * 132 + col] = acc[t][0];
    lds[(mr + 1) * 132 + col] = acc[t][1];
    lds[(mr + 2) * 132 + col] = acc[t][2];
    lds[(mr + 3) * 132 + col] = acc[t][3];
  }
  __syncthreads();
  const int rr = tid >> 2, cs = (tid & 3) * 32;
  const int m = blockIdx.x * 64 + rr;
  if (m < n) {
    float aa = 0.f;
    if (VAR == 2) aa = 1.f / (1.f + __expf(-skipp[0]));
    unsigned short ob[32];
    #pragma unroll
    for (int j = 0; j < 32; ++j) {
      float v = lds[rr * 132 + cs + j] + bias[cs + j];
      if (VAR == 1) v = tanhf(v);
      if (VAR == 2) {
        float blv = b2f(blend[(size_t)m * 128 + cs + j]);
        v = v * aa + blv * (1.f - aa);
      }
      ob[j] = f2bf(v);
    }
    #pragma unroll
    for (int q = 0; q < 4; ++q)
      *reinterpret_cast<uint4*>(C + (size_t)m * 128 + cs + q * 8) =
          *reinterpret_cast<const uint4*>(&ob[q * 8]);
  }
}

// ======================= misc small kernels =======================
__global__ void conv_wtab_kernel(const float* __restrict__ we, unsigned short* __restrict__ wt) {
  int i = blockIdx.x * 256 + threadIdx.x;           // VOCAB*320
  if (i < VOCAB * 320) {
    int r = i / 320, c = i % 320;
    wt[i] = (c < 300) ? f2bf(we[(size_t)r * 300 + c]) : (unsigned short)0;
  }
}

__global__ void gather_topic_kernel(const float* __restrict__ emb, const int* __restrict__ ids,
                                    unsigned short* __restrict__ out) {
  int i = blockIdx.x * 256 + threadIdx.x;           // N_TOPIC*128
  if (i < N_TOPIC * 128) {
    int node = i >> 7, c = i & 127;
    out[i] = f2bf(emb[(size_t)ids[node] * 128 + c]);
  }
}

__global__ void bcast_q_kernel(const float* __restrict__ b0, const float* __restrict__ b1,
                               unsigned short* __restrict__ q0, unsigned short* __restrict__ q1) {
  int i = blockIdx.x * 256 + threadIdx.x;           // N_DOC*128
  if (i < N_DOC * 128) {
    int c = i & 127;
    q0[i] = f2bf(b0[c]);
    q1[i] = f2bf(b1[c]);
  }
}

// ======================= CSR build (concatenated) =======================
// node bases: td 0, wd 32000, tt 64000, wt 64800, ww 65600
__global__ void count_all_kernel(const int* __restrict__ td, const int* __restrict__ wd,
                                 const int* __restrict__ tt, const int* __restrict__ wt,
                                 const int* __restrict__ ww, int* cnt) {
  int i = blockIdx.x * 256 + threadIdx.x;
  if (i >= EDGES_ALL) return;
  int b;
  if (i < 80000)       b = td[i];
  else if (i < 330000) b = 32000 + wd[i - 80000];
  else if (i < 350000) b = 64000 + tt[i - 330000];
  else if (i < 450000) b = 64800 + wt[i - 350000];
  else                 b = 65600 + ww[i - 450000];
  atomicAdd(&cnt[b], 1);
}

__global__ void fill_all_kernel(const int* __restrict__ td_s, const int* __restrict__ td_d,
                                const int* __restrict__ wd_s, const int* __restrict__ wd_d,
                                const int* __restrict__ tt_s, const int* __restrict__ tt_d,
                                const int* __restrict__ wt_s, const int* __restrict__ wt_d,
                                const int* __restrict__ ww_s, const int* __restrict__ ww_d,
                                int* cursor, int* csrc) {
  int i = blockIdx.x * 256 + threadIdx.x;
  if (i >= EDGES_ALL) return;
  int b, s;
  if (i < 80000)       { b = td_d[i];                    s = td_s[i]; }
  else if (i < 330000) { b = 32000 + wd_d[i - 80000];    s = wd_s[i - 80000]; }
  else if (i < 350000) { b = 64000 + tt_d[i - 330000];   s = tt_s[i - 330000]; }
  else if (i < 450000) { b = 64800 + wt_d[i - 350000];   s = wt_s[i - 350000]; }
  else                 { b = 65600 + ww_d[i - 450000];   s = ww_s[i - 450000]; }
  int p = atomicAdd(&cursor[b], 1);
  csrc[p] = s;
}

__global__ void scan_kernel(const int* __restrict__ cnt, int* off, int* cursor, int n) {
  __shared__ int tile[1024];
  __shared__ int carry_s;
  int tid = threadIdx.x;
  if (tid == 0) carry_s = 0;
  __syncthreads();
  for (int base = 0; base < n; base += 4096) {
    int i0 = base + tid * 4;
    int v[4]; int s = 0;
    #pragma unroll
    for (int j = 0; j < 4; ++j) { int i = i0 + j; v[j] = (i < n) ? cnt[i] : 0; s += v[j]; }
    tile[tid] = s; __syncthreads();
    for (int ofs = 1; ofs < 1024; ofs <<= 1) {
      int t = (tid >= ofs) ? tile[tid - ofs] : 0; __syncthreads();
      tile[tid] += t; __syncthreads();
    }
    int run = tile[tid] - s + carry_s;
    #pragma unroll
    for (int j = 0; j < 4; ++j) {
      int i = i0 + j;
      if (i < n) { off[i] = run; cursor[i] = run; }
      run += v[j];
    }
    __syncthreads();
    if (tid == 1023) carry_s += tile[1023];
    __syncthreads();
  }
  if (tid == 0) off[n] = carry_s;
}

// ======================= aggregation =======================
// one wave per dst node; lane owns 2 channels; heads = 16-lane groups.
template<int NREL>
__global__ __launch_bounds__(256) void agg_kernel(
    const unsigned short* __restrict__ q0, const unsigned short* __restrict__ k0,
    const unsigned short* __restrict__ v0, const int* __restrict__ offs0,
    const float* __restrict__ pri0,
    const unsigned short* __restrict__ q1, const unsigned short* __restrict__ k1,
    const unsigned short* __restrict__ v1, const int* __restrict__ offs1,
    const float* __restrict__ pri1,
    const int* __restrict__ csrc,
    unsigned short* __restrict__ tout, int n_dst, float scale)
{
  const int wave = threadIdx.x >> 6, lane = threadIdx.x & 63;
  const int node = blockIdx.x * 4 + wave;
  if (node >= n_dst) return;
  const int c0 = lane * 2, h = lane >> 4;
  float o0 = 0.f, o1 = 0.f;
  #pragma unroll
  for (int r = 0; r < NREL; ++r) {
    const unsigned short* q = r ? q1 : q0;
    const unsigned short* k = r ? k1 : k0;
    const unsigned short* v = r ? v1 : v0;
    const int* offs = r ? offs1 : offs0;
    const float prih = (r ? pri1 : pri0)[h] * 0.17677669529663687f;
    const int e0 = offs[node], e1 = offs[node + 1];
    if (e0 == e1) continue;
    const unsigned qq = *reinterpret_cast<const unsigned*>(q + (size_t)node * 128 + c0);
    const float qx = b2f(qq & 0xffffu), qy = b2f(qq >> 16);
    float ss = 0.f, a0 = 0.f, a1 = 0.f;
    for (int e = e0; e < e1; ++e) {
      const int s = csrc[e];
      const unsigned kk = *reinterpret_cast<const unsigned*>(k + (size_t)s * 128 + c0);
      float p = qx * b2f(kk & 0xffffu) + qy * b2f(kk >> 16);
      p += __shfl_xor(p, 1);
      p += __shfl_xor(p, 2);
      p += __shfl_xor(p, 4);
      p += __shfl_xor(p, 8);
      const float wgt = __expf(p * prih);
      const unsigned vv = *reinterpret_cast<const unsigned*>(v + (size_t)s * 128 + c0);
      ss += wgt;
      a0 += wgt * b2f(vv & 0xffffu);
      a1 += wgt * b2f(vv >> 16);
    }
    const float inv = 1.f / ss;
    o0 += a0 * inv; o1 += a1 * inv;
  }
  const unsigned op = (unsigned)f2bf(o0 * scale) | ((unsigned)f2bf(o1 * scale) << 16);
  *reinterpret_cast<unsigned*>(tout + (size_t)node * 128 + c0) = op;
}

// ======================= readout =======================
__global__ void ginit_kernel(unsigned* g) {
  int i = blockIdx.x * 256 + threadIdx.x;
  if (i < BATCH * H_DIM) g[i] = 0x007FFFFFu;  // fenc(-inf)
}

__global__ void segmax_kernel(const unsigned short* __restrict__ hd, const int* __restrict__ gid,
                              unsigned* g) {
  int c = threadIdx.x;
  int d0 = blockIdx.x * 256;
  int dend = min(d0 + 256, N_DOC);
  int cur = -1; float m = 0.f;
  for (int d = d0; d < dend; ++d) {
    int gg = gid[d];
    float v = b2f(hd[(size_t)d * 128 + c]);
    if (gg != cur) {
      if (cur >= 0) atomicMax(&g[cur * 128 + c], fenc(m));
      cur = gg; m = v;
    } else {
      m = fmaxf(m, v);
    }
  }
  if (cur >= 0) atomicMax(&g[cur * 128 + c], fenc(m));
}

__global__ void final_kernel(const unsigned* __restrict__ g, const float* __restrict__ out_w,
                             const float* __restrict__ out_b, const float* __restrict__ y,
                             float* out) {
  int tid = threadIdx.x;
  int b = tid >> 4, seg = tid & 15;
  float p = 0.f;
  #pragma unroll
  for (int j = 0; j < 8; ++j) {
    int c = seg * 8 + j;
    p += fdec(g[b * 128 + c]) * out_w[c];
  }
  p += __shfl_xor(p, 1);
  p += __shfl_xor(p, 2);
  p += __shfl_xor(p, 4);
  p += __shfl_xor(p, 8);
  __shared__ float logits[BATCH];
  __shared__ float losses[BATCH];
  if (seg == 0) logits[b] = p + out_b[0];
  __syncthreads();
  if (tid < BATCH) {
    float l = logits[tid];
    out[1 + tid] = 1.f / (1.f + expf(-l));
    float ls_pos = (l > 0.f) ? -log1pf(expf(-l)) : l - log1pf(expf(l));
    float ls_neg = (l < 0.f) ? -log1pf(expf(l)) : -l - log1pf(expf(-l));
    losses[tid] = -(y[tid] * ls_pos + (1.f - y[tid]) * ls_neg);
  }
  __syncthreads();
  if (tid == 0) {
    float s = 0.f;
    for (int j = 0; j < BATCH; ++j) s += losses[j];
    out[0] = s / (float)BATCH;
  }
}

// ======================= host =======================
extern "C" void kernel_launch(void* const* d_in, const int* in_sizes, int n_in,
                              void* d_out, int out_size, void* d_ws, size_t ws_size,
                              hipStream_t stream)
{
  const float* word_embeds  = (const float*)d_in[0];
  const float* topic_embeds = (const float*)d_in[1];
  const float* KW  = (const float*)d_in[2];
  const float* Kb  = (const float*)d_in[3];
  const float* QW  = (const float*)d_in[4];
  const float* Qb  = (const float*)d_in[5];
  const float* VW  = (const float*)d_in[6];
  const float* Vb  = (const float*)d_in[7];
  const float* AW  = (const float*)d_in[8];
  const float* Ab  = (const float*)d_in[9];
  const float* rel_att = (const float*)d_in[10];
  const float* rel_msg = (const float*)d_in[11];
  const float* rel_pri = (const float*)d_in[12];
  const float* skip    = (const float*)d_in[13];
  const float* adapt_w = (const float*)d_in[14];
  const float* adapt_b = (const float*)d_in[15];
  const float* out_w   = (const float*)d_in[16];
  const float* out_b   = (const float*)d_in[17];
  const float* y_data  = (const float*)d_in[18];
  const int* word_ids  = (const int*)d_in[19];
  const int* topic_ids = (const int*)d_in[20];
  const int* doc_gid   = (const int*)d_in[21];
  const int* td_src = (const int*)d_in[22];
  const int* td_dst = (const int*)d_in[23];
  const int* tt_src = (const int*)d_in[24];
  const int* tt_dst = (const int*)d_in[25];
  const int* wd_src = (const int*)d_in[26];
  const int* wd_dst = (const int*)d_in[27];
  const int* wt_src = (const int*)d_in[28];
  const int* wt_dst = (const int*)d_in[29];
  const int* ww_src = (const int*)d_in[30];
  const int* ww_dst = (const int*)d_in[31];

  char* base = (char*)d_ws;
  size_t off_b = 0;
  auto alloc = [&](size_t bytes) -> char* {
    char* p = base + off_b;
    off_b = (off_b + bytes + 255) & ~(size_t)255;
    return p;
  };
  typedef unsigned short u16;

  u16* wtab = (u16*)alloc((size_t)VOCAB * 320 * 2);
  u16* hw   = (u16*)alloc((size_t)N_WORD * 128 * 2);
  u16* hd   = (u16*)alloc((size_t)N_DOC * 128 * 2);
  u16* ht   = (u16*)alloc((size_t)N_TOPIC * 128 * 2);
  u16* k_w  = (u16*)alloc((size_t)N_WORD * 128 * 2);
  u16* k_t  = (u16*)alloc((size_t)N_TOPIC * 128 * 2);
  u16* v_td = (u16*)alloc((size_t)N_TOPIC * 128 * 2);
  u16* v_tt = (u16*)alloc((size_t)N_TOPIC * 128 * 2);
  u16* v_wd = (u16*)alloc((size_t)N_WORD * 128 * 2);
  u16* v_wt = (u16*)alloc((size_t)N_WORD * 128 * 2);
  u16* v_ww = (u16*)alloc((size_t)N_WORD * 128 * 2);
  u16* q_td = (u16*)alloc((size_t)N_DOC * 128 * 2);
  u16* q_wd = (u16*)alloc((size_t)N_DOC * 128 * 2);
  u16* q_tt = (u16*)alloc((size_t)N_TOPIC * 128 * 2);
  u16* q_wt = (u16*)alloc((size_t)N_TOPIC * 128 * 2);
  u16* q_ww = (u16*)alloc((size_t)N_WORD * 128 * 2);
  u16* t_d  = (u16*)alloc((size_t)N_DOC * 128 * 2);
  u16* t_t  = (u16*)alloc((size_t)N_TOPIC * 128 * 2);
  u16* t_w  = (u16*)alloc((size_t)N_WORD * 128 * 2);
  unsigned* g = (unsigned*)alloc((size_t)BATCH * 128 * 4);

  int* cnt_all  = (int*)alloc((size_t)NODES_ALL * 4);
  int* offs_all = (int*)alloc(((size_t)NODES_ALL + 1) * 4);
  int* csrc_all = (int*)alloc((size_t)EDGES_ALL * 4);

  u16* blw        = (u16*)alloc((size_t)(40960 + 30 * 16384) * 2);
  float* bias_are = (float*)alloc((size_t)31 * 128 * 4);

  auto BLp = [&](int wid) -> const u16* {
    return (wid == 0) ? blw : blw + 40960 + (size_t)(wid - 1) * 16384;
  };
  auto BIp = [&](int wid) -> const float* { return bias_are + wid * 128; };
  // wid mapping: 0 adapt; 1+li*15+{0:KWt,1:KWw,2:AWd,3:AWt,4:AWw,5+r:Qfold,10+r:Vfold}
  auto WID = [&](int li, int j) { return 1 + li * 15 + j; };

  // node bases in concatenated CSR: td 0, wd 32000, tt 64000, wt 64800, ww 65600
  const int NB_TD = 0, NB_WD = 32000, NB_TT = 64000, NB_WT = 64800, NB_WW = 65600;

  // ---- prep: weights + tables + CSR ----
  prep_kernel<<<248, 256, 0, stream>>>(KW, Kb, QW, Qb, VW, Vb, AW, Ab,
                                       rel_att, rel_msg, adapt_w, adapt_b, blw, bias_are);
  conv_wtab_kernel<<<(VOCAB * 320 + 255) / 256, 256, 0, stream>>>(word_embeds, wtab);
  gather_topic_kernel<<<(N_TOPIC * 128 + 255) / 256, 256, 0, stream>>>(topic_embeds, topic_ids, ht);

  hipMemsetAsync(cnt_all, 0, (size_t)NODES_ALL * 4, stream);
  count_all_kernel<<<(EDGES_ALL + 255) / 256, 256, 0, stream>>>(td_dst, wd_dst, tt_dst, wt_dst, ww_dst, cnt_all);
  scan_kernel<<<1, 1024, 0, stream>>>(cnt_all, offs_all, cnt_all, NODES_ALL);  // cnt becomes cursor
  fill_all_kernel<<<(EDGES_ALL + 255) / 256, 256, 0, stream>>>(
      td_src, td_dst, wd_src, wd_dst, tt_src, tt_dst, wt_src, wt_dst, ww_src, ww_dst,
      cnt_all, csrc_all);

  hipMemsetAsync(hd, 0, (size_t)N_DOC * 128 * 2, stream);

  // ---- adapt: hw = tanh(gather(wtab, word_ids) @ adapt_w + adapt_b) ----
  gemm_kernel<10, 1><<<(N_WORD + 63) / 64, 256, 0, stream>>>(
      wtab, word_ids, BLp(0), BIp(0), hw, nullptr, nullptr, N_WORD);

  const int GW = (N_WORD + 63) / 64, GD = (N_DOC + 63) / 64, GT = (N_TOPIC + 63) / 64;

  for (int li = 0; li < 2; ++li) {
    // K projections
    gemm_kernel<4, 0><<<GT, 256, 0, stream>>>(ht, nullptr, BLp(WID(li, 0)), BIp(WID(li, 0)), k_t, nullptr, nullptr, N_TOPIC);
    gemm_kernel<4, 0><<<GW, 256, 0, stream>>>(hw, nullptr, BLp(WID(li, 1)), BIp(WID(li, 1)), k_w, nullptr, nullptr, N_WORD);
    // V' projections (rel_msg folded), per relation
    gemm_kernel<4, 0><<<GT, 256, 0, stream>>>(ht, nullptr, BLp(WID(li, 10 + 0)), BIp(WID(li, 10 + 0)), v_td, nullptr, nullptr, N_TOPIC);
    gemm_kernel<4, 0><<<GT, 256, 0, stream>>>(ht, nullptr, BLp(WID(li, 10 + 1)), BIp(WID(li, 10 + 1)), v_tt, nullptr, nullptr, N_TOPIC);
    gemm_kernel<4, 0><<<GW, 256, 0, stream>>>(hw, nullptr, BLp(WID(li, 10 + 2)), BIp(WID(li, 10 + 2)), v_wd, nullptr, nullptr, N_WORD);
    gemm_kernel<4, 0><<<GW, 256, 0, stream>>>(hw, nullptr, BLp(WID(li, 10 + 3)), BIp(WID(li, 10 + 3)), v_wt, nullptr, nullptr, N_WORD);
    gemm_kernel<4, 0><<<GW, 256, 0, stream>>>(hw, nullptr, BLp(WID(li, 10 + 4)), BIp(WID(li, 10 + 4)), v_ww, nullptr, nullptr, N_WORD);
    // Q' projections (rel_att folded), per relation (dst side)
    if (li == 0) {
      bcast_q_kernel<<<(N_DOC * 128 + 255) / 256, 256, 0, stream>>>(BIp(WID(0, 5 + 0)), BIp(WID(0, 5 + 2)), q_td, q_wd);
    } else {
      gemm_kernel<4, 0><<<GD, 256, 0, stream>>>(hd, nullptr, BLp(WID(li, 5 + 0)), BIp(WID(li, 5 + 0)), q_td, nullptr, nullptr, N_DOC);
      gemm_kernel<4, 0><<<GD, 256, 0, stream>>>(hd, nullptr, BLp(WID(li, 5 + 2)), BIp(WID(li, 5 + 2)), q_wd, nullptr, nullptr, N_DOC);
    }
    gemm_kernel<4, 0><<<GT, 256, 0, stream>>>(ht, nullptr, BLp(WID(li, 5 + 1)), BIp(WID(li, 5 + 1)), q_tt, nullptr, nullptr, N_TOPIC);
    gemm_kernel<4, 0><<<GT, 256, 0, stream>>>(ht, nullptr, BLp(WID(li, 5 + 3)), BIp(WID(li, 5 + 3)), q_wt, nullptr, nullptr, N_TOPIC);
    gemm_kernel<4, 0><<<GW, 256, 0, stream>>>(hw, nullptr, BLp(WID(li, 5 + 4)), BIp(WID(li, 5 + 4)), q_ww, nullptr, nullptr, N_WORD);

    // aggregates (rel indices for pri: td=0 tt=1 wd=2 wt=3 ww=4)
    const float* priB = rel_pri + (size_t)li * 5 * 4;
    agg_kernel<2><<<(N_DOC + 3) / 4, 256, 0, stream>>>(
        q_td, k_t, v_td, offs_all + NB_TD, priB + 0 * 4,
        q_wd, k_w, v_wd, offs_all + NB_WD, priB + 2 * 4,
        csrc_all, t_d, N_DOC, 0.5f);
    agg_kernel<2><<<(N_TOPIC + 3) / 4, 256, 0, stream>>>(
        q_tt, k_t, v_tt, offs_all + NB_TT, priB + 1 * 4,
        q_wt, k_w, v_wt, offs_all + NB_WT, priB + 3 * 4,
        csrc_all, t_t, N_TOPIC, 0.5f);
    agg_kernel<1><<<(N_WORD + 3) / 4, 256, 0, stream>>>(
        q_ww, k_w, v_ww, offs_all + NB_WW, priB + 4 * 4,
        nullptr, nullptr, nullptr, nullptr, nullptr,
        csrc_all, t_w, N_WORD, 1.0f);

    // comb
    gemm_kernel<4, 2><<<GD, 256, 0, stream>>>(t_d, nullptr, BLp(WID(li, 2)), BIp(WID(li, 2)), hd, hd, skip + (size_t)li * 3 + 0, N_DOC);
    gemm_kernel<4, 2><<<GT, 256, 0, stream>>>(t_t, nullptr, BLp(WID(li, 3)), BIp(WID(li, 3)), ht, ht, skip + (size_t)li * 3 + 1, N_TOPIC);
    gemm_kernel<4, 2><<<GW, 256, 0, stream>>>(t_w, nullptr, BLp(WID(li, 4)), BIp(WID(li, 4)), hw, hw, skip + (size_t)li * 3 + 2, N_WORD);
  }

  // ---- readout ----
  ginit_kernel<<<(BATCH * 128 + 255) / 256, 256, 0, stream>>>(g);
  segmax_kernel<<<(N_DOC + 255) / 256, 128, 0, stream>>>(hd, doc_gid, g);
  final_kernel<<<1, 256, 0, stream>>>(g, out_w, out_b, y_data, (float*)d_out);
}

// Round 3
// 718.029 us; speedup vs baseline: 6.4556x; 1.6850x over previous
//
#include <hip/hip_runtime.h>
#include <cstdint>
#include <cstddef>

#define H_DIM 128
#define N_DOC 32000
#define N_TOPIC 800
#define N_WORD 80000
#define BATCH 16
#define VOCAB 15000
#define NODES_ALL (N_DOC + N_DOC + N_TOPIC + N_TOPIC + N_WORD)   // 145600
#define EDGES_ALL 850000
#define NBLK_SCAN 143     // ceil(145600/1024)
#define N4_SCAN 36400     // 145600/4

typedef short bf16x8 __attribute__((ext_vector_type(8)));
typedef float f32x4 __attribute__((ext_vector_type(4)));
typedef unsigned short u16;

static __device__ __forceinline__ u16 f2bf(float x) {
  unsigned u = __float_as_uint(x);
  u += 0x7fffu + ((u >> 16) & 1u);
  return (u16)(u >> 16);
}
static __device__ __forceinline__ float b2f(unsigned h) {
  return __uint_as_float(h << 16);
}
static __device__ __forceinline__ unsigned fenc(float f) {
  unsigned u = __float_as_uint(f);
  return (u & 0x80000000u) ? ~u : (u | 0x80000000u);
}
static __device__ __forceinline__ float fdec(unsigned k) {
  return (k & 0x80000000u) ? __uint_as_float(k ^ 0x80000000u) : __uint_as_float(~k);
}

static __device__ __forceinline__ int wave_iscan(int v, int lane) {
  #pragma unroll
  for (int d = 1; d < 64; d <<= 1) {
    int t = __shfl_up(v, d);
    if (lane >= d) v += t;
  }
  return v;
}

// ======================= weight prep =======================
__global__ __launch_bounds__(256) void prep_kernel(
    const float* __restrict__ KW, const float* __restrict__ Kb,
    const float* __restrict__ QW, const float* __restrict__ Qb,
    const float* __restrict__ VW, const float* __restrict__ Vb,
    const float* __restrict__ AW, const float* __restrict__ Ab,
    const float* __restrict__ rel_att, const float* __restrict__ rel_msg,
    const float* __restrict__ adapt_w, const float* __restrict__ adapt_b,
    u16* __restrict__ bl_arena, float* __restrict__ bias_arena)
{
  const int wid = blockIdx.x >> 3, t = blockIdx.x & 7;
  int KS, Kreal, fold;
  const float *W, *b, *R = nullptr;
  if (wid == 0) { KS = 10; Kreal = 300; fold = 0; W = adapt_w; b = adapt_b; }
  else {
    KS = 4; Kreal = 128;
    const int wl = wid - 1, li = wl / 15, j = wl % 15;
    if (j < 5) {
      fold = 0;
      const float *Wb, *bb; int nid;
      if (j == 0)      { Wb = KW; bb = Kb; nid = 1; }
      else if (j == 1) { Wb = KW; bb = Kb; nid = 2; }
      else             { Wb = AW; bb = Ab; nid = j - 2; }
      W = Wb + ((size_t)li * 3 + nid) * 16384; b = bb + ((size_t)li * 3 + nid) * 128;
    } else if (j < 10) {
      fold = 1; const int r = j - 5;
      const int nid = (r == 0) ? 0 : (r == 1) ? 1 : (r == 2) ? 0 : (r == 3) ? 1 : 2;
      W = QW + ((size_t)li * 3 + nid) * 16384; b = Qb + ((size_t)li * 3 + nid) * 128;
      R = rel_att + ((size_t)li * 5 + r) * 4096;
    } else {
      fold = 2; const int r = j - 10;
      const int nid = (r <= 1) ? 1 : 2;
      W = VW + ((size_t)li * 3 + nid) * 16384; b = Vb + ((size_t)li * 3 + nid) * 128;
      R = rel_msg + ((size_t)li * 5 + r) * 4096;
    }
  }
  u16* obl = (wid == 0) ? bl_arena : bl_arena + 40960 + (size_t)(wid - 1) * 16384;
  float* obias = bias_arena + wid * 128;

  const int nelem = KS * 512;
  for (int e = threadIdx.x; e < nelem; e += 256) {
    const int s = e >> 9, rem = e & 511, l = rem >> 3, jj = rem & 7;
    const int k = s * 32 + ((l >> 4) << 3) + jj;
    const int nn = t * 16 + (l & 15);
    float v = 0.f;
    if (k < Kreal) {
      if (fold == 0) v = W[(size_t)k * 128 + nn];
      else {
        const int h = nn >> 5, d = nn & 31;
        const float* Wr = W + (size_t)k * 128 + h * 32;
        const float* Rh = R + h * 1024;
        if (fold == 1) { for (int f = 0; f < 32; ++f) v += Wr[f] * Rh[d * 32 + f]; }
        else           { for (int f = 0; f < 32; ++f) v += Wr[f] * Rh[f * 32 + d]; }
      }
    }
    obl[(size_t)(t * KS + s) * 512 + rem] = f2bf(v);
  }
  if (t == 0 && threadIdx.x < 128) {
    const int nn = threadIdx.x;
    float v = 0.f;
    if (fold == 0) v = b[nn];
    else {
      const int h = nn >> 5, d = nn & 31;
      const float* Rh = R + h * 1024;
      if (fold == 1) { for (int f = 0; f < 32; ++f) v += b[h * 32 + f] * Rh[d * 32 + f]; }
      else           { for (int f = 0; f < 32; ++f) v += b[h * 32 + f] * Rh[f * 32 + d]; }
    }
    obias[nn] = v;
  }
}

// ======================= MFMA GEMM (single + multi-output) =======================
struct Outs {
  const u16* BL[5];
  const float* bias[5];
  u16* C[5];
};

// VAR: 0 plain, 1 tanh, 2 comb(a*proj+(1-a)*blend)
template<int KS, int VAR>
__global__ __launch_bounds__(256) void gemm_kernel(
    const u16* __restrict__ A, const int* __restrict__ idx,
    const u16* __restrict__ BL, const float* __restrict__ bias,
    u16* __restrict__ C, const u16* __restrict__ blend,
    const float* __restrict__ skipp, int n)
{
  __shared__ float lds[64 * 132];
  const int tid = threadIdx.x;
  const int lane = tid & 63, w = tid >> 6;
  const int m0 = blockIdx.x * 64 + w * 16;
  int rl = m0 + (lane & 15);
  if (rl >= n) rl = n - 1;
  const int row = idx ? idx[rl] : rl;
  const int g = lane >> 4;

  bf16x8 a[KS];
  const u16* Ap = A + (size_t)row * (KS * 32) + g * 8;
  #pragma unroll
  for (int s = 0; s < KS; ++s)
    a[s] = *reinterpret_cast<const bf16x8*>(Ap + s * 32);

  f32x4 acc[8];
  #pragma unroll
  for (int t = 0; t < 8; ++t) acc[t] = (f32x4)0.f;

  const u16* Bp = BL + (size_t)lane * 8;
  #pragma unroll
  for (int s = 0; s < KS; ++s) {
    #pragma unroll
    for (int t = 0; t < 8; ++t) {
      bf16x8 bfr = *reinterpret_cast<const bf16x8*>(Bp + (size_t)(t * KS + s) * 512);
      acc[t] = __builtin_amdgcn_mfma_f32_16x16x32_bf16(a[s], bfr, acc[t], 0, 0, 0);
    }
  }
  #pragma unroll
  for (int t = 0; t < 8; ++t) {
    const int col = t * 16 + (lane & 15);
    const int mr = w * 16 + g * 4;
    lds[(mr + 0) * 132 + col] = acc[t][0];
    lds[(mr + 1) * 132 + col] = acc[t][1];
    lds[(mr + 2) * 132 + col] = acc[t][2];
    lds[(mr + 3) * 132 + col] = acc[t][3];
  }
  __syncthreads();
  const int rr = tid >> 2, cs = (tid & 3) * 32;
  const int m = blockIdx.x * 64 + rr;
  if (m < n) {
    float aa = 0.f;
    if (VAR == 2) aa = 1.f / (1.f + __expf(-skipp[0]));
    u16 ob[32];
    #pragma unroll
    for (int j = 0; j < 32; ++j) {
      float v = lds[rr * 132 + cs + j] + bias[cs + j];
      if (VAR == 1) v = tanhf(v);
      if (VAR == 2) {
        float blv = b2f(blend[(size_t)m * 128 + cs + j]);
        v = v * aa + blv * (1.f - aa);
      }
      ob[j] = f2bf(v);
    }
    #pragma unroll
    for (int q = 0; q < 4; ++q)
      *reinterpret_cast<uint4*>(C + (size_t)m * 128 + cs + q * 8) =
          *reinterpret_cast<const uint4*>(&ob[q * 8]);
  }
}

template<int KS, int NOUT>
__global__ __launch_bounds__(256) void gemmN_kernel(
    const u16* __restrict__ A, const int* __restrict__ idx, Outs P, int n)
{
  __shared__ float lds[64 * 132];
  const int tid = threadIdx.x;
  const int lane = tid & 63, w = tid >> 6;
  const int m0 = blockIdx.x * 64 + w * 16;
  int rl = m0 + (lane & 15);
  if (rl >= n) rl = n - 1;
  const int row = idx ? idx[rl] : rl;
  const int g = lane >> 4;

  bf16x8 a[KS];
  const u16* Ap = A + (size_t)row * (KS * 32) + g * 8;
  #pragma unroll
  for (int s = 0; s < KS; ++s)
    a[s] = *reinterpret_cast<const bf16x8*>(Ap + s * 32);

  const int rr = tid >> 2, cs = (tid & 3) * 32;
  const int m = blockIdx.x * 64 + rr;

  #pragma unroll
  for (int o = 0; o < NOUT; ++o) {
    f32x4 acc[8];
    #pragma unroll
    for (int t = 0; t < 8; ++t) acc[t] = (f32x4)0.f;
    const u16* Bp = P.BL[o] + (size_t)lane * 8;
    #pragma unroll
    for (int s = 0; s < KS; ++s) {
      #pragma unroll
      for (int t = 0; t < 8; ++t) {
        bf16x8 bfr = *reinterpret_cast<const bf16x8*>(Bp + (size_t)(t * KS + s) * 512);
        acc[t] = __builtin_amdgcn_mfma_f32_16x16x32_bf16(a[s], bfr, acc[t], 0, 0, 0);
      }
    }
    if (o) __syncthreads();           // all reads of previous output done
    #pragma unroll
    for (int t = 0; t < 8; ++t) {
      const int col = t * 16 + (lane & 15);
      const int mr = w * 16 + g * 4;
      lds[(mr + 0) * 132 + col] = acc[t][0];
      lds[(mr + 1) * 132 + col] = acc[t][1];
      lds[(mr + 2) * 132 + col] = acc[t][2];
      lds[(mr + 3) * 132 + col] = acc[t][3];
    }
    __syncthreads();
    if (m < n) {
      const float* bias = P.bias[o];
      u16 ob[32];
      #pragma unroll
      for (int j = 0; j < 32; ++j)
        ob[j] = f2bf(lds[rr * 132 + cs + j] + bias[cs + j]);
      #pragma unroll
      for (int q = 0; q < 4; ++q)
        *reinterpret_cast<uint4*>(P.C[o] + (size_t)m * 128 + cs + q * 8) =
            *reinterpret_cast<const uint4*>(&ob[q * 8]);
    }
  }
}

// ======================= misc small kernels =======================
__global__ void conv_wtab_kernel(const float* __restrict__ we, u16* __restrict__ wt) {
  int i = blockIdx.x * 256 + threadIdx.x;
  if (i < VOCAB * 320) {
    int r = i / 320, c = i - r * 320;
    wt[i] = (c < 300) ? f2bf(we[(size_t)r * 300 + c]) : (u16)0;
  }
}

__global__ void gather_topic_kernel(const float* __restrict__ emb, const int* __restrict__ ids,
                                    u16* __restrict__ out) {
  int i = blockIdx.x * 256 + threadIdx.x;
  if (i < N_TOPIC * 128) {
    int node = i >> 7, c = i & 127;
    out[i] = f2bf(emb[(size_t)ids[node] * 128 + c]);
  }
}

__global__ void bcast_q_kernel(const float* __restrict__ b0, const float* __restrict__ b1,
                               u16* __restrict__ q0, u16* __restrict__ q1) {
  int i = blockIdx.x * 256 + threadIdx.x;
  if (i < N_DOC * 128) {
    int c = i & 127;
    q0[i] = f2bf(b0[c]);
    q1[i] = f2bf(b1[c]);
  }
}

// ======================= CSR build =======================
__global__ void count_all_kernel(const int* __restrict__ td, const int* __restrict__ wd,
                                 const int* __restrict__ tt, const int* __restrict__ wt,
                                 const int* __restrict__ ww, int* cnt) {
  int i = blockIdx.x * 256 + threadIdx.x;
  if (i >= EDGES_ALL) return;
  int b;
  if (i < 80000)       b = td[i];
  else if (i < 330000) b = 32000 + wd[i - 80000];
  else if (i < 350000) b = 64000 + tt[i - 330000];
  else if (i < 450000) b = 64800 + wt[i - 350000];
  else                 b = 65600 + ww[i - 450000];
  atomicAdd(&cnt[b], 1);
}

__global__ void fill_all_kernel(const int* __restrict__ td_s, const int* __restrict__ td_d,
                                const int* __restrict__ wd_s, const int* __restrict__ wd_d,
                                const int* __restrict__ tt_s, const int* __restrict__ tt_d,
                                const int* __restrict__ wt_s, const int* __restrict__ wt_d,
                                const int* __restrict__ ww_s, const int* __restrict__ ww_d,
                                int* cursor, int* csrc) {
  int i = blockIdx.x * 256 + threadIdx.x;
  if (i >= EDGES_ALL) return;
  int b, s;
  if (i < 80000)       { b = td_d[i];                    s = td_s[i]; }
  else if (i < 330000) { b = 32000 + wd_d[i - 80000];    s = wd_s[i - 80000]; }
  else if (i < 350000) { b = 64000 + tt_d[i - 330000];   s = tt_s[i - 330000]; }
  else if (i < 450000) { b = 64800 + wt_d[i - 350000];   s = wt_s[i - 350000]; }
  else                 { b = 65600 + ww_d[i - 450000];   s = ww_s[i - 450000]; }
  int p = atomicAdd(&cursor[b], 1);
  csrc[p] = s;
}

// ---- hierarchical scan: A per-block reduce, B scan block sums, C local scan ----
__global__ __launch_bounds__(256) void scanA_kernel(const int* __restrict__ cnt, int* __restrict__ bsum) {
  const int tid = threadIdx.x, lane = tid & 63, wv = tid >> 6;
  const int i4 = blockIdx.x * 256 + tid;
  int4 v = make_int4(0, 0, 0, 0);
  if (i4 < N4_SCAN) v = reinterpret_cast<const int4*>(cnt)[i4];
  int s = v.x + v.y + v.z + v.w;
  #pragma unroll
  for (int d = 1; d < 64; d <<= 1) s += __shfl_xor(s, d);
  __shared__ int ws[4];
  if (lane == 0) ws[wv] = s;
  __syncthreads();
  if (tid == 0) bsum[blockIdx.x] = ws[0] + ws[1] + ws[2] + ws[3];
}

__global__ __launch_bounds__(256) void scanB_kernel(const int* __restrict__ bsum,
                                                    int* __restrict__ bpre, int* __restrict__ offs) {
  const int tid = threadIdx.x, lane = tid & 63, wv = tid >> 6;
  int v = (tid < NBLK_SCAN) ? bsum[tid] : 0;
  int incl = wave_iscan(v, lane);
  __shared__ int ws[4];
  if (lane == 63) ws[wv] = incl;
  __syncthreads();
  int pre = 0;
  for (int j = 0; j < 4; ++j) if (j < wv) pre += ws[j];
  incl += pre;
  if (tid < NBLK_SCAN) bpre[tid] = incl - v;
  if (tid == NBLK_SCAN - 1) offs[NODES_ALL] = incl;
}

__global__ __launch_bounds__(256) void scanC_kernel(const int* __restrict__ cnt,
                                                    const int* __restrict__ bpre,
                                                    int* __restrict__ offs, int* __restrict__ cursor) {
  const int tid = threadIdx.x, lane = tid & 63, wv = tid >> 6;
  const int i4 = blockIdx.x * 256 + tid;
  int4 v = make_int4(0, 0, 0, 0);
  if (i4 < N4_SCAN) v = reinterpret_cast<const int4*>(cnt)[i4];
  const int tsum = v.x + v.y + v.z + v.w;
  int incl = wave_iscan(tsum, lane);
  __shared__ int ws[4];
  if (lane == 63) ws[wv] = incl;
  __syncthreads();
  int pre = bpre[blockIdx.x];
  for (int j = 0; j < 4; ++j) if (j < wv) pre += ws[j];
  int o0 = pre + incl - tsum;
  if (i4 < N4_SCAN) {
    int4 ov = make_int4(o0, o0 + v.x, o0 + v.x + v.y, o0 + v.x + v.y + v.z);
    reinterpret_cast<int4*>(offs)[i4] = ov;
    reinterpret_cast<int4*>(cursor)[i4] = ov;
  }
}

// ======================= aggregation =======================
#define EDGE_BODY(kptr, vptr, ee)                                              \
  {                                                                            \
    const int sN = csrc[ee];                                                   \
    const unsigned kk = *reinterpret_cast<const unsigned*>(kptr + (size_t)sN * 128 + c0); \
    float p = qx * b2f(kk & 0xffffu) + qy * b2f(kk >> 16);                     \
    p += __shfl_xor(p, 1); p += __shfl_xor(p, 2);                              \
    p += __shfl_xor(p, 4); p += __shfl_xor(p, 8);                              \
    const float wgt = __expf(p * prih);                                        \
    const unsigned vv = *reinterpret_cast<const unsigned*>(vptr + (size_t)sN * 128 + c0); \
    ss += wgt; a0 += wgt * b2f(vv & 0xffffu); a1 += wgt * b2f(vv >> 16);       \
  }

template<int NREL>
__global__ __launch_bounds__(256) void agg_kernel(
    const u16* __restrict__ q0, const u16* __restrict__ k0,
    const u16* __restrict__ v0, const int* __restrict__ offs0,
    const float* __restrict__ pri0,
    const u16* __restrict__ q1, const u16* __restrict__ k1,
    const u16* __restrict__ v1, const int* __restrict__ offs1,
    const float* __restrict__ pri1,
    const int* __restrict__ csrc,
    u16* __restrict__ tout, int n_dst, float scale)
{
  const int wave = threadIdx.x >> 6, lane = threadIdx.x & 63;
  const int node = blockIdx.x * 4 + wave;
  if (node >= n_dst) return;
  const int c0 = lane * 2, h = lane >> 4;
  float o0 = 0.f, o1 = 0.f;
  #pragma unroll
  for (int r = 0; r < NREL; ++r) {
    const u16* q = r ? q1 : q0;
    const u16* k = r ? k1 : k0;
    const u16* v = r ? v1 : v0;
    const int* offs = r ? offs1 : offs0;
    const float prih = (r ? pri1 : pri0)[h] * 0.17677669529663687f;
    const int e0 = offs[node], e1 = offs[node + 1];
    if (e0 == e1) continue;
    const unsigned qq = *reinterpret_cast<const unsigned*>(q + (size_t)node * 128 + c0);
    const float qx = b2f(qq & 0xffffu), qy = b2f(qq >> 16);
    float ss = 0.f, a0 = 0.f, a1 = 0.f;
    int e = e0;
    for (; e + 2 <= e1; e += 2) {
      EDGE_BODY(k, v, e)
      EDGE_BODY(k, v, e + 1)
    }
    if (e < e1) EDGE_BODY(k, v, e)
    const float inv = 1.f / ss;
    o0 += a0 * inv; o1 += a1 * inv;
  }
  const unsigned op = (unsigned)f2bf(o0 * scale) | ((unsigned)f2bf(o1 * scale) << 16);
  *reinterpret_cast<unsigned*>(tout + (size_t)node * 128 + c0) = op;
}

// one block (4 waves) per topic node; waves split each relation's edge range
__global__ __launch_bounds__(256) void agg_topic_kernel(
    const u16* __restrict__ q0, const u16* __restrict__ k0,
    const u16* __restrict__ v0, const int* __restrict__ offs0,
    const float* __restrict__ pri0,
    const u16* __restrict__ q1, const u16* __restrict__ k1,
    const u16* __restrict__ v1, const int* __restrict__ offs1,
    const float* __restrict__ pri1,
    const int* __restrict__ csrc,
    u16* __restrict__ tout, float scale)
{
  const int node = blockIdx.x;
  const int wv = threadIdx.x >> 6, lane = threadIdx.x & 63;
  const int c0 = lane * 2, h = lane >> 4;
  __shared__ float pa0[2][4][64], pa1[2][4][64], pss[2][4][64];
  #pragma unroll
  for (int r = 0; r < 2; ++r) {
    const u16* q = r ? q1 : q0;
    const u16* k = r ? k1 : k0;
    const u16* v = r ? v1 : v0;
    const int* offs = r ? offs1 : offs0;
    const float prih = (r ? pri1 : pri0)[h] * 0.17677669529663687f;
    const int e0 = offs[node], e1 = offs[node + 1];
    const unsigned qq = *reinterpret_cast<const unsigned*>(q + (size_t)node * 128 + c0);
    const float qx = b2f(qq & 0xffffu), qy = b2f(qq >> 16);
    const int len = e1 - e0, chunk = (len + 3) >> 2;
    const int myb = e0 + wv * chunk;
    const int mye = min(myb + chunk, e1);
    float ss = 0.f, a0 = 0.f, a1 = 0.f;
    int e = myb;
    for (; e + 2 <= mye; e += 2) {
      EDGE_BODY(k, v, e)
      EDGE_BODY(k, v, e + 1)
    }
    if (e < mye) EDGE_BODY(k, v, e)
    pa0[r][wv][lane] = a0; pa1[r][wv][lane] = a1; pss[r][wv][lane] = ss;
  }
  __syncthreads();
  if (wv == 0) {
    float o0 = 0.f, o1 = 0.f;
    #pragma unroll
    for (int r = 0; r < 2; ++r) {
      float a0 = pa0[r][0][lane] + pa0[r][1][lane] + pa0[r][2][lane] + pa0[r][3][lane];
      float a1 = pa1[r][0][lane] + pa1[r][1][lane] + pa1[r][2][lane] + pa1[r][3][lane];
      float ss = pss[r][0][lane] + pss[r][1][lane] + pss[r][2][lane] + pss[r][3][lane];
      if (ss > 0.f) { float inv = 1.f / ss; o0 += a0 * inv; o1 += a1 * inv; }
    }
    const unsigned op = (unsigned)f2bf(o0 * scale) | ((unsigned)f2bf(o1 * scale) << 16);
    *reinterpret_cast<unsigned*>(tout + (size_t)node * 128 + c0) = op;
  }
}

// ======================= readout =======================
__global__ void ginit_kernel(unsigned* g) {
  int i = blockIdx.x * 256 + threadIdx.x;
  if (i < BATCH * H_DIM) g[i] = 0x007FFFFFu;
}

__global__ void segmax_kernel(const u16* __restrict__ hd, const int* __restrict__ gid,
                              unsigned* g) {
  int c = threadIdx.x;
  int d0 = blockIdx.x * 128;
  int dend = min(d0 + 128, N_DOC);
  int cur = -1; float m = 0.f;
  for (int d = d0; d < dend; ++d) {
    int gg = gid[d];
    float v = b2f(hd[(size_t)d * 128 + c]);
    if (gg != cur) {
      if (cur >= 0) atomicMax(&g[cur * 128 + c], fenc(m));
      cur = gg; m = v;
    } else {
      m = fmaxf(m, v);
    }
  }
  if (cur >= 0) atomicMax(&g[cur * 128 + c], fenc(m));
}

__global__ void final_kernel(const unsigned* __restrict__ g, const float* __restrict__ out_w,
                             const float* __restrict__ out_b, const float* __restrict__ y,
                             float* out) {
  int tid = threadIdx.x;
  int b = tid >> 4, seg = tid & 15;
  float p = 0.f;
  #pragma unroll
  for (int j = 0; j < 8; ++j) {
    int c = seg * 8 + j;
    p += fdec(g[b * 128 + c]) * out_w[c];
  }
  p += __shfl_xor(p, 1);
  p += __shfl_xor(p, 2);
  p += __shfl_xor(p, 4);
  p += __shfl_xor(p, 8);
  __shared__ float logits[BATCH];
  __shared__ float losses[BATCH];
  if (seg == 0) logits[b] = p + out_b[0];
  __syncthreads();
  if (tid < BATCH) {
    float l = logits[tid];
    out[1 + tid] = 1.f / (1.f + expf(-l));
    float ls_pos = (l > 0.f) ? -log1pf(expf(-l)) : l - log1pf(expf(l));
    float ls_neg = (l < 0.f) ? -log1pf(expf(l)) : -l - log1pf(expf(-l));
    losses[tid] = -(y[tid] * ls_pos + (1.f - y[tid]) * ls_neg);
  }
  __syncthreads();
  if (tid == 0) {
    float s = 0.f;
    for (int j = 0; j < BATCH; ++j) s += losses[j];
    out[0] = s / (float)BATCH;
  }
}

// ======================= host =======================
extern "C" void kernel_launch(void* const* d_in, const int* in_sizes, int n_in,
                              void* d_out, int out_size, void* d_ws, size_t ws_size,
                              hipStream_t stream)
{
  const float* word_embeds  = (const float*)d_in[0];
  const float* topic_embeds = (const float*)d_in[1];
  const float* KW  = (const float*)d_in[2];
  const float* Kb  = (const float*)d_in[3];
  const float* QW  = (const float*)d_in[4];
  const float* Qb  = (const float*)d_in[5];
  const float* VW  = (const float*)d_in[6];
  const float* Vb  = (const float*)d_in[7];
  const float* AW  = (const float*)d_in[8];
  const float* Ab  = (const float*)d_in[9];
  const float* rel_att = (const float*)d_in[10];
  const float* rel_msg = (const float*)d_in[11];
  const float* rel_pri = (const float*)d_in[12];
  const float* skip    = (const float*)d_in[13];
  const float* adapt_w = (const float*)d_in[14];
  const float* adapt_b = (const float*)d_in[15];
  const float* out_w   = (const float*)d_in[16];
  const float* out_b   = (const float*)d_in[17];
  const float* y_data  = (const float*)d_in[18];
  const int* word_ids  = (const int*)d_in[19];
  const int* topic_ids = (const int*)d_in[20];
  const int* doc_gid   = (const int*)d_in[21];
  const int* td_src = (const int*)d_in[22];
  const int* td_dst = (const int*)d_in[23];
  const int* tt_src = (const int*)d_in[24];
  const int* tt_dst = (const int*)d_in[25];
  const int* wd_src = (const int*)d_in[26];
  const int* wd_dst = (const int*)d_in[27];
  const int* wt_src = (const int*)d_in[28];
  const int* wt_dst = (const int*)d_in[29];
  const int* ww_src = (const int*)d_in[30];
  const int* ww_dst = (const int*)d_in[31];

  char* base = (char*)d_ws;
  size_t off_b = 0;
  auto alloc = [&](size_t bytes) -> char* {
    char* p = base + off_b;
    off_b = (off_b + bytes + 255) & ~(size_t)255;
    return p;
  };

  u16* wtab = (u16*)alloc((size_t)VOCAB * 320 * 2);
  u16* hw   = (u16*)alloc((size_t)N_WORD * 128 * 2);
  u16* hd   = (u16*)alloc((size_t)N_DOC * 128 * 2);
  u16* ht   = (u16*)alloc((size_t)N_TOPIC * 128 * 2);
  u16* k_w  = (u16*)alloc((size_t)N_WORD * 128 * 2);
  u16* k_t  = (u16*)alloc((size_t)N_TOPIC * 128 * 2);
  u16* v_td = (u16*)alloc((size_t)N_TOPIC * 128 * 2);
  u16* v_tt = (u16*)alloc((size_t)N_TOPIC * 128 * 2);
  u16* v_wd = (u16*)alloc((size_t)N_WORD * 128 * 2);
  u16* v_wt = (u16*)alloc((size_t)N_WORD * 128 * 2);
  u16* v_ww = (u16*)alloc((size_t)N_WORD * 128 * 2);
  u16* q_td = (u16*)alloc((size_t)N_DOC * 128 * 2);
  u16* q_wd = (u16*)alloc((size_t)N_DOC * 128 * 2);
  u16* q_tt = (u16*)alloc((size_t)N_TOPIC * 128 * 2);
  u16* q_wt = (u16*)alloc((size_t)N_TOPIC * 128 * 2);
  u16* q_ww = (u16*)alloc((size_t)N_WORD * 128 * 2);
  u16* t_d  = (u16*)alloc((size_t)N_DOC * 128 * 2);
  u16* t_t  = (u16*)alloc((size_t)N_TOPIC * 128 * 2);
  u16* t_w  = (u16*)alloc((size_t)N_WORD * 128 * 2);
  unsigned* g = (unsigned*)alloc((size_t)BATCH * 128 * 4);

  int* cnt_all  = (int*)alloc((size_t)NODES_ALL * 4);
  int* offs_all = (int*)alloc(((size_t)NODES_ALL + 1) * 4);
  int* csrc_all = (int*)alloc((size_t)EDGES_ALL * 4);
  int* bsum     = (int*)alloc((size_t)NBLK_SCAN * 4);
  int* bpre     = (int*)alloc((size_t)NBLK_SCAN * 4);

  u16* blw        = (u16*)alloc((size_t)(40960 + 30 * 16384) * 2);
  float* bias_are = (float*)alloc((size_t)31 * 128 * 4);

  auto BLp = [&](int wid) -> const u16* {
    return (wid == 0) ? blw : blw + 40960 + (size_t)(wid - 1) * 16384;
  };
  auto BIp = [&](int wid) -> const float* { return bias_are + wid * 128; };
  auto WID = [&](int li, int j) { return 1 + li * 15 + j; };

  const int NB_TD = 0, NB_WD = 32000, NB_TT = 64000, NB_WT = 64800, NB_WW = 65600;

  // ---- prep ----
  prep_kernel<<<248, 256, 0, stream>>>(KW, Kb, QW, Qb, VW, Vb, AW, Ab,
                                       rel_att, rel_msg, adapt_w, adapt_b, blw, bias_are);
  conv_wtab_kernel<<<(VOCAB * 320 + 255) / 256, 256, 0, stream>>>(word_embeds, wtab);
  gather_topic_kernel<<<(N_TOPIC * 128 + 255) / 256, 256, 0, stream>>>(topic_embeds, topic_ids, ht);

  hipMemsetAsync(cnt_all, 0, (size_t)NODES_ALL * 4, stream);
  count_all_kernel<<<(EDGES_ALL + 255) / 256, 256, 0, stream>>>(td_dst, wd_dst, tt_dst, wt_dst, ww_dst, cnt_all);
  scanA_kernel<<<NBLK_SCAN, 256, 0, stream>>>(cnt_all, bsum);
  scanB_kernel<<<1, 256, 0, stream>>>(bsum, bpre, offs_all);
  scanC_kernel<<<NBLK_SCAN, 256, 0, stream>>>(cnt_all, bpre, offs_all, cnt_all); // cnt becomes cursor
  fill_all_kernel<<<(EDGES_ALL + 255) / 256, 256, 0, stream>>>(
      td_src, td_dst, wd_src, wd_dst, tt_src, tt_dst, wt_src, wt_dst, ww_src, ww_dst,
      cnt_all, csrc_all);

  hipMemsetAsync(hd, 0, (size_t)N_DOC * 128 * 2, stream);

  // ---- adapt ----
  gemm_kernel<10, 1><<<(N_WORD + 63) / 64, 256, 0, stream>>>(
      wtab, word_ids, BLp(0), BIp(0), hw, nullptr, nullptr, N_WORD);

  const int GW = (N_WORD + 63) / 64, GD = (N_DOC + 63) / 64, GT = (N_TOPIC + 63) / 64;

  for (int li = 0; li < 2; ++li) {
    // word-side fused projections: k_w, v_wd, v_wt, v_ww, q_ww
    {
      Outs P;
      const int wids[5] = {WID(li, 1), WID(li, 12), WID(li, 13), WID(li, 14), WID(li, 9)};
      u16* cs[5] = {k_w, v_wd, v_wt, v_ww, q_ww};
      for (int o = 0; o < 5; ++o) { P.BL[o] = BLp(wids[o]); P.bias[o] = BIp(wids[o]); P.C[o] = cs[o]; }
      gemmN_kernel<4, 5><<<GW, 256, 0, stream>>>(hw, nullptr, P, N_WORD);
    }
    // topic-side fused projections: k_t, v_td, v_tt, q_tt, q_wt
    {
      Outs P;
      const int wids[5] = {WID(li, 0), WID(li, 10), WID(li, 11), WID(li, 6), WID(li, 8)};
      u16* cs[5] = {k_t, v_td, v_tt, q_tt, q_wt};
      for (int o = 0; o < 5; ++o) { P.BL[o] = BLp(wids[o]); P.bias[o] = BIp(wids[o]); P.C[o] = cs[o]; }
      gemmN_kernel<4, 5><<<GT, 256, 0, stream>>>(ht, nullptr, P, N_TOPIC);
    }
    // doc-side Q projections: q_td, q_wd
    if (li == 0) {
      bcast_q_kernel<<<(N_DOC * 128 + 255) / 256, 256, 0, stream>>>(BIp(WID(0, 5)), BIp(WID(0, 7)), q_td, q_wd);
    } else {
      Outs P;
      const int wids[2] = {WID(li, 5), WID(li, 7)};
      u16* cs[2] = {q_td, q_wd};
      for (int o = 0; o < 2; ++o) { P.BL[o] = BLp(wids[o]); P.bias[o] = BIp(wids[o]); P.C[o] = cs[o]; }
      gemmN_kernel<4, 2><<<GD, 256, 0, stream>>>(hd, nullptr, P, N_DOC);
    }

    const float* priB = rel_pri + (size_t)li * 5 * 4;
    agg_kernel<2><<<(N_DOC + 3) / 4, 256, 0, stream>>>(
        q_td, k_t, v_td, offs_all + NB_TD, priB + 0 * 4,
        q_wd, k_w, v_wd, offs_all + NB_WD, priB + 2 * 4,
        csrc_all, t_d, N_DOC, 0.5f);
    agg_topic_kernel<<<N_TOPIC, 256, 0, stream>>>(
        q_tt, k_t, v_tt, offs_all + NB_TT, priB + 1 * 4,
        q_wt, k_w, v_wt, offs_all + NB_WT, priB + 3 * 4,
        csrc_all, t_t, 0.5f);
    agg_kernel<1><<<(N_WORD + 3) / 4, 256, 0, stream>>>(
        q_ww, k_w, v_ww, offs_all + NB_WW, priB + 4 * 4,
        nullptr, nullptr, nullptr, nullptr, nullptr,
        csrc_all, t_w, N_WORD, 1.0f);

    // comb
    gemm_kernel<4, 2><<<GD, 256, 0, stream>>>(t_d, nullptr, BLp(WID(li, 2)), BIp(WID(li, 2)), hd, hd, skip + (size_t)li * 3 + 0, N_DOC);
    gemm_kernel<4, 2><<<GT, 256, 0, stream>>>(t_t, nullptr, BLp(WID(li, 3)), BIp(WID(li, 3)), ht, ht, skip + (size_t)li * 3 + 1, N_TOPIC);
    gemm_kernel<4, 2><<<GW, 256, 0, stream>>>(t_w, nullptr, BLp(WID(li, 4)), BIp(WID(li, 4)), hw, hw, skip + (size_t)li * 3 + 2, N_WORD);
  }

  // ---- readout ----
  ginit_kernel<<<(BATCH * 128 + 255) / 256, 256, 0, stream>>>(g);
  segmax_kernel<<<(N_DOC + 127) / 128, 128, 0, stream>>>(hd, doc_gid, g);
  final_kernel<<<1, 256, 0, stream>>>(g, out_w, out_b, y_data, (float*)d_out);
}

// Round 4
// 556.917 us; speedup vs baseline: 8.3231x; 1.2893x over previous
//
#include <hip/hip_runtime.h>
#include <cstdint>
#include <cstddef>

#define H_DIM 128
#define N_DOC 32000
#define N_TOPIC 800
#define N_WORD 80000
#define BATCH 16
#define VOCAB 15000
#define NODES_ALL 145600
#define EDGES_ALL 850000
#define NBLK_SCAN 143
#define N4_SCAN 36400

typedef short bf16x8 __attribute__((ext_vector_type(8)));
typedef float f32x4 __attribute__((ext_vector_type(4)));
typedef unsigned short u16;

static __device__ __forceinline__ u16 f2bf(float x) {
  unsigned u = __float_as_uint(x);
  u += 0x7fffu + ((u >> 16) & 1u);
  return (u16)(u >> 16);
}
static __device__ __forceinline__ float b2f(unsigned h) {
  return __uint_as_float(h << 16);
}
static __device__ __forceinline__ unsigned fenc(float f) {
  unsigned u = __float_as_uint(f);
  return (u & 0x80000000u) ? ~u : (u | 0x80000000u);
}
static __device__ __forceinline__ float fdec(unsigned k) {
  return (k & 0x80000000u) ? __uint_as_float(k ^ 0x80000000u) : __uint_as_float(~k);
}
static __device__ __forceinline__ int wave_iscan(int v, int lane) {
  #pragma unroll
  for (int d = 1; d < 64; d <<= 1) {
    int t = __shfl_up(v, d);
    if (lane >= d) v += t;
  }
  return v;
}
static __device__ __forceinline__ unsigned blend2(unsigned pr, unsigned bl, float aa) {
  float v0 = b2f(pr & 0xffffu) * aa + b2f(bl & 0xffffu) * (1.f - aa);
  float v1 = b2f(pr >> 16) * aa + b2f(bl >> 16) * (1.f - aa);
  return (unsigned)f2bf(v0) | ((unsigned)f2bf(v1) << 16);
}

// ======================= weight prep =======================
// wid 0: adapt (KS=10, K=300). wid 1..28: wl=wid-1, li=wl/14, j=wl%14:
//  j0 KW[li,1], j1 KW[li,2], j2 VW[li,1], j3 VW[li,2] (plain)
//  j4..8  Qfold r=j-4:  W'[k, h*32+d] = sum_f QW[k, h*32+f] * Ratt[h,d,f]
//  j9..13 combfold r=j-9: W'[h*32+dd, nn] = scale * sum_f Rmsg[h,dd,f] * AW[h*32+f, nn]
// BL frag layout: (t*KS+s)*512 + l*8 + jj  <- W'[s*32+(l>>4)*8+jj][t*16+(l&15)]
__global__ __launch_bounds__(256) void prep_kernel(
    const float* __restrict__ KW, const float* __restrict__ Kb,
    const float* __restrict__ QW, const float* __restrict__ Qb,
    const float* __restrict__ VW, const float* __restrict__ Vb,
    const float* __restrict__ AW, const float* __restrict__ Ab,
    const float* __restrict__ rel_att, const float* __restrict__ rel_msg,
    const float* __restrict__ adapt_w, const float* __restrict__ adapt_b,
    u16* __restrict__ bl_arena, float* __restrict__ bias_arena)
{
  const int wid = blockIdx.x >> 3, t = blockIdx.x & 7;
  int KS, Kreal, fold;
  const float *W, *b, *R = nullptr;
  float scale = 1.f;
  if (wid == 0) { KS = 10; Kreal = 300; fold = 0; W = adapt_w; b = adapt_b; }
  else {
    KS = 4; Kreal = 128;
    const int wl = wid - 1, li = wl / 14, j = wl % 14;
    const int dstnid[5] = {0, 1, 0, 1, 2};
    if (j < 4) {
      fold = 0;
      const float* Wb = (j < 2) ? KW : VW;
      const float* bb = (j < 2) ? Kb : Vb;
      const int nid = (j & 1) ? 2 : 1;
      W = Wb + ((size_t)li * 3 + nid) * 16384; b = bb + ((size_t)li * 3 + nid) * 128;
    } else if (j < 9) {
      fold = 1; const int r = j - 4; const int nid = dstnid[r];
      W = QW + ((size_t)li * 3 + nid) * 16384; b = Qb + ((size_t)li * 3 + nid) * 128;
      R = rel_att + ((size_t)li * 5 + r) * 4096;
    } else {
      fold = 3; const int r = j - 9; const int nid = dstnid[r];
      W = AW + ((size_t)li * 3 + nid) * 16384; b = Ab + ((size_t)li * 3 + nid) * 128;
      R = rel_msg + ((size_t)li * 5 + r) * 4096;
      scale = (r == 4) ? 1.f : 0.5f;
    }
  }
  u16* obl = (wid == 0) ? bl_arena : bl_arena + 40960 + (size_t)(wid - 1) * 16384;
  float* obias = bias_arena + wid * 128;

  const int nelem = KS * 512;
  for (int e = threadIdx.x; e < nelem; e += 256) {
    const int s = e >> 9, rem = e & 511, l = rem >> 3, jj = rem & 7;
    const int k = s * 32 + ((l >> 4) << 3) + jj;
    const int nn = t * 16 + (l & 15);
    float v = 0.f;
    if (k < Kreal) {
      if (fold == 0) v = W[(size_t)k * 128 + nn];
      else if (fold == 1) {
        const int h = nn >> 5, d = nn & 31;
        const float* Wr = W + (size_t)k * 128 + h * 32;
        const float* Rh = R + h * 1024;
        for (int f = 0; f < 32; ++f) v += Wr[f] * Rh[d * 32 + f];
      } else {
        const int h = k >> 5, dd = k & 31;
        const float* Rh = R + h * 1024 + dd * 32;
        const float* Wc = W + (size_t)h * 32 * 128 + nn;
        float sa = 0.f;
        for (int f = 0; f < 32; ++f) sa += Rh[f] * Wc[(size_t)f * 128];
        v = sa * scale;
      }
    }
    obl[(size_t)(t * KS + s) * 512 + rem] = f2bf(v);
  }
  if (t == 0 && threadIdx.x < 128) {
    const int nn = threadIdx.x;
    float v = 0.f;
    if (fold != 1) v = b[nn];
    else {
      const int h = nn >> 5, d = nn & 31;
      const float* Rh = R + h * 1024;
      for (int f = 0; f < 32; ++f) v += b[h * 32 + f] * Rh[d * 32 + f];
    }
    obias[nn] = v;
  }
}

// ======================= MFMA GEMM kernels =======================
// single output; VAR: 0 plain, 1 tanh, 2 comb
template<int KS, int VAR>
__global__ __launch_bounds__(256) void gemm_kernel(
    const u16* __restrict__ A, int AS, const int* __restrict__ idx,
    const u16* __restrict__ BL, const float* __restrict__ bias,
    u16* __restrict__ C, const u16* __restrict__ blend,
    const float* __restrict__ skipp, int n)
{
  __shared__ u16 lds16[64 * 132];
  const int tid = threadIdx.x, lane = tid & 63, w = tid >> 6;
  const int m0 = blockIdx.x * 64 + w * 16;
  int rl = m0 + (lane & 15);
  if (rl >= n) rl = n - 1;
  const int row = idx ? idx[rl] : rl;
  const int g = lane >> 4;

  bf16x8 a[KS];
  const u16* Ap = A + (size_t)row * AS + g * 8;
  #pragma unroll
  for (int s = 0; s < KS; ++s) a[s] = *reinterpret_cast<const bf16x8*>(Ap + s * 32);

  f32x4 acc[8];
  #pragma unroll
  for (int t = 0; t < 8; ++t) acc[t] = (f32x4)0.f;
  const u16* Bp = BL + (size_t)lane * 8;
  #pragma unroll
  for (int s = 0; s < KS; ++s) {
    #pragma unroll
    for (int t = 0; t < 8; ++t) {
      bf16x8 bfr = *reinterpret_cast<const bf16x8*>(Bp + (size_t)(t * KS + s) * 512);
      acc[t] = __builtin_amdgcn_mfma_f32_16x16x32_bf16(a[s], bfr, acc[t], 0, 0, 0);
    }
  }
  #pragma unroll
  for (int t = 0; t < 8; ++t) {
    const int col = t * 16 + (lane & 15);
    const float bb = bias[col];
    const int mr = w * 16 + g * 4;
    #pragma unroll
    for (int j = 0; j < 4; ++j) {
      float v = acc[t][j] + bb;
      if (VAR == 1) v = tanhf(v);
      lds16[(mr + j) * 132 + col] = f2bf(v);
    }
  }
  __syncthreads();
  const int rr = tid >> 2, cs = (tid & 3) * 32, m = blockIdx.x * 64 + rr;
  if (m < n) {
    uint2 r8[8];
    #pragma unroll
    for (int q = 0; q < 8; ++q) r8[q] = *reinterpret_cast<const uint2*>(&lds16[rr * 132 + cs + q * 4]);
    if (VAR == 2) {
      const float aa = 1.f / (1.f + __expf(-skipp[0]));
      #pragma unroll
      for (int q2 = 0; q2 < 4; ++q2) {
        uint4 blv = *reinterpret_cast<const uint4*>(blend + (size_t)m * 128 + cs + q2 * 8);
        r8[2 * q2].x     = blend2(r8[2 * q2].x, blv.x, aa);
        r8[2 * q2].y     = blend2(r8[2 * q2].y, blv.y, aa);
        r8[2 * q2 + 1].x = blend2(r8[2 * q2 + 1].x, blv.z, aa);
        r8[2 * q2 + 1].y = blend2(r8[2 * q2 + 1].y, blv.w, aa);
      }
    }
    #pragma unroll
    for (int q2 = 0; q2 < 4; ++q2) {
      uint4 st;
      st.x = r8[2 * q2].x; st.y = r8[2 * q2].y;
      st.z = r8[2 * q2 + 1].x; st.w = r8[2 * q2 + 1].y;
      *reinterpret_cast<uint4*>(C + (size_t)m * 128 + cs + q2 * 8) = st;
    }
  }
}

struct Outs4 {
  const u16* BL[4];
  const float* bias[4];
  u16* C[4];
  int cs[4];
};

template<int KS, int NOUT>
__global__ __launch_bounds__(256) void gemmN_kernel(
    const u16* __restrict__ A, int AS, const int* __restrict__ idx, Outs4 P, int n)
{
  __shared__ u16 lds16[64 * 132];
  const int tid = threadIdx.x, lane = tid & 63, w = tid >> 6;
  const int m0 = blockIdx.x * 64 + w * 16;
  int rl = m0 + (lane & 15);
  if (rl >= n) rl = n - 1;
  const int row = idx ? idx[rl] : rl;
  const int g = lane >> 4;

  bf16x8 a[KS];
  const u16* Ap = A + (size_t)row * AS + g * 8;
  #pragma unroll
  for (int s = 0; s < KS; ++s) a[s] = *reinterpret_cast<const bf16x8*>(Ap + s * 32);

  const int rr = tid >> 2, cs = (tid & 3) * 32, m = blockIdx.x * 64 + rr;

  #pragma unroll
  for (int o = 0; o < NOUT; ++o) {
    f32x4 acc[8];
    #pragma unroll
    for (int t = 0; t < 8; ++t) acc[t] = (f32x4)0.f;
    const u16* Bp = P.BL[o] + (size_t)lane * 8;
    #pragma unroll
    for (int s = 0; s < KS; ++s) {
      #pragma unroll
      for (int t = 0; t < 8; ++t) {
        bf16x8 bfr = *reinterpret_cast<const bf16x8*>(Bp + (size_t)(t * KS + s) * 512);
        acc[t] = __builtin_amdgcn_mfma_f32_16x16x32_bf16(a[s], bfr, acc[t], 0, 0, 0);
      }
    }
    if (o) __syncthreads();
    const float* bias = P.bias[o];
    #pragma unroll
    for (int t = 0; t < 8; ++t) {
      const int col = t * 16 + (lane & 15);
      const float bb = bias[col];
      const int mr = w * 16 + g * 4;
      #pragma unroll
      for (int j = 0; j < 4; ++j)
        lds16[(mr + j) * 132 + col] = f2bf(acc[t][j] + bb);
    }
    __syncthreads();
    if (m < n) {
      const int ostr = P.cs[o];
      #pragma unroll
      for (int q2 = 0; q2 < 4; ++q2) {
        uint2 x0 = *reinterpret_cast<const uint2*>(&lds16[rr * 132 + cs + q2 * 8]);
        uint2 x1 = *reinterpret_cast<const uint2*>(&lds16[rr * 132 + cs + q2 * 8 + 4]);
        uint4 st; st.x = x0.x; st.y = x0.y; st.z = x1.x; st.w = x1.y;
        *reinterpret_cast<uint4*>(P.C[o] + (size_t)m * ostr + cs + q2 * 8) = st;
      }
    }
  }
}

// dual-A comb GEMM: out = (a0@W0 + a1@W1 + bias)*sig(skip) + blend*(1-sig); blend==C
template<int KS>
__global__ __launch_bounds__(256) void gemm2_kernel(
    const u16* __restrict__ A2, const u16* __restrict__ BL0, const u16* __restrict__ BL1,
    const float* __restrict__ bias, u16* __restrict__ C,
    const float* __restrict__ skipp, int n)
{
  __shared__ u16 lds16[64 * 132];
  const int tid = threadIdx.x, lane = tid & 63, w = tid >> 6;
  const int m0 = blockIdx.x * 64 + w * 16;
  int rl = m0 + (lane & 15);
  if (rl >= n) rl = n - 1;
  const int g = lane >> 4;

  bf16x8 a0[KS], a1[KS];
  const u16* Ap = A2 + (size_t)rl * 256 + g * 8;
  #pragma unroll
  for (int s = 0; s < KS; ++s) {
    a0[s] = *reinterpret_cast<const bf16x8*>(Ap + s * 32);
    a1[s] = *reinterpret_cast<const bf16x8*>(Ap + 128 + s * 32);
  }
  f32x4 acc[8];
  #pragma unroll
  for (int t = 0; t < 8; ++t) acc[t] = (f32x4)0.f;
  const u16* Bp0 = BL0 + (size_t)lane * 8;
  const u16* Bp1 = BL1 + (size_t)lane * 8;
  #pragma unroll
  for (int s = 0; s < KS; ++s) {
    #pragma unroll
    for (int t = 0; t < 8; ++t) {
      bf16x8 b0 = *reinterpret_cast<const bf16x8*>(Bp0 + (size_t)(t * KS + s) * 512);
      acc[t] = __builtin_amdgcn_mfma_f32_16x16x32_bf16(a0[s], b0, acc[t], 0, 0, 0);
      bf16x8 b1 = *reinterpret_cast<const bf16x8*>(Bp1 + (size_t)(t * KS + s) * 512);
      acc[t] = __builtin_amdgcn_mfma_f32_16x16x32_bf16(a1[s], b1, acc[t], 0, 0, 0);
    }
  }
  #pragma unroll
  for (int t = 0; t < 8; ++t) {
    const int col = t * 16 + (lane & 15);
    const float bb = bias[col];
    const int mr = w * 16 + g * 4;
    #pragma unroll
    for (int j = 0; j < 4; ++j)
      lds16[(mr + j) * 132 + col] = f2bf(acc[t][j] + bb);
  }
  __syncthreads();
  const int rr = tid >> 2, cs = (tid & 3) * 32, m = blockIdx.x * 64 + rr;
  if (m < n) {
    const float aa = 1.f / (1.f + __expf(-skipp[0]));
    uint2 r8[8];
    #pragma unroll
    for (int q = 0; q < 8; ++q) r8[q] = *reinterpret_cast<const uint2*>(&lds16[rr * 132 + cs + q * 4]);
    #pragma unroll
    for (int q2 = 0; q2 < 4; ++q2) {
      uint4 blv = *reinterpret_cast<const uint4*>(C + (size_t)m * 128 + cs + q2 * 8);
      uint4 st;
      st.x = blend2(r8[2 * q2].x, blv.x, aa);
      st.y = blend2(r8[2 * q2].y, blv.y, aa);
      st.z = blend2(r8[2 * q2 + 1].x, blv.z, aa);
      st.w = blend2(r8[2 * q2 + 1].y, blv.w, aa);
      *reinterpret_cast<uint4*>(C + (size_t)m * 128 + cs + q2 * 8) = st;
    }
  }
}

// ======================= misc small kernels =======================
__global__ void conv_wtab_kernel(const float* __restrict__ we, u16* __restrict__ wt) {
  int i = blockIdx.x * 256 + threadIdx.x;
  if (i < VOCAB * 320) {
    int r = i / 320, c = i - r * 320;
    wt[i] = (c < 300) ? f2bf(we[(size_t)r * 300 + c]) : (u16)0;
  }
}

__global__ void gather_topic_kernel(const float* __restrict__ emb, const int* __restrict__ ids,
                                    u16* __restrict__ out) {
  int i = blockIdx.x * 256 + threadIdx.x;
  if (i < N_TOPIC * 128) {
    int node = i >> 7, c = i & 127;
    out[i] = f2bf(emb[(size_t)ids[node] * 128 + c]);
  }
}

__global__ void bcast_q_kernel(const float* __restrict__ b0, const float* __restrict__ b1,
                               u16* __restrict__ q0, u16* __restrict__ q1) {
  int i = blockIdx.x * 256 + threadIdx.x;
  if (i < N_DOC * 128) {
    int c = i & 127;
    q0[i] = f2bf(b0[c]);
    q1[i] = f2bf(b1[c]);
  }
}

// ======================= CSR build =======================
__global__ void count_all_kernel(const int* __restrict__ td, const int* __restrict__ wd,
                                 const int* __restrict__ tt, const int* __restrict__ wt,
                                 const int* __restrict__ ww, int* cnt) {
  int i = blockIdx.x * 256 + threadIdx.x;
  if (i >= EDGES_ALL) return;
  int b;
  if (i < 80000)       b = td[i];
  else if (i < 330000) b = 32000 + wd[i - 80000];
  else if (i < 350000) b = 64000 + tt[i - 330000];
  else if (i < 450000) b = 64800 + wt[i - 350000];
  else                 b = 65600 + ww[i - 450000];
  atomicAdd(&cnt[b], 1);
}

__global__ void fill_all_kernel(const int* __restrict__ td_s, const int* __restrict__ td_d,
                                const int* __restrict__ wd_s, const int* __restrict__ wd_d,
                                const int* __restrict__ tt_s, const int* __restrict__ tt_d,
                                const int* __restrict__ wt_s, const int* __restrict__ wt_d,
                                const int* __restrict__ ww_s, const int* __restrict__ ww_d,
                                int* cursor, int* csrc) {
  int i = blockIdx.x * 256 + threadIdx.x;
  if (i >= EDGES_ALL) return;
  int b, s;
  if (i < 80000)       { b = td_d[i];                  s = td_s[i]; }
  else if (i < 330000) { b = 32000 + wd_d[i - 80000];  s = wd_s[i - 80000]; }
  else if (i < 350000) { b = 64000 + tt_d[i - 330000]; s = tt_s[i - 330000]; }
  else if (i < 450000) { b = 64800 + wt_d[i - 350000]; s = wt_s[i - 350000]; }
  else                 { b = 65600 + ww_d[i - 450000]; s = ww_s[i - 450000]; }
  int p = atomicAdd(&cursor[b], 1);
  csrc[p] = s;
}

__global__ __launch_bounds__(256) void scanA_kernel(const int* __restrict__ cnt, int* __restrict__ bsum) {
  const int tid = threadIdx.x, lane = tid & 63, wv = tid >> 6;
  const int i4 = blockIdx.x * 256 + tid;
  int4 v = make_int4(0, 0, 0, 0);
  if (i4 < N4_SCAN) v = reinterpret_cast<const int4*>(cnt)[i4];
  int s = v.x + v.y + v.z + v.w;
  #pragma unroll
  for (int d = 1; d < 64; d <<= 1) s += __shfl_xor(s, d);
  __shared__ int ws[4];
  if (lane == 0) ws[wv] = s;
  __syncthreads();
  if (tid == 0) bsum[blockIdx.x] = ws[0] + ws[1] + ws[2] + ws[3];
}

__global__ __launch_bounds__(256) void scanB_kernel(const int* __restrict__ bsum,
                                                    int* __restrict__ bpre, int* __restrict__ offs) {
  const int tid = threadIdx.x, lane = tid & 63, wv = tid >> 6;
  int v = (tid < NBLK_SCAN) ? bsum[tid] : 0;
  int incl = wave_iscan(v, lane);
  __shared__ int ws[4];
  if (lane == 63) ws[wv] = incl;
  __syncthreads();
  int pre = 0;
  for (int j = 0; j < 4; ++j) if (j < wv) pre += ws[j];
  incl += pre;
  if (tid < NBLK_SCAN) bpre[tid] = incl - v;
  if (tid == NBLK_SCAN - 1) offs[NODES_ALL] = incl;
}

__global__ __launch_bounds__(256) void scanC_kernel(const int* __restrict__ cnt,
                                                    const int* __restrict__ bpre,
                                                    int* __restrict__ offs, int* __restrict__ cursor) {
  const int tid = threadIdx.x, lane = tid & 63, wv = tid >> 6;
  const int i4 = blockIdx.x * 256 + tid;
  int4 v = make_int4(0, 0, 0, 0);
  if (i4 < N4_SCAN) v = reinterpret_cast<const int4*>(cnt)[i4];
  const int tsum = v.x + v.y + v.z + v.w;
  int incl = wave_iscan(tsum, lane);
  __shared__ int ws[4];
  if (lane == 63) ws[wv] = incl;
  __syncthreads();
  int pre = bpre[blockIdx.x];
  for (int j = 0; j < 4; ++j) if (j < wv) pre += ws[j];
  int o0 = pre + incl - tsum;
  if (i4 < N4_SCAN) {
    int4 ov = make_int4(o0, o0 + v.x, o0 + v.x + v.y, o0 + v.x + v.y + v.z);
    reinterpret_cast<int4*>(offs)[i4] = ov;
    reinterpret_cast<int4*>(cursor)[i4] = ov;
  }
}

// ======================= aggregation (fused, raw output) =======================
struct AggArgs {
  const u16 *q_td, *q_wd, *q_tt, *q_wt, *q_ww;
  const u16 *kv_t, *kv_w;
  const int *csrc, *offs;
  const float *pri;        // layer base: + r*4
  u16 *t2_d, *t2_t, *t_w;
};

static __device__ __forceinline__ void agg_rel(
    const u16* __restrict__ q, const u16* __restrict__ kv,
    const int* __restrict__ offs, const int* __restrict__ csrc,
    const float* __restrict__ pri,
    int node, int lo, int st, int sl, float acc[8], float& ssOut)
{
  const int e0 = offs[node], e1 = offs[node + 1];
  float ss = 0.f;
  #pragma unroll
  for (int i = 0; i < 8; ++i) acc[i] = 0.f;
  if (e1 > e0) {
    const float prih = pri[sl >> 2] * 0.17677669529663687f;
    const bf16x8 qv = *reinterpret_cast<const bf16x8*>(q + (size_t)node * 128 + sl * 8);
    float q8[8];
    #pragma unroll
    for (int i = 0; i < 8; ++i) q8[i] = b2f((u16)qv[i]);
    for (int base = e0; base < e1; base += st) {
      const int e = base + lo;
      const bool valid = e < e1;
      const int s = csrc[valid ? e : e0];
      const bf16x8 k8 = *reinterpret_cast<const bf16x8*>(kv + (size_t)s * 256 + sl * 8);
      float dot = 0.f;
      #pragma unroll
      for (int i = 0; i < 8; ++i) dot += q8[i] * b2f((u16)k8[i]);
      dot += __shfl_xor(dot, 1);
      dot += __shfl_xor(dot, 2);
      const float wg = valid ? __expf(dot * prih) : 0.f;
      const bf16x8 v8 = *reinterpret_cast<const bf16x8*>(kv + (size_t)s * 256 + 128 + sl * 8);
      ss += wg;
      #pragma unroll
      for (int i = 0; i < 8; ++i) acc[i] += wg * b2f((u16)v8[i]);
    }
  }
  ss += __shfl_xor(ss, 16); ss += __shfl_xor(ss, 32);
  #pragma unroll
  for (int i = 0; i < 8; ++i) {
    acc[i] += __shfl_xor(acc[i], 16);
    acc[i] += __shfl_xor(acc[i], 32);
  }
  ssOut = ss;
}

static __device__ __forceinline__ void agg_store(const float acc[8], float ss,
                                                 u16* dst, bool do_store)
{
  const float inv = (ss > 0.f) ? 1.f / ss : 0.f;
  uint4 pk;
  pk.x = (unsigned)f2bf(acc[0] * inv) | ((unsigned)f2bf(acc[1] * inv) << 16);
  pk.y = (unsigned)f2bf(acc[2] * inv) | ((unsigned)f2bf(acc[3] * inv) << 16);
  pk.z = (unsigned)f2bf(acc[4] * inv) | ((unsigned)f2bf(acc[5] * inv) << 16);
  pk.w = (unsigned)f2bf(acc[6] * inv) | ((unsigned)f2bf(acc[7] * inv) << 16);
  if (do_store) *reinterpret_cast<uint4*>(dst) = pk;
}

// blocks [0,8000): doc (node=bid*4+wv); [8000,28000): word; [28000,28800): topic (block/node)
__global__ __launch_bounds__(256) void agg_all_kernel(AggArgs A)
{
  __shared__ float lacc[4][16][8];
  __shared__ float lss[4][16];
  const int tid = threadIdx.x, lane = tid & 63, wv = tid >> 6;
  const int sub = lane >> 4, sl = lane & 15;
  const int bid = blockIdx.x;
  float acc[8]; float ss;
  if (bid < 8000) {
    const int node = bid * 4 + wv;
    agg_rel(A.q_td, A.kv_t, A.offs + 0,     A.csrc, A.pri + 0,  node, sub, 4, sl, acc, ss);
    agg_store(acc, ss, A.t2_d + (size_t)node * 256 + sl * 8, sub == 0);
    agg_rel(A.q_wd, A.kv_w, A.offs + 32000, A.csrc, A.pri + 8,  node, sub, 4, sl, acc, ss);
    agg_store(acc, ss, A.t2_d + (size_t)node * 256 + 128 + sl * 8, sub == 0);
  } else if (bid < 28000) {
    const int node = (bid - 8000) * 4 + wv;
    agg_rel(A.q_ww, A.kv_w, A.offs + 65600, A.csrc, A.pri + 16, node, sub, 4, sl, acc, ss);
    agg_store(acc, ss, A.t_w + (size_t)node * 128 + sl * 8, sub == 0);
  } else {
    const int node = bid - 28000;
    for (int r = 0; r < 2; ++r) {
      agg_rel(r ? A.q_wt : A.q_tt, r ? A.kv_w : A.kv_t,
              A.offs + (r ? 64800 : 64000), A.csrc, A.pri + (r ? 12 : 4),
              node, wv * 4 + sub, 16, sl, acc, ss);
      if (sub == 0) {
        lss[wv][sl] = ss;
        #pragma unroll
        for (int i = 0; i < 8; ++i) lacc[wv][sl][i] = acc[i];
      }
      __syncthreads();
      if (tid < 16) {
        float s2 = lss[0][tid] + lss[1][tid] + lss[2][tid] + lss[3][tid];
        float a2[8];
        #pragma unroll
        for (int i = 0; i < 8; ++i)
          a2[i] = lacc[0][tid][i] + lacc[1][tid][i] + lacc[2][tid][i] + lacc[3][tid][i];
        agg_store(a2, s2, A.t2_t + (size_t)node * 256 + r * 128 + tid * 8, true);
      }
      __syncthreads();
    }
  }
}

// ======================= readout =======================
__global__ void ginit_kernel(unsigned* g) {
  int i = blockIdx.x * 256 + threadIdx.x;
  if (i < BATCH * H_DIM) g[i] = 0x007FFFFFu;
}

__global__ void segmax_kernel(const u16* __restrict__ hd, const int* __restrict__ gid,
                              unsigned* g) {
  int c = threadIdx.x;
  int d0 = blockIdx.x * 128;
  int dend = min(d0 + 128, N_DOC);
  int cur = -1; float m = 0.f;
  for (int d = d0; d < dend; ++d) {
    int gg = gid[d];
    float v = b2f(hd[(size_t)d * 128 + c]);
    if (gg != cur) {
      if (cur >= 0) atomicMax(&g[cur * 128 + c], fenc(m));
      cur = gg; m = v;
    } else {
      m = fmaxf(m, v);
    }
  }
  if (cur >= 0) atomicMax(&g[cur * 128 + c], fenc(m));
}

__global__ void final_kernel(const unsigned* __restrict__ g, const float* __restrict__ out_w,
                             const float* __restrict__ out_b, const float* __restrict__ y,
                             float* out) {
  int tid = threadIdx.x;
  int b = tid >> 4, seg = tid & 15;
  float p = 0.f;
  #pragma unroll
  for (int j = 0; j < 8; ++j) {
    int c = seg * 8 + j;
    p += fdec(g[b * 128 + c]) * out_w[c];
  }
  p += __shfl_xor(p, 1);
  p += __shfl_xor(p, 2);
  p += __shfl_xor(p, 4);
  p += __shfl_xor(p, 8);
  __shared__ float logits[BATCH];
  __shared__ float losses[BATCH];
  if (seg == 0) logits[b] = p + out_b[0];
  __syncthreads();
  if (tid < BATCH) {
    float l = logits[tid];
    out[1 + tid] = 1.f / (1.f + expf(-l));
    float ls_pos = (l > 0.f) ? -log1pf(expf(-l)) : l - log1pf(expf(l));
    float ls_neg = (l < 0.f) ? -log1pf(expf(l)) : -l - log1pf(expf(-l));
    losses[tid] = -(y[tid] * ls_pos + (1.f - y[tid]) * ls_neg);
  }
  __syncthreads();
  if (tid == 0) {
    float s = 0.f;
    for (int j = 0; j < BATCH; ++j) s += losses[j];
    out[0] = s / (float)BATCH;
  }
}

// ======================= host =======================
extern "C" void kernel_launch(void* const* d_in, const int* in_sizes, int n_in,
                              void* d_out, int out_size, void* d_ws, size_t ws_size,
                              hipStream_t stream)
{
  const float* word_embeds  = (const float*)d_in[0];
  const float* topic_embeds = (const float*)d_in[1];
  const float* KW  = (const float*)d_in[2];
  const float* Kb  = (const float*)d_in[3];
  const float* QW  = (const float*)d_in[4];
  const float* Qb  = (const float*)d_in[5];
  const float* VW  = (const float*)d_in[6];
  const float* Vb  = (const float*)d_in[7];
  const float* AW  = (const float*)d_in[8];
  const float* Ab  = (const float*)d_in[9];
  const float* rel_att = (const float*)d_in[10];
  const float* rel_msg = (const float*)d_in[11];
  const float* rel_pri = (const float*)d_in[12];
  const float* skip    = (const float*)d_in[13];
  const float* adapt_w = (const float*)d_in[14];
  const float* adapt_b = (const float*)d_in[15];
  const float* out_w   = (const float*)d_in[16];
  const float* out_b   = (const float*)d_in[17];
  const float* y_data  = (const float*)d_in[18];
  const int* word_ids  = (const int*)d_in[19];
  const int* topic_ids = (const int*)d_in[20];
  const int* doc_gid   = (const int*)d_in[21];
  const int* td_src = (const int*)d_in[22];
  const int* td_dst = (const int*)d_in[23];
  const int* tt_src = (const int*)d_in[24];
  const int* tt_dst = (const int*)d_in[25];
  const int* wd_src = (const int*)d_in[26];
  const int* wd_dst = (const int*)d_in[27];
  const int* wt_src = (const int*)d_in[28];
  const int* wt_dst = (const int*)d_in[29];
  const int* ww_src = (const int*)d_in[30];
  const int* ww_dst = (const int*)d_in[31];

  char* base = (char*)d_ws;
  size_t off_b = 0;
  auto alloc = [&](size_t bytes) -> char* {
    char* p = base + off_b;
    off_b = (off_b + bytes + 255) & ~(size_t)255;
    return p;
  };

  u16* wtab = (u16*)alloc((size_t)VOCAB * 320 * 2);
  u16* hw   = (u16*)alloc((size_t)N_WORD * 128 * 2);
  u16* hd   = (u16*)alloc((size_t)N_DOC * 128 * 2);
  u16* ht   = (u16*)alloc((size_t)N_TOPIC * 128 * 2);
  u16* kv_w = (u16*)alloc((size_t)N_WORD * 256 * 2);
  u16* kv_t = (u16*)alloc((size_t)N_TOPIC * 256 * 2);
  u16* q_td = (u16*)alloc((size_t)N_DOC * 128 * 2);
  u16* q_wd = (u16*)alloc((size_t)N_DOC * 128 * 2);
  u16* q_tt = (u16*)alloc((size_t)N_TOPIC * 128 * 2);
  u16* q_wt = (u16*)alloc((size_t)N_TOPIC * 128 * 2);
  u16* q_ww = (u16*)alloc((size_t)N_WORD * 128 * 2);
  u16* t2_d = (u16*)alloc((size_t)N_DOC * 256 * 2);
  u16* t2_t = (u16*)alloc((size_t)N_TOPIC * 256 * 2);
  u16* t_w  = (u16*)alloc((size_t)N_WORD * 128 * 2);
  unsigned* g = (unsigned*)alloc((size_t)BATCH * 128 * 4);

  int* cnt_all  = (int*)alloc((size_t)NODES_ALL * 4);
  int* offs_all = (int*)alloc(((size_t)NODES_ALL + 1) * 4);
  int* csrc_all = (int*)alloc((size_t)EDGES_ALL * 4);
  int* bsum     = (int*)alloc((size_t)NBLK_SCAN * 4);
  int* bpre     = (int*)alloc((size_t)NBLK_SCAN * 4);

  u16* blw        = (u16*)alloc((size_t)(40960 + 28 * 16384) * 2);
  float* bias_are = (float*)alloc((size_t)29 * 128 * 4);

  auto BLp = [&](int wid) -> const u16* {
    return (wid == 0) ? blw : blw + 40960 + (size_t)(wid - 1) * 16384;
  };
  auto BIp = [&](int wid) -> const float* { return bias_are + wid * 128; };
  auto WID = [&](int li, int j) { return 1 + li * 14 + j; };

  // ---- prep ----
  prep_kernel<<<29 * 8, 256, 0, stream>>>(KW, Kb, QW, Qb, VW, Vb, AW, Ab,
                                          rel_att, rel_msg, adapt_w, adapt_b, blw, bias_are);
  conv_wtab_kernel<<<(VOCAB * 320 + 255) / 256, 256, 0, stream>>>(word_embeds, wtab);
  gather_topic_kernel<<<(N_TOPIC * 128 + 255) / 256, 256, 0, stream>>>(topic_embeds, topic_ids, ht);

  hipMemsetAsync(cnt_all, 0, (size_t)NODES_ALL * 4, stream);
  count_all_kernel<<<(EDGES_ALL + 255) / 256, 256, 0, stream>>>(td_dst, wd_dst, tt_dst, wt_dst, ww_dst, cnt_all);
  scanA_kernel<<<NBLK_SCAN, 256, 0, stream>>>(cnt_all, bsum);
  scanB_kernel<<<1, 256, 0, stream>>>(bsum, bpre, offs_all);
  scanC_kernel<<<NBLK_SCAN, 256, 0, stream>>>(cnt_all, bpre, offs_all, cnt_all);
  fill_all_kernel<<<(EDGES_ALL + 255) / 256, 256, 0, stream>>>(
      td_src, td_dst, wd_src, wd_dst, tt_src, tt_dst, wt_src, wt_dst, ww_src, ww_dst,
      cnt_all, csrc_all);

  hipMemsetAsync(hd, 0, (size_t)N_DOC * 128 * 2, stream);

  // ---- adapt ----
  gemm_kernel<10, 1><<<(N_WORD + 63) / 64, 256, 0, stream>>>(
      wtab, 320, word_ids, BLp(0), BIp(0), hw, nullptr, nullptr, N_WORD);

  const int GW = (N_WORD + 63) / 64, GD = (N_DOC + 63) / 64, GT = (N_TOPIC + 63) / 64;

  for (int li = 0; li < 2; ++li) {
    // word-side: k -> kv_w[+0], v -> kv_w[+128], q_ww
    {
      Outs4 P = {};
      const int wids[3] = {WID(li, 1), WID(li, 3), WID(li, 8)};
      u16* cs[3] = {kv_w, kv_w + 128, q_ww};
      const int strs[3] = {256, 256, 128};
      for (int o = 0; o < 3; ++o) { P.BL[o] = BLp(wids[o]); P.bias[o] = BIp(wids[o]); P.C[o] = cs[o]; P.cs[o] = strs[o]; }
      gemmN_kernel<4, 3><<<GW, 256, 0, stream>>>(hw, 128, nullptr, P, N_WORD);
    }
    // topic-side: k, v, q_tt, q_wt
    {
      Outs4 P = {};
      const int wids[4] = {WID(li, 0), WID(li, 2), WID(li, 5), WID(li, 7)};
      u16* cs[4] = {kv_t, kv_t + 128, q_tt, q_wt};
      const int strs[4] = {256, 256, 128, 128};
      for (int o = 0; o < 4; ++o) { P.BL[o] = BLp(wids[o]); P.bias[o] = BIp(wids[o]); P.C[o] = cs[o]; P.cs[o] = strs[o]; }
      gemmN_kernel<4, 4><<<GT, 256, 0, stream>>>(ht, 128, nullptr, P, N_TOPIC);
    }
    // doc-side Q
    if (li == 0) {
      bcast_q_kernel<<<(N_DOC * 128 + 255) / 256, 256, 0, stream>>>(BIp(WID(0, 4)), BIp(WID(0, 6)), q_td, q_wd);
    } else {
      Outs4 P = {};
      const int wids[2] = {WID(li, 4), WID(li, 6)};
      u16* cs[2] = {q_td, q_wd};
      for (int o = 0; o < 2; ++o) { P.BL[o] = BLp(wids[o]); P.bias[o] = BIp(wids[o]); P.C[o] = cs[o]; P.cs[o] = 128; }
      gemmN_kernel<4, 2><<<GD, 256, 0, stream>>>(hd, 128, nullptr, P, N_DOC);
    }

    // fused aggregation
    AggArgs A;
    A.q_td = q_td; A.q_wd = q_wd; A.q_tt = q_tt; A.q_wt = q_wt; A.q_ww = q_ww;
    A.kv_t = kv_t; A.kv_w = kv_w;
    A.csrc = csrc_all; A.offs = offs_all;
    A.pri = rel_pri + (size_t)li * 5 * 4;
    A.t2_d = t2_d; A.t2_t = t2_t; A.t_w = t_w;
    agg_all_kernel<<<28800, 256, 0, stream>>>(A);

    // comb (M folded into weights)
    gemm2_kernel<4><<<GD, 256, 0, stream>>>(t2_d, BLp(WID(li, 9)), BLp(WID(li, 11)),
                                            BIp(WID(li, 9)), hd, skip + (size_t)li * 3 + 0, N_DOC);
    gemm2_kernel<4><<<GT, 256, 0, stream>>>(t2_t, BLp(WID(li, 10)), BLp(WID(li, 12)),
                                            BIp(WID(li, 10)), ht, skip + (size_t)li * 3 + 1, N_TOPIC);
    gemm_kernel<4, 2><<<GW, 256, 0, stream>>>(t_w, 128, nullptr, BLp(WID(li, 13)), BIp(WID(li, 13)),
                                              hw, hw, skip + (size_t)li * 3 + 2, N_WORD);
  }

  // ---- readout ----
  ginit_kernel<<<(BATCH * 128 + 255) / 256, 256, 0, stream>>>(g);
  segmax_kernel<<<(N_DOC + 127) / 128, 128, 0, stream>>>(hd, doc_gid, g);
  final_kernel<<<1, 256, 0, stream>>>(g, out_w, out_b, y_data, (float*)d_out);
}

// Round 5
// 495.121 us; speedup vs baseline: 9.3619x; 1.1248x over previous
//
#include <hip/hip_runtime.h>
#include <cstdint>
#include <cstddef>

#define H_DIM 128
#define N_DOC 32000
#define N_TOPIC 800
#define N_WORD 80000
#define BATCH 16
#define VOCAB 15000
#define NODES_ALL 145600
#define EDGES_ALL 850000
#define NBLK_SCAN 143
#define N4_SCAN 36400

typedef short bf16x8 __attribute__((ext_vector_type(8)));
typedef float f32x4 __attribute__((ext_vector_type(4)));
typedef float f32x2 __attribute__((ext_vector_type(2)));
typedef unsigned short u16;
typedef unsigned char u8;

static __device__ __forceinline__ u16 f2bf(float x) {
  unsigned u = __float_as_uint(x);
  u += 0x7fffu + ((u >> 16) & 1u);
  return (u16)(u >> 16);
}
static __device__ __forceinline__ float b2f(unsigned h) {
  return __uint_as_float(h << 16);
}
static __device__ __forceinline__ unsigned fenc(float f) {
  unsigned u = __float_as_uint(f);
  return (u & 0x80000000u) ? ~u : (u | 0x80000000u);
}
static __device__ __forceinline__ float fdec(unsigned k) {
  return (k & 0x80000000u) ? __uint_as_float(k ^ 0x80000000u) : __uint_as_float(~k);
}
static __device__ __forceinline__ int wave_iscan(int v, int lane) {
  #pragma unroll
  for (int d = 1; d < 64; d <<= 1) {
    int t = __shfl_up(v, d);
    if (lane >= d) v += t;
  }
  return v;
}
static __device__ __forceinline__ unsigned blend2(unsigned pr, unsigned bl, float aa) {
  float v0 = b2f(pr & 0xffffu) * aa + b2f(bl & 0xffffu) * (1.f - aa);
  float v1 = b2f(pr >> 16) * aa + b2f(bl >> 16) * (1.f - aa);
  return (unsigned)f2bf(v0) | ((unsigned)f2bf(v1) << 16);
}

// ======================= weight prep =======================
// wid 0: adapt (KS=10, K=300). wid 1..28: wl=wid-1, li=wl/14, j=wl%14:
//  j0 KW[li,1], j1 KW[li,2], j2 VW[li,1], j3 VW[li,2] (plain)
//  j4..8  Qfold r=j-4:  W'[k, h*32+d] = sum_f QW[k, h*32+f] * Ratt[h,d,f]
//  j9..13 combfold r=j-9: W'[h*32+dd, nn] = scale * sum_f Rmsg[h,dd,f] * AW[h*32+f, nn]
__global__ __launch_bounds__(256) void prep_kernel(
    const float* __restrict__ KW, const float* __restrict__ Kb,
    const float* __restrict__ QW, const float* __restrict__ Qb,
    const float* __restrict__ VW, const float* __restrict__ Vb,
    const float* __restrict__ AW, const float* __restrict__ Ab,
    const float* __restrict__ rel_att, const float* __restrict__ rel_msg,
    const float* __restrict__ adapt_w, const float* __restrict__ adapt_b,
    u16* __restrict__ bl_arena, float* __restrict__ bias_arena)
{
  const int wid = blockIdx.x >> 3, t = blockIdx.x & 7;
  int KS, Kreal, fold;
  const float *W, *b, *R = nullptr;
  float scale = 1.f;
  if (wid == 0) { KS = 10; Kreal = 300; fold = 0; W = adapt_w; b = adapt_b; }
  else {
    KS = 4; Kreal = 128;
    const int wl = wid - 1, li = wl / 14, j = wl % 14;
    const int dstnid[5] = {0, 1, 0, 1, 2};
    if (j < 4) {
      fold = 0;
      const float* Wb = (j < 2) ? KW : VW;
      const float* bb = (j < 2) ? Kb : Vb;
      const int nid = (j & 1) ? 2 : 1;
      W = Wb + ((size_t)li * 3 + nid) * 16384; b = bb + ((size_t)li * 3 + nid) * 128;
    } else if (j < 9) {
      fold = 1; const int r = j - 4; const int nid = dstnid[r];
      W = QW + ((size_t)li * 3 + nid) * 16384; b = Qb + ((size_t)li * 3 + nid) * 128;
      R = rel_att + ((size_t)li * 5 + r) * 4096;
    } else {
      fold = 3; const int r = j - 9; const int nid = dstnid[r];
      W = AW + ((size_t)li * 3 + nid) * 16384; b = Ab + ((size_t)li * 3 + nid) * 128;
      R = rel_msg + ((size_t)li * 5 + r) * 4096;
      scale = (r == 4) ? 1.f : 0.5f;
    }
  }
  u16* obl = (wid == 0) ? bl_arena : bl_arena + 40960 + (size_t)(wid - 1) * 16384;
  float* obias = bias_arena + wid * 128;

  const int nelem = KS * 512;
  for (int e = threadIdx.x; e < nelem; e += 256) {
    const int s = e >> 9, rem = e & 511, l = rem >> 3, jj = rem & 7;
    const int k = s * 32 + ((l >> 4) << 3) + jj;
    const int nn = t * 16 + (l & 15);
    float v = 0.f;
    if (k < Kreal) {
      if (fold == 0) v = W[(size_t)k * 128 + nn];
      else if (fold == 1) {
        const int h = nn >> 5, d = nn & 31;
        const float* Wr = W + (size_t)k * 128 + h * 32;
        const float* Rh = R + h * 1024;
        for (int f = 0; f < 32; ++f) v += Wr[f] * Rh[d * 32 + f];
      } else {
        const int h = k >> 5, dd = k & 31;
        const float* Rh = R + h * 1024 + dd * 32;
        const float* Wc = W + (size_t)h * 32 * 128 + nn;
        float sa = 0.f;
        for (int f = 0; f < 32; ++f) sa += Rh[f] * Wc[(size_t)f * 128];
        v = sa * scale;
      }
    }
    obl[(size_t)(t * KS + s) * 512 + rem] = f2bf(v);
  }
  if (t == 0 && threadIdx.x < 128) {
    const int nn = threadIdx.x;
    float v = 0.f;
    if (fold != 1) v = b[nn];
    else {
      const int h = nn >> 5, d = nn & 31;
      const float* Rh = R + h * 1024;
      for (int f = 0; f < 32; ++f) v += b[h * 32 + f] * Rh[d * 32 + f];
    }
    obias[nn] = v;
  }
}

// ======================= MFMA GEMM kernels =======================
// single output; VAR: 0 plain, 1 tanh, 2 comb
template<int KS, int VAR>
__global__ __launch_bounds__(256) void gemm_kernel(
    const u16* __restrict__ A, int AS, const int* __restrict__ idx,
    const u16* __restrict__ BL, const float* __restrict__ bias,
    u16* __restrict__ C, const u16* __restrict__ blend,
    const float* __restrict__ skipp, int n)
{
  __shared__ u16 lds16[64 * 132];
  const int tid = threadIdx.x, lane = tid & 63, w = tid >> 6;
  const int m0 = blockIdx.x * 64 + w * 16;
  int rl = m0 + (lane & 15);
  if (rl >= n) rl = n - 1;
  const int row = idx ? idx[rl] : rl;
  const int g = lane >> 4;

  bf16x8 a[KS];
  const u16* Ap = A + (size_t)row * AS + g * 8;
  #pragma unroll
  for (int s = 0; s < KS; ++s) a[s] = *reinterpret_cast<const bf16x8*>(Ap + s * 32);

  f32x4 acc[8];
  #pragma unroll
  for (int t = 0; t < 8; ++t) acc[t] = (f32x4)0.f;
  const u16* Bp = BL + (size_t)lane * 8;
  #pragma unroll
  for (int s = 0; s < KS; ++s) {
    #pragma unroll
    for (int t = 0; t < 8; ++t) {
      bf16x8 bfr = *reinterpret_cast<const bf16x8*>(Bp + (size_t)(t * KS + s) * 512);
      acc[t] = __builtin_amdgcn_mfma_f32_16x16x32_bf16(a[s], bfr, acc[t], 0, 0, 0);
    }
  }
  #pragma unroll
  for (int t = 0; t < 8; ++t) {
    const int col = t * 16 + (lane & 15);
    const float bb = bias[col];
    const int mr = w * 16 + g * 4;
    #pragma unroll
    for (int j = 0; j < 4; ++j) {
      float v = acc[t][j] + bb;
      if (VAR == 1) v = tanhf(v);
      lds16[(mr + j) * 132 + col] = f2bf(v);
    }
  }
  __syncthreads();
  const int rr = tid >> 2, cs = (tid & 3) * 32, m = blockIdx.x * 64 + rr;
  if (m < n) {
    uint2 r8[8];
    #pragma unroll
    for (int q = 0; q < 8; ++q) r8[q] = *reinterpret_cast<const uint2*>(&lds16[rr * 132 + cs + q * 4]);
    if (VAR == 2) {
      const float aa = 1.f / (1.f + __expf(-skipp[0]));
      #pragma unroll
      for (int q2 = 0; q2 < 4; ++q2) {
        uint4 blv = *reinterpret_cast<const uint4*>(blend + (size_t)m * 128 + cs + q2 * 8);
        r8[2 * q2].x     = blend2(r8[2 * q2].x, blv.x, aa);
        r8[2 * q2].y     = blend2(r8[2 * q2].y, blv.y, aa);
        r8[2 * q2 + 1].x = blend2(r8[2 * q2 + 1].x, blv.z, aa);
        r8[2 * q2 + 1].y = blend2(r8[2 * q2 + 1].y, blv.w, aa);
      }
    }
    #pragma unroll
    for (int q2 = 0; q2 < 4; ++q2) {
      uint4 st;
      st.x = r8[2 * q2].x; st.y = r8[2 * q2].y;
      st.z = r8[2 * q2 + 1].x; st.w = r8[2 * q2 + 1].y;
      *reinterpret_cast<uint4*>(C + (size_t)m * 128 + cs + q2 * 8) = st;
    }
  }
}

struct Outs4 {
  const u16* BL[4];
  const float* bias[4];
  void* C[4];
  int bs[4];     // byte stride per row
  int kind[4];   // 0 = bf16, 1 = fp8
};

template<int KS, int NOUT>
__global__ __launch_bounds__(256) void gemmN_kernel(
    const u16* __restrict__ A, int AS, const int* __restrict__ idx, Outs4 P, int n)
{
  __shared__ u16 lds16[64 * 132];
  const int tid = threadIdx.x, lane = tid & 63, w = tid >> 6;
  const int m0 = blockIdx.x * 64 + w * 16;
  int rl = m0 + (lane & 15);
  if (rl >= n) rl = n - 1;
  const int row = idx ? idx[rl] : rl;
  const int g = lane >> 4;

  bf16x8 a[KS];
  const u16* Ap = A + (size_t)row * AS + g * 8;
  #pragma unroll
  for (int s = 0; s < KS; ++s) a[s] = *reinterpret_cast<const bf16x8*>(Ap + s * 32);

  const int rr = tid >> 2, cs = (tid & 3) * 32, m = blockIdx.x * 64 + rr;

  #pragma unroll
  for (int o = 0; o < NOUT; ++o) {
    f32x4 acc[8];
    #pragma unroll
    for (int t = 0; t < 8; ++t) acc[t] = (f32x4)0.f;
    const u16* Bp = P.BL[o] + (size_t)lane * 8;
    #pragma unroll
    for (int s = 0; s < KS; ++s) {
      #pragma unroll
      for (int t = 0; t < 8; ++t) {
        bf16x8 bfr = *reinterpret_cast<const bf16x8*>(Bp + (size_t)(t * KS + s) * 512);
        acc[t] = __builtin_amdgcn_mfma_f32_16x16x32_bf16(a[s], bfr, acc[t], 0, 0, 0);
      }
    }
    if (o) __syncthreads();
    const float* bias = P.bias[o];
    #pragma unroll
    for (int t = 0; t < 8; ++t) {
      const int col = t * 16 + (lane & 15);
      const float bb = bias[col];
      const int mr = w * 16 + g * 4;
      #pragma unroll
      for (int j = 0; j < 4; ++j)
        lds16[(mr + j) * 132 + col] = f2bf(acc[t][j] + bb);
    }
    __syncthreads();
    if (m < n) {
      if (P.kind[o] == 0) {
        u16* Cp = (u16*)((char*)P.C[o] + (size_t)m * P.bs[o]) + cs;
        #pragma unroll
        for (int q2 = 0; q2 < 4; ++q2) {
          uint2 x0 = *reinterpret_cast<const uint2*>(&lds16[rr * 132 + cs + q2 * 8]);
          uint2 x1 = *reinterpret_cast<const uint2*>(&lds16[rr * 132 + cs + q2 * 8 + 4]);
          uint4 st; st.x = x0.x; st.y = x0.y; st.z = x1.x; st.w = x1.y;
          *reinterpret_cast<uint4*>(Cp + q2 * 8) = st;
        }
      } else {
        u8* Cp = (u8*)P.C[o] + (size_t)m * P.bs[o] + cs;
        unsigned wpk[8];
        #pragma unroll
        for (int p = 0; p < 8; ++p) {
          float f0 = b2f(lds16[rr * 132 + cs + p * 4 + 0]);
          float f1 = b2f(lds16[rr * 132 + cs + p * 4 + 1]);
          float f2 = b2f(lds16[rr * 132 + cs + p * 4 + 2]);
          float f3 = b2f(lds16[rr * 132 + cs + p * 4 + 3]);
          int t0 = __builtin_amdgcn_cvt_pk_fp8_f32(f0, f1, 0, false);
          wpk[p] = (unsigned)__builtin_amdgcn_cvt_pk_fp8_f32(f2, f3, t0, true);
        }
        *reinterpret_cast<uint4*>(Cp)      = make_uint4(wpk[0], wpk[1], wpk[2], wpk[3]);
        *reinterpret_cast<uint4*>(Cp + 16) = make_uint4(wpk[4], wpk[5], wpk[6], wpk[7]);
      }
    }
  }
}

// dual-A comb GEMM: out = (a0@W0 + a1@W1 + bias)*sig(skip) + blend*(1-sig); blend==C
template<int KS>
__global__ __launch_bounds__(256) void gemm2_kernel(
    const u16* __restrict__ A2, const u16* __restrict__ BL0, const u16* __restrict__ BL1,
    const float* __restrict__ bias, u16* __restrict__ C,
    const float* __restrict__ skipp, int n)
{
  __shared__ u16 lds16[64 * 132];
  const int tid = threadIdx.x, lane = tid & 63, w = tid >> 6;
  const int m0 = blockIdx.x * 64 + w * 16;
  int rl = m0 + (lane & 15);
  if (rl >= n) rl = n - 1;
  const int g = lane >> 4;

  bf16x8 a0[KS], a1[KS];
  const u16* Ap = A2 + (size_t)rl * 256 + g * 8;
  #pragma unroll
  for (int s = 0; s < KS; ++s) {
    a0[s] = *reinterpret_cast<const bf16x8*>(Ap + s * 32);
    a1[s] = *reinterpret_cast<const bf16x8*>(Ap + 128 + s * 32);
  }
  f32x4 acc[8];
  #pragma unroll
  for (int t = 0; t < 8; ++t) acc[t] = (f32x4)0.f;
  const u16* Bp0 = BL0 + (size_t)lane * 8;
  const u16* Bp1 = BL1 + (size_t)lane * 8;
  #pragma unroll
  for (int s = 0; s < KS; ++s) {
    #pragma unroll
    for (int t = 0; t < 8; ++t) {
      bf16x8 b0 = *reinterpret_cast<const bf16x8*>(Bp0 + (size_t)(t * KS + s) * 512);
      acc[t] = __builtin_amdgcn_mfma_f32_16x16x32_bf16(a0[s], b0, acc[t], 0, 0, 0);
      bf16x8 b1 = *reinterpret_cast<const bf16x8*>(Bp1 + (size_t)(t * KS + s) * 512);
      acc[t] = __builtin_amdgcn_mfma_f32_16x16x32_bf16(a1[s], b1, acc[t], 0, 0, 0);
    }
  }
  #pragma unroll
  for (int t = 0; t < 8; ++t) {
    const int col = t * 16 + (lane & 15);
    const float bb = bias[col];
    const int mr = w * 16 + g * 4;
    #pragma unroll
    for (int j = 0; j < 4; ++j)
      lds16[(mr + j) * 132 + col] = f2bf(acc[t][j] + bb);
  }
  __syncthreads();
  const int rr = tid >> 2, cs = (tid & 3) * 32, m = blockIdx.x * 64 + rr;
  if (m < n) {
    const float aa = 1.f / (1.f + __expf(-skipp[0]));
    uint2 r8[8];
    #pragma unroll
    for (int q = 0; q < 8; ++q) r8[q] = *reinterpret_cast<const uint2*>(&lds16[rr * 132 + cs + q * 4]);
    #pragma unroll
    for (int q2 = 0; q2 < 4; ++q2) {
      uint4 blv = *reinterpret_cast<const uint4*>(C + (size_t)m * 128 + cs + q2 * 8);
      uint4 st;
      st.x = blend2(r8[2 * q2].x, blv.x, aa);
      st.y = blend2(r8[2 * q2].y, blv.y, aa);
      st.z = blend2(r8[2 * q2 + 1].x, blv.z, aa);
      st.w = blend2(r8[2 * q2 + 1].y, blv.w, aa);
      *reinterpret_cast<uint4*>(C + (size_t)m * 128 + cs + q2 * 8) = st;
    }
  }
}

// ======================= misc small kernels =======================
__global__ void conv_wtab_kernel(const float* __restrict__ we, u16* __restrict__ wt) {
  int i = blockIdx.x * 256 + threadIdx.x;
  if (i < VOCAB * 320) {
    int r = i / 320, c = i - r * 320;
    wt[i] = (c < 300) ? f2bf(we[(size_t)r * 300 + c]) : (u16)0;
  }
}

__global__ void gather_topic_kernel(const float* __restrict__ emb, const int* __restrict__ ids,
                                    u16* __restrict__ out) {
  int i = blockIdx.x * 256 + threadIdx.x;
  if (i < N_TOPIC * 128) {
    int node = i >> 7, c = i & 127;
    out[i] = f2bf(emb[(size_t)ids[node] * 128 + c]);
  }
}

__global__ void bcast_q_kernel(const float* __restrict__ b0, const float* __restrict__ b1,
                               u16* __restrict__ q0, u16* __restrict__ q1) {
  int i = blockIdx.x * 256 + threadIdx.x;
  if (i < N_DOC * 128) {
    int c = i & 127;
    q0[i] = f2bf(b0[c]);
    q1[i] = f2bf(b1[c]);
  }
}

// ======================= CSR build =======================
__global__ void count_all_kernel(const int* __restrict__ td, const int* __restrict__ wd,
                                 const int* __restrict__ tt, const int* __restrict__ wt,
                                 const int* __restrict__ ww, int* cnt) {
  int i = blockIdx.x * 256 + threadIdx.x;
  if (i >= EDGES_ALL) return;
  int b;
  if (i < 80000)       b = td[i];
  else if (i < 330000) b = 32000 + wd[i - 80000];
  else if (i < 350000) b = 64000 + tt[i - 330000];
  else if (i < 450000) b = 64800 + wt[i - 350000];
  else                 b = 65600 + ww[i - 450000];
  atomicAdd(&cnt[b], 1);
}

__global__ void fill_all_kernel(const int* __restrict__ td_s, const int* __restrict__ td_d,
                                const int* __restrict__ wd_s, const int* __restrict__ wd_d,
                                const int* __restrict__ tt_s, const int* __restrict__ tt_d,
                                const int* __restrict__ wt_s, const int* __restrict__ wt_d,
                                const int* __restrict__ ww_s, const int* __restrict__ ww_d,
                                int* cursor, int* csrc) {
  int i = blockIdx.x * 256 + threadIdx.x;
  if (i >= EDGES_ALL) return;
  int b, s;
  if (i < 80000)       { b = td_d[i];                  s = td_s[i]; }
  else if (i < 330000) { b = 32000 + wd_d[i - 80000];  s = wd_s[i - 80000]; }
  else if (i < 350000) { b = 64000 + tt_d[i - 330000]; s = tt_s[i - 330000]; }
  else if (i < 450000) { b = 64800 + wt_d[i - 350000]; s = wt_s[i - 350000]; }
  else                 { b = 65600 + ww_d[i - 450000]; s = ww_s[i - 450000]; }
  int p = atomicAdd(&cursor[b], 1);
  csrc[p] = s;
}

__global__ __launch_bounds__(256) void scanA_kernel(const int* __restrict__ cnt, int* __restrict__ bsum) {
  const int tid = threadIdx.x, lane = tid & 63, wv = tid >> 6;
  const int i4 = blockIdx.x * 256 + tid;
  int4 v = make_int4(0, 0, 0, 0);
  if (i4 < N4_SCAN) v = reinterpret_cast<const int4*>(cnt)[i4];
  int s = v.x + v.y + v.z + v.w;
  #pragma unroll
  for (int d = 1; d < 64; d <<= 1) s += __shfl_xor(s, d);
  __shared__ int ws[4];
  if (lane == 0) ws[wv] = s;
  __syncthreads();
  if (tid == 0) bsum[blockIdx.x] = ws[0] + ws[1] + ws[2] + ws[3];
}

__global__ __launch_bounds__(256) void scanB_kernel(const int* __restrict__ bsum,
                                                    int* __restrict__ bpre, int* __restrict__ offs) {
  const int tid = threadIdx.x, lane = tid & 63, wv = tid >> 6;
  int v = (tid < NBLK_SCAN) ? bsum[tid] : 0;
  int incl = wave_iscan(v, lane);
  __shared__ int ws[4];
  if (lane == 63) ws[wv] = incl;
  __syncthreads();
  int pre = 0;
  for (int j = 0; j < 4; ++j) if (j < wv) pre += ws[j];
  incl += pre;
  if (tid < NBLK_SCAN) bpre[tid] = incl - v;
  if (tid == NBLK_SCAN - 1) offs[NODES_ALL] = incl;
}

__global__ __launch_bounds__(256) void scanC_kernel(const int* __restrict__ cnt,
                                                    const int* __restrict__ bpre,
                                                    int* __restrict__ offs, int* __restrict__ cursor) {
  const int tid = threadIdx.x, lane = tid & 63, wv = tid >> 6;
  const int i4 = blockIdx.x * 256 + tid;
  int4 v = make_int4(0, 0, 0, 0);
  if (i4 < N4_SCAN) v = reinterpret_cast<const int4*>(cnt)[i4];
  const int tsum = v.x + v.y + v.z + v.w;
  int incl = wave_iscan(tsum, lane);
  __shared__ int ws[4];
  if (lane == 63) ws[wv] = incl;
  __syncthreads();
  int pre = bpre[blockIdx.x];
  for (int j = 0; j < 4; ++j) if (j < wv) pre += ws[j];
  int o0 = pre + incl - tsum;
  if (i4 < N4_SCAN) {
    int4 ov = make_int4(o0, o0 + v.x, o0 + v.x + v.y, o0 + v.x + v.y + v.z);
    reinterpret_cast<int4*>(offs)[i4] = ov;
    reinterpret_cast<int4*>(cursor)[i4] = ov;
  }
}

// ======================= aggregation (fp8 K/V, 8 lanes/edge) =======================
struct AggArgs {
  const u16 *q_td, *q_wd, *q_tt, *q_wt, *q_ww;
  const u8 *kv_t, *kv_w;       // row: 128 B k + 128 B v (fp8 e4m3)
  const int *csrc, *offs;
  const float *pri;            // layer base; + r*4
  u16 *t2_d, *t2_t, *t_w;
};

static __device__ __forceinline__ void agg_rel8(
    const u16* __restrict__ q, const u8* __restrict__ kv,
    const int* __restrict__ offs, const int* __restrict__ csrc,
    const float* __restrict__ pri,
    int node, int lo, int st, int sl, float acc[16], float& ssOut)
{
  const int e0 = offs[node], e1 = offs[node + 1];
  float ss = 0.f;
  #pragma unroll
  for (int i = 0; i < 16; ++i) acc[i] = 0.f;
  if (e1 > e0) {
    const float prih = pri[sl >> 1] * 0.17677669529663687f;  // head = sl/2
    float q16[16];
    const bf16x8 qa = *reinterpret_cast<const bf16x8*>(q + (size_t)node * 128 + sl * 16);
    const bf16x8 qb = *reinterpret_cast<const bf16x8*>(q + (size_t)node * 128 + sl * 16 + 8);
    #pragma unroll
    for (int i = 0; i < 8; ++i) { q16[i] = b2f((u16)qa[i]); q16[8 + i] = b2f((u16)qb[i]); }
    for (int base = e0; base < e1; base += st) {
      const int e = base + lo;
      const bool valid = e < e1;
      const int s = csrc[valid ? e : e0];
      const uint4 kk = *reinterpret_cast<const uint4*>(kv + (size_t)s * 256 + sl * 16);
      const unsigned kw[4] = {kk.x, kk.y, kk.z, kk.w};
      float dot = 0.f;
      #pragma unroll
      for (int p = 0; p < 4; ++p) {
        f32x2 l0 = __builtin_amdgcn_cvt_pk_f32_fp8((int)kw[p], false);
        f32x2 l1 = __builtin_amdgcn_cvt_pk_f32_fp8((int)kw[p], true);
        dot += q16[p * 4 + 0] * l0[0] + q16[p * 4 + 1] * l0[1]
             + q16[p * 4 + 2] * l1[0] + q16[p * 4 + 3] * l1[1];
      }
      dot += __shfl_xor(dot, 1);  // 2 lanes per head (32 ch)
      const float wg = valid ? __expf(dot * prih) : 0.f;
      const uint4 vv = *reinterpret_cast<const uint4*>(kv + (size_t)s * 256 + 128 + sl * 16);
      const unsigned vw[4] = {vv.x, vv.y, vv.z, vv.w};
      ss += wg;
      #pragma unroll
      for (int p = 0; p < 4; ++p) {
        f32x2 l0 = __builtin_amdgcn_cvt_pk_f32_fp8((int)vw[p], false);
        f32x2 l1 = __builtin_amdgcn_cvt_pk_f32_fp8((int)vw[p], true);
        acc[p * 4 + 0] += wg * l0[0]; acc[p * 4 + 1] += wg * l0[1];
        acc[p * 4 + 2] += wg * l1[0]; acc[p * 4 + 3] += wg * l1[1];
      }
    }
  }
  ss += __shfl_xor(ss, 8); ss += __shfl_xor(ss, 16); ss += __shfl_xor(ss, 32);
  #pragma unroll
  for (int i = 0; i < 16; ++i) {
    acc[i] += __shfl_xor(acc[i], 8);
    acc[i] += __shfl_xor(acc[i], 16);
    acc[i] += __shfl_xor(acc[i], 32);
  }
  ssOut = ss;
}

static __device__ __forceinline__ void agg_store16(const float acc[16], float ss,
                                                   u16* dst, bool do_store)
{
  const float inv = (ss > 0.f) ? 1.f / ss : 0.f;
  if (do_store) {
    unsigned pk[8];
    #pragma unroll
    for (int p = 0; p < 8; ++p)
      pk[p] = (unsigned)f2bf(acc[2 * p] * inv) | ((unsigned)f2bf(acc[2 * p + 1] * inv) << 16);
    *reinterpret_cast<uint4*>(dst)     = make_uint4(pk[0], pk[1], pk[2], pk[3]);
    *reinterpret_cast<uint4*>(dst + 8) = make_uint4(pk[4], pk[5], pk[6], pk[7]);
  }
}

// grid 28800 (layer 0): [0,8000) doc, [8000,28000) word, [28000,28800) topic.
// grid 8000 (layer 1): doc only.
__global__ __launch_bounds__(256) void agg_all_kernel(AggArgs A)
{
  __shared__ float lacc[4][8][16];
  __shared__ float lss[4][8];
  const int tid = threadIdx.x, lane = tid & 63, wv = tid >> 6;
  const int sub = lane >> 3, sl = lane & 7;
  const int bid = blockIdx.x;
  float acc[16]; float ss;
  if (bid < 8000) {
    const int node = bid * 4 + wv;
    agg_rel8(A.q_td, A.kv_t, A.offs + 0,     A.csrc, A.pri + 0,  node, sub, 8, sl, acc, ss);
    agg_store16(acc, ss, A.t2_d + (size_t)node * 256 + sl * 16, sub == 0);
    agg_rel8(A.q_wd, A.kv_w, A.offs + 32000, A.csrc, A.pri + 8,  node, sub, 8, sl, acc, ss);
    agg_store16(acc, ss, A.t2_d + (size_t)node * 256 + 128 + sl * 16, sub == 0);
  } else if (bid < 28000) {
    const int node = (bid - 8000) * 4 + wv;
    agg_rel8(A.q_ww, A.kv_w, A.offs + 65600, A.csrc, A.pri + 16, node, sub, 8, sl, acc, ss);
    agg_store16(acc, ss, A.t_w + (size_t)node * 128 + sl * 16, sub == 0);
  } else {
    const int node = bid - 28000;
    for (int r = 0; r < 2; ++r) {
      agg_rel8(r ? A.q_wt : A.q_tt, r ? A.kv_w : A.kv_t,
               A.offs + (r ? 64800 : 64000), A.csrc, A.pri + (r ? 12 : 4),
               node, wv * 8 + sub, 32, sl, acc, ss);
      if (sub == 0) {
        lss[wv][sl] = ss;
        #pragma unroll
        for (int i = 0; i < 16; ++i) lacc[wv][sl][i] = acc[i];
      }
      __syncthreads();
      if (tid < 8) {
        float s2 = lss[0][tid] + lss[1][tid] + lss[2][tid] + lss[3][tid];
        float a2[16];
        #pragma unroll
        for (int i = 0; i < 16; ++i)
          a2[i] = lacc[0][tid][i] + lacc[1][tid][i] + lacc[2][tid][i] + lacc[3][tid][i];
        agg_store16(a2, s2, A.t2_t + (size_t)node * 256 + r * 128 + tid * 16, true);
      }
      __syncthreads();
    }
  }
}

// ======================= readout =======================
__global__ void ginit_kernel(unsigned* g) {
  int i = blockIdx.x * 256 + threadIdx.x;
  if (i < BATCH * H_DIM) g[i] = 0x007FFFFFu;
}

__global__ void segmax_kernel(const u16* __restrict__ hd, const int* __restrict__ gid,
                              unsigned* g) {
  int c = threadIdx.x;
  int d0 = blockIdx.x * 128;
  int dend = min(d0 + 128, N_DOC);
  int cur = -1; float m = 0.f;
  for (int d = d0; d < dend; ++d) {
    int gg = gid[d];
    float v = b2f(hd[(size_t)d * 128 + c]);
    if (gg != cur) {
      if (cur >= 0) atomicMax(&g[cur * 128 + c], fenc(m));
      cur = gg; m = v;
    } else {
      m = fmaxf(m, v);
    }
  }
  if (cur >= 0) atomicMax(&g[cur * 128 + c], fenc(m));
}

__global__ void final_kernel(const unsigned* __restrict__ g, const float* __restrict__ out_w,
                             const float* __restrict__ out_b, const float* __restrict__ y,
                             float* out) {
  int tid = threadIdx.x;
  int b = tid >> 4, seg = tid & 15;
  float p = 0.f;
  #pragma unroll
  for (int j = 0; j < 8; ++j) {
    int c = seg * 8 + j;
    p += fdec(g[b * 128 + c]) * out_w[c];
  }
  p += __shfl_xor(p, 1);
  p += __shfl_xor(p, 2);
  p += __shfl_xor(p, 4);
  p += __shfl_xor(p, 8);
  __shared__ float logits[BATCH];
  __shared__ float losses[BATCH];
  if (seg == 0) logits[b] = p + out_b[0];
  __syncthreads();
  if (tid < BATCH) {
    float l = logits[tid];
    out[1 + tid] = 1.f / (1.f + expf(-l));
    float ls_pos = (l > 0.f) ? -log1pf(expf(-l)) : l - log1pf(expf(l));
    float ls_neg = (l < 0.f) ? -log1pf(expf(l)) : -l - log1pf(expf(-l));
    losses[tid] = -(y[tid] * ls_pos + (1.f - y[tid]) * ls_neg);
  }
  __syncthreads();
  if (tid == 0) {
    float s = 0.f;
    for (int j = 0; j < BATCH; ++j) s += losses[j];
    out[0] = s / (float)BATCH;
  }
}

// ======================= host =======================
extern "C" void kernel_launch(void* const* d_in, const int* in_sizes, int n_in,
                              void* d_out, int out_size, void* d_ws, size_t ws_size,
                              hipStream_t stream)
{
  const float* word_embeds  = (const float*)d_in[0];
  const float* topic_embeds = (const float*)d_in[1];
  const float* KW  = (const float*)d_in[2];
  const float* Kb  = (const float*)d_in[3];
  const float* QW  = (const float*)d_in[4];
  const float* Qb  = (const float*)d_in[5];
  const float* VW  = (const float*)d_in[6];
  const float* Vb  = (const float*)d_in[7];
  const float* AW  = (const float*)d_in[8];
  const float* Ab  = (const float*)d_in[9];
  const float* rel_att = (const float*)d_in[10];
  const float* rel_msg = (const float*)d_in[11];
  const float* rel_pri = (const float*)d_in[12];
  const float* skip    = (const float*)d_in[13];
  const float* adapt_w = (const float*)d_in[14];
  const float* adapt_b = (const float*)d_in[15];
  const float* out_w   = (const float*)d_in[16];
  const float* out_b   = (const float*)d_in[17];
  const float* y_data  = (const float*)d_in[18];
  const int* word_ids  = (const int*)d_in[19];
  const int* topic_ids = (const int*)d_in[20];
  const int* doc_gid   = (const int*)d_in[21];
  const int* td_src = (const int*)d_in[22];
  const int* td_dst = (const int*)d_in[23];
  const int* tt_src = (const int*)d_in[24];
  const int* tt_dst = (const int*)d_in[25];
  const int* wd_src = (const int*)d_in[26];
  const int* wd_dst = (const int*)d_in[27];
  const int* wt_src = (const int*)d_in[28];
  const int* wt_dst = (const int*)d_in[29];
  const int* ww_src = (const int*)d_in[30];
  const int* ww_dst = (const int*)d_in[31];

  char* base = (char*)d_ws;
  size_t off_b = 0;
  auto alloc = [&](size_t bytes) -> char* {
    char* p = base + off_b;
    off_b = (off_b + bytes + 255) & ~(size_t)255;
    return p;
  };

  u16* wtab = (u16*)alloc((size_t)VOCAB * 320 * 2);
  u16* hw   = (u16*)alloc((size_t)N_WORD * 128 * 2);
  u16* hd   = (u16*)alloc((size_t)N_DOC * 128 * 2);
  u16* ht   = (u16*)alloc((size_t)N_TOPIC * 128 * 2);
  u8*  kv_w = (u8*)alloc((size_t)N_WORD * 256);
  u8*  kv_t = (u8*)alloc((size_t)N_TOPIC * 256);
  u16* q_td = (u16*)alloc((size_t)N_DOC * 128 * 2);
  u16* q_wd = (u16*)alloc((size_t)N_DOC * 128 * 2);
  u16* q_tt = (u16*)alloc((size_t)N_TOPIC * 128 * 2);
  u16* q_wt = (u16*)alloc((size_t)N_TOPIC * 128 * 2);
  u16* q_ww = (u16*)alloc((size_t)N_WORD * 128 * 2);
  u16* t2_d = (u16*)alloc((size_t)N_DOC * 256 * 2);
  u16* t2_t = (u16*)alloc((size_t)N_TOPIC * 256 * 2);
  u16* t_w  = (u16*)alloc((size_t)N_WORD * 128 * 2);
  unsigned* g = (unsigned*)alloc((size_t)BATCH * 128 * 4);

  int* cnt_all  = (int*)alloc((size_t)NODES_ALL * 4);
  int* offs_all = (int*)alloc(((size_t)NODES_ALL + 1) * 4);
  int* csrc_all = (int*)alloc((size_t)EDGES_ALL * 4);
  int* bsum     = (int*)alloc((size_t)NBLK_SCAN * 4);
  int* bpre     = (int*)alloc((size_t)NBLK_SCAN * 4);

  u16* blw        = (u16*)alloc((size_t)(40960 + 28 * 16384) * 2);
  float* bias_are = (float*)alloc((size_t)29 * 128 * 4);

  auto BLp = [&](int wid) -> const u16* {
    return (wid == 0) ? blw : blw + 40960 + (size_t)(wid - 1) * 16384;
  };
  auto BIp = [&](int wid) -> const float* { return bias_are + wid * 128; };
  auto WID = [&](int li, int j) { return 1 + li * 14 + j; };

  // ---- prep ----
  prep_kernel<<<29 * 8, 256, 0, stream>>>(KW, Kb, QW, Qb, VW, Vb, AW, Ab,
                                          rel_att, rel_msg, adapt_w, adapt_b, blw, bias_are);
  conv_wtab_kernel<<<(VOCAB * 320 + 255) / 256, 256, 0, stream>>>(word_embeds, wtab);
  gather_topic_kernel<<<(N_TOPIC * 128 + 255) / 256, 256, 0, stream>>>(topic_embeds, topic_ids, ht);

  hipMemsetAsync(cnt_all, 0, (size_t)NODES_ALL * 4, stream);
  count_all_kernel<<<(EDGES_ALL + 255) / 256, 256, 0, stream>>>(td_dst, wd_dst, tt_dst, wt_dst, ww_dst, cnt_all);
  scanA_kernel<<<NBLK_SCAN, 256, 0, stream>>>(cnt_all, bsum);
  scanB_kernel<<<1, 256, 0, stream>>>(bsum, bpre, offs_all);
  scanC_kernel<<<NBLK_SCAN, 256, 0, stream>>>(cnt_all, bpre, offs_all, cnt_all);
  fill_all_kernel<<<(EDGES_ALL + 255) / 256, 256, 0, stream>>>(
      td_src, td_dst, wd_src, wd_dst, tt_src, tt_dst, wt_src, wt_dst, ww_src, ww_dst,
      cnt_all, csrc_all);

  hipMemsetAsync(hd, 0, (size_t)N_DOC * 128 * 2, stream);

  // ---- adapt ----
  gemm_kernel<10, 1><<<(N_WORD + 63) / 64, 256, 0, stream>>>(
      wtab, 320, word_ids, BLp(0), BIp(0), hw, nullptr, nullptr, N_WORD);

  const int GW = (N_WORD + 63) / 64, GD = (N_DOC + 63) / 64, GT = (N_TOPIC + 63) / 64;

  // ================= layer 0 (full) =================
  {
    const int li = 0;
    {  // word-side: k_w (fp8), v_w (fp8), q_ww (bf16)
      Outs4 P = {};
      const int wids[3] = {WID(li, 1), WID(li, 3), WID(li, 8)};
      void* cs[3] = {kv_w, kv_w + 128, q_ww};
      const int bss[3] = {256, 256, 256};
      const int knd[3] = {1, 1, 0};
      for (int o = 0; o < 3; ++o) { P.BL[o] = BLp(wids[o]); P.bias[o] = BIp(wids[o]); P.C[o] = cs[o]; P.bs[o] = bss[o]; P.kind[o] = knd[o]; }
      gemmN_kernel<4, 3><<<GW, 256, 0, stream>>>(hw, 128, nullptr, P, N_WORD);
    }
    {  // topic-side: k_t, v_t (fp8), q_tt, q_wt (bf16)
      Outs4 P = {};
      const int wids[4] = {WID(li, 0), WID(li, 2), WID(li, 5), WID(li, 7)};
      void* cs[4] = {kv_t, kv_t + 128, q_tt, q_wt};
      const int bss[4] = {256, 256, 256, 256};
      const int knd[4] = {1, 1, 0, 0};
      for (int o = 0; o < 4; ++o) { P.BL[o] = BLp(wids[o]); P.bias[o] = BIp(wids[o]); P.C[o] = cs[o]; P.bs[o] = bss[o]; P.kind[o] = knd[o]; }
      gemmN_kernel<4, 4><<<GT, 256, 0, stream>>>(ht, 128, nullptr, P, N_TOPIC);
    }
    bcast_q_kernel<<<(N_DOC * 128 + 255) / 256, 256, 0, stream>>>(BIp(WID(0, 4)), BIp(WID(0, 6)), q_td, q_wd);

    AggArgs A;
    A.q_td = q_td; A.q_wd = q_wd; A.q_tt = q_tt; A.q_wt = q_wt; A.q_ww = q_ww;
    A.kv_t = kv_t; A.kv_w = kv_w;
    A.csrc = csrc_all; A.offs = offs_all;
    A.pri = rel_pri + (size_t)li * 5 * 4;
    A.t2_d = t2_d; A.t2_t = t2_t; A.t_w = t_w;
    agg_all_kernel<<<28800, 256, 0, stream>>>(A);

    gemm2_kernel<4><<<GD, 256, 0, stream>>>(t2_d, BLp(WID(li, 9)), BLp(WID(li, 11)),
                                            BIp(WID(li, 9)), hd, skip + (size_t)li * 3 + 0, N_DOC);
    gemm2_kernel<4><<<GT, 256, 0, stream>>>(t2_t, BLp(WID(li, 10)), BLp(WID(li, 12)),
                                            BIp(WID(li, 10)), ht, skip + (size_t)li * 3 + 1, N_TOPIC);
    gemm_kernel<4, 2><<<GW, 256, 0, stream>>>(t_w, 128, nullptr, BLp(WID(li, 13)), BIp(WID(li, 13)),
                                              hw, hw, skip + (size_t)li * 3 + 2, N_WORD);
  }

  // ================= layer 1 (docs only are live) =================
  {
    const int li = 1;
    {  // word-side: k_w, v_w (fp8)
      Outs4 P = {};
      const int wids[2] = {WID(li, 1), WID(li, 3)};
      void* cs[2] = {kv_w, kv_w + 128};
      for (int o = 0; o < 2; ++o) { P.BL[o] = BLp(wids[o]); P.bias[o] = BIp(wids[o]); P.C[o] = cs[o]; P.bs[o] = 256; P.kind[o] = 1; }
      gemmN_kernel<4, 2><<<GW, 256, 0, stream>>>(hw, 128, nullptr, P, N_WORD);
    }
    {  // topic-side: k_t, v_t (fp8)
      Outs4 P = {};
      const int wids[2] = {WID(li, 0), WID(li, 2)};
      void* cs[2] = {kv_t, kv_t + 128};
      for (int o = 0; o < 2; ++o) { P.BL[o] = BLp(wids[o]); P.bias[o] = BIp(wids[o]); P.C[o] = cs[o]; P.bs[o] = 256; P.kind[o] = 1; }
      gemmN_kernel<4, 2><<<GT, 256, 0, stream>>>(ht, 128, nullptr, P, N_TOPIC);
    }
    {  // doc-side Q: q_td, q_wd (bf16)
      Outs4 P = {};
      const int wids[2] = {WID(li, 4), WID(li, 6)};
      void* cs[2] = {q_td, q_wd};
      for (int o = 0; o < 2; ++o) { P.BL[o] = BLp(wids[o]); P.bias[o] = BIp(wids[o]); P.C[o] = cs[o]; P.bs[o] = 256; P.kind[o] = 0; }
      gemmN_kernel<4, 2><<<GD, 256, 0, stream>>>(hd, 128, nullptr, P, N_DOC);
    }

    AggArgs A;
    A.q_td = q_td; A.q_wd = q_wd; A.q_tt = q_tt; A.q_wt = q_wt; A.q_ww = q_ww;
    A.kv_t = kv_t; A.kv_w = kv_w;
    A.csrc = csrc_all; A.offs = offs_all;
    A.pri = rel_pri + (size_t)li * 5 * 4;
    A.t2_d = t2_d; A.t2_t = t2_t; A.t_w = t_w;
    agg_all_kernel<<<8000, 256, 0, stream>>>(A);   // doc blocks only

    gemm2_kernel<4><<<GD, 256, 0, stream>>>(t2_d, BLp(WID(li, 9)), BLp(WID(li, 11)),
                                            BIp(WID(li, 9)), hd, skip + (size_t)li * 3 + 0, N_DOC);
  }

  // ---- readout ----
  ginit_kernel<<<(BATCH * 128 + 255) / 256, 256, 0, stream>>>(g);
  segmax_kernel<<<(N_DOC + 127) / 128, 128, 0, stream>>>(hd, doc_gid, g);
  final_kernel<<<1, 256, 0, stream>>>(g, out_w, out_b, y_data, (float*)d_out);
}

// Round 7
// 461.586 us; speedup vs baseline: 10.0421x; 1.0727x over previous
//
#include <hip/hip_runtime.h>
#include <cstdint>
#include <cstddef>

#define H_DIM 128
#define N_DOC 32000
#define N_TOPIC 800
#define N_WORD 80000
#define BATCH 16
#define VOCAB 15000
#define NODES_ALL 145600
#define EDGES_ALL 850000
#define NBLK_SCAN 143
#define N4_SCAN 36400

typedef short bf16x8 __attribute__((ext_vector_type(8)));
typedef float f32x4 __attribute__((ext_vector_type(4)));
typedef float f32x2 __attribute__((ext_vector_type(2)));
typedef unsigned short u16;
typedef unsigned char u8;

static __device__ __forceinline__ u16 f2bf(float x) {
  unsigned u = __float_as_uint(x);
  u += 0x7fffu + ((u >> 16) & 1u);
  return (u16)(u >> 16);
}
static __device__ __forceinline__ float b2f(unsigned h) {
  return __uint_as_float(h << 16);
}
static __device__ __forceinline__ unsigned fenc(float f) {
  unsigned u = __float_as_uint(f);
  return (u & 0x80000000u) ? ~u : (u | 0x80000000u);
}
static __device__ __forceinline__ float fdec(unsigned k) {
  return (k & 0x80000000u) ? __uint_as_float(k ^ 0x80000000u) : __uint_as_float(~k);
}
static __device__ __forceinline__ int wave_iscan(int v, int lane) {
  #pragma unroll
  for (int d = 1; d < 64; d <<= 1) {
    int t = __shfl_up(v, d);
    if (lane >= d) v += t;
  }
  return v;
}
static __device__ __forceinline__ unsigned blend2(unsigned pr, unsigned bl, float aa) {
  float v0 = b2f(pr & 0xffffu) * aa + b2f(bl & 0xffffu) * (1.f - aa);
  float v1 = b2f(pr >> 16) * aa + b2f(bl >> 16) * (1.f - aa);
  return (unsigned)f2bf(v0) | ((unsigned)f2bf(v1) << 16);
}

// ======================= weight prep =======================
__global__ __launch_bounds__(256) void prep_kernel(
    const float* __restrict__ KW, const float* __restrict__ Kb,
    const float* __restrict__ QW, const float* __restrict__ Qb,
    const float* __restrict__ VW, const float* __restrict__ Vb,
    const float* __restrict__ AW, const float* __restrict__ Ab,
    const float* __restrict__ rel_att, const float* __restrict__ rel_msg,
    const float* __restrict__ adapt_w, const float* __restrict__ adapt_b,
    u16* __restrict__ bl_arena, float* __restrict__ bias_arena)
{
  const int wid = blockIdx.x >> 3, t = blockIdx.x & 7;
  int KS, Kreal, fold;
  const float *W, *b, *R = nullptr;
  float scale = 1.f;
  if (wid == 0) { KS = 10; Kreal = 300; fold = 0; W = adapt_w; b = adapt_b; }
  else {
    KS = 4; Kreal = 128;
    const int wl = wid - 1, li = wl / 14, j = wl % 14;
    const int dstnid[5] = {0, 1, 0, 1, 2};
    if (j < 4) {
      fold = 0;
      const float* Wb = (j < 2) ? KW : VW;
      const float* bb = (j < 2) ? Kb : Vb;
      const int nid = (j & 1) ? 2 : 1;
      W = Wb + ((size_t)li * 3 + nid) * 16384; b = bb + ((size_t)li * 3 + nid) * 128;
    } else if (j < 9) {
      fold = 1; const int r = j - 4; const int nid = dstnid[r];
      W = QW + ((size_t)li * 3 + nid) * 16384; b = Qb + ((size_t)li * 3 + nid) * 128;
      R = rel_att + ((size_t)li * 5 + r) * 4096;
    } else {
      fold = 3; const int r = j - 9; const int nid = dstnid[r];
      W = AW + ((size_t)li * 3 + nid) * 16384; b = Ab + ((size_t)li * 3 + nid) * 128;
      R = rel_msg + ((size_t)li * 5 + r) * 4096;
      scale = (r == 4) ? 1.f : 0.5f;
    }
  }
  u16* obl = (wid == 0) ? bl_arena : bl_arena + 40960 + (size_t)(wid - 1) * 16384;
  float* obias = bias_arena + wid * 128;

  const int nelem = KS * 512;
  for (int e = threadIdx.x; e < nelem; e += 256) {
    const int s = e >> 9, rem = e & 511, l = rem >> 3, jj = rem & 7;
    const int k = s * 32 + ((l >> 4) << 3) + jj;
    const int nn = t * 16 + (l & 15);
    float v = 0.f;
    if (k < Kreal) {
      if (fold == 0) v = W[(size_t)k * 128 + nn];
      else if (fold == 1) {
        const int h = nn >> 5, d = nn & 31;
        const float* Wr = W + (size_t)k * 128 + h * 32;
        const float* Rh = R + h * 1024;
        for (int f = 0; f < 32; ++f) v += Wr[f] * Rh[d * 32 + f];
      } else {
        const int h = k >> 5, dd = k & 31;
        const float* Rh = R + h * 1024 + dd * 32;
        const float* Wc = W + (size_t)h * 32 * 128 + nn;
        float sa = 0.f;
        for (int f = 0; f < 32; ++f) sa += Rh[f] * Wc[(size_t)f * 128];
        v = sa * scale;
      }
    }
    obl[(size_t)(t * KS + s) * 512 + rem] = f2bf(v);
  }
  if (t == 0 && threadIdx.x < 128) {
    const int nn = threadIdx.x;
    float v = 0.f;
    if (fold != 1) v = b[nn];
    else {
      const int h = nn >> 5, d = nn & 31;
      const float* Rh = R + h * 1024;
      for (int f = 0; f < 32; ++f) v += b[h * 32 + f] * Rh[d * 32 + f];
    }
    obias[nn] = v;
  }
}

// ======================= MFMA GEMM kernels =======================
template<int KS, int VAR>
__global__ __launch_bounds__(256) void gemm_kernel(
    const u16* __restrict__ A, int AS, const int* __restrict__ idx,
    const u16* __restrict__ BL, const float* __restrict__ bias,
    u16* __restrict__ C, const u16* __restrict__ blend,
    const float* __restrict__ skipp, int n)
{
  __shared__ u16 lds16[64 * 132];
  const int tid = threadIdx.x, lane = tid & 63, w = tid >> 6;
  const int m0 = blockIdx.x * 64 + w * 16;
  int rl = m0 + (lane & 15);
  if (rl >= n) rl = n - 1;
  const int row = idx ? idx[rl] : rl;
  const int g = lane >> 4;

  bf16x8 a[KS];
  const u16* Ap = A + (size_t)row * AS + g * 8;
  #pragma unroll
  for (int s = 0; s < KS; ++s) a[s] = *reinterpret_cast<const bf16x8*>(Ap + s * 32);

  f32x4 acc[8];
  #pragma unroll
  for (int t = 0; t < 8; ++t) acc[t] = (f32x4)0.f;
  const u16* Bp = BL + (size_t)lane * 8;
  #pragma unroll
  for (int s = 0; s < KS; ++s) {
    #pragma unroll
    for (int t = 0; t < 8; ++t) {
      bf16x8 bfr = *reinterpret_cast<const bf16x8*>(Bp + (size_t)(t * KS + s) * 512);
      acc[t] = __builtin_amdgcn_mfma_f32_16x16x32_bf16(a[s], bfr, acc[t], 0, 0, 0);
    }
  }
  #pragma unroll
  for (int t = 0; t < 8; ++t) {
    const int col = t * 16 + (lane & 15);
    const float bb = bias[col];
    const int mr = w * 16 + g * 4;
    #pragma unroll
    for (int j = 0; j < 4; ++j) {
      float v = acc[t][j] + bb;
      if (VAR == 1) v = tanhf(v);
      lds16[(mr + j) * 132 + col] = f2bf(v);
    }
  }
  __syncthreads();
  const int rr = tid >> 2, cs = (tid & 3) * 32, m = blockIdx.x * 64 + rr;
  if (m < n) {
    uint2 r8[8];
    #pragma unroll
    for (int q = 0; q < 8; ++q) r8[q] = *reinterpret_cast<const uint2*>(&lds16[rr * 132 + cs + q * 4]);
    if (VAR == 2) {
      const float aa = 1.f / (1.f + __expf(-skipp[0]));
      #pragma unroll
      for (int q2 = 0; q2 < 4; ++q2) {
        uint4 blv = *reinterpret_cast<const uint4*>(blend + (size_t)m * 128 + cs + q2 * 8);
        r8[2 * q2].x     = blend2(r8[2 * q2].x, blv.x, aa);
        r8[2 * q2].y     = blend2(r8[2 * q2].y, blv.y, aa);
        r8[2 * q2 + 1].x = blend2(r8[2 * q2 + 1].x, blv.z, aa);
        r8[2 * q2 + 1].y = blend2(r8[2 * q2 + 1].y, blv.w, aa);
      }
    }
    #pragma unroll
    for (int q2 = 0; q2 < 4; ++q2) {
      uint4 st;
      st.x = r8[2 * q2].x; st.y = r8[2 * q2].y;
      st.z = r8[2 * q2 + 1].x; st.w = r8[2 * q2 + 1].y;
      *reinterpret_cast<uint4*>(C + (size_t)m * 128 + cs + q2 * 8) = st;
    }
  }
}

struct Outs4 {
  const u16* BL[4];
  const float* bias[4];
  void* C[4];
  int bs[4];     // byte stride per row
  int kind[4];   // 0 = bf16, 1 = fp8 k-half of 16B chunk, 2 = fp8 v-half
};

template<int KS, int NOUT>
__global__ __launch_bounds__(256) void gemmN_kernel(
    const u16* __restrict__ A, int AS, const int* __restrict__ idx, Outs4 P, int n)
{
  __shared__ u16 lds16[64 * 132];
  const int tid = threadIdx.x, lane = tid & 63, w = tid >> 6;
  const int m0 = blockIdx.x * 64 + w * 16;
  int rl = m0 + (lane & 15);
  if (rl >= n) rl = n - 1;
  const int row = idx ? idx[rl] : rl;
  const int g = lane >> 4;

  bf16x8 a[KS];
  const u16* Ap = A + (size_t)row * AS + g * 8;
  #pragma unroll
  for (int s = 0; s < KS; ++s) a[s] = *reinterpret_cast<const bf16x8*>(Ap + s * 32);

  const int rr = tid >> 2, cs = (tid & 3) * 32, m = blockIdx.x * 64 + rr;

  #pragma unroll
  for (int o = 0; o < NOUT; ++o) {
    f32x4 acc[8];
    #pragma unroll
    for (int t = 0; t < 8; ++t) acc[t] = (f32x4)0.f;
    const u16* Bp = P.BL[o] + (size_t)lane * 8;
    #pragma unroll
    for (int s = 0; s < KS; ++s) {
      #pragma unroll
      for (int t = 0; t < 8; ++t) {
        bf16x8 bfr = *reinterpret_cast<const bf16x8*>(Bp + (size_t)(t * KS + s) * 512);
        acc[t] = __builtin_amdgcn_mfma_f32_16x16x32_bf16(a[s], bfr, acc[t], 0, 0, 0);
      }
    }
    if (o) __syncthreads();
    const float* bias = P.bias[o];
    #pragma unroll
    for (int t = 0; t < 8; ++t) {
      const int col = t * 16 + (lane & 15);
      const float bb = bias[col];
      const int mr = w * 16 + g * 4;
      #pragma unroll
      for (int j = 0; j < 4; ++j)
        lds16[(mr + j) * 132 + col] = f2bf(acc[t][j] + bb);
    }
    __syncthreads();
    if (m < n) {
      if (P.kind[o] == 0) {
        u16* Cp = (u16*)((char*)P.C[o] + (size_t)m * P.bs[o]) + cs;
        #pragma unroll
        for (int q2 = 0; q2 < 4; ++q2) {
          uint2 x0 = *reinterpret_cast<const uint2*>(&lds16[rr * 132 + cs + q2 * 8]);
          uint2 x1 = *reinterpret_cast<const uint2*>(&lds16[rr * 132 + cs + q2 * 8 + 4]);
          uint4 st; st.x = x0.x; st.y = x0.y; st.z = x1.x; st.w = x1.y;
          *reinterpret_cast<uint4*>(Cp + q2 * 8) = st;
        }
      } else {
        // interleaved kv row: 16 chunks x 16B; chunk j = k[j*8..+8] | v[j*8..+8]
        u8* Cp = (u8*)P.C[o] + (size_t)m * P.bs[o] + (cs >> 3) * 16 + ((P.kind[o] == 2) ? 8 : 0);
        #pragma unroll
        for (int q2 = 0; q2 < 4; ++q2) {
          unsigned w0, w1;
          {
            float f0 = b2f(lds16[rr * 132 + cs + q2 * 8 + 0]);
            float f1 = b2f(lds16[rr * 132 + cs + q2 * 8 + 1]);
            float f2 = b2f(lds16[rr * 132 + cs + q2 * 8 + 2]);
            float f3 = b2f(lds16[rr * 132 + cs + q2 * 8 + 3]);
            int t0 = __builtin_amdgcn_cvt_pk_fp8_f32(f0, f1, 0, false);
            w0 = (unsigned)__builtin_amdgcn_cvt_pk_fp8_f32(f2, f3, t0, true);
          }
          {
            float f0 = b2f(lds16[rr * 132 + cs + q2 * 8 + 4]);
            float f1 = b2f(lds16[rr * 132 + cs + q2 * 8 + 5]);
            float f2 = b2f(lds16[rr * 132 + cs + q2 * 8 + 6]);
            float f3 = b2f(lds16[rr * 132 + cs + q2 * 8 + 7]);
            int t0 = __builtin_amdgcn_cvt_pk_fp8_f32(f0, f1, 0, false);
            w1 = (unsigned)__builtin_amdgcn_cvt_pk_fp8_f32(f2, f3, t0, true);
          }
          *reinterpret_cast<uint2*>(Cp + q2 * 16) = make_uint2(w0, w1);
        }
      }
    }
  }
}

// dual-A comb GEMM
template<int KS>
__global__ __launch_bounds__(256) void gemm2_kernel(
    const u16* __restrict__ A2, const u16* __restrict__ BL0, const u16* __restrict__ BL1,
    const float* __restrict__ bias, u16* __restrict__ C,
    const float* __restrict__ skipp, int n)
{
  __shared__ u16 lds16[64 * 132];
  const int tid = threadIdx.x, lane = tid & 63, w = tid >> 6;
  const int m0 = blockIdx.x * 64 + w * 16;
  int rl = m0 + (lane & 15);
  if (rl >= n) rl = n - 1;
  const int g = lane >> 4;

  bf16x8 a0[KS], a1[KS];
  const u16* Ap = A2 + (size_t)rl * 256 + g * 8;
  #pragma unroll
  for (int s = 0; s < KS; ++s) {
    a0[s] = *reinterpret_cast<const bf16x8*>(Ap + s * 32);
    a1[s] = *reinterpret_cast<const bf16x8*>(Ap + 128 + s * 32);
  }
  f32x4 acc[8];
  #pragma unroll
  for (int t = 0; t < 8; ++t) acc[t] = (f32x4)0.f;
  const u16* Bp0 = BL0 + (size_t)lane * 8;
  const u16* Bp1 = BL1 + (size_t)lane * 8;
  #pragma unroll
  for (int s = 0; s < KS; ++s) {
    #pragma unroll
    for (int t = 0; t < 8; ++t) {
      bf16x8 b0 = *reinterpret_cast<const bf16x8*>(Bp0 + (size_t)(t * KS + s) * 512);
      acc[t] = __builtin_amdgcn_mfma_f32_16x16x32_bf16(a0[s], b0, acc[t], 0, 0, 0);
      bf16x8 b1 = *reinterpret_cast<const bf16x8*>(Bp1 + (size_t)(t * KS + s) * 512);
      acc[t] = __builtin_amdgcn_mfma_f32_16x16x32_bf16(a1[s], b1, acc[t], 0, 0, 0);
    }
  }
  #pragma unroll
  for (int t = 0; t < 8; ++t) {
    const int col = t * 16 + (lane & 15);
    const float bb = bias[col];
    const int mr = w * 16 + g * 4;
    #pragma unroll
    for (int j = 0; j < 4; ++j)
      lds16[(mr + j) * 132 + col] = f2bf(acc[t][j] + bb);
  }
  __syncthreads();
  const int rr = tid >> 2, cs = (tid & 3) * 32, m = blockIdx.x * 64 + rr;
  if (m < n) {
    const float aa = 1.f / (1.f + __expf(-skipp[0]));
    uint2 r8[8];
    #pragma unroll
    for (int q = 0; q < 8; ++q) r8[q] = *reinterpret_cast<const uint2*>(&lds16[rr * 132 + cs + q * 4]);
    #pragma unroll
    for (int q2 = 0; q2 < 4; ++q2) {
      uint4 blv = *reinterpret_cast<const uint4*>(C + (size_t)m * 128 + cs + q2 * 8);
      uint4 st;
      st.x = blend2(r8[2 * q2].x, blv.x, aa);
      st.y = blend2(r8[2 * q2].y, blv.y, aa);
      st.z = blend2(r8[2 * q2 + 1].x, blv.z, aa);
      st.w = blend2(r8[2 * q2 + 1].y, blv.w, aa);
      *reinterpret_cast<uint4*>(C + (size_t)m * 128 + cs + q2 * 8) = st;
    }
  }
}

// ======================= misc small kernels =======================
__global__ void conv_wtab_kernel(const float* __restrict__ we, u16* __restrict__ wt) {
  int i = blockIdx.x * 256 + threadIdx.x;
  if (i < VOCAB * 320) {
    int r = i / 320, c = i - r * 320;
    wt[i] = (c < 300) ? f2bf(we[(size_t)r * 300 + c]) : (u16)0;
  }
}

__global__ void gather_topic_kernel(const float* __restrict__ emb, const int* __restrict__ ids,
                                    u16* __restrict__ out) {
  int i = blockIdx.x * 256 + threadIdx.x;
  if (i < N_TOPIC * 128) {
    int node = i >> 7, c = i & 127;
    out[i] = f2bf(emb[(size_t)ids[node] * 128 + c]);
  }
}

__global__ void bcast_q_kernel(const float* __restrict__ b0, const float* __restrict__ b1,
                               u16* __restrict__ q0, u16* __restrict__ q1) {
  int i = blockIdx.x * 256 + threadIdx.x;
  if (i < N_DOC * 128) {
    int c = i & 127;
    q0[i] = f2bf(b0[c]);
    q1[i] = f2bf(b1[c]);
  }
}

// ======================= CSR build =======================
__global__ void count_all_kernel(const int* __restrict__ td, const int* __restrict__ wd,
                                 const int* __restrict__ tt, const int* __restrict__ wt,
                                 const int* __restrict__ ww, int* cnt) {
  int i = blockIdx.x * 256 + threadIdx.x;
  if (i >= EDGES_ALL) return;
  int b;
  if (i < 80000)       b = td[i];
  else if (i < 330000) b = 32000 + wd[i - 80000];
  else if (i < 350000) b = 64000 + tt[i - 330000];
  else if (i < 450000) b = 64800 + wt[i - 350000];
  else                 b = 65600 + ww[i - 450000];
  atomicAdd(&cnt[b], 1);
}

__global__ void fill_all_kernel(const int* __restrict__ td_s, const int* __restrict__ td_d,
                                const int* __restrict__ wd_s, const int* __restrict__ wd_d,
                                const int* __restrict__ tt_s, const int* __restrict__ tt_d,
                                const int* __restrict__ wt_s, const int* __restrict__ wt_d,
                                const int* __restrict__ ww_s, const int* __restrict__ ww_d,
                                int* cursor, int* csrc) {
  int i = blockIdx.x * 256 + threadIdx.x;
  if (i >= EDGES_ALL) return;
  int b, s;
  if (i < 80000)       { b = td_d[i];                  s = td_s[i]; }
  else if (i < 330000) { b = 32000 + wd_d[i - 80000];  s = wd_s[i - 80000]; }
  else if (i < 350000) { b = 64000 + tt_d[i - 330000]; s = tt_s[i - 330000]; }
  else if (i < 450000) { b = 64800 + wt_d[i - 350000]; s = wt_s[i - 350000]; }
  else                 { b = 65600 + ww_d[i - 450000]; s = ww_s[i - 450000]; }
  int p = atomicAdd(&cursor[b], 1);
  csrc[p] = s;
}

__global__ __launch_bounds__(256) void scanA_kernel(const int* __restrict__ cnt, int* __restrict__ bsum) {
  const int tid = threadIdx.x, lane = tid & 63, wv = tid >> 6;
  const int i4 = blockIdx.x * 256 + tid;
  int4 v = make_int4(0, 0, 0, 0);
  if (i4 < N4_SCAN) v = reinterpret_cast<const int4*>(cnt)[i4];
  int s = v.x + v.y + v.z + v.w;
  #pragma unroll
  for (int d = 1; d < 64; d <<= 1) s += __shfl_xor(s, d);
  __shared__ int ws[4];
  if (lane == 0) ws[wv] = s;
  __syncthreads();
  if (tid == 0) bsum[blockIdx.x] = ws[0] + ws[1] + ws[2] + ws[3];
}

__global__ __launch_bounds__(256) void scanB_kernel(const int* __restrict__ bsum,
                                                    int* __restrict__ bpre, int* __restrict__ offs) {
  const int tid = threadIdx.x, lane = tid & 63, wv = tid >> 6;
  int v = (tid < NBLK_SCAN) ? bsum[tid] : 0;
  int incl = wave_iscan(v, lane);
  __shared__ int ws[4];
  if (lane == 63) ws[wv] = incl;
  __syncthreads();
  int pre = 0;
  for (int j = 0; j < 4; ++j) if (j < wv) pre += ws[j];
  incl += pre;
  if (tid < NBLK_SCAN) bpre[tid] = incl - v;
  if (tid == NBLK_SCAN - 1) offs[NODES_ALL] = incl;
}

__global__ __launch_bounds__(256) void scanC_kernel(const int* __restrict__ cnt,
                                                    const int* __restrict__ bpre,
                                                    int* __restrict__ offs, int* __restrict__ cursor) {
  const int tid = threadIdx.x, lane = tid & 63, wv = tid >> 6;
  const int i4 = blockIdx.x * 256 + tid;
  int4 v = make_int4(0, 0, 0, 0);
  if (i4 < N4_SCAN) v = reinterpret_cast<const int4*>(cnt)[i4];
  const int tsum = v.x + v.y + v.z + v.w;
  int incl = wave_iscan(tsum, lane);
  __shared__ int ws[4];
  if (lane == 63) ws[wv] = incl;
  __syncthreads();
  int pre = bpre[blockIdx.x];
  for (int j = 0; j < 4; ++j) if (j < wv) pre += ws[j];
  int o0 = pre + incl - tsum;
  if (i4 < N4_SCAN) {
    int4 ov = make_int4(o0, o0 + v.x, o0 + v.x + v.y, o0 + v.x + v.y + v.z);
    reinterpret_cast<int4*>(offs)[i4] = ov;
    reinterpret_cast<int4*>(cursor)[i4] = ov;
  }
}

// ======================= aggregation =======================
// kv rows: 256 B = 16 chunks x 16 B, chunk j = k[ch j*8..+8] | v[ch j*8..+8] (fp8 e4m3)
// 16 lanes/edge (sl = lane&15, 8 ch each); 4 edge groups (sub = lane>>4); unroll 2.
struct AggArgs {
  const u16 *q_td, *q_wd, *q_tt, *q_wt, *q_ww;
  const u8 *kv_t, *kv_w;
  const int *csrc, *offs;
  const float *pri;
  u16 *t2_d, *t2_t, *t_w;
};

template<bool HI>
static __device__ __forceinline__ f32x2 cvt8(int w) {
  return __builtin_amdgcn_cvt_pk_f32_fp8(w, HI);
}

// After return: red = 2 fully sub-reduced channels at chbase(lane); ss_out = wave total.
static __device__ __forceinline__ void agg_core(
    const u16* __restrict__ q, const u8* __restrict__ kv,
    const int* __restrict__ offs, const int* __restrict__ csrc,
    const float* __restrict__ pri,
    int node, int grp, int stride, int sl, int lane,
    f32x2& red, float& ss_out)
{
  const int e0 = offs[node], e1 = offs[node + 1];
  f32x2 acc0 = (f32x2)0.f, acc1 = (f32x2)0.f, acc2 = (f32x2)0.f, acc3 = (f32x2)0.f;
  float ss = 0.f;
  if (e1 > e0) {
    const float prih = pri[sl >> 2] * 0.17677669529663687f;
    const bf16x8 qv = *reinterpret_cast<const bf16x8*>(q + (size_t)node * 128 + sl * 8);
    f32x2 q2[4];
    #pragma unroll
    for (int p = 0; p < 4; ++p) {
      f32x2 t; t[0] = b2f((u16)qv[2 * p]); t[1] = b2f((u16)qv[2 * p + 1]); q2[p] = t;
    }
    const int last = e1 - 1;
    for (int base = e0; base < e1; base += 2 * stride) {
      const int eA = base + grp, eB = base + stride + grp;
      const bool vA = eA < e1, vB = eB < e1;
      const int sA = csrc[vA ? eA : last];
      const int sB = csrc[vB ? eB : last];
      const uint4 cA = *reinterpret_cast<const uint4*>(kv + (size_t)sA * 256 + sl * 16);
      const uint4 cB = *reinterpret_cast<const uint4*>(kv + (size_t)sB * 256 + sl * 16);
      // dots
      f32x2 dA = q2[0] * cvt8<false>((int)cA.x);
      dA += q2[1] * cvt8<true>((int)cA.x);
      dA += q2[2] * cvt8<false>((int)cA.y);
      dA += q2[3] * cvt8<true>((int)cA.y);
      f32x2 dB = q2[0] * cvt8<false>((int)cB.x);
      dB += q2[1] * cvt8<true>((int)cB.x);
      dB += q2[2] * cvt8<false>((int)cB.y);
      dB += q2[3] * cvt8<true>((int)cB.y);
      float dotA = dA[0] + dA[1];
      float dotB = dB[0] + dB[1];
      dotA += __shfl_xor(dotA, 1); dotA += __shfl_xor(dotA, 2);
      dotB += __shfl_xor(dotB, 1); dotB += __shfl_xor(dotB, 2);
      const float wA = vA ? __expf(dotA * prih) : 0.f;
      const float wB = vB ? __expf(dotB * prih) : 0.f;
      ss += wA + wB;
      f32x2 wA2; wA2[0] = wA; wA2[1] = wA;
      f32x2 wB2; wB2[0] = wB; wB2[1] = wB;
      acc0 += wA2 * cvt8<false>((int)cA.z);
      acc1 += wA2 * cvt8<true>((int)cA.z);
      acc2 += wA2 * cvt8<false>((int)cA.w);
      acc3 += wA2 * cvt8<true>((int)cA.w);
      acc0 += wB2 * cvt8<false>((int)cB.z);
      acc1 += wB2 * cvt8<true>((int)cB.z);
      acc2 += wB2 * cvt8<false>((int)cB.w);
      acc3 += wB2 * cvt8<true>((int)cB.w);
    }
  }
  // wave-level sub reduce (4 groups), split-butterfly
  ss += __shfl_xor(ss, 16); ss += __shfl_xor(ss, 32);
  const bool h16 = (lane & 16) != 0, h32 = (lane & 32) != 0;
  f32x2 k0 = h16 ? acc2 : acc0;
  f32x2 k1 = h16 ? acc3 : acc1;
  f32x2 s0 = h16 ? acc0 : acc2;
  f32x2 s1 = h16 ? acc1 : acc3;
  k0[0] += __shfl_xor(s0[0], 16); k0[1] += __shfl_xor(s0[1], 16);
  k1[0] += __shfl_xor(s1[0], 16); k1[1] += __shfl_xor(s1[1], 16);
  f32x2 kk = h32 ? k1 : k0;
  f32x2 sd = h32 ? k0 : k1;
  kk[0] += __shfl_xor(sd[0], 32); kk[1] += __shfl_xor(sd[1], 32);
  red = kk; ss_out = ss;
}

static __device__ __forceinline__ int chbase_of(int lane) {
  return (lane & 15) * 8 + ((lane >> 4) & 1) * 4 + ((lane >> 5) & 1) * 2;
}

// grid (layer0, topic_n=800): [0,800) topic; [800,8800) doc; [8800,28800) word.
// grid (layer1, topic_n=0): 8000 doc blocks.
__global__ __launch_bounds__(256) void agg_all_kernel(AggArgs A, int topic_n)
{
  __shared__ float lacc[4][128];
  __shared__ float lssA[4];
  const int tid = threadIdx.x, lane = tid & 63, wv = tid >> 6;
  const int sub = lane >> 4, sl = lane & 15;
  const int bid = blockIdx.x;
  const int chb = chbase_of(lane);
  f32x2 red; float ss;

  if (bid < topic_n) {
    const int node = bid;
    for (int r = 0; r < 2; ++r) {
      agg_core(r ? A.q_wt : A.q_tt, r ? A.kv_w : A.kv_t,
               A.offs + (r ? 64800 : 64000), A.csrc, A.pri + (r ? 12 : 4),
               node, wv * 4 + sub, 16, sl, lane, red, ss);
      lacc[wv][chb] = red[0]; lacc[wv][chb + 1] = red[1];
      if (lane == 0) lssA[wv] = ss;
      __syncthreads();
      if (tid < 128) {
        float a = lacc[0][tid] + lacc[1][tid] + lacc[2][tid] + lacc[3][tid];
        float st = lssA[0] + lssA[1] + lssA[2] + lssA[3];
        float inv = (st > 0.f) ? 1.f / st : 0.f;
        A.t2_t[(size_t)node * 256 + r * 128 + tid] = f2bf(a * inv);
      }
      __syncthreads();
    }
  } else if (bid < topic_n + 8000) {
    const int node = (bid - topic_n) * 4 + wv;
    agg_core(A.q_td, A.kv_t, A.offs + 0, A.csrc, A.pri + 0, node, sub, 4, sl, lane, red, ss);
    {
      float inv = (ss > 0.f) ? 1.f / ss : 0.f;
      unsigned pk = (unsigned)f2bf(red[0] * inv) | ((unsigned)f2bf(red[1] * inv) << 16);
      *reinterpret_cast<unsigned*>(A.t2_d + (size_t)node * 256 + chb) = pk;
    }
    agg_core(A.q_wd, A.kv_w, A.offs + 32000, A.csrc, A.pri + 8, node, sub, 4, sl, lane, red, ss);
    {
      float inv = (ss > 0.f) ? 1.f / ss : 0.f;
      unsigned pk = (unsigned)f2bf(red[0] * inv) | ((unsigned)f2bf(red[1] * inv) << 16);
      *reinterpret_cast<unsigned*>(A.t2_d + (size_t)node * 256 + 128 + chb) = pk;
    }
  } else {
    const int node = (bid - topic_n - 8000) * 4 + wv;
    agg_core(A.q_ww, A.kv_w, A.offs + 65600, A.csrc, A.pri + 16, node, sub, 4, sl, lane, red, ss);
    float inv = (ss > 0.f) ? 1.f / ss : 0.f;
    unsigned pk = (unsigned)f2bf(red[0] * inv) | ((unsigned)f2bf(red[1] * inv) << 16);
    *reinterpret_cast<unsigned*>(A.t_w + (size_t)node * 128 + chb) = pk;
  }
}

// ======================= readout =======================
__global__ void ginit_kernel(unsigned* g) {
  int i = blockIdx.x * 256 + threadIdx.x;
  if (i < BATCH * H_DIM) g[i] = 0x007FFFFFu;
}

__global__ void segmax_kernel(const u16* __restrict__ hd, const int* __restrict__ gid,
                              unsigned* g) {
  int c = threadIdx.x;
  int d0 = blockIdx.x * 128;
  int dend = min(d0 + 128, N_DOC);
  int cur = -1; float m = 0.f;
  for (int d = d0; d < dend; ++d) {
    int gg = gid[d];
    float v = b2f(hd[(size_t)d * 128 + c]);
    if (gg != cur) {
      if (cur >= 0) atomicMax(&g[cur * 128 + c], fenc(m));
      cur = gg; m = v;
    } else {
      m = fmaxf(m, v);
    }
  }
  if (cur >= 0) atomicMax(&g[cur * 128 + c], fenc(m));
}

__global__ void final_kernel(const unsigned* __restrict__ g, const float* __restrict__ out_w,
                             const float* __restrict__ out_b, const float* __restrict__ y,
                             float* out) {
  int tid = threadIdx.x;
  int b = tid >> 4, seg = tid & 15;
  float p = 0.f;
  #pragma unroll
  for (int j = 0; j < 8; ++j) {
    int c = seg * 8 + j;
    p += fdec(g[b * 128 + c]) * out_w[c];
  }
  p += __shfl_xor(p, 1);
  p += __shfl_xor(p, 2);
  p += __shfl_xor(p, 4);
  p += __shfl_xor(p, 8);
  __shared__ float logits[BATCH];
  __shared__ float losses[BATCH];
  if (seg == 0) logits[b] = p + out_b[0];
  __syncthreads();
  if (tid < BATCH) {
    float l = logits[tid];
    out[1 + tid] = 1.f / (1.f + expf(-l));
    float ls_pos = (l > 0.f) ? -log1pf(expf(-l)) : l - log1pf(expf(l));
    float ls_neg = (l < 0.f) ? -log1pf(expf(l)) : -l - log1pf(expf(-l));
    losses[tid] = -(y[tid] * ls_pos + (1.f - y[tid]) * ls_neg);
  }
  __syncthreads();
  if (tid == 0) {
    float s = 0.f;
    for (int j = 0; j < BATCH; ++j) s += losses[j];
    out[0] = s / (float)BATCH;
  }
}

// ======================= host =======================
extern "C" void kernel_launch(void* const* d_in, const int* in_sizes, int n_in,
                              void* d_out, int out_size, void* d_ws, size_t ws_size,
                              hipStream_t stream)
{
  const float* word_embeds  = (const float*)d_in[0];
  const float* topic_embeds = (const float*)d_in[1];
  const float* KW  = (const float*)d_in[2];
  const float* Kb  = (const float*)d_in[3];
  const float* QW  = (const float*)d_in[4];
  const float* Qb  = (const float*)d_in[5];
  const float* VW  = (const float*)d_in[6];
  const float* Vb  = (const float*)d_in[7];
  const float* AW  = (const float*)d_in[8];
  const float* Ab  = (const float*)d_in[9];
  const float* rel_att = (const float*)d_in[10];
  const float* rel_msg = (const float*)d_in[11];
  const float* rel_pri = (const float*)d_in[12];
  const float* skip    = (const float*)d_in[13];
  const float* adapt_w = (const float*)d_in[14];
  const float* adapt_b = (const float*)d_in[15];
  const float* out_w   = (const float*)d_in[16];
  const float* out_b   = (const float*)d_in[17];
  const float* y_data  = (const float*)d_in[18];
  const int* word_ids  = (const int*)d_in[19];
  const int* topic_ids = (const int*)d_in[20];
  const int* doc_gid   = (const int*)d_in[21];
  const int* td_src = (const int*)d_in[22];
  const int* td_dst = (const int*)d_in[23];
  const int* tt_src = (const int*)d_in[24];
  const int* tt_dst = (const int*)d_in[25];
  const int* wd_src = (const int*)d_in[26];
  const int* wd_dst = (const int*)d_in[27];
  const int* wt_src = (const int*)d_in[28];
  const int* wt_dst = (const int*)d_in[29];
  const int* ww_src = (const int*)d_in[30];
  const int* ww_dst = (const int*)d_in[31];

  char* base = (char*)d_ws;
  size_t off_b = 0;
  auto alloc = [&](size_t bytes) -> char* {
    char* p = base + off_b;
    off_b = (off_b + bytes + 255) & ~(size_t)255;
    return p;
  };

  u16* wtab = (u16*)alloc((size_t)VOCAB * 320 * 2);
  u16* hw   = (u16*)alloc((size_t)N_WORD * 128 * 2);
  u16* hd   = (u16*)alloc((size_t)N_DOC * 128 * 2);
  u16* ht   = (u16*)alloc((size_t)N_TOPIC * 128 * 2);
  u8*  kv_w = (u8*)alloc((size_t)N_WORD * 256);
  u8*  kv_t = (u8*)alloc((size_t)N_TOPIC * 256);
  u16* q_td = (u16*)alloc((size_t)N_DOC * 128 * 2);
  u16* q_wd = (u16*)alloc((size_t)N_DOC * 128 * 2);
  u16* q_tt = (u16*)alloc((size_t)N_TOPIC * 128 * 2);
  u16* q_wt = (u16*)alloc((size_t)N_TOPIC * 128 * 2);
  u16* q_ww = (u16*)alloc((size_t)N_WORD * 128 * 2);
  u16* t2_d = (u16*)alloc((size_t)N_DOC * 256 * 2);
  u16* t2_t = (u16*)alloc((size_t)N_TOPIC * 256 * 2);
  u16* t_w  = (u16*)alloc((size_t)N_WORD * 128 * 2);
  unsigned* g = (unsigned*)alloc((size_t)BATCH * 128 * 4);

  int* cnt_all  = (int*)alloc((size_t)NODES_ALL * 4);
  int* offs_all = (int*)alloc(((size_t)NODES_ALL + 1) * 4);
  int* csrc_all = (int*)alloc((size_t)EDGES_ALL * 4);
  int* bsum     = (int*)alloc((size_t)NBLK_SCAN * 4);
  int* bpre     = (int*)alloc((size_t)NBLK_SCAN * 4);

  u16* blw        = (u16*)alloc((size_t)(40960 + 28 * 16384) * 2);
  float* bias_are = (float*)alloc((size_t)29 * 128 * 4);

  auto BLp = [&](int wid) -> const u16* {
    return (wid == 0) ? blw : blw + 40960 + (size_t)(wid - 1) * 16384;
  };
  auto BIp = [&](int wid) -> const float* { return bias_are + wid * 128; };
  auto WID = [&](int li, int j) { return 1 + li * 14 + j; };

  // ---- prep ----
  prep_kernel<<<29 * 8, 256, 0, stream>>>(KW, Kb, QW, Qb, VW, Vb, AW, Ab,
                                          rel_att, rel_msg, adapt_w, adapt_b, blw, bias_are);
  conv_wtab_kernel<<<(VOCAB * 320 + 255) / 256, 256, 0, stream>>>(word_embeds, wtab);
  gather_topic_kernel<<<(N_TOPIC * 128 + 255) / 256, 256, 0, stream>>>(topic_embeds, topic_ids, ht);

  hipMemsetAsync(cnt_all, 0, (size_t)NODES_ALL * 4, stream);
  count_all_kernel<<<(EDGES_ALL + 255) / 256, 256, 0, stream>>>(td_dst, wd_dst, tt_dst, wt_dst, ww_dst, cnt_all);
  scanA_kernel<<<NBLK_SCAN, 256, 0, stream>>>(cnt_all, bsum);
  scanB_kernel<<<1, 256, 0, stream>>>(bsum, bpre, offs_all);
  scanC_kernel<<<NBLK_SCAN, 256, 0, stream>>>(cnt_all, bpre, offs_all, cnt_all);
  fill_all_kernel<<<(EDGES_ALL + 255) / 256, 256, 0, stream>>>(
      td_src, td_dst, wd_src, wd_dst, tt_src, tt_dst, wt_src, wt_dst, ww_src, ww_dst,
      cnt_all, csrc_all);

  hipMemsetAsync(hd, 0, (size_t)N_DOC * 128 * 2, stream);

  // ---- adapt ----
  gemm_kernel<10, 1><<<(N_WORD + 63) / 64, 256, 0, stream>>>(
      wtab, 320, word_ids, BLp(0), BIp(0), hw, nullptr, nullptr, N_WORD);

  const int GW = (N_WORD + 63) / 64, GD = (N_DOC + 63) / 64, GT = (N_TOPIC + 63) / 64;

  // ================= layer 0 =================
  {
    const int li = 0;
    {  // word-side: k (fp8-k), v (fp8-v), q_ww (bf16)
      Outs4 P = {};
      const int wids[3] = {WID(li, 1), WID(li, 3), WID(li, 8)};
      void* cs[3] = {kv_w, kv_w, q_ww};
      const int knd[3] = {1, 2, 0};
      for (int o = 0; o < 3; ++o) { P.BL[o] = BLp(wids[o]); P.bias[o] = BIp(wids[o]); P.C[o] = cs[o]; P.bs[o] = 256; P.kind[o] = knd[o]; }
      gemmN_kernel<4, 3><<<GW, 256, 0, stream>>>(hw, 128, nullptr, P, N_WORD);
    }
    {  // topic-side
      Outs4 P = {};
      const int wids[4] = {WID(li, 0), WID(li, 2), WID(li, 5), WID(li, 7)};
      void* cs[4] = {kv_t, kv_t, q_tt, q_wt};
      const int knd[4] = {1, 2, 0, 0};
      for (int o = 0; o < 4; ++o) { P.BL[o] = BLp(wids[o]); P.bias[o] = BIp(wids[o]); P.C[o] = cs[o]; P.bs[o] = 256; P.kind[o] = knd[o]; }
      gemmN_kernel<4, 4><<<GT, 256, 0, stream>>>(ht, 128, nullptr, P, N_TOPIC);
    }
    bcast_q_kernel<<<(N_DOC * 128 + 255) / 256, 256, 0, stream>>>(BIp(WID(0, 4)), BIp(WID(0, 6)), q_td, q_wd);

    AggArgs A;
    A.q_td = q_td; A.q_wd = q_wd; A.q_tt = q_tt; A.q_wt = q_wt; A.q_ww = q_ww;
    A.kv_t = kv_t; A.kv_w = kv_w;
    A.csrc = csrc_all; A.offs = offs_all;
    A.pri = rel_pri + (size_t)li * 5 * 4;
    A.t2_d = t2_d; A.t2_t = t2_t; A.t_w = t_w;
    agg_all_kernel<<<28800, 256, 0, stream>>>(A, 800);

    gemm2_kernel<4><<<GD, 256, 0, stream>>>(t2_d, BLp(WID(li, 9)), BLp(WID(li, 11)),
                                            BIp(WID(li, 9)), hd, skip + (size_t)li * 3 + 0, N_DOC);
    gemm2_kernel<4><<<GT, 256, 0, stream>>>(t2_t, BLp(WID(li, 10)), BLp(WID(li, 12)),
                                            BIp(WID(li, 10)), ht, skip + (size_t)li * 3 + 1, N_TOPIC);
    gemm_kernel<4, 2><<<GW, 256, 0, stream>>>(t_w, 128, nullptr, BLp(WID(li, 13)), BIp(WID(li, 13)),
                                              hw, hw, skip + (size_t)li * 3 + 2, N_WORD);
  }

  // ================= layer 1 (docs only live) =================
  {
    const int li = 1;
    {  // word-side k/v
      Outs4 P = {};
      const int wids[2] = {WID(li, 1), WID(li, 3)};
      void* cs[2] = {kv_w, kv_w};
      const int knd[2] = {1, 2};
      for (int o = 0; o < 2; ++o) { P.BL[o] = BLp(wids[o]); P.bias[o] = BIp(wids[o]); P.C[o] = cs[o]; P.bs[o] = 256; P.kind[o] = knd[o]; }
      gemmN_kernel<4, 2><<<GW, 256, 0, stream>>>(hw, 128, nullptr, P, N_WORD);
    }
    {  // topic-side k/v
      Outs4 P = {};
      const int wids[2] = {WID(li, 0), WID(li, 2)};
      void* cs[2] = {kv_t, kv_t};
      const int knd[2] = {1, 2};
      for (int o = 0; o < 2; ++o) { P.BL[o] = BLp(wids[o]); P.bias[o] = BIp(wids[o]); P.C[o] = cs[o]; P.bs[o] = 256; P.kind[o] = knd[o]; }
      gemmN_kernel<4, 2><<<GT, 256, 0, stream>>>(ht, 128, nullptr, P, N_TOPIC);
    }
    {  // doc Q
      Outs4 P = {};
      const int wids[2] = {WID(li, 4), WID(li, 6)};
      void* cs[2] = {q_td, q_wd};
      for (int o = 0; o < 2; ++o) { P.BL[o] = BLp(wids[o]); P.bias[o] = BIp(wids[o]); P.C[o] = cs[o]; P.bs[o] = 256; P.kind[o] = 0; }
      gemmN_kernel<4, 2><<<GD, 256, 0, stream>>>(hd, 128, nullptr, P, N_DOC);
    }

    AggArgs A;
    A.q_td = q_td; A.q_wd = q_wd; A.q_tt = q_tt; A.q_wt = q_wt; A.q_ww = q_ww;
    A.kv_t = kv_t; A.kv_w = kv_w;
    A.csrc = csrc_all; A.offs = offs_all;
    A.pri = rel_pri + (size_t)li * 5 * 4;
    A.t2_d = t2_d; A.t2_t = t2_t; A.t_w = t_w;
    agg_all_kernel<<<8000, 256, 0, stream>>>(A, 0);

    gemm2_kernel<4><<<GD, 256, 0, stream>>>(t2_d, BLp(WID(li, 9)), BLp(WID(li, 11)),
                                            BIp(WID(li, 9)), hd, skip + (size_t)li * 3 + 0, N_DOC);
  }

  // ---- readout ----
  ginit_kernel<<<(BATCH * 128 + 255) / 256, 256, 0, stream>>>(g);
  segmax_kernel<<<(N_DOC + 127) / 128, 128, 0, stream>>>(hd, doc_gid, g);
  final_kernel<<<1, 256, 0, stream>>>(g, out_w, out_b, y_data, (float*)d_out);
}

// Round 8
// 430.319 us; speedup vs baseline: 10.7718x; 1.0727x over previous
//
#include <hip/hip_runtime.h>
#include <cstdint>
#include <cstddef>

#define H_DIM 128
#define N_DOC 32000
#define N_TOPIC 800
#define N_WORD 80000
#define BATCH 16
#define VOCAB 15000
#define NODES_ALL 145600
#define EDGES_ALL 850000
#define NBLK_SCAN 143
#define N4_SCAN 36400

typedef short bf16x8 __attribute__((ext_vector_type(8)));
typedef float f32x4 __attribute__((ext_vector_type(4)));
typedef float f32x2 __attribute__((ext_vector_type(2)));
typedef unsigned short u16;
typedef unsigned char u8;

static __device__ __forceinline__ u16 f2bf(float x) {
  unsigned u = __float_as_uint(x);
  u += 0x7fffu + ((u >> 16) & 1u);
  return (u16)(u >> 16);
}
static __device__ __forceinline__ float b2f(unsigned h) {
  return __uint_as_float(h << 16);
}
static __device__ __forceinline__ unsigned fenc(float f) {
  unsigned u = __float_as_uint(f);
  return (u & 0x80000000u) ? ~u : (u | 0x80000000u);
}
static __device__ __forceinline__ float fdec(unsigned k) {
  return (k & 0x80000000u) ? __uint_as_float(k ^ 0x80000000u) : __uint_as_float(~k);
}
static __device__ __forceinline__ int wave_iscan(int v, int lane) {
  #pragma unroll
  for (int d = 1; d < 64; d <<= 1) {
    int t = __shfl_up(v, d);
    if (lane >= d) v += t;
  }
  return v;
}
static __device__ __forceinline__ unsigned blend2(unsigned pr, unsigned bl, float aa) {
  float v0 = b2f(pr & 0xffffu) * aa + b2f(bl & 0xffffu) * (1.f - aa);
  float v1 = b2f(pr >> 16) * aa + b2f(bl >> 16) * (1.f - aa);
  return (unsigned)f2bf(v0) | ((unsigned)f2bf(v1) << 16);
}
template<bool HI>
static __device__ __forceinline__ f32x2 cvt8(int w) {
  return __builtin_amdgcn_cvt_pk_f32_fp8(w, HI);
}

// ======================= weight prep =======================
__global__ __launch_bounds__(256) void prep_kernel(
    const float* __restrict__ KW, const float* __restrict__ Kb,
    const float* __restrict__ QW, const float* __restrict__ Qb,
    const float* __restrict__ VW, const float* __restrict__ Vb,
    const float* __restrict__ AW, const float* __restrict__ Ab,
    const float* __restrict__ rel_att, const float* __restrict__ rel_msg,
    const float* __restrict__ adapt_w, const float* __restrict__ adapt_b,
    u16* __restrict__ bl_arena, float* __restrict__ bias_arena)
{
  const int wid = blockIdx.x >> 3, t = blockIdx.x & 7;
  int KS, Kreal, fold;
  const float *W, *b, *R = nullptr;
  float scale = 1.f;
  if (wid == 0) { KS = 10; Kreal = 300; fold = 0; W = adapt_w; b = adapt_b; }
  else {
    KS = 4; Kreal = 128;
    const int wl = wid - 1, li = wl / 14, j = wl % 14;
    const int dstnid[5] = {0, 1, 0, 1, 2};
    if (j < 4) {
      fold = 0;
      const float* Wb = (j < 2) ? KW : VW;
      const float* bb = (j < 2) ? Kb : Vb;
      const int nid = (j & 1) ? 2 : 1;
      W = Wb + ((size_t)li * 3 + nid) * 16384; b = bb + ((size_t)li * 3 + nid) * 128;
    } else if (j < 9) {
      fold = 1; const int r = j - 4; const int nid = dstnid[r];
      W = QW + ((size_t)li * 3 + nid) * 16384; b = Qb + ((size_t)li * 3 + nid) * 128;
      R = rel_att + ((size_t)li * 5 + r) * 4096;
    } else {
      fold = 3; const int r = j - 9; const int nid = dstnid[r];
      W = AW + ((size_t)li * 3 + nid) * 16384; b = Ab + ((size_t)li * 3 + nid) * 128;
      R = rel_msg + ((size_t)li * 5 + r) * 4096;
      scale = (r == 4) ? 1.f : 0.5f;
    }
  }
  u16* obl = (wid == 0) ? bl_arena : bl_arena + 40960 + (size_t)(wid - 1) * 16384;
  float* obias = bias_arena + wid * 128;

  const int nelem = KS * 512;
  for (int e = threadIdx.x; e < nelem; e += 256) {
    const int s = e >> 9, rem = e & 511, l = rem >> 3, jj = rem & 7;
    const int k = s * 32 + ((l >> 4) << 3) + jj;
    const int nn = t * 16 + (l & 15);
    float v = 0.f;
    if (k < Kreal) {
      if (fold == 0) v = W[(size_t)k * 128 + nn];
      else if (fold == 1) {
        const int h = nn >> 5, d = nn & 31;
        const float* Wr = W + (size_t)k * 128 + h * 32;
        const float* Rh = R + h * 1024;
        for (int f = 0; f < 32; ++f) v += Wr[f] * Rh[d * 32 + f];
      } else {
        const int h = k >> 5, dd = k & 31;
        const float* Rh = R + h * 1024 + dd * 32;
        const float* Wc = W + (size_t)h * 32 * 128 + nn;
        float sa = 0.f;
        for (int f = 0; f < 32; ++f) sa += Rh[f] * Wc[(size_t)f * 128];
        v = sa * scale;
      }
    }
    obl[(size_t)(t * KS + s) * 512 + rem] = f2bf(v);
  }
  if (t == 0 && threadIdx.x < 128) {
    const int nn = threadIdx.x;
    float v = 0.f;
    if (fold != 1) v = b[nn];
    else {
      const int h = nn >> 5, d = nn & 31;
      const float* Rh = R + h * 1024;
      for (int f = 0; f < 32; ++f) v += b[h * 32 + f] * Rh[d * 32 + f];
    }
    obias[nn] = v;
  }
}

// ======================= GEMM helpers =======================
static __device__ __forceinline__ void kv_write_half(
    const u16* lds16, int rr, int cs, u8* kv, size_t m, int vhalf)
{
  u8* Cp = kv + m * 256 + (cs >> 3) * 16 + (vhalf ? 8 : 0);
  #pragma unroll
  for (int q2 = 0; q2 < 4; ++q2) {
    unsigned w0, w1;
    {
      float f0 = b2f(lds16[rr * 132 + cs + q2 * 8 + 0]);
      float f1 = b2f(lds16[rr * 132 + cs + q2 * 8 + 1]);
      float f2 = b2f(lds16[rr * 132 + cs + q2 * 8 + 2]);
      float f3 = b2f(lds16[rr * 132 + cs + q2 * 8 + 3]);
      int t0 = __builtin_amdgcn_cvt_pk_fp8_f32(f0, f1, 0, false);
      w0 = (unsigned)__builtin_amdgcn_cvt_pk_fp8_f32(f2, f3, t0, true);
    }
    {
      float f0 = b2f(lds16[rr * 132 + cs + q2 * 8 + 4]);
      float f1 = b2f(lds16[rr * 132 + cs + q2 * 8 + 5]);
      float f2 = b2f(lds16[rr * 132 + cs + q2 * 8 + 6]);
      float f3 = b2f(lds16[rr * 132 + cs + q2 * 8 + 7]);
      int t0 = __builtin_amdgcn_cvt_pk_fp8_f32(f0, f1, 0, false);
      w1 = (unsigned)__builtin_amdgcn_cvt_pk_fp8_f32(f2, f3, t0, true);
    }
    *reinterpret_cast<uint2*>(Cp + q2 * 16) = make_uint2(w0, w1);
  }
}

static __device__ __forceinline__ void bf16_write_row(
    const u16* lds16, int rr, int cs, u16* C, size_t m)
{
  u16* Cp = C + m * 128 + cs;
  #pragma unroll
  for (int q2 = 0; q2 < 4; ++q2) {
    uint2 x0 = *reinterpret_cast<const uint2*>(&lds16[rr * 132 + cs + q2 * 8]);
    uint2 x1 = *reinterpret_cast<const uint2*>(&lds16[rr * 132 + cs + q2 * 8 + 4]);
    uint4 st; st.x = x0.x; st.y = x0.y; st.z = x1.x; st.w = x1.y;
    *reinterpret_cast<uint4*>(Cp + q2 * 8) = st;
  }
}

#define GEMM_ACC(AV, BLP)                                                        \
  {                                                                              \
    const u16* Bp = (BLP) + (size_t)lane * 8;                                    \
    _Pragma("unroll")                                                            \
    for (int s = 0; s < 4; ++s) {                                                \
      _Pragma("unroll")                                                          \
      for (int t = 0; t < 8; ++t) {                                              \
        bf16x8 bfr = *reinterpret_cast<const bf16x8*>(Bp + (size_t)(t * 4 + s) * 512); \
        acc[t] = __builtin_amdgcn_mfma_f32_16x16x32_bf16(AV[s], bfr, acc[t], 0, 0, 0); \
      }                                                                          \
    }                                                                            \
  }

#define ACC_TO_LDS(BIAS)                                                         \
  {                                                                              \
    _Pragma("unroll")                                                            \
    for (int t = 0; t < 8; ++t) {                                                \
      const int col = t * 16 + (lane & 15);                                      \
      const float bb = (BIAS)[col];                                              \
      const int mr = w * 16 + g * 4;                                             \
      _Pragma("unroll")                                                          \
      for (int j = 0; j < 4; ++j)                                                \
        lds16[(mr + j) * 132 + col] = f2bf(acc[t][j] + bb);                      \
    }                                                                            \
  }

// ======================= plain GEMM (adapt) =======================
template<int KS, int VAR>
__global__ __launch_bounds__(256) void gemm_kernel(
    const u16* __restrict__ A, int AS, const int* __restrict__ idx,
    const u16* __restrict__ BL, const float* __restrict__ bias,
    u16* __restrict__ C, int n)
{
  __shared__ u16 lds16[64 * 132];
  const int tid = threadIdx.x, lane = tid & 63, w = tid >> 6;
  const int m0 = blockIdx.x * 64 + w * 16;
  int rl = m0 + (lane & 15);
  if (rl >= n) rl = n - 1;
  const int row = idx ? idx[rl] : rl;
  const int g = lane >> 4;

  bf16x8 a[KS];
  const u16* Ap = A + (size_t)row * AS + g * 8;
  #pragma unroll
  for (int s = 0; s < KS; ++s) a[s] = *reinterpret_cast<const bf16x8*>(Ap + s * 32);

  f32x4 acc[8];
  #pragma unroll
  for (int t = 0; t < 8; ++t) acc[t] = (f32x4)0.f;
  const u16* Bp = BL + (size_t)lane * 8;
  #pragma unroll
  for (int s = 0; s < KS; ++s) {
    #pragma unroll
    for (int t = 0; t < 8; ++t) {
      bf16x8 bfr = *reinterpret_cast<const bf16x8*>(Bp + (size_t)(t * KS + s) * 512);
      acc[t] = __builtin_amdgcn_mfma_f32_16x16x32_bf16(a[s], bfr, acc[t], 0, 0, 0);
    }
  }
  #pragma unroll
  for (int t = 0; t < 8; ++t) {
    const int col = t * 16 + (lane & 15);
    const float bb = bias[col];
    const int mr = w * 16 + g * 4;
    #pragma unroll
    for (int j = 0; j < 4; ++j) {
      float v = acc[t][j] + bb;
      if (VAR == 1) v = tanhf(v);
      lds16[(mr + j) * 132 + col] = f2bf(v);
    }
  }
  __syncthreads();
  const int rr = tid >> 2, cs = (tid & 3) * 32, m = blockIdx.x * 64 + rr;
  if (m < n) bf16_write_row(lds16, rr, cs, C, m);
}

// ======================= L1 topic k/v GEMM =======================
__global__ __launch_bounds__(256) void gemm_kv_kernel(
    const u16* __restrict__ A,
    const u16* __restrict__ BLk, const float* __restrict__ bk,
    const u16* __restrict__ BLv, const float* __restrict__ bv,
    u8* __restrict__ kv, int n)
{
  __shared__ u16 lds16[64 * 132];
  const int tid = threadIdx.x, lane = tid & 63, w = tid >> 6;
  int rl = blockIdx.x * 64 + w * 16 + (lane & 15);
  if (rl >= n) rl = n - 1;
  const int g = lane >> 4;
  bf16x8 a[4];
  const u16* Ap = A + (size_t)rl * 128 + g * 8;
  #pragma unroll
  for (int s = 0; s < 4; ++s) a[s] = *reinterpret_cast<const bf16x8*>(Ap + s * 32);
  const int rr = tid >> 2, cs = (tid & 3) * 32, m = blockIdx.x * 64 + rr;

  f32x4 acc[8];
  #pragma unroll
  for (int t = 0; t < 8; ++t) acc[t] = (f32x4)0.f;
  GEMM_ACC(a, BLk)
  ACC_TO_LDS(bk)
  __syncthreads();
  if (m < n) kv_write_half(lds16, rr, cs, kv, m, 0);

  #pragma unroll
  for (int t = 0; t < 8; ++t) acc[t] = (f32x4)0.f;
  GEMM_ACC(a, BLv)
  __syncthreads();
  ACC_TO_LDS(bv)
  __syncthreads();
  if (m < n) kv_write_half(lds16, rr, cs, kv, m, 1);
}

// ======================= L0 word projections (k+u, v+vp, q_ww) =======================
__global__ __launch_bounds__(256) void gemmN_l0w_kernel(
    const u16* __restrict__ A,
    const u16* __restrict__ BLk, const float* __restrict__ bk,
    const u16* __restrict__ BLv, const float* __restrict__ bv,
    const u16* __restrict__ BLq, const float* __restrict__ bq,
    const float* __restrict__ qc, const float* __restrict__ priw,
    u8* __restrict__ kv, u8* __restrict__ vp, float* __restrict__ uf,
    u16* __restrict__ qout, int n)
{
  __shared__ u16 lds16[64 * 132];
  const int tid = threadIdx.x, lane = tid & 63, w = tid >> 6;
  int rl = blockIdx.x * 64 + w * 16 + (lane & 15);
  if (rl >= n) rl = n - 1;
  const int g = lane >> 4;
  bf16x8 a[4];
  const u16* Ap = A + (size_t)rl * 128 + g * 8;
  #pragma unroll
  for (int s = 0; s < 4; ++s) a[s] = *reinterpret_cast<const bf16x8*>(Ap + s * 32);
  const int rr = tid >> 2, cs = (tid & 3) * 32, m = blockIdx.x * 64 + rr;

  // k
  f32x4 acc[8];
  #pragma unroll
  for (int t = 0; t < 8; ++t) acc[t] = (f32x4)0.f;
  GEMM_ACC(a, BLk)
  ACC_TO_LDS(bk)
  __syncthreads();
  float u_keep = 0.f;
  if (m < n) {
    kv_write_half(lds16, rr, cs, kv, m, 0);
    float dot = 0.f;
    #pragma unroll
    for (int j = 0; j < 32; ++j)
      dot += b2f(lds16[rr * 132 + cs + j]) * qc[cs + j];
    u_keep = __expf(dot * (priw[cs >> 5] * 0.17677669529663687f));
    uf[m * 4 + (cs >> 5)] = u_keep;
  }
  // v
  #pragma unroll
  for (int t = 0; t < 8; ++t) acc[t] = (f32x4)0.f;
  GEMM_ACC(a, BLv)
  __syncthreads();
  ACC_TO_LDS(bv)
  __syncthreads();
  if (m < n) {
    kv_write_half(lds16, rr, cs, kv, m, 1);
    unsigned wpk[8];
    #pragma unroll
    for (int p = 0; p < 8; ++p) {
      float f0 = u_keep * b2f(lds16[rr * 132 + cs + p * 4 + 0]);
      float f1 = u_keep * b2f(lds16[rr * 132 + cs + p * 4 + 1]);
      float f2 = u_keep * b2f(lds16[rr * 132 + cs + p * 4 + 2]);
      float f3 = u_keep * b2f(lds16[rr * 132 + cs + p * 4 + 3]);
      int t0 = __builtin_amdgcn_cvt_pk_fp8_f32(f0, f1, 0, false);
      wpk[p] = (unsigned)__builtin_amdgcn_cvt_pk_fp8_f32(f2, f3, t0, true);
    }
    *reinterpret_cast<uint4*>(vp + (size_t)m * 128 + cs)      = make_uint4(wpk[0], wpk[1], wpk[2], wpk[3]);
    *reinterpret_cast<uint4*>(vp + (size_t)m * 128 + cs + 16) = make_uint4(wpk[4], wpk[5], wpk[6], wpk[7]);
  }
  // q
  #pragma unroll
  for (int t = 0; t < 8; ++t) acc[t] = (f32x4)0.f;
  GEMM_ACC(a, BLq)
  __syncthreads();
  ACC_TO_LDS(bq)
  __syncthreads();
  if (m < n) bf16_write_row(lds16, rr, cs, qout, m);
}

// ======================= L0 topic projections (k+u, v+vp, q_tt, q_wt) =======================
__global__ __launch_bounds__(256) void gemmN_l0t_kernel(
    const u16* __restrict__ A,
    const u16* __restrict__ BLk, const float* __restrict__ bk,
    const u16* __restrict__ BLv, const float* __restrict__ bv,
    const u16* __restrict__ BLq0, const float* __restrict__ bq0,
    const u16* __restrict__ BLq1, const float* __restrict__ bq1,
    const float* __restrict__ qc, const float* __restrict__ prit,
    u8* __restrict__ kv, u8* __restrict__ vp, float* __restrict__ uf,
    u16* __restrict__ q0, u16* __restrict__ q1, int n)
{
  __shared__ u16 lds16[64 * 132];
  const int tid = threadIdx.x, lane = tid & 63, w = tid >> 6;
  int rl = blockIdx.x * 64 + w * 16 + (lane & 15);
  if (rl >= n) rl = n - 1;
  const int g = lane >> 4;
  bf16x8 a[4];
  const u16* Ap = A + (size_t)rl * 128 + g * 8;
  #pragma unroll
  for (int s = 0; s < 4; ++s) a[s] = *reinterpret_cast<const bf16x8*>(Ap + s * 32);
  const int rr = tid >> 2, cs = (tid & 3) * 32, m = blockIdx.x * 64 + rr;

  f32x4 acc[8];
  #pragma unroll
  for (int t = 0; t < 8; ++t) acc[t] = (f32x4)0.f;
  GEMM_ACC(a, BLk)
  ACC_TO_LDS(bk)
  __syncthreads();
  float u_keep = 0.f;
  if (m < n) {
    kv_write_half(lds16, rr, cs, kv, m, 0);
    float dot = 0.f;
    #pragma unroll
    for (int j = 0; j < 32; ++j)
      dot += b2f(lds16[rr * 132 + cs + j]) * qc[cs + j];
    u_keep = __expf(dot * (prit[cs >> 5] * 0.17677669529663687f));
    uf[m * 4 + (cs >> 5)] = u_keep;
  }
  #pragma unroll
  for (int t = 0; t < 8; ++t) acc[t] = (f32x4)0.f;
  GEMM_ACC(a, BLv)
  __syncthreads();
  ACC_TO_LDS(bv)
  __syncthreads();
  if (m < n) {
    kv_write_half(lds16, rr, cs, kv, m, 1);
    unsigned wpk[8];
    #pragma unroll
    for (int p = 0; p < 8; ++p) {
      float f0 = u_keep * b2f(lds16[rr * 132 + cs + p * 4 + 0]);
      float f1 = u_keep * b2f(lds16[rr * 132 + cs + p * 4 + 1]);
      float f2 = u_keep * b2f(lds16[rr * 132 + cs + p * 4 + 2]);
      float f3 = u_keep * b2f(lds16[rr * 132 + cs + p * 4 + 3]);
      int t0 = __builtin_amdgcn_cvt_pk_fp8_f32(f0, f1, 0, false);
      wpk[p] = (unsigned)__builtin_amdgcn_cvt_pk_fp8_f32(f2, f3, t0, true);
    }
    *reinterpret_cast<uint4*>(vp + (size_t)m * 128 + cs)      = make_uint4(wpk[0], wpk[1], wpk[2], wpk[3]);
    *reinterpret_cast<uint4*>(vp + (size_t)m * 128 + cs + 16) = make_uint4(wpk[4], wpk[5], wpk[6], wpk[7]);
  }
  #pragma unroll
  for (int t = 0; t < 8; ++t) acc[t] = (f32x4)0.f;
  GEMM_ACC(a, BLq0)
  __syncthreads();
  ACC_TO_LDS(bq0)
  __syncthreads();
  if (m < n) bf16_write_row(lds16, rr, cs, q0, m);

  #pragma unroll
  for (int t = 0; t < 8; ++t) acc[t] = (f32x4)0.f;
  GEMM_ACC(a, BLq1)
  __syncthreads();
  ACC_TO_LDS(bq1)
  __syncthreads();
  if (m < n) bf16_write_row(lds16, rr, cs, q1, m);
}

// ======================= dual-A comb GEMM (topic L0, doc L1) =======================
template<int KS>
__global__ __launch_bounds__(256) void gemm2_kernel(
    const u16* __restrict__ A2, const u16* __restrict__ BL0, const u16* __restrict__ BL1,
    const float* __restrict__ bias, u16* __restrict__ C,
    const float* __restrict__ skipp, int n)
{
  __shared__ u16 lds16[64 * 132];
  const int tid = threadIdx.x, lane = tid & 63, w = tid >> 6;
  int rl = blockIdx.x * 64 + w * 16 + (lane & 15);
  if (rl >= n) rl = n - 1;
  const int g = lane >> 4;

  bf16x8 a0[KS], a1[KS];
  const u16* Ap = A2 + (size_t)rl * 256 + g * 8;
  #pragma unroll
  for (int s = 0; s < KS; ++s) {
    a0[s] = *reinterpret_cast<const bf16x8*>(Ap + s * 32);
    a1[s] = *reinterpret_cast<const bf16x8*>(Ap + 128 + s * 32);
  }
  f32x4 acc[8];
  #pragma unroll
  for (int t = 0; t < 8; ++t) acc[t] = (f32x4)0.f;
  const u16* Bp0 = BL0 + (size_t)lane * 8;
  const u16* Bp1 = BL1 + (size_t)lane * 8;
  #pragma unroll
  for (int s = 0; s < KS; ++s) {
    #pragma unroll
    for (int t = 0; t < 8; ++t) {
      bf16x8 b0 = *reinterpret_cast<const bf16x8*>(Bp0 + (size_t)(t * KS + s) * 512);
      acc[t] = __builtin_amdgcn_mfma_f32_16x16x32_bf16(a0[s], b0, acc[t], 0, 0, 0);
      bf16x8 b1 = *reinterpret_cast<const bf16x8*>(Bp1 + (size_t)(t * KS + s) * 512);
      acc[t] = __builtin_amdgcn_mfma_f32_16x16x32_bf16(a1[s], b1, acc[t], 0, 0, 0);
    }
  }
  ACC_TO_LDS(bias)
  __syncthreads();
  const int rr = tid >> 2, cs = (tid & 3) * 32, m = blockIdx.x * 64 + rr;
  if (m < n) {
    const float aa = 1.f / (1.f + __expf(-skipp[0]));
    uint2 r8[8];
    #pragma unroll
    for (int q = 0; q < 8; ++q) r8[q] = *reinterpret_cast<const uint2*>(&lds16[rr * 132 + cs + q * 4]);
    #pragma unroll
    for (int q2 = 0; q2 < 4; ++q2) {
      uint4 blv = *reinterpret_cast<const uint4*>(C + (size_t)m * 128 + cs + q2 * 8);
      uint4 st;
      st.x = blend2(r8[2 * q2].x, blv.x, aa);
      st.y = blend2(r8[2 * q2].y, blv.y, aa);
      st.z = blend2(r8[2 * q2 + 1].x, blv.z, aa);
      st.w = blend2(r8[2 * q2 + 1].y, blv.w, aa);
      *reinterpret_cast<uint4*>(C + (size_t)m * 128 + cs + q2 * 8) = st;
    }
  }
}

// ======================= fused comb_d(L0, blend=0) + L1 doc q projections =======================
__global__ __launch_bounds__(256) void comb_dq_kernel(
    const u16* __restrict__ A2, const u16* __restrict__ BL0, const u16* __restrict__ BL1,
    const float* __restrict__ bias, const float* __restrict__ skipp,
    const u16* __restrict__ BLq0, const float* __restrict__ bq0,
    const u16* __restrict__ BLq1, const float* __restrict__ bq1,
    u16* __restrict__ hd, u16* __restrict__ q0, u16* __restrict__ q1, int n)
{
  __shared__ u16 lds16[64 * 132];
  const int tid = threadIdx.x, lane = tid & 63, w = tid >> 6;
  int rl = blockIdx.x * 64 + w * 16 + (lane & 15);
  if (rl >= n) rl = n - 1;
  const int g = lane >> 4;

  bf16x8 a0[4], a1[4];
  const u16* Ap = A2 + (size_t)rl * 256 + g * 8;
  #pragma unroll
  for (int s = 0; s < 4; ++s) {
    a0[s] = *reinterpret_cast<const bf16x8*>(Ap + s * 32);
    a1[s] = *reinterpret_cast<const bf16x8*>(Ap + 128 + s * 32);
  }
  f32x4 acc[8];
  #pragma unroll
  for (int t = 0; t < 8; ++t) acc[t] = (f32x4)0.f;
  {
    const u16* Bp0 = BL0 + (size_t)lane * 8;
    const u16* Bp1 = BL1 + (size_t)lane * 8;
    #pragma unroll
    for (int s = 0; s < 4; ++s) {
      #pragma unroll
      for (int t = 0; t < 8; ++t) {
        bf16x8 b0 = *reinterpret_cast<const bf16x8*>(Bp0 + (size_t)(t * 4 + s) * 512);
        acc[t] = __builtin_amdgcn_mfma_f32_16x16x32_bf16(a0[s], b0, acc[t], 0, 0, 0);
        bf16x8 b1 = *reinterpret_cast<const bf16x8*>(Bp1 + (size_t)(t * 4 + s) * 512);
        acc[t] = __builtin_amdgcn_mfma_f32_16x16x32_bf16(a1[s], b1, acc[t], 0, 0, 0);
      }
    }
  }
  const float aa = 1.f / (1.f + __expf(-skipp[0]));
  #pragma unroll
  for (int t = 0; t < 8; ++t) {
    const int col = t * 16 + (lane & 15);
    const float bb = bias[col];
    const int mr = w * 16 + g * 4;
    #pragma unroll
    for (int j = 0; j < 4; ++j)
      lds16[(mr + j) * 132 + col] = f2bf((acc[t][j] + bb) * aa);   // blend with hd=0
  }
  __syncthreads();
  const int rr = tid >> 2, cs = (tid & 3) * 32, m = blockIdx.x * 64 + rr;
  if (m < n) bf16_write_row(lds16, rr, cs, hd, m);
  // reload A from LDS (hd_new fragments)
  bf16x8 an[4];
  {
    const int rloc = w * 16 + (lane & 15);
    #pragma unroll
    for (int s = 0; s < 4; ++s)
      an[s] = *reinterpret_cast<const bf16x8*>(&lds16[rloc * 132 + s * 32 + g * 8]);
  }
  // q0
  #pragma unroll
  for (int t = 0; t < 8; ++t) acc[t] = (f32x4)0.f;
  GEMM_ACC(an, BLq0)
  __syncthreads();
  ACC_TO_LDS(bq0)
  __syncthreads();
  if (m < n) bf16_write_row(lds16, rr, cs, q0, m);
  // q1
  #pragma unroll
  for (int t = 0; t < 8; ++t) acc[t] = (f32x4)0.f;
  GEMM_ACC(an, BLq1)
  __syncthreads();
  ACC_TO_LDS(bq1)
  __syncthreads();
  if (m < n) bf16_write_row(lds16, rr, cs, q1, m);
}

// ======================= fused comb_w(L0) + L1 word k/v =======================
__global__ __launch_bounds__(256) void comb_kv_kernel(
    const u16* __restrict__ Aw, const u16* __restrict__ hwold,
    const u16* __restrict__ BLc, const float* __restrict__ bc,
    const u16* __restrict__ BLk, const float* __restrict__ bk,
    const u16* __restrict__ BLv, const float* __restrict__ bv,
    const float* __restrict__ skipp, u8* __restrict__ kv, int n)
{
  __shared__ u16 lds16[64 * 132];
  const int tid = threadIdx.x, lane = tid & 63, w = tid >> 6;
  int rl = blockIdx.x * 64 + w * 16 + (lane & 15);
  if (rl >= n) rl = n - 1;
  const int g = lane >> 4;

  bf16x8 a[4];
  const u16* Ap = Aw + (size_t)rl * 128 + g * 8;
  #pragma unroll
  for (int s = 0; s < 4; ++s) a[s] = *reinterpret_cast<const bf16x8*>(Ap + s * 32);

  f32x4 acc[8];
  #pragma unroll
  for (int t = 0; t < 8; ++t) acc[t] = (f32x4)0.f;
  GEMM_ACC(a, BLc)
  ACC_TO_LDS(bc)
  __syncthreads();
  const int rr = tid >> 2, cs = (tid & 3) * 32, m = blockIdx.x * 64 + rr;
  // blend with hw_old in LDS
  if (m < n) {
    const float aa = 1.f / (1.f + __expf(-skipp[0]));
    #pragma unroll
    for (int q2 = 0; q2 < 4; ++q2) {
      uint2 x0 = *reinterpret_cast<const uint2*>(&lds16[rr * 132 + cs + q2 * 8]);
      uint2 x1 = *reinterpret_cast<const uint2*>(&lds16[rr * 132 + cs + q2 * 8 + 4]);
      uint4 blv = *reinterpret_cast<const uint4*>(hwold + (size_t)m * 128 + cs + q2 * 8);
      uint2 y0, y1;
      y0.x = blend2(x0.x, blv.x, aa); y0.y = blend2(x0.y, blv.y, aa);
      y1.x = blend2(x1.x, blv.z, aa); y1.y = blend2(x1.y, blv.w, aa);
      *reinterpret_cast<uint2*>(&lds16[rr * 132 + cs + q2 * 8])     = y0;
      *reinterpret_cast<uint2*>(&lds16[rr * 132 + cs + q2 * 8 + 4]) = y1;
    }
  }
  __syncthreads();
  bf16x8 an[4];
  {
    const int rloc = w * 16 + (lane & 15);
    #pragma unroll
    for (int s = 0; s < 4; ++s)
      an[s] = *reinterpret_cast<const bf16x8*>(&lds16[rloc * 132 + s * 32 + g * 8]);
  }
  // k
  #pragma unroll
  for (int t = 0; t < 8; ++t) acc[t] = (f32x4)0.f;
  GEMM_ACC(an, BLk)
  __syncthreads();
  ACC_TO_LDS(bk)
  __syncthreads();
  if (m < n) kv_write_half(lds16, rr, cs, kv, m, 0);
  // v
  #pragma unroll
  for (int t = 0; t < 8; ++t) acc[t] = (f32x4)0.f;
  GEMM_ACC(an, BLv)
  __syncthreads();
  ACC_TO_LDS(bv)
  __syncthreads();
  if (m < n) kv_write_half(lds16, rr, cs, kv, m, 1);
}

// ======================= misc small kernels =======================
__global__ void conv_wtab_kernel(const float* __restrict__ we, u16* __restrict__ wt) {
  int i = blockIdx.x * 256 + threadIdx.x;
  if (i < VOCAB * 320) {
    int r = i / 320, c = i - r * 320;
    wt[i] = (c < 300) ? f2bf(we[(size_t)r * 300 + c]) : (u16)0;
  }
}

__global__ void gather_topic_kernel(const float* __restrict__ emb, const int* __restrict__ ids,
                                    u16* __restrict__ out) {
  int i = blockIdx.x * 256 + threadIdx.x;
  if (i < N_TOPIC * 128) {
    int node = i >> 7, c = i & 127;
    out[i] = f2bf(emb[(size_t)ids[node] * 128 + c]);
  }
}

// ======================= CSR build =======================
__global__ void count_all_kernel(const int* __restrict__ td, const int* __restrict__ wd,
                                 const int* __restrict__ tt, const int* __restrict__ wt,
                                 const int* __restrict__ ww, int* cnt) {
  int i = blockIdx.x * 256 + threadIdx.x;
  if (i >= EDGES_ALL) return;
  int b;
  if (i < 80000)       b = td[i];
  else if (i < 330000) b = 32000 + wd[i - 80000];
  else if (i < 350000) b = 64000 + tt[i - 330000];
  else if (i < 450000) b = 64800 + wt[i - 350000];
  else                 b = 65600 + ww[i - 450000];
  atomicAdd(&cnt[b], 1);
}

__global__ void fill_all_kernel(const int* __restrict__ td_s, const int* __restrict__ td_d,
                                const int* __restrict__ wd_s, const int* __restrict__ wd_d,
                                const int* __restrict__ tt_s, const int* __restrict__ tt_d,
                                const int* __restrict__ wt_s, const int* __restrict__ wt_d,
                                const int* __restrict__ ww_s, const int* __restrict__ ww_d,
                                int* cursor, int* csrc) {
  int i = blockIdx.x * 256 + threadIdx.x;
  if (i >= EDGES_ALL) return;
  int b, s;
  if (i < 80000)       { b = td_d[i];                  s = td_s[i]; }
  else if (i < 330000) { b = 32000 + wd_d[i - 80000];  s = wd_s[i - 80000]; }
  else if (i < 350000) { b = 64000 + tt_d[i - 330000]; s = tt_s[i - 330000]; }
  else if (i < 450000) { b = 64800 + wt_d[i - 350000]; s = wt_s[i - 350000]; }
  else                 { b = 65600 + ww_d[i - 450000]; s = ww_s[i - 450000]; }
  int p = atomicAdd(&cursor[b], 1);
  csrc[p] = s;
}

__global__ __launch_bounds__(256) void scanA_kernel(const int* __restrict__ cnt, int* __restrict__ bsum) {
  const int tid = threadIdx.x, lane = tid & 63, wv = tid >> 6;
  const int i4 = blockIdx.x * 256 + tid;
  int4 v = make_int4(0, 0, 0, 0);
  if (i4 < N4_SCAN) v = reinterpret_cast<const int4*>(cnt)[i4];
  int s = v.x + v.y + v.z + v.w;
  #pragma unroll
  for (int d = 1; d < 64; d <<= 1) s += __shfl_xor(s, d);
  __shared__ int ws[4];
  if (lane == 0) ws[wv] = s;
  __syncthreads();
  if (tid == 0) bsum[blockIdx.x] = ws[0] + ws[1] + ws[2] + ws[3];
}

__global__ __launch_bounds__(256) void scanB_kernel(const int* __restrict__ bsum,
                                                    int* __restrict__ bpre, int* __restrict__ offs) {
  const int tid = threadIdx.x, lane = tid & 63, wv = tid >> 6;
  int v = (tid < NBLK_SCAN) ? bsum[tid] : 0;
  int incl = wave_iscan(v, lane);
  __shared__ int ws[4];
  if (lane == 63) ws[wv] = incl;
  __syncthreads();
  int pre = 0;
  for (int j = 0; j < 4; ++j) if (j < wv) pre += ws[j];
  incl += pre;
  if (tid < NBLK_SCAN) bpre[tid] = incl - v;
  if (tid == NBLK_SCAN - 1) offs[NODES_ALL] = incl;
}

__global__ __launch_bounds__(256) void scanC_kernel(const int* __restrict__ cnt,
                                                    const int* __restrict__ bpre,
                                                    int* __restrict__ offs, int* __restrict__ cursor) {
  const int tid = threadIdx.x, lane = tid & 63, wv = tid >> 6;
  const int i4 = blockIdx.x * 256 + tid;
  int4 v = make_int4(0, 0, 0, 0);
  if (i4 < N4_SCAN) v = reinterpret_cast<const int4*>(cnt)[i4];
  const int tsum = v.x + v.y + v.z + v.w;
  int incl = wave_iscan(tsum, lane);
  __shared__ int ws[4];
  if (lane == 63) ws[wv] = incl;
  __syncthreads();
  int pre = bpre[blockIdx.x];
  for (int j = 0; j < 4; ++j) if (j < wv) pre += ws[j];
  int o0 = pre + incl - tsum;
  if (i4 < N4_SCAN) {
    int4 ov = make_int4(o0, o0 + v.x, o0 + v.x + v.y, o0 + v.x + v.y + v.z);
    reinterpret_cast<int4*>(offs)[i4] = ov;
    reinterpret_cast<int4*>(cursor)[i4] = ov;
  }
}

// ======================= aggregation =======================
struct AggArgs {
  const u16 *q_td, *q_wd, *q_tt, *q_wt, *q_ww;
  const u8 *kv_t, *kv_w, *vp_t, *vp_w;
  const float *uf_t, *uf_w;
  const int *csrc, *offs;
  const float *pri;
  u16 *t2_d, *t2_t, *t_w;
};

static __device__ __forceinline__ void butterfly4(
    f32x2 acc0, f32x2 acc1, f32x2 acc2, f32x2 acc3, float ss,
    int lane, f32x2& red, float& ss_out)
{
  ss += __shfl_xor(ss, 16); ss += __shfl_xor(ss, 32);
  const bool h16 = (lane & 16) != 0, h32 = (lane & 32) != 0;
  f32x2 k0 = h16 ? acc2 : acc0;
  f32x2 k1 = h16 ? acc3 : acc1;
  f32x2 s0 = h16 ? acc0 : acc2;
  f32x2 s1 = h16 ? acc1 : acc3;
  k0[0] += __shfl_xor(s0[0], 16); k0[1] += __shfl_xor(s0[1], 16);
  k1[0] += __shfl_xor(s1[0], 16); k1[1] += __shfl_xor(s1[1], 16);
  f32x2 kk = h32 ? k1 : k0;
  f32x2 sd = h32 ? k0 : k1;
  kk[0] += __shfl_xor(sd[0], 32); kk[1] += __shfl_xor(sd[1], 32);
  red = kk; ss_out = ss;
}

// full q.k attention path (16 lanes/edge, interleaved kv, unroll 2)
static __device__ __forceinline__ void agg_core(
    const u16* __restrict__ q, const u8* __restrict__ kv,
    const int* __restrict__ offs, const int* __restrict__ csrc,
    const float* __restrict__ pri,
    int node, int grp, int stride, int sl, int lane,
    f32x2& red, float& ss_out)
{
  const int e0 = offs[node], e1 = offs[node + 1];
  f32x2 acc0 = (f32x2)0.f, acc1 = (f32x2)0.f, acc2 = (f32x2)0.f, acc3 = (f32x2)0.f;
  float ss = 0.f;
  if (e1 > e0) {
    const float prih = pri[sl >> 2] * 0.17677669529663687f;
    const bf16x8 qv = *reinterpret_cast<const bf16x8*>(q + (size_t)node * 128 + sl * 8);
    f32x2 q2[4];
    #pragma unroll
    for (int p = 0; p < 4; ++p) {
      f32x2 t; t[0] = b2f((u16)qv[2 * p]); t[1] = b2f((u16)qv[2 * p + 1]); q2[p] = t;
    }
    const int last = e1 - 1;
    for (int base = e0; base < e1; base += 2 * stride) {
      const int eA = base + grp, eB = base + stride + grp;
      const bool vA = eA < e1, vB = eB < e1;
      const int sA = csrc[vA ? eA : last];
      const int sB = csrc[vB ? eB : last];
      const uint4 cA = *reinterpret_cast<const uint4*>(kv + (size_t)sA * 256 + sl * 16);
      const uint4 cB = *reinterpret_cast<const uint4*>(kv + (size_t)sB * 256 + sl * 16);
      f32x2 dA = q2[0] * cvt8<false>((int)cA.x);
      dA += q2[1] * cvt8<true>((int)cA.x);
      dA += q2[2] * cvt8<false>((int)cA.y);
      dA += q2[3] * cvt8<true>((int)cA.y);
      f32x2 dB = q2[0] * cvt8<false>((int)cB.x);
      dB += q2[1] * cvt8<true>((int)cB.x);
      dB += q2[2] * cvt8<false>((int)cB.y);
      dB += q2[3] * cvt8<true>((int)cB.y);
      float dotA = dA[0] + dA[1];
      float dotB = dB[0] + dB[1];
      dotA += __shfl_xor(dotA, 1); dotA += __shfl_xor(dotA, 2);
      dotB += __shfl_xor(dotB, 1); dotB += __shfl_xor(dotB, 2);
      const float wA = vA ? __expf(dotA * prih) : 0.f;
      const float wB = vB ? __expf(dotB * prih) : 0.f;
      ss += wA + wB;
      f32x2 wA2; wA2[0] = wA; wA2[1] = wA;
      f32x2 wB2; wB2[0] = wB; wB2[1] = wB;
      acc0 += wA2 * cvt8<false>((int)cA.z);
      acc1 += wA2 * cvt8<true>((int)cA.z);
      acc2 += wA2 * cvt8<false>((int)cA.w);
      acc3 += wA2 * cvt8<true>((int)cA.w);
      acc0 += wB2 * cvt8<false>((int)cB.z);
      acc1 += wB2 * cvt8<true>((int)cB.z);
      acc2 += wB2 * cvt8<false>((int)cB.w);
      acc3 += wB2 * cvt8<true>((int)cB.w);
    }
  }
  butterfly4(acc0, acc1, acc2, acc3, ss, lane, red, ss_out);
}

// L0-doc path: precomputed u (source-only attention) + pre-weighted vp: plain gather-sum
static __device__ __forceinline__ void agg_docu(
    const u8* __restrict__ vp, const float* __restrict__ uf,
    const int* __restrict__ offs, const int* __restrict__ csrc,
    int node, int sub, int sl, int lane,
    f32x2& red, float& ss_out)
{
  const int e0 = offs[node], e1 = offs[node + 1];
  f32x2 acc0 = (f32x2)0.f, acc1 = (f32x2)0.f, acc2 = (f32x2)0.f, acc3 = (f32x2)0.f;
  float ss = 0.f;
  if (e1 > e0) {
    const int h = sl >> 2;
    const int last = e1 - 1;
    for (int base = e0; base < e1; base += 8) {
      const int eA = base + sub, eB = base + 4 + sub;
      const bool vA = eA < e1, vB = eB < e1;
      const int sA = csrc[vA ? eA : last];
      const int sB = csrc[vB ? eB : last];
      uint2 cA = *reinterpret_cast<const uint2*>(vp + (size_t)sA * 128 + sl * 8);
      uint2 cB = *reinterpret_cast<const uint2*>(vp + (size_t)sB * 128 + sl * 8);
      float uA = uf[sA * 4 + h];
      float uB = uf[sB * 4 + h];
      if (!vA) { cA = make_uint2(0u, 0u); uA = 0.f; }
      if (!vB) { cB = make_uint2(0u, 0u); uB = 0.f; }
      ss += uA + uB;
      acc0 += cvt8<false>((int)cA.x); acc1 += cvt8<true>((int)cA.x);
      acc2 += cvt8<false>((int)cA.y); acc3 += cvt8<true>((int)cA.y);
      acc0 += cvt8<false>((int)cB.x); acc1 += cvt8<true>((int)cB.x);
      acc2 += cvt8<false>((int)cB.y); acc3 += cvt8<true>((int)cB.y);
    }
  }
  butterfly4(acc0, acc1, acc2, acc3, ss, lane, red, ss_out);
}

static __device__ __forceinline__ int chbase_of(int lane) {
  return (lane & 15) * 8 + ((lane >> 4) & 1) * 4 + ((lane >> 5) & 1) * 2;
}

// DOCU=1 (layer 0): doc branch uses precomputed-u gather; DOCU=0 (layer 1): q.k path.
// grid L0: [0,800) topic; [800,8800) doc; [8800,28800) word. grid L1: 8000 doc.
template<int DOCU>
__global__ __launch_bounds__(256) void agg_all_kernel(AggArgs A, int topic_n)
{
  __shared__ float lacc[4][128];
  __shared__ float lssA[4];
  const int tid = threadIdx.x, lane = tid & 63, wv = tid >> 6;
  const int sub = lane >> 4, sl = lane & 15;
  const int bid = blockIdx.x;
  const int chb = chbase_of(lane);
  f32x2 red; float ss;

  if (bid < topic_n) {
    const int node = bid;
    for (int r = 0; r < 2; ++r) {
      agg_core(r ? A.q_wt : A.q_tt, r ? A.kv_w : A.kv_t,
               A.offs + (r ? 64800 : 64000), A.csrc, A.pri + (r ? 12 : 4),
               node, wv * 4 + sub, 16, sl, lane, red, ss);
      lacc[wv][chb] = red[0]; lacc[wv][chb + 1] = red[1];
      if (lane == 0) lssA[wv] = ss;
      __syncthreads();
      if (tid < 128) {
        float a = lacc[0][tid] + lacc[1][tid] + lacc[2][tid] + lacc[3][tid];
        float st = lssA[0] + lssA[1] + lssA[2] + lssA[3];
        float inv = (st > 0.f) ? 1.f / st : 0.f;
        A.t2_t[(size_t)node * 256 + r * 128 + tid] = f2bf(a * inv);
      }
      __syncthreads();
    }
  } else if (bid < topic_n + 8000) {
    const int node = (bid - topic_n) * 4 + wv;
    if (DOCU) {
      agg_docu(A.vp_t, A.uf_t, A.offs + 0, A.csrc, node, sub, sl, lane, red, ss);
    } else {
      agg_core(A.q_td, A.kv_t, A.offs + 0, A.csrc, A.pri + 0, node, sub, 4, sl, lane, red, ss);
    }
    {
      float inv = (ss > 0.f) ? 1.f / ss : 0.f;
      unsigned pk = (unsigned)f2bf(red[0] * inv) | ((unsigned)f2bf(red[1] * inv) << 16);
      *reinterpret_cast<unsigned*>(A.t2_d + (size_t)node * 256 + chb) = pk;
    }
    if (DOCU) {
      agg_docu(A.vp_w, A.uf_w, A.offs + 32000, A.csrc, node, sub, sl, lane, red, ss);
    } else {
      agg_core(A.q_wd, A.kv_w, A.offs + 32000, A.csrc, A.pri + 8, node, sub, 4, sl, lane, red, ss);
    }
    {
      float inv = (ss > 0.f) ? 1.f / ss : 0.f;
      unsigned pk = (unsigned)f2bf(red[0] * inv) | ((unsigned)f2bf(red[1] * inv) << 16);
      *reinterpret_cast<unsigned*>(A.t2_d + (size_t)node * 256 + 128 + chb) = pk;
    }
  } else {
    const int node = (bid - topic_n - 8000) * 4 + wv;
    agg_core(A.q_ww, A.kv_w, A.offs + 65600, A.csrc, A.pri + 16, node, sub, 4, sl, lane, red, ss);
    float inv = (ss > 0.f) ? 1.f / ss : 0.f;
    unsigned pk = (unsigned)f2bf(red[0] * inv) | ((unsigned)f2bf(red[1] * inv) << 16);
    *reinterpret_cast<unsigned*>(A.t_w + (size_t)node * 128 + chb) = pk;
  }
}

// ======================= readout =======================
__global__ void ginit_kernel(unsigned* g) {
  int i = blockIdx.x * 256 + threadIdx.x;
  if (i < BATCH * H_DIM) g[i] = 0x007FFFFFu;
}

__global__ void segmax_kernel(const u16* __restrict__ hd, const int* __restrict__ gid,
                              unsigned* g) {
  int c = threadIdx.x;
  int d0 = blockIdx.x * 128;
  int dend = min(d0 + 128, N_DOC);
  int cur = -1; float m = 0.f;
  for (int d = d0; d < dend; ++d) {
    int gg = gid[d];
    float v = b2f(hd[(size_t)d * 128 + c]);
    if (gg != cur) {
      if (cur >= 0) atomicMax(&g[cur * 128 + c], fenc(m));
      cur = gg; m = v;
    } else {
      m = fmaxf(m, v);
    }
  }
  if (cur >= 0) atomicMax(&g[cur * 128 + c], fenc(m));
}

__global__ void final_kernel(const unsigned* __restrict__ g, const float* __restrict__ out_w,
                             const float* __restrict__ out_b, const float* __restrict__ y,
                             float* out) {
  int tid = threadIdx.x;
  int b = tid >> 4, seg = tid & 15;
  float p = 0.f;
  #pragma unroll
  for (int j = 0; j < 8; ++j) {
    int c = seg * 8 + j;
    p += fdec(g[b * 128 + c]) * out_w[c];
  }
  p += __shfl_xor(p, 1);
  p += __shfl_xor(p, 2);
  p += __shfl_xor(p, 4);
  p += __shfl_xor(p, 8);
  __shared__ float logits[BATCH];
  __shared__ float losses[BATCH];
  if (seg == 0) logits[b] = p + out_b[0];
  __syncthreads();
  if (tid < BATCH) {
    float l = logits[tid];
    out[1 + tid] = 1.f / (1.f + expf(-l));
    float ls_pos = (l > 0.f) ? -log1pf(expf(-l)) : l - log1pf(expf(l));
    float ls_neg = (l < 0.f) ? -log1pf(expf(l)) : -l - log1pf(expf(-l));
    losses[tid] = -(y[tid] * ls_pos + (1.f - y[tid]) * ls_neg);
  }
  __syncthreads();
  if (tid == 0) {
    float s = 0.f;
    for (int j = 0; j < BATCH; ++j) s += losses[j];
    out[0] = s / (float)BATCH;
  }
}

// ======================= host =======================
extern "C" void kernel_launch(void* const* d_in, const int* in_sizes, int n_in,
                              void* d_out, int out_size, void* d_ws, size_t ws_size,
                              hipStream_t stream)
{
  const float* word_embeds  = (const float*)d_in[0];
  const float* topic_embeds = (const float*)d_in[1];
  const float* KW  = (const float*)d_in[2];
  const float* Kb  = (const float*)d_in[3];
  const float* QW  = (const float*)d_in[4];
  const float* Qb  = (const float*)d_in[5];
  const float* VW  = (const float*)d_in[6];
  const float* Vb  = (const float*)d_in[7];
  const float* AW  = (const float*)d_in[8];
  const float* Ab  = (const float*)d_in[9];
  const float* rel_att = (const float*)d_in[10];
  const float* rel_msg = (const float*)d_in[11];
  const float* rel_pri = (const float*)d_in[12];
  const float* skip    = (const float*)d_in[13];
  const float* adapt_w = (const float*)d_in[14];
  const float* adapt_b = (const float*)d_in[15];
  const float* out_w   = (const float*)d_in[16];
  const float* out_b   = (const float*)d_in[17];
  const float* y_data  = (const float*)d_in[18];
  const int* word_ids  = (const int*)d_in[19];
  const int* topic_ids = (const int*)d_in[20];
  const int* doc_gid   = (const int*)d_in[21];
  const int* td_src = (const int*)d_in[22];
  const int* td_dst = (const int*)d_in[23];
  const int* tt_src = (const int*)d_in[24];
  const int* tt_dst = (const int*)d_in[25];
  const int* wd_src = (const int*)d_in[26];
  const int* wd_dst = (const int*)d_in[27];
  const int* wt_src = (const int*)d_in[28];
  const int* wt_dst = (const int*)d_in[29];
  const int* ww_src = (const int*)d_in[30];
  const int* ww_dst = (const int*)d_in[31];

  char* base = (char*)d_ws;
  size_t off_b = 0;
  auto alloc = [&](size_t bytes) -> char* {
    char* p = base + off_b;
    off_b = (off_b + bytes + 255) & ~(size_t)255;
    return p;
  };

  u16* wtab = (u16*)alloc((size_t)VOCAB * 320 * 2);
  u16* hw   = (u16*)alloc((size_t)N_WORD * 128 * 2);
  u16* hd   = (u16*)alloc((size_t)N_DOC * 128 * 2);
  u16* ht   = (u16*)alloc((size_t)N_TOPIC * 128 * 2);
  u8*  kv_w = (u8*)alloc((size_t)N_WORD * 256);
  u8*  kv_t = (u8*)alloc((size_t)N_TOPIC * 256);
  u8*  vp_w = (u8*)alloc((size_t)N_WORD * 128);
  u8*  vp_t = (u8*)alloc((size_t)N_TOPIC * 128);
  float* uf_w = (float*)alloc((size_t)N_WORD * 4 * 4);
  float* uf_t = (float*)alloc((size_t)N_TOPIC * 4 * 4);
  u16* q_td = (u16*)alloc((size_t)N_DOC * 128 * 2);
  u16* q_wd = (u16*)alloc((size_t)N_DOC * 128 * 2);
  u16* q_tt = (u16*)alloc((size_t)N_TOPIC * 128 * 2);
  u16* q_wt = (u16*)alloc((size_t)N_TOPIC * 128 * 2);
  u16* q_ww = (u16*)alloc((size_t)N_WORD * 128 * 2);
  u16* t2_d = (u16*)alloc((size_t)N_DOC * 256 * 2);
  u16* t2_t = (u16*)alloc((size_t)N_TOPIC * 256 * 2);
  u16* t_w  = (u16*)alloc((size_t)N_WORD * 128 * 2);
  unsigned* g = (unsigned*)alloc((size_t)BATCH * 128 * 4);

  int* cnt_all  = (int*)alloc((size_t)NODES_ALL * 4);
  int* offs_all = (int*)alloc(((size_t)NODES_ALL + 1) * 4);
  int* csrc_all = (int*)alloc((size_t)EDGES_ALL * 4);
  int* bsum     = (int*)alloc((size_t)NBLK_SCAN * 4);
  int* bpre     = (int*)alloc((size_t)NBLK_SCAN * 4);

  u16* blw        = (u16*)alloc((size_t)(40960 + 28 * 16384) * 2);
  float* bias_are = (float*)alloc((size_t)29 * 128 * 4);

  auto BLp = [&](int wid) -> const u16* {
    return (wid == 0) ? blw : blw + 40960 + (size_t)(wid - 1) * 16384;
  };
  auto BIp = [&](int wid) -> const float* { return bias_are + wid * 128; };
  auto WID = [&](int li, int j) { return 1 + li * 14 + j; };

  // ---- prep ----
  prep_kernel<<<29 * 8, 256, 0, stream>>>(KW, Kb, QW, Qb, VW, Vb, AW, Ab,
                                          rel_att, rel_msg, adapt_w, adapt_b, blw, bias_are);
  conv_wtab_kernel<<<(VOCAB * 320 + 255) / 256, 256, 0, stream>>>(word_embeds, wtab);
  gather_topic_kernel<<<(N_TOPIC * 128 + 255) / 256, 256, 0, stream>>>(topic_embeds, topic_ids, ht);

  hipMemsetAsync(cnt_all, 0, (size_t)NODES_ALL * 4, stream);
  count_all_kernel<<<(EDGES_ALL + 255) / 256, 256, 0, stream>>>(td_dst, wd_dst, tt_dst, wt_dst, ww_dst, cnt_all);
  scanA_kernel<<<NBLK_SCAN, 256, 0, stream>>>(cnt_all, bsum);
  scanB_kernel<<<1, 256, 0, stream>>>(bsum, bpre, offs_all);
  scanC_kernel<<<NBLK_SCAN, 256, 0, stream>>>(cnt_all, bpre, offs_all, cnt_all);
  fill_all_kernel<<<(EDGES_ALL + 255) / 256, 256, 0, stream>>>(
      td_src, td_dst, wd_src, wd_dst, tt_src, tt_dst, wt_src, wt_dst, ww_src, ww_dst,
      cnt_all, csrc_all);

  // ---- adapt ----
  gemm_kernel<10, 1><<<(N_WORD + 63) / 64, 256, 0, stream>>>(
      wtab, 320, word_ids, BLp(0), BIp(0), hw, N_WORD);

  const int GW = (N_WORD + 63) / 64, GD = (N_DOC + 63) / 64, GT = (N_TOPIC + 63) / 64;

  // ================= layer 0 =================
  gemmN_l0w_kernel<<<GW, 256, 0, stream>>>(
      hw,
      BLp(WID(0, 1)), BIp(WID(0, 1)),   // k_w
      BLp(WID(0, 3)), BIp(WID(0, 3)),   // v_w
      BLp(WID(0, 8)), BIp(WID(0, 8)),   // q_ww
      BIp(WID(0, 6)),                   // q_wd const (bias fold)
      rel_pri + 8,                      // pri wd, layer 0
      kv_w, vp_w, uf_w, q_ww, N_WORD);
  gemmN_l0t_kernel<<<GT, 256, 0, stream>>>(
      ht,
      BLp(WID(0, 0)), BIp(WID(0, 0)),   // k_t
      BLp(WID(0, 2)), BIp(WID(0, 2)),   // v_t
      BLp(WID(0, 5)), BIp(WID(0, 5)),   // q_tt
      BLp(WID(0, 7)), BIp(WID(0, 7)),   // q_wt
      BIp(WID(0, 4)),                   // q_td const
      rel_pri + 0,                      // pri td, layer 0
      kv_t, vp_t, uf_t, q_tt, q_wt, N_TOPIC);

  AggArgs A0;
  A0.q_td = q_td; A0.q_wd = q_wd; A0.q_tt = q_tt; A0.q_wt = q_wt; A0.q_ww = q_ww;
  A0.kv_t = kv_t; A0.kv_w = kv_w; A0.vp_t = vp_t; A0.vp_w = vp_w;
  A0.uf_t = uf_t; A0.uf_w = uf_w;
  A0.csrc = csrc_all; A0.offs = offs_all;
  A0.pri = rel_pri;
  A0.t2_d = t2_d; A0.t2_t = t2_t; A0.t_w = t_w;
  agg_all_kernel<1><<<28800, 256, 0, stream>>>(A0, 800);

  // comb_d(L0, hd=0) fused with L1 doc q projections
  comb_dq_kernel<<<GD, 256, 0, stream>>>(
      t2_d, BLp(WID(0, 9)), BLp(WID(0, 11)), BIp(WID(0, 9)), skip + 0,
      BLp(WID(1, 4)), BIp(WID(1, 4)), BLp(WID(1, 6)), BIp(WID(1, 6)),
      hd, q_td, q_wd, N_DOC);
  // comb_t(L0)
  gemm2_kernel<4><<<GT, 256, 0, stream>>>(t2_t, BLp(WID(0, 10)), BLp(WID(0, 12)),
                                          BIp(WID(0, 10)), ht, skip + 1, N_TOPIC);
  // comb_w(L0) fused with L1 word k/v (hw_new stays in LDS)
  comb_kv_kernel<<<GW, 256, 0, stream>>>(
      t_w, hw, BLp(WID(0, 13)), BIp(WID(0, 13)),
      BLp(WID(1, 1)), BIp(WID(1, 1)), BLp(WID(1, 3)), BIp(WID(1, 3)),
      skip + 2, kv_w, N_WORD);

  // ================= layer 1 (docs only live) =================
  gemm_kv_kernel<<<GT, 256, 0, stream>>>(
      ht, BLp(WID(1, 0)), BIp(WID(1, 0)), BLp(WID(1, 2)), BIp(WID(1, 2)), kv_t, N_TOPIC);

  AggArgs A1 = A0;
  A1.pri = rel_pri + 20;
  agg_all_kernel<0><<<8000, 256, 0, stream>>>(A1, 0);

  gemm2_kernel<4><<<GD, 256, 0, stream>>>(t2_d, BLp(WID(1, 9)), BLp(WID(1, 11)),
                                          BIp(WID(1, 9)), hd, skip + 3, N_DOC);

  // ---- readout ----
  ginit_kernel<<<(BATCH * 128 + 255) / 256, 256, 0, stream>>>(g);
  segmax_kernel<<<(N_DOC + 127) / 128, 128, 0, stream>>>(hd, doc_gid, g);
  final_kernel<<<1, 256, 0, stream>>>(g, out_w, out_b, y_data, (float*)d_out);
}

// Round 9
// 378.349 us; speedup vs baseline: 12.2513x; 1.1374x over previous
//
#include <hip/hip_runtime.h>
#include <cstdint>
#include <cstddef>

#define H_DIM 128
#define N_DOC 32000
#define N_TOPIC 800
#define N_WORD 80000
#define BATCH 16
#define VOCAB 15000
#define NODES_ALL 145600
#define EDGES_ALL 850000
#define NBLK_SCAN 143
#define N4_SCAN 36400

typedef short bf16x8 __attribute__((ext_vector_type(8)));
typedef float f32x4 __attribute__((ext_vector_type(4)));
typedef float f32x2 __attribute__((ext_vector_type(2)));
typedef unsigned short u16;
typedef unsigned char u8;

static __device__ __forceinline__ u16 f2bf(float x) {
  unsigned u = __float_as_uint(x);
  u += 0x7fffu + ((u >> 16) & 1u);
  return (u16)(u >> 16);
}
static __device__ __forceinline__ float b2f(unsigned h) {
  return __uint_as_float(h << 16);
}
static __device__ __forceinline__ unsigned fenc(float f) {
  unsigned u = __float_as_uint(f);
  return (u & 0x80000000u) ? ~u : (u | 0x80000000u);
}
static __device__ __forceinline__ float fdec(unsigned k) {
  return (k & 0x80000000u) ? __uint_as_float(k ^ 0x80000000u) : __uint_as_float(~k);
}
static __device__ __forceinline__ int wave_iscan(int v, int lane) {
  #pragma unroll
  for (int d = 1; d < 64; d <<= 1) {
    int t = __shfl_up(v, d);
    if (lane >= d) v += t;
  }
  return v;
}
static __device__ __forceinline__ unsigned blend2(unsigned pr, unsigned bl, float aa) {
  float v0 = b2f(pr & 0xffffu) * aa + b2f(bl & 0xffffu) * (1.f - aa);
  float v1 = b2f(pr >> 16) * aa + b2f(bl >> 16) * (1.f - aa);
  return (unsigned)f2bf(v0) | ((unsigned)f2bf(v1) << 16);
}
template<bool HI>
static __device__ __forceinline__ f32x2 cvt8(int w) {
  return __builtin_amdgcn_cvt_pk_f32_fp8(w, HI);
}

// ======================= weight prep =======================
__global__ __launch_bounds__(256) void prep_kernel(
    const float* __restrict__ KW, const float* __restrict__ Kb,
    const float* __restrict__ QW, const float* __restrict__ Qb,
    const float* __restrict__ VW, const float* __restrict__ Vb,
    const float* __restrict__ AW, const float* __restrict__ Ab,
    const float* __restrict__ rel_att, const float* __restrict__ rel_msg,
    const float* __restrict__ adapt_w, const float* __restrict__ adapt_b,
    u16* __restrict__ bl_arena, float* __restrict__ bias_arena)
{
  const int wid = blockIdx.x >> 3, t = blockIdx.x & 7;
  int KS, Kreal, fold;
  const float *W, *b, *R = nullptr;
  float scale = 1.f;
  if (wid == 0) { KS = 10; Kreal = 300; fold = 0; W = adapt_w; b = adapt_b; }
  else {
    KS = 4; Kreal = 128;
    const int wl = wid - 1, li = wl / 14, j = wl % 14;
    const int dstnid[5] = {0, 1, 0, 1, 2};
    if (j < 4) {
      fold = 0;
      const float* Wb = (j < 2) ? KW : VW;
      const float* bb = (j < 2) ? Kb : Vb;
      const int nid = (j & 1) ? 2 : 1;
      W = Wb + ((size_t)li * 3 + nid) * 16384; b = bb + ((size_t)li * 3 + nid) * 128;
    } else if (j < 9) {
      fold = 1; const int r = j - 4; const int nid = dstnid[r];
      W = QW + ((size_t)li * 3 + nid) * 16384; b = Qb + ((size_t)li * 3 + nid) * 128;
      R = rel_att + ((size_t)li * 5 + r) * 4096;
    } else {
      fold = 3; const int r = j - 9; const int nid = dstnid[r];
      W = AW + ((size_t)li * 3 + nid) * 16384; b = Ab + ((size_t)li * 3 + nid) * 128;
      R = rel_msg + ((size_t)li * 5 + r) * 4096;
      scale = (r == 4) ? 1.f : 0.5f;
    }
  }
  u16* obl = (wid == 0) ? bl_arena : bl_arena + 40960 + (size_t)(wid - 1) * 16384;
  float* obias = bias_arena + wid * 128;

  const int nelem = KS * 512;
  for (int e = threadIdx.x; e < nelem; e += 256) {
    const int s = e >> 9, rem = e & 511, l = rem >> 3, jj = rem & 7;
    const int k = s * 32 + ((l >> 4) << 3) + jj;
    const int nn = t * 16 + (l & 15);
    float v = 0.f;
    if (k < Kreal) {
      if (fold == 0) v = W[(size_t)k * 128 + nn];
      else if (fold == 1) {
        const int h = nn >> 5, d = nn & 31;
        const float* Wr = W + (size_t)k * 128 + h * 32;
        const float* Rh = R + h * 1024;
        for (int f = 0; f < 32; ++f) v += Wr[f] * Rh[d * 32 + f];
      } else {
        const int h = k >> 5, dd = k & 31;
        const float* Rh = R + h * 1024 + dd * 32;
        const float* Wc = W + (size_t)h * 32 * 128 + nn;
        float sa = 0.f;
        for (int f = 0; f < 32; ++f) sa += Rh[f] * Wc[(size_t)f * 128];
        v = sa * scale;
      }
    }
    obl[(size_t)(t * KS + s) * 512 + rem] = f2bf(v);
  }
  if (t == 0 && threadIdx.x < 128) {
    const int nn = threadIdx.x;
    float v = 0.f;
    if (fold != 1) v = b[nn];
    else {
      const int h = nn >> 5, d = nn & 31;
      const float* Rh = R + h * 1024;
      for (int f = 0; f < 32; ++f) v += b[h * 32 + f] * Rh[d * 32 + f];
    }
    obias[nn] = v;
  }
}

// ======================= GEMM helpers =======================
static __device__ __forceinline__ void kv_write_half(
    const u16* lds16, int rr, int cs, u8* kv, size_t m, int vhalf)
{
  u8* Cp = kv + m * 256 + (cs >> 3) * 16 + (vhalf ? 8 : 0);
  #pragma unroll
  for (int q2 = 0; q2 < 4; ++q2) {
    unsigned w0, w1;
    {
      float f0 = b2f(lds16[rr * 132 + cs + q2 * 8 + 0]);
      float f1 = b2f(lds16[rr * 132 + cs + q2 * 8 + 1]);
      float f2 = b2f(lds16[rr * 132 + cs + q2 * 8 + 2]);
      float f3 = b2f(lds16[rr * 132 + cs + q2 * 8 + 3]);
      int t0 = __builtin_amdgcn_cvt_pk_fp8_f32(f0, f1, 0, false);
      w0 = (unsigned)__builtin_amdgcn_cvt_pk_fp8_f32(f2, f3, t0, true);
    }
    {
      float f0 = b2f(lds16[rr * 132 + cs + q2 * 8 + 4]);
      float f1 = b2f(lds16[rr * 132 + cs + q2 * 8 + 5]);
      float f2 = b2f(lds16[rr * 132 + cs + q2 * 8 + 6]);
      float f3 = b2f(lds16[rr * 132 + cs + q2 * 8 + 7]);
      int t0 = __builtin_amdgcn_cvt_pk_fp8_f32(f0, f1, 0, false);
      w1 = (unsigned)__builtin_amdgcn_cvt_pk_fp8_f32(f2, f3, t0, true);
    }
    *reinterpret_cast<uint2*>(Cp + q2 * 16) = make_uint2(w0, w1);
  }
}

static __device__ __forceinline__ void bf16_write_row(
    const u16* lds16, int rr, int cs, u16* C, size_t m)
{
  u16* Cp = C + m * 128 + cs;
  #pragma unroll
  for (int q2 = 0; q2 < 4; ++q2) {
    uint2 x0 = *reinterpret_cast<const uint2*>(&lds16[rr * 132 + cs + q2 * 8]);
    uint2 x1 = *reinterpret_cast<const uint2*>(&lds16[rr * 132 + cs + q2 * 8 + 4]);
    uint4 st; st.x = x0.x; st.y = x0.y; st.z = x1.x; st.w = x1.y;
    *reinterpret_cast<uint4*>(Cp + q2 * 8) = st;
  }
}

#define GEMM_ACC(AV, BLP)                                                        \
  {                                                                              \
    const u16* Bp = (BLP) + (size_t)lane * 8;                                    \
    _Pragma("unroll")                                                            \
    for (int s = 0; s < 4; ++s) {                                                \
      _Pragma("unroll")                                                          \
      for (int t = 0; t < 8; ++t) {                                              \
        bf16x8 bfr = *reinterpret_cast<const bf16x8*>(Bp + (size_t)(t * 4 + s) * 512); \
        acc[t] = __builtin_amdgcn_mfma_f32_16x16x32_bf16(AV[s], bfr, acc[t], 0, 0, 0); \
      }                                                                          \
    }                                                                            \
  }

#define ACC_TO_LDS(BIAS)                                                         \
  {                                                                              \
    _Pragma("unroll")                                                            \
    for (int t = 0; t < 8; ++t) {                                                \
      const int col = t * 16 + (lane & 15);                                      \
      const float bb = (BIAS)[col];                                              \
      const int mr = w * 16 + g * 4;                                             \
      _Pragma("unroll")                                                          \
      for (int j = 0; j < 4; ++j)                                                \
        lds16[(mr + j) * 132 + col] = f2bf(acc[t][j] + bb);                      \
    }                                                                            \
  }

// ======================= fused adapt + L0 word projections =======================
// hw = tanh(gather(wtab)@Wa+ba); then from LDS: k(+u), v(+vp), q_ww
__global__ __launch_bounds__(256) void adapt_l0w_kernel(
    const u16* __restrict__ wtab, const int* __restrict__ word_ids,
    const u16* __restrict__ BLa, const float* __restrict__ ba,
    const u16* __restrict__ BLk, const float* __restrict__ bk,
    const u16* __restrict__ BLv, const float* __restrict__ bv,
    const u16* __restrict__ BLq, const float* __restrict__ bq,
    const float* __restrict__ qc, const float* __restrict__ priw,
    u16* __restrict__ hw, u8* __restrict__ kv, u8* __restrict__ vp,
    float* __restrict__ uf, u16* __restrict__ qout, int n)
{
  __shared__ u16 lds16[64 * 132];
  const int tid = threadIdx.x, lane = tid & 63, w = tid >> 6;
  int rl = blockIdx.x * 64 + w * 16 + (lane & 15);
  if (rl >= n) rl = n - 1;
  const int row = word_ids[rl];
  const int g = lane >> 4;

  bf16x8 a10[10];
  const u16* Ap = wtab + (size_t)row * 320 + g * 8;
  #pragma unroll
  for (int s = 0; s < 10; ++s) a10[s] = *reinterpret_cast<const bf16x8*>(Ap + s * 32);

  const int rr = tid >> 2, cs = (tid & 3) * 32, m = blockIdx.x * 64 + rr;

  f32x4 acc[8];
  #pragma unroll
  for (int t = 0; t < 8; ++t) acc[t] = (f32x4)0.f;
  {
    const u16* Bp = BLa + (size_t)lane * 8;
    #pragma unroll
    for (int s = 0; s < 10; ++s) {
      #pragma unroll
      for (int t = 0; t < 8; ++t) {
        bf16x8 bfr = *reinterpret_cast<const bf16x8*>(Bp + (size_t)(t * 10 + s) * 512);
        acc[t] = __builtin_amdgcn_mfma_f32_16x16x32_bf16(a10[s], bfr, acc[t], 0, 0, 0);
      }
    }
  }
  #pragma unroll
  for (int t = 0; t < 8; ++t) {
    const int col = t * 16 + (lane & 15);
    const float bb = ba[col];
    const int mr = w * 16 + g * 4;
    #pragma unroll
    for (int j = 0; j < 4; ++j)
      lds16[(mr + j) * 132 + col] = f2bf(tanhf(acc[t][j] + bb));
  }
  __syncthreads();
  if (m < n) bf16_write_row(lds16, rr, cs, hw, m);
  bf16x8 an[4];
  {
    const int rloc = w * 16 + (lane & 15);
    #pragma unroll
    for (int s = 0; s < 4; ++s)
      an[s] = *reinterpret_cast<const bf16x8*>(&lds16[rloc * 132 + s * 32 + g * 8]);
  }
  __syncthreads();

  // k (+u)
  #pragma unroll
  for (int t = 0; t < 8; ++t) acc[t] = (f32x4)0.f;
  GEMM_ACC(an, BLk)
  ACC_TO_LDS(bk)
  __syncthreads();
  float u_keep = 0.f;
  if (m < n) {
    kv_write_half(lds16, rr, cs, kv, m, 0);
    float dot = 0.f;
    #pragma unroll
    for (int j = 0; j < 32; ++j)
      dot += b2f(lds16[rr * 132 + cs + j]) * qc[cs + j];
    u_keep = __expf(dot * (priw[cs >> 5] * 0.17677669529663687f));
    uf[m * 4 + (cs >> 5)] = u_keep;
  }
  // v (+vp)
  #pragma unroll
  for (int t = 0; t < 8; ++t) acc[t] = (f32x4)0.f;
  GEMM_ACC(an, BLv)
  __syncthreads();
  ACC_TO_LDS(bv)
  __syncthreads();
  if (m < n) {
    kv_write_half(lds16, rr, cs, kv, m, 1);
    unsigned wpk[8];
    #pragma unroll
    for (int p = 0; p < 8; ++p) {
      float f0 = u_keep * b2f(lds16[rr * 132 + cs + p * 4 + 0]);
      float f1 = u_keep * b2f(lds16[rr * 132 + cs + p * 4 + 1]);
      float f2 = u_keep * b2f(lds16[rr * 132 + cs + p * 4 + 2]);
      float f3 = u_keep * b2f(lds16[rr * 132 + cs + p * 4 + 3]);
      int t0 = __builtin_amdgcn_cvt_pk_fp8_f32(f0, f1, 0, false);
      wpk[p] = (unsigned)__builtin_amdgcn_cvt_pk_fp8_f32(f2, f3, t0, true);
    }
    *reinterpret_cast<uint4*>(vp + (size_t)m * 128 + cs)      = make_uint4(wpk[0], wpk[1], wpk[2], wpk[3]);
    *reinterpret_cast<uint4*>(vp + (size_t)m * 128 + cs + 16) = make_uint4(wpk[4], wpk[5], wpk[6], wpk[7]);
  }
  // q_ww
  #pragma unroll
  for (int t = 0; t < 8; ++t) acc[t] = (f32x4)0.f;
  GEMM_ACC(an, BLq)
  __syncthreads();
  ACC_TO_LDS(bq)
  __syncthreads();
  if (m < n) bf16_write_row(lds16, rr, cs, qout, m);
}

// ======================= L1 topic k/v GEMM =======================
__global__ __launch_bounds__(256) void gemm_kv_kernel(
    const u16* __restrict__ A,
    const u16* __restrict__ BLk, const float* __restrict__ bk,
    const u16* __restrict__ BLv, const float* __restrict__ bv,
    u8* __restrict__ kv, int n)
{
  __shared__ u16 lds16[64 * 132];
  const int tid = threadIdx.x, lane = tid & 63, w = tid >> 6;
  int rl = blockIdx.x * 64 + w * 16 + (lane & 15);
  if (rl >= n) rl = n - 1;
  const int g = lane >> 4;
  bf16x8 a[4];
  const u16* Ap = A + (size_t)rl * 128 + g * 8;
  #pragma unroll
  for (int s = 0; s < 4; ++s) a[s] = *reinterpret_cast<const bf16x8*>(Ap + s * 32);
  const int rr = tid >> 2, cs = (tid & 3) * 32, m = blockIdx.x * 64 + rr;

  f32x4 acc[8];
  #pragma unroll
  for (int t = 0; t < 8; ++t) acc[t] = (f32x4)0.f;
  GEMM_ACC(a, BLk)
  ACC_TO_LDS(bk)
  __syncthreads();
  if (m < n) kv_write_half(lds16, rr, cs, kv, m, 0);

  #pragma unroll
  for (int t = 0; t < 8; ++t) acc[t] = (f32x4)0.f;
  GEMM_ACC(a, BLv)
  __syncthreads();
  ACC_TO_LDS(bv)
  __syncthreads();
  if (m < n) kv_write_half(lds16, rr, cs, kv, m, 1);
}

// ======================= L0 topic projections =======================
__global__ __launch_bounds__(256) void gemmN_l0t_kernel(
    const u16* __restrict__ A,
    const u16* __restrict__ BLk, const float* __restrict__ bk,
    const u16* __restrict__ BLv, const float* __restrict__ bv,
    const u16* __restrict__ BLq0, const float* __restrict__ bq0,
    const u16* __restrict__ BLq1, const float* __restrict__ bq1,
    const float* __restrict__ qc, const float* __restrict__ prit,
    u8* __restrict__ kv, u8* __restrict__ vp, float* __restrict__ uf,
    u16* __restrict__ q0, u16* __restrict__ q1, int n)
{
  __shared__ u16 lds16[64 * 132];
  const int tid = threadIdx.x, lane = tid & 63, w = tid >> 6;
  int rl = blockIdx.x * 64 + w * 16 + (lane & 15);
  if (rl >= n) rl = n - 1;
  const int g = lane >> 4;
  bf16x8 a[4];
  const u16* Ap = A + (size_t)rl * 128 + g * 8;
  #pragma unroll
  for (int s = 0; s < 4; ++s) a[s] = *reinterpret_cast<const bf16x8*>(Ap + s * 32);
  const int rr = tid >> 2, cs = (tid & 3) * 32, m = blockIdx.x * 64 + rr;

  f32x4 acc[8];
  #pragma unroll
  for (int t = 0; t < 8; ++t) acc[t] = (f32x4)0.f;
  GEMM_ACC(a, BLk)
  ACC_TO_LDS(bk)
  __syncthreads();
  float u_keep = 0.f;
  if (m < n) {
    kv_write_half(lds16, rr, cs, kv, m, 0);
    float dot = 0.f;
    #pragma unroll
    for (int j = 0; j < 32; ++j)
      dot += b2f(lds16[rr * 132 + cs + j]) * qc[cs + j];
    u_keep = __expf(dot * (prit[cs >> 5] * 0.17677669529663687f));
    uf[m * 4 + (cs >> 5)] = u_keep;
  }
  #pragma unroll
  for (int t = 0; t < 8; ++t) acc[t] = (f32x4)0.f;
  GEMM_ACC(a, BLv)
  __syncthreads();
  ACC_TO_LDS(bv)
  __syncthreads();
  if (m < n) {
    kv_write_half(lds16, rr, cs, kv, m, 1);
    unsigned wpk[8];
    #pragma unroll
    for (int p = 0; p < 8; ++p) {
      float f0 = u_keep * b2f(lds16[rr * 132 + cs + p * 4 + 0]);
      float f1 = u_keep * b2f(lds16[rr * 132 + cs + p * 4 + 1]);
      float f2 = u_keep * b2f(lds16[rr * 132 + cs + p * 4 + 2]);
      float f3 = u_keep * b2f(lds16[rr * 132 + cs + p * 4 + 3]);
      int t0 = __builtin_amdgcn_cvt_pk_fp8_f32(f0, f1, 0, false);
      wpk[p] = (unsigned)__builtin_amdgcn_cvt_pk_fp8_f32(f2, f3, t0, true);
    }
    *reinterpret_cast<uint4*>(vp + (size_t)m * 128 + cs)      = make_uint4(wpk[0], wpk[1], wpk[2], wpk[3]);
    *reinterpret_cast<uint4*>(vp + (size_t)m * 128 + cs + 16) = make_uint4(wpk[4], wpk[5], wpk[6], wpk[7]);
  }
  #pragma unroll
  for (int t = 0; t < 8; ++t) acc[t] = (f32x4)0.f;
  GEMM_ACC(a, BLq0)
  __syncthreads();
  ACC_TO_LDS(bq0)
  __syncthreads();
  if (m < n) bf16_write_row(lds16, rr, cs, q0, m);

  #pragma unroll
  for (int t = 0; t < 8; ++t) acc[t] = (f32x4)0.f;
  GEMM_ACC(a, BLq1)
  __syncthreads();
  ACC_TO_LDS(bq1)
  __syncthreads();
  if (m < n) bf16_write_row(lds16, rr, cs, q1, m);
}

// ======================= dual-A comb GEMM =======================
template<int KS>
__global__ __launch_bounds__(256) void gemm2_kernel(
    const u16* __restrict__ A2, const u16* __restrict__ BL0, const u16* __restrict__ BL1,
    const float* __restrict__ bias, u16* __restrict__ C,
    const float* __restrict__ skipp, int n)
{
  __shared__ u16 lds16[64 * 132];
  const int tid = threadIdx.x, lane = tid & 63, w = tid >> 6;
  int rl = blockIdx.x * 64 + w * 16 + (lane & 15);
  if (rl >= n) rl = n - 1;
  const int g = lane >> 4;

  bf16x8 a0[KS], a1[KS];
  const u16* Ap = A2 + (size_t)rl * 256 + g * 8;
  #pragma unroll
  for (int s = 0; s < KS; ++s) {
    a0[s] = *reinterpret_cast<const bf16x8*>(Ap + s * 32);
    a1[s] = *reinterpret_cast<const bf16x8*>(Ap + 128 + s * 32);
  }
  f32x4 acc[8];
  #pragma unroll
  for (int t = 0; t < 8; ++t) acc[t] = (f32x4)0.f;
  const u16* Bp0 = BL0 + (size_t)lane * 8;
  const u16* Bp1 = BL1 + (size_t)lane * 8;
  #pragma unroll
  for (int s = 0; s < KS; ++s) {
    #pragma unroll
    for (int t = 0; t < 8; ++t) {
      bf16x8 b0 = *reinterpret_cast<const bf16x8*>(Bp0 + (size_t)(t * KS + s) * 512);
      acc[t] = __builtin_amdgcn_mfma_f32_16x16x32_bf16(a0[s], b0, acc[t], 0, 0, 0);
      bf16x8 b1 = *reinterpret_cast<const bf16x8*>(Bp1 + (size_t)(t * KS + s) * 512);
      acc[t] = __builtin_amdgcn_mfma_f32_16x16x32_bf16(a1[s], b1, acc[t], 0, 0, 0);
    }
  }
  ACC_TO_LDS(bias)
  __syncthreads();
  const int rr = tid >> 2, cs = (tid & 3) * 32, m = blockIdx.x * 64 + rr;
  if (m < n) {
    const float aa = 1.f / (1.f + __expf(-skipp[0]));
    uint2 r8[8];
    #pragma unroll
    for (int q = 0; q < 8; ++q) r8[q] = *reinterpret_cast<const uint2*>(&lds16[rr * 132 + cs + q * 4]);
    #pragma unroll
    for (int q2 = 0; q2 < 4; ++q2) {
      uint4 blv = *reinterpret_cast<const uint4*>(C + (size_t)m * 128 + cs + q2 * 8);
      uint4 st;
      st.x = blend2(r8[2 * q2].x, blv.x, aa);
      st.y = blend2(r8[2 * q2].y, blv.y, aa);
      st.z = blend2(r8[2 * q2 + 1].x, blv.z, aa);
      st.w = blend2(r8[2 * q2 + 1].y, blv.w, aa);
      *reinterpret_cast<uint4*>(C + (size_t)m * 128 + cs + q2 * 8) = st;
    }
  }
}

// ======================= fused comb_d(L0, blend=0) + L1 doc q projections =======================
__global__ __launch_bounds__(256) void comb_dq_kernel(
    const u16* __restrict__ A2, const u16* __restrict__ BL0, const u16* __restrict__ BL1,
    const float* __restrict__ bias, const float* __restrict__ skipp,
    const u16* __restrict__ BLq0, const float* __restrict__ bq0,
    const u16* __restrict__ BLq1, const float* __restrict__ bq1,
    u16* __restrict__ hd, u16* __restrict__ q0, u16* __restrict__ q1, int n)
{
  __shared__ u16 lds16[64 * 132];
  const int tid = threadIdx.x, lane = tid & 63, w = tid >> 6;
  int rl = blockIdx.x * 64 + w * 16 + (lane & 15);
  if (rl >= n) rl = n - 1;
  const int g = lane >> 4;

  bf16x8 a0[4], a1[4];
  const u16* Ap = A2 + (size_t)rl * 256 + g * 8;
  #pragma unroll
  for (int s = 0; s < 4; ++s) {
    a0[s] = *reinterpret_cast<const bf16x8*>(Ap + s * 32);
    a1[s] = *reinterpret_cast<const bf16x8*>(Ap + 128 + s * 32);
  }
  f32x4 acc[8];
  #pragma unroll
  for (int t = 0; t < 8; ++t) acc[t] = (f32x4)0.f;
  {
    const u16* Bp0 = BL0 + (size_t)lane * 8;
    const u16* Bp1 = BL1 + (size_t)lane * 8;
    #pragma unroll
    for (int s = 0; s < 4; ++s) {
      #pragma unroll
      for (int t = 0; t < 8; ++t) {
        bf16x8 b0 = *reinterpret_cast<const bf16x8*>(Bp0 + (size_t)(t * 4 + s) * 512);
        acc[t] = __builtin_amdgcn_mfma_f32_16x16x32_bf16(a0[s], b0, acc[t], 0, 0, 0);
        bf16x8 b1 = *reinterpret_cast<const bf16x8*>(Bp1 + (size_t)(t * 4 + s) * 512);
        acc[t] = __builtin_amdgcn_mfma_f32_16x16x32_bf16(a1[s], b1, acc[t], 0, 0, 0);
      }
    }
  }
  const float aa = 1.f / (1.f + __expf(-skipp[0]));
  #pragma unroll
  for (int t = 0; t < 8; ++t) {
    const int col = t * 16 + (lane & 15);
    const float bb = bias[col];
    const int mr = w * 16 + g * 4;
    #pragma unroll
    for (int j = 0; j < 4; ++j)
      lds16[(mr + j) * 132 + col] = f2bf((acc[t][j] + bb) * aa);
  }
  __syncthreads();
  const int rr = tid >> 2, cs = (tid & 3) * 32, m = blockIdx.x * 64 + rr;
  if (m < n) bf16_write_row(lds16, rr, cs, hd, m);
  bf16x8 an[4];
  {
    const int rloc = w * 16 + (lane & 15);
    #pragma unroll
    for (int s = 0; s < 4; ++s)
      an[s] = *reinterpret_cast<const bf16x8*>(&lds16[rloc * 132 + s * 32 + g * 8]);
  }
  #pragma unroll
  for (int t = 0; t < 8; ++t) acc[t] = (f32x4)0.f;
  GEMM_ACC(an, BLq0)
  __syncthreads();
  ACC_TO_LDS(bq0)
  __syncthreads();
  if (m < n) bf16_write_row(lds16, rr, cs, q0, m);
  #pragma unroll
  for (int t = 0; t < 8; ++t) acc[t] = (f32x4)0.f;
  GEMM_ACC(an, BLq1)
  __syncthreads();
  ACC_TO_LDS(bq1)
  __syncthreads();
  if (m < n) bf16_write_row(lds16, rr, cs, q1, m);
}

// ======================= fused comb_w(L0) + L1 word k/v =======================
__global__ __launch_bounds__(256) void comb_kv_kernel(
    const u16* __restrict__ Aw, const u16* __restrict__ hwold,
    const u16* __restrict__ BLc, const float* __restrict__ bc,
    const u16* __restrict__ BLk, const float* __restrict__ bk,
    const u16* __restrict__ BLv, const float* __restrict__ bv,
    const float* __restrict__ skipp, u8* __restrict__ kv, int n)
{
  __shared__ u16 lds16[64 * 132];
  const int tid = threadIdx.x, lane = tid & 63, w = tid >> 6;
  int rl = blockIdx.x * 64 + w * 16 + (lane & 15);
  if (rl >= n) rl = n - 1;
  const int g = lane >> 4;

  bf16x8 a[4];
  const u16* Ap = Aw + (size_t)rl * 128 + g * 8;
  #pragma unroll
  for (int s = 0; s < 4; ++s) a[s] = *reinterpret_cast<const bf16x8*>(Ap + s * 32);

  f32x4 acc[8];
  #pragma unroll
  for (int t = 0; t < 8; ++t) acc[t] = (f32x4)0.f;
  GEMM_ACC(a, BLc)
  ACC_TO_LDS(bc)
  __syncthreads();
  const int rr = tid >> 2, cs = (tid & 3) * 32, m = blockIdx.x * 64 + rr;
  if (m < n) {
    const float aa = 1.f / (1.f + __expf(-skipp[0]));
    #pragma unroll
    for (int q2 = 0; q2 < 4; ++q2) {
      uint2 x0 = *reinterpret_cast<const uint2*>(&lds16[rr * 132 + cs + q2 * 8]);
      uint2 x1 = *reinterpret_cast<const uint2*>(&lds16[rr * 132 + cs + q2 * 8 + 4]);
      uint4 blv = *reinterpret_cast<const uint4*>(hwold + (size_t)m * 128 + cs + q2 * 8);
      uint2 y0, y1;
      y0.x = blend2(x0.x, blv.x, aa); y0.y = blend2(x0.y, blv.y, aa);
      y1.x = blend2(x1.x, blv.z, aa); y1.y = blend2(x1.y, blv.w, aa);
      *reinterpret_cast<uint2*>(&lds16[rr * 132 + cs + q2 * 8])     = y0;
      *reinterpret_cast<uint2*>(&lds16[rr * 132 + cs + q2 * 8 + 4]) = y1;
    }
  }
  __syncthreads();
  bf16x8 an[4];
  {
    const int rloc = w * 16 + (lane & 15);
    #pragma unroll
    for (int s = 0; s < 4; ++s)
      an[s] = *reinterpret_cast<const bf16x8*>(&lds16[rloc * 132 + s * 32 + g * 8]);
  }
  #pragma unroll
  for (int t = 0; t < 8; ++t) acc[t] = (f32x4)0.f;
  GEMM_ACC(an, BLk)
  __syncthreads();
  ACC_TO_LDS(bk)
  __syncthreads();
  if (m < n) kv_write_half(lds16, rr, cs, kv, m, 0);
  #pragma unroll
  for (int t = 0; t < 8; ++t) acc[t] = (f32x4)0.f;
  GEMM_ACC(an, BLv)
  __syncthreads();
  ACC_TO_LDS(bv)
  __syncthreads();
  if (m < n) kv_write_half(lds16, rr, cs, kv, m, 1);
}

// ======================= misc small kernels =======================
__global__ void conv_wtab_kernel(const float* __restrict__ we, u16* __restrict__ wt) {
  int i = blockIdx.x * 256 + threadIdx.x;
  if (i < VOCAB * 320) {
    int r = i / 320, c = i - r * 320;
    wt[i] = (c < 300) ? f2bf(we[(size_t)r * 300 + c]) : (u16)0;
  }
}

__global__ void gather_topic_kernel(const float* __restrict__ emb, const int* __restrict__ ids,
                                    u16* __restrict__ out) {
  int i = blockIdx.x * 256 + threadIdx.x;
  if (i < N_TOPIC * 128) {
    int node = i >> 7, c = i & 127;
    out[i] = f2bf(emb[(size_t)ids[node] * 128 + c]);
  }
}

// ======================= CSR build =======================
__global__ void count_rank_kernel(const int* __restrict__ td, const int* __restrict__ wd,
                                  const int* __restrict__ tt, const int* __restrict__ wt,
                                  const int* __restrict__ ww, int* cnt, int* __restrict__ rank) {
  int i = blockIdx.x * 256 + threadIdx.x;
  if (i >= EDGES_ALL) return;
  int b;
  if (i < 80000)       b = td[i];
  else if (i < 330000) b = 32000 + wd[i - 80000];
  else if (i < 350000) b = 64000 + tt[i - 330000];
  else if (i < 450000) b = 64800 + wt[i - 350000];
  else                 b = 65600 + ww[i - 450000];
  rank[i] = atomicAdd(&cnt[b], 1);
}

__global__ void fill_rank_kernel(const int* __restrict__ td_s, const int* __restrict__ td_d,
                                 const int* __restrict__ wd_s, const int* __restrict__ wd_d,
                                 const int* __restrict__ tt_s, const int* __restrict__ tt_d,
                                 const int* __restrict__ wt_s, const int* __restrict__ wt_d,
                                 const int* __restrict__ ww_s, const int* __restrict__ ww_d,
                                 const int* __restrict__ offs, const int* __restrict__ rank,
                                 int* __restrict__ csrc) {
  int i = blockIdx.x * 256 + threadIdx.x;
  if (i >= EDGES_ALL) return;
  int b, s;
  if (i < 80000)       { b = td_d[i];                  s = td_s[i]; }
  else if (i < 330000) { b = 32000 + wd_d[i - 80000];  s = wd_s[i - 80000]; }
  else if (i < 350000) { b = 64000 + tt_d[i - 330000]; s = tt_s[i - 330000]; }
  else if (i < 450000) { b = 64800 + wt_d[i - 350000]; s = wt_s[i - 350000]; }
  else                 { b = 65600 + ww_d[i - 450000]; s = ww_s[i - 450000]; }
  csrc[offs[b] + rank[i]] = s;
}

__global__ __launch_bounds__(256) void scanA_kernel(const int* __restrict__ cnt, int* __restrict__ bsum) {
  const int tid = threadIdx.x, lane = tid & 63, wv = tid >> 6;
  const int i4 = blockIdx.x * 256 + tid;
  int4 v = make_int4(0, 0, 0, 0);
  if (i4 < N4_SCAN) v = reinterpret_cast<const int4*>(cnt)[i4];
  int s = v.x + v.y + v.z + v.w;
  #pragma unroll
  for (int d = 1; d < 64; d <<= 1) s += __shfl_xor(s, d);
  __shared__ int ws[4];
  if (lane == 0) ws[wv] = s;
  __syncthreads();
  if (tid == 0) bsum[blockIdx.x] = ws[0] + ws[1] + ws[2] + ws[3];
}

__global__ __launch_bounds__(256) void scanB_kernel(const int* __restrict__ bsum,
                                                    int* __restrict__ bpre, int* __restrict__ offs,
                                                    unsigned* __restrict__ g) {
  const int tid = threadIdx.x, lane = tid & 63, wv = tid >> 6;
  int v = (tid < NBLK_SCAN) ? bsum[tid] : 0;
  int incl = wave_iscan(v, lane);
  __shared__ int ws[4];
  if (lane == 63) ws[wv] = incl;
  __syncthreads();
  int pre = 0;
  for (int j = 0; j < 4; ++j) if (j < wv) pre += ws[j];
  incl += pre;
  if (tid < NBLK_SCAN) bpre[tid] = incl - v;
  if (tid == NBLK_SCAN - 1) offs[NODES_ALL] = incl;
  for (int i = tid; i < BATCH * H_DIM; i += 256) g[i] = 0x007FFFFFu;  // fenc(-inf)
}

__global__ __launch_bounds__(256) void scanC_kernel(const int* __restrict__ cnt,
                                                    const int* __restrict__ bpre,
                                                    int* __restrict__ offs) {
  const int tid = threadIdx.x, lane = tid & 63, wv = tid >> 6;
  const int i4 = blockIdx.x * 256 + tid;
  int4 v = make_int4(0, 0, 0, 0);
  if (i4 < N4_SCAN) v = reinterpret_cast<const int4*>(cnt)[i4];
  const int tsum = v.x + v.y + v.z + v.w;
  int incl = wave_iscan(tsum, lane);
  __shared__ int ws[4];
  if (lane == 63) ws[wv] = incl;
  __syncthreads();
  int pre = bpre[blockIdx.x];
  for (int j = 0; j < 4; ++j) if (j < wv) pre += ws[j];
  int o0 = pre + incl - tsum;
  if (i4 < N4_SCAN) {
    int4 ov = make_int4(o0, o0 + v.x, o0 + v.x + v.y, o0 + v.x + v.y + v.z);
    reinterpret_cast<int4*>(offs)[i4] = ov;
  }
}

// ======================= aggregation =======================
struct AggArgs {
  const u16 *q_td, *q_wd, *q_tt, *q_wt, *q_ww;
  const u8 *kv_t, *kv_w, *vp_t, *vp_w;
  const float *uf_t, *uf_w;
  const int *csrc, *offs;
  const float *pri;
  u16 *t2_d, *t2_t, *t_w;
};

static __device__ __forceinline__ void butterfly4(
    f32x2 acc0, f32x2 acc1, f32x2 acc2, f32x2 acc3, float ss,
    int lane, f32x2& red, float& ss_out)
{
  ss += __shfl_xor(ss, 16); ss += __shfl_xor(ss, 32);
  const bool h16 = (lane & 16) != 0, h32 = (lane & 32) != 0;
  f32x2 k0 = h16 ? acc2 : acc0;
  f32x2 k1 = h16 ? acc3 : acc1;
  f32x2 s0 = h16 ? acc0 : acc2;
  f32x2 s1 = h16 ? acc1 : acc3;
  k0[0] += __shfl_xor(s0[0], 16); k0[1] += __shfl_xor(s0[1], 16);
  k1[0] += __shfl_xor(s1[0], 16); k1[1] += __shfl_xor(s1[1], 16);
  f32x2 kk = h32 ? k1 : k0;
  f32x2 sd = h32 ? k0 : k1;
  kk[0] += __shfl_xor(sd[0], 32); kk[1] += __shfl_xor(sd[1], 32);
  red = kk; ss_out = ss;
}

static __device__ __forceinline__ void agg_core(
    const u16* __restrict__ q, const u8* __restrict__ kv,
    const int* __restrict__ offs, const int* __restrict__ csrc,
    const float* __restrict__ pri,
    int node, int grp, int stride, int sl, int lane,
    f32x2& red, float& ss_out)
{
  const int e0 = offs[node], e1 = offs[node + 1];
  f32x2 acc0 = (f32x2)0.f, acc1 = (f32x2)0.f, acc2 = (f32x2)0.f, acc3 = (f32x2)0.f;
  float ss = 0.f;
  if (e1 > e0) {
    const float prih = pri[sl >> 2] * 0.17677669529663687f;
    const bf16x8 qv = *reinterpret_cast<const bf16x8*>(q + (size_t)node * 128 + sl * 8);
    f32x2 q2[4];
    #pragma unroll
    for (int p = 0; p < 4; ++p) {
      f32x2 t; t[0] = b2f((u16)qv[2 * p]); t[1] = b2f((u16)qv[2 * p + 1]); q2[p] = t;
    }
    const int last = e1 - 1;
    for (int base = e0; base < e1; base += 2 * stride) {
      const int eA = base + grp, eB = base + stride + grp;
      const bool vA = eA < e1, vB = eB < e1;
      const int sA = csrc[vA ? eA : last];
      const int sB = csrc[vB ? eB : last];
      const uint4 cA = *reinterpret_cast<const uint4*>(kv + (size_t)sA * 256 + sl * 16);
      const uint4 cB = *reinterpret_cast<const uint4*>(kv + (size_t)sB * 256 + sl * 16);
      f32x2 dA = q2[0] * cvt8<false>((int)cA.x);
      dA += q2[1] * cvt8<true>((int)cA.x);
      dA += q2[2] * cvt8<false>((int)cA.y);
      dA += q2[3] * cvt8<true>((int)cA.y);
      f32x2 dB = q2[0] * cvt8<false>((int)cB.x);
      dB += q2[1] * cvt8<true>((int)cB.x);
      dB += q2[2] * cvt8<false>((int)cB.y);
      dB += q2[3] * cvt8<true>((int)cB.y);
      float dotA = dA[0] + dA[1];
      float dotB = dB[0] + dB[1];
      dotA += __shfl_xor(dotA, 1); dotA += __shfl_xor(dotA, 2);
      dotB += __shfl_xor(dotB, 1); dotB += __shfl_xor(dotB, 2);
      const float wA = vA ? __expf(dotA * prih) : 0.f;
      const float wB = vB ? __expf(dotB * prih) : 0.f;
      ss += wA + wB;
      f32x2 wA2; wA2[0] = wA; wA2[1] = wA;
      f32x2 wB2; wB2[0] = wB; wB2[1] = wB;
      acc0 += wA2 * cvt8<false>((int)cA.z);
      acc1 += wA2 * cvt8<true>((int)cA.z);
      acc2 += wA2 * cvt8<false>((int)cA.w);
      acc3 += wA2 * cvt8<true>((int)cA.w);
      acc0 += wB2 * cvt8<false>((int)cB.z);
      acc1 += wB2 * cvt8<true>((int)cB.z);
      acc2 += wB2 * cvt8<false>((int)cB.w);
      acc3 += wB2 * cvt8<true>((int)cB.w);
    }
  }
  butterfly4(acc0, acc1, acc2, acc3, ss, lane, red, ss_out);
}

static __device__ __forceinline__ void agg_docu(
    const u8* __restrict__ vp, const float* __restrict__ uf,
    const int* __restrict__ offs, const int* __restrict__ csrc,
    int node, int sub, int sl, int lane,
    f32x2& red, float& ss_out)
{
  const int e0 = offs[node], e1 = offs[node + 1];
  f32x2 acc0 = (f32x2)0.f, acc1 = (f32x2)0.f, acc2 = (f32x2)0.f, acc3 = (f32x2)0.f;
  float ss = 0.f;
  if (e1 > e0) {
    const int h = sl >> 2;
    const int last = e1 - 1;
    for (int base = e0; base < e1; base += 8) {
      const int eA = base + sub, eB = base + 4 + sub;
      const bool vA = eA < e1, vB = eB < e1;
      const int sA = csrc[vA ? eA : last];
      const int sB = csrc[vB ? eB : last];
      uint2 cA = *reinterpret_cast<const uint2*>(vp + (size_t)sA * 128 + sl * 8);
      uint2 cB = *reinterpret_cast<const uint2*>(vp + (size_t)sB * 128 + sl * 8);
      float uA = uf[sA * 4 + h];
      float uB = uf[sB * 4 + h];
      if (!vA) { cA = make_uint2(0u, 0u); uA = 0.f; }
      if (!vB) { cB = make_uint2(0u, 0u); uB = 0.f; }
      ss += uA + uB;
      acc0 += cvt8<false>((int)cA.x); acc1 += cvt8<true>((int)cA.x);
      acc2 += cvt8<false>((int)cA.y); acc3 += cvt8<true>((int)cA.y);
      acc0 += cvt8<false>((int)cB.x); acc1 += cvt8<true>((int)cB.x);
      acc2 += cvt8<false>((int)cB.y); acc3 += cvt8<true>((int)cB.y);
    }
  }
  butterfly4(acc0, acc1, acc2, acc3, ss, lane, red, ss_out);
}

static __device__ __forceinline__ int chbase_of(int lane) {
  return (lane & 15) * 8 + ((lane >> 4) & 1) * 4 + ((lane >> 5) & 1) * 2;
}

template<int DOCU>
__global__ __launch_bounds__(256) void agg_all_kernel(AggArgs A, int topic_n)
{
  __shared__ float lacc[4][128];
  __shared__ float lssA[4];
  const int tid = threadIdx.x, lane = tid & 63, wv = tid >> 6;
  const int sub = lane >> 4, sl = lane & 15;
  const int bid = blockIdx.x;
  const int chb = chbase_of(lane);
  f32x2 red; float ss;

  if (bid < topic_n) {
    const int node = bid;
    for (int r = 0; r < 2; ++r) {
      agg_core(r ? A.q_wt : A.q_tt, r ? A.kv_w : A.kv_t,
               A.offs + (r ? 64800 : 64000), A.csrc, A.pri + (r ? 12 : 4),
               node, wv * 4 + sub, 16, sl, lane, red, ss);
      lacc[wv][chb] = red[0]; lacc[wv][chb + 1] = red[1];
      if (lane == 0) lssA[wv] = ss;
      __syncthreads();
      if (tid < 128) {
        float a = lacc[0][tid] + lacc[1][tid] + lacc[2][tid] + lacc[3][tid];
        float st = lssA[0] + lssA[1] + lssA[2] + lssA[3];
        float inv = (st > 0.f) ? 1.f / st : 0.f;
        A.t2_t[(size_t)node * 256 + r * 128 + tid] = f2bf(a * inv);
      }
      __syncthreads();
    }
  } else if (bid < topic_n + 8000) {
    const int node = (bid - topic_n) * 4 + wv;
    if (DOCU) {
      agg_docu(A.vp_t, A.uf_t, A.offs + 0, A.csrc, node, sub, sl, lane, red, ss);
    } else {
      agg_core(A.q_td, A.kv_t, A.offs + 0, A.csrc, A.pri + 0, node, sub, 4, sl, lane, red, ss);
    }
    {
      float inv = (ss > 0.f) ? 1.f / ss : 0.f;
      unsigned pk = (unsigned)f2bf(red[0] * inv) | ((unsigned)f2bf(red[1] * inv) << 16);
      *reinterpret_cast<unsigned*>(A.t2_d + (size_t)node * 256 + chb) = pk;
    }
    if (DOCU) {
      agg_docu(A.vp_w, A.uf_w, A.offs + 32000, A.csrc, node, sub, sl, lane, red, ss);
    } else {
      agg_core(A.q_wd, A.kv_w, A.offs + 32000, A.csrc, A.pri + 8, node, sub, 4, sl, lane, red, ss);
    }
    {
      float inv = (ss > 0.f) ? 1.f / ss : 0.f;
      unsigned pk = (unsigned)f2bf(red[0] * inv) | ((unsigned)f2bf(red[1] * inv) << 16);
      *reinterpret_cast<unsigned*>(A.t2_d + (size_t)node * 256 + 128 + chb) = pk;
    }
  } else {
    const int node = (bid - topic_n - 8000) * 4 + wv;
    agg_core(A.q_ww, A.kv_w, A.offs + 65600, A.csrc, A.pri + 16, node, sub, 4, sl, lane, red, ss);
    float inv = (ss > 0.f) ? 1.f / ss : 0.f;
    unsigned pk = (unsigned)f2bf(red[0] * inv) | ((unsigned)f2bf(red[1] * inv) << 16);
    *reinterpret_cast<unsigned*>(A.t_w + (size_t)node * 128 + chb) = pk;
  }
}

// ======================= readout =======================
__global__ void segmax_kernel(const u16* __restrict__ hd, const int* __restrict__ gid,
                              unsigned* g) {
  int c = threadIdx.x;
  int d0 = blockIdx.x * 128;
  int dend = min(d0 + 128, N_DOC);
  int cur = -1; float m = 0.f;
  for (int d = d0; d < dend; ++d) {
    int gg = gid[d];
    float v = b2f(hd[(size_t)d * 128 + c]);
    if (gg != cur) {
      if (cur >= 0) atomicMax(&g[cur * 128 + c], fenc(m));
      cur = gg; m = v;
    } else {
      m = fmaxf(m, v);
    }
  }
  if (cur >= 0) atomicMax(&g[cur * 128 + c], fenc(m));
}

__global__ void final_kernel(const unsigned* __restrict__ g, const float* __restrict__ out_w,
                             const float* __restrict__ out_b, const float* __restrict__ y,
                             float* out) {
  int tid = threadIdx.x;
  int b = tid >> 4, seg = tid & 15;
  float p = 0.f;
  #pragma unroll
  for (int j = 0; j < 8; ++j) {
    int c = seg * 8 + j;
    p += fdec(g[b * 128 + c]) * out_w[c];
  }
  p += __shfl_xor(p, 1);
  p += __shfl_xor(p, 2);
  p += __shfl_xor(p, 4);
  p += __shfl_xor(p, 8);
  __shared__ float logits[BATCH];
  __shared__ float losses[BATCH];
  if (seg == 0) logits[b] = p + out_b[0];
  __syncthreads();
  if (tid < BATCH) {
    float l = logits[tid];
    out[1 + tid] = 1.f / (1.f + expf(-l));
    float ls_pos = (l > 0.f) ? -log1pf(expf(-l)) : l - log1pf(expf(l));
    float ls_neg = (l < 0.f) ? -log1pf(expf(l)) : -l - log1pf(expf(-l));
    losses[tid] = -(y[tid] * ls_pos + (1.f - y[tid]) * ls_neg);
  }
  __syncthreads();
  if (tid == 0) {
    float s = 0.f;
    for (int j = 0; j < BATCH; ++j) s += losses[j];
    out[0] = s / (float)BATCH;
  }
}

// ======================= host =======================
extern "C" void kernel_launch(void* const* d_in, const int* in_sizes, int n_in,
                              void* d_out, int out_size, void* d_ws, size_t ws_size,
                              hipStream_t stream)
{
  const float* word_embeds  = (const float*)d_in[0];
  const float* topic_embeds = (const float*)d_in[1];
  const float* KW  = (const float*)d_in[2];
  const float* Kb  = (const float*)d_in[3];
  const float* QW  = (const float*)d_in[4];
  const float* Qb  = (const float*)d_in[5];
  const float* VW  = (const float*)d_in[6];
  const float* Vb  = (const float*)d_in[7];
  const float* AW  = (const float*)d_in[8];
  const float* Ab  = (const float*)d_in[9];
  const float* rel_att = (const float*)d_in[10];
  const float* rel_msg = (const float*)d_in[11];
  const float* rel_pri = (const float*)d_in[12];
  const float* skip    = (const float*)d_in[13];
  const float* adapt_w = (const float*)d_in[14];
  const float* adapt_b = (const float*)d_in[15];
  const float* out_w   = (const float*)d_in[16];
  const float* out_b   = (const float*)d_in[17];
  const float* y_data  = (const float*)d_in[18];
  const int* word_ids  = (const int*)d_in[19];
  const int* topic_ids = (const int*)d_in[20];
  const int* doc_gid   = (const int*)d_in[21];
  const int* td_src = (const int*)d_in[22];
  const int* td_dst = (const int*)d_in[23];
  const int* tt_src = (const int*)d_in[24];
  const int* tt_dst = (const int*)d_in[25];
  const int* wd_src = (const int*)d_in[26];
  const int* wd_dst = (const int*)d_in[27];
  const int* wt_src = (const int*)d_in[28];
  const int* wt_dst = (const int*)d_in[29];
  const int* ww_src = (const int*)d_in[30];
  const int* ww_dst = (const int*)d_in[31];

  char* base = (char*)d_ws;
  size_t off_b = 0;
  auto alloc = [&](size_t bytes) -> char* {
    char* p = base + off_b;
    off_b = (off_b + bytes + 255) & ~(size_t)255;
    return p;
  };

  u16* wtab = (u16*)alloc((size_t)VOCAB * 320 * 2);
  u16* hw   = (u16*)alloc((size_t)N_WORD * 128 * 2);
  u16* hd   = (u16*)alloc((size_t)N_DOC * 128 * 2);
  u16* ht   = (u16*)alloc((size_t)N_TOPIC * 128 * 2);
  u8*  kv_w = (u8*)alloc((size_t)N_WORD * 256);
  u8*  kv_t = (u8*)alloc((size_t)N_TOPIC * 256);
  u8*  vp_w = (u8*)alloc((size_t)N_WORD * 128);
  u8*  vp_t = (u8*)alloc((size_t)N_TOPIC * 128);
  float* uf_w = (float*)alloc((size_t)N_WORD * 4 * 4);
  float* uf_t = (float*)alloc((size_t)N_TOPIC * 4 * 4);
  u16* q_td = (u16*)alloc((size_t)N_DOC * 128 * 2);
  u16* q_wd = (u16*)alloc((size_t)N_DOC * 128 * 2);
  u16* q_tt = (u16*)alloc((size_t)N_TOPIC * 128 * 2);
  u16* q_wt = (u16*)alloc((size_t)N_TOPIC * 128 * 2);
  u16* q_ww = (u16*)alloc((size_t)N_WORD * 128 * 2);
  u16* t2_d = (u16*)alloc((size_t)N_DOC * 256 * 2);
  u16* t2_t = (u16*)alloc((size_t)N_TOPIC * 256 * 2);
  u16* t_w  = (u16*)alloc((size_t)N_WORD * 128 * 2);
  unsigned* g = (unsigned*)alloc((size_t)BATCH * 128 * 4);

  int* cnt_all  = (int*)alloc((size_t)NODES_ALL * 4);
  int* offs_all = (int*)alloc(((size_t)NODES_ALL + 1) * 4);
  int* csrc_all = (int*)alloc((size_t)EDGES_ALL * 4);
  int* rank_all = (int*)alloc((size_t)EDGES_ALL * 4);
  int* bsum     = (int*)alloc((size_t)NBLK_SCAN * 4);
  int* bpre     = (int*)alloc((size_t)NBLK_SCAN * 4);

  u16* blw        = (u16*)alloc((size_t)(40960 + 28 * 16384) * 2);
  float* bias_are = (float*)alloc((size_t)29 * 128 * 4);

  auto BLp = [&](int wid) -> const u16* {
    return (wid == 0) ? blw : blw + 40960 + (size_t)(wid - 1) * 16384;
  };
  auto BIp = [&](int wid) -> const float* { return bias_are + wid * 128; };
  auto WID = [&](int li, int j) { return 1 + li * 14 + j; };

  // ---- prep ----
  prep_kernel<<<29 * 8, 256, 0, stream>>>(KW, Kb, QW, Qb, VW, Vb, AW, Ab,
                                          rel_att, rel_msg, adapt_w, adapt_b, blw, bias_are);
  conv_wtab_kernel<<<(VOCAB * 320 + 255) / 256, 256, 0, stream>>>(word_embeds, wtab);
  gather_topic_kernel<<<(N_TOPIC * 128 + 255) / 256, 256, 0, stream>>>(topic_embeds, topic_ids, ht);

  hipMemsetAsync(cnt_all, 0, (size_t)NODES_ALL * 4, stream);
  count_rank_kernel<<<(EDGES_ALL + 255) / 256, 256, 0, stream>>>(
      td_dst, wd_dst, tt_dst, wt_dst, ww_dst, cnt_all, rank_all);
  scanA_kernel<<<NBLK_SCAN, 256, 0, stream>>>(cnt_all, bsum);
  scanB_kernel<<<1, 256, 0, stream>>>(bsum, bpre, offs_all, g);
  scanC_kernel<<<NBLK_SCAN, 256, 0, stream>>>(cnt_all, bpre, offs_all);
  fill_rank_kernel<<<(EDGES_ALL + 255) / 256, 256, 0, stream>>>(
      td_src, td_dst, wd_src, wd_dst, tt_src, tt_dst, wt_src, wt_dst, ww_src, ww_dst,
      offs_all, rank_all, csrc_all);

  const int GW = (N_WORD + 63) / 64, GD = (N_DOC + 63) / 64, GT = (N_TOPIC + 63) / 64;

  // ================= layer 0 =================
  adapt_l0w_kernel<<<GW, 256, 0, stream>>>(
      wtab, word_ids,
      BLp(0), BIp(0),
      BLp(WID(0, 1)), BIp(WID(0, 1)),
      BLp(WID(0, 3)), BIp(WID(0, 3)),
      BLp(WID(0, 8)), BIp(WID(0, 8)),
      BIp(WID(0, 6)), rel_pri + 8,
      hw, kv_w, vp_w, uf_w, q_ww, N_WORD);
  gemmN_l0t_kernel<<<GT, 256, 0, stream>>>(
      ht,
      BLp(WID(0, 0)), BIp(WID(0, 0)),
      BLp(WID(0, 2)), BIp(WID(0, 2)),
      BLp(WID(0, 5)), BIp(WID(0, 5)),
      BLp(WID(0, 7)), BIp(WID(0, 7)),
      BIp(WID(0, 4)), rel_pri + 0,
      kv_t, vp_t, uf_t, q_tt, q_wt, N_TOPIC);

  AggArgs A0;
  A0.q_td = q_td; A0.q_wd = q_wd; A0.q_tt = q_tt; A0.q_wt = q_wt; A0.q_ww = q_ww;
  A0.kv_t = kv_t; A0.kv_w = kv_w; A0.vp_t = vp_t; A0.vp_w = vp_w;
  A0.uf_t = uf_t; A0.uf_w = uf_w;
  A0.csrc = csrc_all; A0.offs = offs_all;
  A0.pri = rel_pri;
  A0.t2_d = t2_d; A0.t2_t = t2_t; A0.t_w = t_w;
  agg_all_kernel<1><<<28800, 256, 0, stream>>>(A0, 800);

  comb_dq_kernel<<<GD, 256, 0, stream>>>(
      t2_d, BLp(WID(0, 9)), BLp(WID(0, 11)), BIp(WID(0, 9)), skip + 0,
      BLp(WID(1, 4)), BIp(WID(1, 4)), BLp(WID(1, 6)), BIp(WID(1, 6)),
      hd, q_td, q_wd, N_DOC);
  gemm2_kernel<4><<<GT, 256, 0, stream>>>(t2_t, BLp(WID(0, 10)), BLp(WID(0, 12)),
                                          BIp(WID(0, 10)), ht, skip + 1, N_TOPIC);
  comb_kv_kernel<<<GW, 256, 0, stream>>>(
      t_w, hw, BLp(WID(0, 13)), BIp(WID(0, 13)),
      BLp(WID(1, 1)), BIp(WID(1, 1)), BLp(WID(1, 3)), BIp(WID(1, 3)),
      skip + 2, kv_w, N_WORD);

  // ================= layer 1 =================
  gemm_kv_kernel<<<GT, 256, 0, stream>>>(
      ht, BLp(WID(1, 0)), BIp(WID(1, 0)), BLp(WID(1, 2)), BIp(WID(1, 2)), kv_t, N_TOPIC);

  AggArgs A1 = A0;
  A1.pri = rel_pri + 20;
  agg_all_kernel<0><<<8000, 256, 0, stream>>>(A1, 0);

  gemm2_kernel<4><<<GD, 256, 0, stream>>>(t2_d, BLp(WID(1, 9)), BLp(WID(1, 11)),
                                          BIp(WID(1, 9)), hd, skip + 3, N_DOC);

  // ---- readout ----
  segmax_kernel<<<(N_DOC + 127) / 128, 128, 0, stream>>>(hd, doc_gid, g);
  final_kernel<<<1, 256, 0, stream>>>(g, out_w, out_b, y_data, (float*)d_out);
}

// Round 10
// 377.560 us; speedup vs baseline: 12.2769x; 1.0021x over previous
//
#include <hip/hip_runtime.h>
#include <cstdint>
#include <cstddef>

#define H_DIM 128
#define N_DOC 32000
#define N_TOPIC 800
#define N_WORD 80000
#define BATCH 16
#define VOCAB 15000
#define NODES_ALL 145600
#define EDGES_ALL 850000
#define NBLK_SCAN 143
#define N4_SCAN 36400
#define LDSW 136   // u16 row stride: 272 B, 16B-aligned

typedef short bf16x8 __attribute__((ext_vector_type(8)));
typedef float f32x4 __attribute__((ext_vector_type(4)));
typedef float f32x2 __attribute__((ext_vector_type(2)));
typedef unsigned short u16;
typedef unsigned char u8;

static __device__ __forceinline__ u16 f2bf(float x) {
  unsigned u = __float_as_uint(x);
  u += 0x7fffu + ((u >> 16) & 1u);
  return (u16)(u >> 16);
}
static __device__ __forceinline__ float b2f(unsigned h) {
  return __uint_as_float(h << 16);
}
static __device__ __forceinline__ unsigned fenc(float f) {
  unsigned u = __float_as_uint(f);
  return (u & 0x80000000u) ? ~u : (u | 0x80000000u);
}
static __device__ __forceinline__ float fdec(unsigned k) {
  return (k & 0x80000000u) ? __uint_as_float(k ^ 0x80000000u) : __uint_as_float(~k);
}
static __device__ __forceinline__ int wave_iscan(int v, int lane) {
  #pragma unroll
  for (int d = 1; d < 64; d <<= 1) {
    int t = __shfl_up(v, d);
    if (lane >= d) v += t;
  }
  return v;
}
static __device__ __forceinline__ unsigned blend2(unsigned pr, unsigned bl, float aa) {
  float v0 = b2f(pr & 0xffffu) * aa + b2f(bl & 0xffffu) * (1.f - aa);
  float v1 = b2f(pr >> 16) * aa + b2f(bl >> 16) * (1.f - aa);
  return (unsigned)f2bf(v0) | ((unsigned)f2bf(v1) << 16);
}
template<bool HI>
static __device__ __forceinline__ f32x2 cvt8(int w) {
  return __builtin_amdgcn_cvt_pk_f32_fp8(w, HI);
}

// ======================= weight prep =======================
__global__ __launch_bounds__(256) void prep_kernel(
    const float* __restrict__ KW, const float* __restrict__ Kb,
    const float* __restrict__ QW, const float* __restrict__ Qb,
    const float* __restrict__ VW, const float* __restrict__ Vb,
    const float* __restrict__ AW, const float* __restrict__ Ab,
    const float* __restrict__ rel_att, const float* __restrict__ rel_msg,
    const float* __restrict__ adapt_w, const float* __restrict__ adapt_b,
    u16* __restrict__ bl_arena, float* __restrict__ bias_arena)
{
  const int wid = blockIdx.x >> 3, t = blockIdx.x & 7;
  int KS, Kreal, fold;
  const float *W, *b, *R = nullptr;
  float scale = 1.f;
  if (wid == 0) { KS = 10; Kreal = 300; fold = 0; W = adapt_w; b = adapt_b; }
  else {
    KS = 4; Kreal = 128;
    const int wl = wid - 1, li = wl / 14, j = wl % 14;
    const int dstnid[5] = {0, 1, 0, 1, 2};
    if (j < 4) {
      fold = 0;
      const float* Wb = (j < 2) ? KW : VW;
      const float* bb = (j < 2) ? Kb : Vb;
      const int nid = (j & 1) ? 2 : 1;
      W = Wb + ((size_t)li * 3 + nid) * 16384; b = bb + ((size_t)li * 3 + nid) * 128;
    } else if (j < 9) {
      fold = 1; const int r = j - 4; const int nid = dstnid[r];
      W = QW + ((size_t)li * 3 + nid) * 16384; b = Qb + ((size_t)li * 3 + nid) * 128;
      R = rel_att + ((size_t)li * 5 + r) * 4096;
    } else {
      fold = 3; const int r = j - 9; const int nid = dstnid[r];
      W = AW + ((size_t)li * 3 + nid) * 16384; b = Ab + ((size_t)li * 3 + nid) * 128;
      R = rel_msg + ((size_t)li * 5 + r) * 4096;
      scale = (r == 4) ? 1.f : 0.5f;
    }
  }
  u16* obl = (wid == 0) ? bl_arena : bl_arena + 40960 + (size_t)(wid - 1) * 16384;
  float* obias = bias_arena + wid * 128;

  const int nelem = KS * 512;
  for (int e = threadIdx.x; e < nelem; e += 256) {
    const int s = e >> 9, rem = e & 511, l = rem >> 3, jj = rem & 7;
    const int k = s * 32 + ((l >> 4) << 3) + jj;
    const int nn = t * 16 + (l & 15);
    float v = 0.f;
    if (k < Kreal) {
      if (fold == 0) v = W[(size_t)k * 128 + nn];
      else if (fold == 1) {
        const int h = nn >> 5, d = nn & 31;
        const float* Wr = W + (size_t)k * 128 + h * 32;
        const float* Rh = R + h * 1024;
        for (int f = 0; f < 32; ++f) v += Wr[f] * Rh[d * 32 + f];
      } else {
        const int h = k >> 5, dd = k & 31;
        const float* Rh = R + h * 1024 + dd * 32;
        const float* Wc = W + (size_t)h * 32 * 128 + nn;
        float sa = 0.f;
        for (int f = 0; f < 32; ++f) sa += Rh[f] * Wc[(size_t)f * 128];
        v = sa * scale;
      }
    }
    obl[(size_t)(t * KS + s) * 512 + rem] = f2bf(v);
  }
  if (t == 0 && threadIdx.x < 128) {
    const int nn = threadIdx.x;
    float v = 0.f;
    if (fold != 1) v = b[nn];
    else {
      const int h = nn >> 5, d = nn & 31;
      const float* Rh = R + h * 1024;
      for (int f = 0; f < 32; ++f) v += b[h * 32 + f] * Rh[d * 32 + f];
    }
    obias[nn] = v;
  }
}

// ======================= GEMM helpers (vectorized LDS reads) =======================
static __device__ __forceinline__ void kv_write_half(
    const u16* lds16, int rr, int cs, u8* kv, size_t m, int vhalf)
{
  u8* Cp = kv + m * 256 + (cs >> 3) * 16 + (vhalf ? 8 : 0);
  #pragma unroll
  for (int q2 = 0; q2 < 4; ++q2) {
    uint4 ld = *reinterpret_cast<const uint4*>(&lds16[rr * LDSW + cs + q2 * 8]);
    int t0 = __builtin_amdgcn_cvt_pk_fp8_f32(b2f(ld.x & 0xffffu), b2f(ld.x >> 16), 0, false);
    unsigned w0 = (unsigned)__builtin_amdgcn_cvt_pk_fp8_f32(b2f(ld.y & 0xffffu), b2f(ld.y >> 16), t0, true);
    int t1 = __builtin_amdgcn_cvt_pk_fp8_f32(b2f(ld.z & 0xffffu), b2f(ld.z >> 16), 0, false);
    unsigned w1 = (unsigned)__builtin_amdgcn_cvt_pk_fp8_f32(b2f(ld.w & 0xffffu), b2f(ld.w >> 16), t1, true);
    *reinterpret_cast<uint2*>(Cp + q2 * 16) = make_uint2(w0, w1);
  }
}

static __device__ __forceinline__ void bf16_write_row(
    const u16* lds16, int rr, int cs, u16* C, size_t m)
{
  u16* Cp = C + m * 128 + cs;
  #pragma unroll
  for (int q2 = 0; q2 < 4; ++q2)
    *reinterpret_cast<uint4*>(Cp + q2 * 8) =
        *reinterpret_cast<const uint4*>(&lds16[rr * LDSW + cs + q2 * 8]);
}

#define GEMM_ACC(AV, BLP)                                                        \
  {                                                                              \
    const u16* Bp = (BLP) + (size_t)lane * 8;                                    \
    _Pragma("unroll")                                                            \
    for (int s = 0; s < 4; ++s) {                                                \
      _Pragma("unroll")                                                          \
      for (int t = 0; t < 8; ++t) {                                              \
        bf16x8 bfr = *reinterpret_cast<const bf16x8*>(Bp + (size_t)(t * 4 + s) * 512); \
        acc[t] = __builtin_amdgcn_mfma_f32_16x16x32_bf16(AV[s], bfr, acc[t], 0, 0, 0); \
      }                                                                          \
    }                                                                            \
  }

#define ACC_TO_LDS(BIAS)                                                         \
  {                                                                              \
    _Pragma("unroll")                                                            \
    for (int t = 0; t < 8; ++t) {                                                \
      const int col = t * 16 + (lane & 15);                                      \
      const float bb = (BIAS)[col];                                              \
      const int mr = w * 16 + g * 4;                                             \
      _Pragma("unroll")                                                          \
      for (int j = 0; j < 4; ++j)                                                \
        lds16[(mr + j) * LDSW + col] = f2bf(acc[t][j] + bb);                     \
    }                                                                            \
  }

// dot of 32 LDS bf16 (row rr, cols cs..cs+31) with qc[cs..cs+31]
static __device__ __forceinline__ float lds_qc_dot(
    const u16* lds16, int rr, int cs, const float* __restrict__ qc)
{
  float dot = 0.f;
  #pragma unroll
  for (int q2 = 0; q2 < 4; ++q2) {
    uint4 ld = *reinterpret_cast<const uint4*>(&lds16[rr * LDSW + cs + q2 * 8]);
    float4 qa = *reinterpret_cast<const float4*>(&qc[cs + q2 * 8]);
    float4 qb = *reinterpret_cast<const float4*>(&qc[cs + q2 * 8 + 4]);
    dot += b2f(ld.x & 0xffffu) * qa.x + b2f(ld.x >> 16) * qa.y
         + b2f(ld.y & 0xffffu) * qa.z + b2f(ld.y >> 16) * qa.w
         + b2f(ld.z & 0xffffu) * qb.x + b2f(ld.z >> 16) * qb.y
         + b2f(ld.w & 0xffffu) * qb.z + b2f(ld.w >> 16) * qb.w;
  }
  return dot;
}

// vp write: fp8(u * lds row)
static __device__ __forceinline__ void vp_write(
    const u16* lds16, int rr, int cs, float u_keep, u8* vp, size_t m)
{
  unsigned wpk[8];
  #pragma unroll
  for (int q2 = 0; q2 < 4; ++q2) {
    uint4 ld = *reinterpret_cast<const uint4*>(&lds16[rr * LDSW + cs + q2 * 8]);
    int t0 = __builtin_amdgcn_cvt_pk_fp8_f32(u_keep * b2f(ld.x & 0xffffu), u_keep * b2f(ld.x >> 16), 0, false);
    wpk[2 * q2] = (unsigned)__builtin_amdgcn_cvt_pk_fp8_f32(u_keep * b2f(ld.y & 0xffffu), u_keep * b2f(ld.y >> 16), t0, true);
    int t1 = __builtin_amdgcn_cvt_pk_fp8_f32(u_keep * b2f(ld.z & 0xffffu), u_keep * b2f(ld.z >> 16), 0, false);
    wpk[2 * q2 + 1] = (unsigned)__builtin_amdgcn_cvt_pk_fp8_f32(u_keep * b2f(ld.w & 0xffffu), u_keep * b2f(ld.w >> 16), t1, true);
  }
  *reinterpret_cast<uint4*>(vp + m * 128 + cs)      = make_uint4(wpk[0], wpk[1], wpk[2], wpk[3]);
  *reinterpret_cast<uint4*>(vp + m * 128 + cs + 16) = make_uint4(wpk[4], wpk[5], wpk[6], wpk[7]);
}

// ======================= fused adapt + L0 word projections =======================
__global__ __launch_bounds__(256) void adapt_l0w_kernel(
    const u16* __restrict__ wtab, const int* __restrict__ word_ids,
    const u16* __restrict__ BLa, const float* __restrict__ ba,
    const u16* __restrict__ BLk, const float* __restrict__ bk,
    const u16* __restrict__ BLv, const float* __restrict__ bv,
    const u16* __restrict__ BLq, const float* __restrict__ bq,
    const float* __restrict__ qc, const float* __restrict__ priw,
    u16* __restrict__ hw, u8* __restrict__ kv, u8* __restrict__ vp,
    float* __restrict__ uf, u16* __restrict__ qout, int n)
{
  __shared__ u16 lds16[64 * LDSW];
  const int tid = threadIdx.x, lane = tid & 63, w = tid >> 6;
  int rl = blockIdx.x * 64 + w * 16 + (lane & 15);
  if (rl >= n) rl = n - 1;
  const int row = word_ids[rl];
  const int g = lane >> 4;

  bf16x8 a10[10];
  const u16* Ap = wtab + (size_t)row * 320 + g * 8;
  #pragma unroll
  for (int s = 0; s < 10; ++s) a10[s] = *reinterpret_cast<const bf16x8*>(Ap + s * 32);

  const int rr = tid >> 2, cs = (tid & 3) * 32, m = blockIdx.x * 64 + rr;

  f32x4 acc[8];
  #pragma unroll
  for (int t = 0; t < 8; ++t) acc[t] = (f32x4)0.f;
  {
    const u16* Bp = BLa + (size_t)lane * 8;
    #pragma unroll
    for (int s = 0; s < 10; ++s) {
      #pragma unroll
      for (int t = 0; t < 8; ++t) {
        bf16x8 bfr = *reinterpret_cast<const bf16x8*>(Bp + (size_t)(t * 10 + s) * 512);
        acc[t] = __builtin_amdgcn_mfma_f32_16x16x32_bf16(a10[s], bfr, acc[t], 0, 0, 0);
      }
    }
  }
  #pragma unroll
  for (int t = 0; t < 8; ++t) {
    const int col = t * 16 + (lane & 15);
    const float bb = ba[col];
    const int mr = w * 16 + g * 4;
    #pragma unroll
    for (int j = 0; j < 4; ++j)
      lds16[(mr + j) * LDSW + col] = f2bf(tanhf(acc[t][j] + bb));
  }
  __syncthreads();
  if (m < n) bf16_write_row(lds16, rr, cs, hw, m);
  bf16x8 an[4];
  {
    const int rloc = w * 16 + (lane & 15);
    #pragma unroll
    for (int s = 0; s < 4; ++s)
      an[s] = *reinterpret_cast<const bf16x8*>(&lds16[rloc * LDSW + s * 32 + g * 8]);
  }
  __syncthreads();

  // k (+u)
  #pragma unroll
  for (int t = 0; t < 8; ++t) acc[t] = (f32x4)0.f;
  GEMM_ACC(an, BLk)
  ACC_TO_LDS(bk)
  __syncthreads();
  float u_keep = 0.f;
  if (m < n) {
    kv_write_half(lds16, rr, cs, kv, m, 0);
    float dot = lds_qc_dot(lds16, rr, cs, qc);
    u_keep = __expf(dot * (priw[cs >> 5] * 0.17677669529663687f));
    uf[m * 4 + (cs >> 5)] = u_keep;
  }
  // v (+vp)
  #pragma unroll
  for (int t = 0; t < 8; ++t) acc[t] = (f32x4)0.f;
  GEMM_ACC(an, BLv)
  __syncthreads();
  ACC_TO_LDS(bv)
  __syncthreads();
  if (m < n) {
    kv_write_half(lds16, rr, cs, kv, m, 1);
    vp_write(lds16, rr, cs, u_keep, vp, m);
  }
  // q_ww
  #pragma unroll
  for (int t = 0; t < 8; ++t) acc[t] = (f32x4)0.f;
  GEMM_ACC(an, BLq)
  __syncthreads();
  ACC_TO_LDS(bq)
  __syncthreads();
  if (m < n) bf16_write_row(lds16, rr, cs, qout, m);
}

// ======================= L1 topic k/v GEMM =======================
__global__ __launch_bounds__(256) void gemm_kv_kernel(
    const u16* __restrict__ A,
    const u16* __restrict__ BLk, const float* __restrict__ bk,
    const u16* __restrict__ BLv, const float* __restrict__ bv,
    u8* __restrict__ kv, int n)
{
  __shared__ u16 lds16[64 * LDSW];
  const int tid = threadIdx.x, lane = tid & 63, w = tid >> 6;
  int rl = blockIdx.x * 64 + w * 16 + (lane & 15);
  if (rl >= n) rl = n - 1;
  const int g = lane >> 4;
  bf16x8 a[4];
  const u16* Ap = A + (size_t)rl * 128 + g * 8;
  #pragma unroll
  for (int s = 0; s < 4; ++s) a[s] = *reinterpret_cast<const bf16x8*>(Ap + s * 32);
  const int rr = tid >> 2, cs = (tid & 3) * 32, m = blockIdx.x * 64 + rr;

  f32x4 acc[8];
  #pragma unroll
  for (int t = 0; t < 8; ++t) acc[t] = (f32x4)0.f;
  GEMM_ACC(a, BLk)
  ACC_TO_LDS(bk)
  __syncthreads();
  if (m < n) kv_write_half(lds16, rr, cs, kv, m, 0);

  #pragma unroll
  for (int t = 0; t < 8; ++t) acc[t] = (f32x4)0.f;
  GEMM_ACC(a, BLv)
  __syncthreads();
  ACC_TO_LDS(bv)
  __syncthreads();
  if (m < n) kv_write_half(lds16, rr, cs, kv, m, 1);
}

// ======================= L0 topic projections =======================
__global__ __launch_bounds__(256) void gemmN_l0t_kernel(
    const u16* __restrict__ A,
    const u16* __restrict__ BLk, const float* __restrict__ bk,
    const u16* __restrict__ BLv, const float* __restrict__ bv,
    const u16* __restrict__ BLq0, const float* __restrict__ bq0,
    const u16* __restrict__ BLq1, const float* __restrict__ bq1,
    const float* __restrict__ qc, const float* __restrict__ prit,
    u8* __restrict__ kv, u8* __restrict__ vp, float* __restrict__ uf,
    u16* __restrict__ q0, u16* __restrict__ q1, int n)
{
  __shared__ u16 lds16[64 * LDSW];
  const int tid = threadIdx.x, lane = tid & 63, w = tid >> 6;
  int rl = blockIdx.x * 64 + w * 16 + (lane & 15);
  if (rl >= n) rl = n - 1;
  const int g = lane >> 4;
  bf16x8 a[4];
  const u16* Ap = A + (size_t)rl * 128 + g * 8;
  #pragma unroll
  for (int s = 0; s < 4; ++s) a[s] = *reinterpret_cast<const bf16x8*>(Ap + s * 32);
  const int rr = tid >> 2, cs = (tid & 3) * 32, m = blockIdx.x * 64 + rr;

  f32x4 acc[8];
  #pragma unroll
  for (int t = 0; t < 8; ++t) acc[t] = (f32x4)0.f;
  GEMM_ACC(a, BLk)
  ACC_TO_LDS(bk)
  __syncthreads();
  float u_keep = 0.f;
  if (m < n) {
    kv_write_half(lds16, rr, cs, kv, m, 0);
    float dot = lds_qc_dot(lds16, rr, cs, qc);
    u_keep = __expf(dot * (prit[cs >> 5] * 0.17677669529663687f));
    uf[m * 4 + (cs >> 5)] = u_keep;
  }
  #pragma unroll
  for (int t = 0; t < 8; ++t) acc[t] = (f32x4)0.f;
  GEMM_ACC(a, BLv)
  __syncthreads();
  ACC_TO_LDS(bv)
  __syncthreads();
  if (m < n) {
    kv_write_half(lds16, rr, cs, kv, m, 1);
    vp_write(lds16, rr, cs, u_keep, vp, m);
  }
  #pragma unroll
  for (int t = 0; t < 8; ++t) acc[t] = (f32x4)0.f;
  GEMM_ACC(a, BLq0)
  __syncthreads();
  ACC_TO_LDS(bq0)
  __syncthreads();
  if (m < n) bf16_write_row(lds16, rr, cs, q0, m);

  #pragma unroll
  for (int t = 0; t < 8; ++t) acc[t] = (f32x4)0.f;
  GEMM_ACC(a, BLq1)
  __syncthreads();
  ACC_TO_LDS(bq1)
  __syncthreads();
  if (m < n) bf16_write_row(lds16, rr, cs, q1, m);
}

// ======================= dual-A comb GEMM =======================
template<int KS>
__global__ __launch_bounds__(256) void gemm2_kernel(
    const u16* __restrict__ A2, const u16* __restrict__ BL0, const u16* __restrict__ BL1,
    const float* __restrict__ bias, u16* __restrict__ C,
    const float* __restrict__ skipp, int n)
{
  __shared__ u16 lds16[64 * LDSW];
  const int tid = threadIdx.x, lane = tid & 63, w = tid >> 6;
  int rl = blockIdx.x * 64 + w * 16 + (lane & 15);
  if (rl >= n) rl = n - 1;
  const int g = lane >> 4;

  bf16x8 a0[KS], a1[KS];
  const u16* Ap = A2 + (size_t)rl * 256 + g * 8;
  #pragma unroll
  for (int s = 0; s < KS; ++s) {
    a0[s] = *reinterpret_cast<const bf16x8*>(Ap + s * 32);
    a1[s] = *reinterpret_cast<const bf16x8*>(Ap + 128 + s * 32);
  }
  f32x4 acc[8];
  #pragma unroll
  for (int t = 0; t < 8; ++t) acc[t] = (f32x4)0.f;
  const u16* Bp0 = BL0 + (size_t)lane * 8;
  const u16* Bp1 = BL1 + (size_t)lane * 8;
  #pragma unroll
  for (int s = 0; s < KS; ++s) {
    #pragma unroll
    for (int t = 0; t < 8; ++t) {
      bf16x8 b0 = *reinterpret_cast<const bf16x8*>(Bp0 + (size_t)(t * KS + s) * 512);
      acc[t] = __builtin_amdgcn_mfma_f32_16x16x32_bf16(a0[s], b0, acc[t], 0, 0, 0);
      bf16x8 b1 = *reinterpret_cast<const bf16x8*>(Bp1 + (size_t)(t * KS + s) * 512);
      acc[t] = __builtin_amdgcn_mfma_f32_16x16x32_bf16(a1[s], b1, acc[t], 0, 0, 0);
    }
  }
  ACC_TO_LDS(bias)
  __syncthreads();
  const int rr = tid >> 2, cs = (tid & 3) * 32, m = blockIdx.x * 64 + rr;
  if (m < n) {
    const float aa = 1.f / (1.f + __expf(-skipp[0]));
    #pragma unroll
    for (int q2 = 0; q2 < 4; ++q2) {
      uint4 pr = *reinterpret_cast<const uint4*>(&lds16[rr * LDSW + cs + q2 * 8]);
      uint4 blv = *reinterpret_cast<const uint4*>(C + (size_t)m * 128 + cs + q2 * 8);
      uint4 st;
      st.x = blend2(pr.x, blv.x, aa);
      st.y = blend2(pr.y, blv.y, aa);
      st.z = blend2(pr.z, blv.z, aa);
      st.w = blend2(pr.w, blv.w, aa);
      *reinterpret_cast<uint4*>(C + (size_t)m * 128 + cs + q2 * 8) = st;
    }
  }
}

// ======================= fused comb_d(L0, blend=0) + L1 doc q projections =======================
__global__ __launch_bounds__(256) void comb_dq_kernel(
    const u16* __restrict__ A2, const u16* __restrict__ BL0, const u16* __restrict__ BL1,
    const float* __restrict__ bias, const float* __restrict__ skipp,
    const u16* __restrict__ BLq0, const float* __restrict__ bq0,
    const u16* __restrict__ BLq1, const float* __restrict__ bq1,
    u16* __restrict__ hd, u16* __restrict__ q0, u16* __restrict__ q1, int n)
{
  __shared__ u16 lds16[64 * LDSW];
  const int tid = threadIdx.x, lane = tid & 63, w = tid >> 6;
  int rl = blockIdx.x * 64 + w * 16 + (lane & 15);
  if (rl >= n) rl = n - 1;
  const int g = lane >> 4;

  bf16x8 a0[4], a1[4];
  const u16* Ap = A2 + (size_t)rl * 256 + g * 8;
  #pragma unroll
  for (int s = 0; s < 4; ++s) {
    a0[s] = *reinterpret_cast<const bf16x8*>(Ap + s * 32);
    a1[s] = *reinterpret_cast<const bf16x8*>(Ap + 128 + s * 32);
  }
  f32x4 acc[8];
  #pragma unroll
  for (int t = 0; t < 8; ++t) acc[t] = (f32x4)0.f;
  {
    const u16* Bp0 = BL0 + (size_t)lane * 8;
    const u16* Bp1 = BL1 + (size_t)lane * 8;
    #pragma unroll
    for (int s = 0; s < 4; ++s) {
      #pragma unroll
      for (int t = 0; t < 8; ++t) {
        bf16x8 b0 = *reinterpret_cast<const bf16x8*>(Bp0 + (size_t)(t * 4 + s) * 512);
        acc[t] = __builtin_amdgcn_mfma_f32_16x16x32_bf16(a0[s], b0, acc[t], 0, 0, 0);
        bf16x8 b1 = *reinterpret_cast<const bf16x8*>(Bp1 + (size_t)(t * 4 + s) * 512);
        acc[t] = __builtin_amdgcn_mfma_f32_16x16x32_bf16(a1[s], b1, acc[t], 0, 0, 0);
      }
    }
  }
  const float aa = 1.f / (1.f + __expf(-skipp[0]));
  #pragma unroll
  for (int t = 0; t < 8; ++t) {
    const int col = t * 16 + (lane & 15);
    const float bb = bias[col];
    const int mr = w * 16 + g * 4;
    #pragma unroll
    for (int j = 0; j < 4; ++j)
      lds16[(mr + j) * LDSW + col] = f2bf((acc[t][j] + bb) * aa);
  }
  __syncthreads();
  const int rr = tid >> 2, cs = (tid & 3) * 32, m = blockIdx.x * 64 + rr;
  if (m < n) bf16_write_row(lds16, rr, cs, hd, m);
  bf16x8 an[4];
  {
    const int rloc = w * 16 + (lane & 15);
    #pragma unroll
    for (int s = 0; s < 4; ++s)
      an[s] = *reinterpret_cast<const bf16x8*>(&lds16[rloc * LDSW + s * 32 + g * 8]);
  }
  #pragma unroll
  for (int t = 0; t < 8; ++t) acc[t] = (f32x4)0.f;
  GEMM_ACC(an, BLq0)
  __syncthreads();
  ACC_TO_LDS(bq0)
  __syncthreads();
  if (m < n) bf16_write_row(lds16, rr, cs, q0, m);
  #pragma unroll
  for (int t = 0; t < 8; ++t) acc[t] = (f32x4)0.f;
  GEMM_ACC(an, BLq1)
  __syncthreads();
  ACC_TO_LDS(bq1)
  __syncthreads();
  if (m < n) bf16_write_row(lds16, rr, cs, q1, m);
}

// ======================= fused comb_w(L0) + L1 word k/v =======================
__global__ __launch_bounds__(256) void comb_kv_kernel(
    const u16* __restrict__ Aw, const u16* __restrict__ hwold,
    const u16* __restrict__ BLc, const float* __restrict__ bc,
    const u16* __restrict__ BLk, const float* __restrict__ bk,
    const u16* __restrict__ BLv, const float* __restrict__ bv,
    const float* __restrict__ skipp, u8* __restrict__ kv, int n)
{
  __shared__ u16 lds16[64 * LDSW];
  const int tid = threadIdx.x, lane = tid & 63, w = tid >> 6;
  int rl = blockIdx.x * 64 + w * 16 + (lane & 15);
  if (rl >= n) rl = n - 1;
  const int g = lane >> 4;

  bf16x8 a[4];
  const u16* Ap = Aw + (size_t)rl * 128 + g * 8;
  #pragma unroll
  for (int s = 0; s < 4; ++s) a[s] = *reinterpret_cast<const bf16x8*>(Ap + s * 32);

  f32x4 acc[8];
  #pragma unroll
  for (int t = 0; t < 8; ++t) acc[t] = (f32x4)0.f;
  GEMM_ACC(a, BLc)
  ACC_TO_LDS(bc)
  __syncthreads();
  const int rr = tid >> 2, cs = (tid & 3) * 32, m = blockIdx.x * 64 + rr;
  if (m < n) {
    const float aa = 1.f / (1.f + __expf(-skipp[0]));
    #pragma unroll
    for (int q2 = 0; q2 < 4; ++q2) {
      uint4 pr = *reinterpret_cast<const uint4*>(&lds16[rr * LDSW + cs + q2 * 8]);
      uint4 blv = *reinterpret_cast<const uint4*>(hwold + (size_t)m * 128 + cs + q2 * 8);
      uint4 st;
      st.x = blend2(pr.x, blv.x, aa);
      st.y = blend2(pr.y, blv.y, aa);
      st.z = blend2(pr.z, blv.z, aa);
      st.w = blend2(pr.w, blv.w, aa);
      *reinterpret_cast<uint4*>(&lds16[rr * LDSW + cs + q2 * 8]) = st;
    }
  }
  __syncthreads();
  bf16x8 an[4];
  {
    const int rloc = w * 16 + (lane & 15);
    #pragma unroll
    for (int s = 0; s < 4; ++s)
      an[s] = *reinterpret_cast<const bf16x8*>(&lds16[rloc * LDSW + s * 32 + g * 8]);
  }
  #pragma unroll
  for (int t = 0; t < 8; ++t) acc[t] = (f32x4)0.f;
  GEMM_ACC(an, BLk)
  __syncthreads();
  ACC_TO_LDS(bk)
  __syncthreads();
  if (m < n) kv_write_half(lds16, rr, cs, kv, m, 0);
  #pragma unroll
  for (int t = 0; t < 8; ++t) acc[t] = (f32x4)0.f;
  GEMM_ACC(an, BLv)
  __syncthreads();
  ACC_TO_LDS(bv)
  __syncthreads();
  if (m < n) kv_write_half(lds16, rr, cs, kv, m, 1);
}

// ======================= misc small kernels =======================
__global__ void conv_wtab_kernel(const float* __restrict__ we, u16* __restrict__ wt) {
  int i = blockIdx.x * 256 + threadIdx.x;
  if (i < VOCAB * 320) {
    int r = i / 320, c = i - r * 320;
    wt[i] = (c < 300) ? f2bf(we[(size_t)r * 300 + c]) : (u16)0;
  }
}

__global__ void gather_topic_kernel(const float* __restrict__ emb, const int* __restrict__ ids,
                                    u16* __restrict__ out) {
  int i = blockIdx.x * 256 + threadIdx.x;
  if (i < N_TOPIC * 128) {
    int node = i >> 7, c = i & 127;
    out[i] = f2bf(emb[(size_t)ids[node] * 128 + c]);
  }
}

// ======================= CSR build =======================
__global__ void count_rank_kernel(const int* __restrict__ td, const int* __restrict__ wd,
                                  const int* __restrict__ tt, const int* __restrict__ wt,
                                  const int* __restrict__ ww, int* cnt, int* __restrict__ rank) {
  int i = blockIdx.x * 256 + threadIdx.x;
  if (i >= EDGES_ALL) return;
  int b;
  if (i < 80000)       b = td[i];
  else if (i < 330000) b = 32000 + wd[i - 80000];
  else if (i < 350000) b = 64000 + tt[i - 330000];
  else if (i < 450000) b = 64800 + wt[i - 350000];
  else                 b = 65600 + ww[i - 450000];
  rank[i] = atomicAdd(&cnt[b], 1);
}

__global__ void fill_rank_kernel(const int* __restrict__ td_s, const int* __restrict__ td_d,
                                 const int* __restrict__ wd_s, const int* __restrict__ wd_d,
                                 const int* __restrict__ tt_s, const int* __restrict__ tt_d,
                                 const int* __restrict__ wt_s, const int* __restrict__ wt_d,
                                 const int* __restrict__ ww_s, const int* __restrict__ ww_d,
                                 const int* __restrict__ offs, const int* __restrict__ rank,
                                 int* __restrict__ csrc) {
  int i = blockIdx.x * 256 + threadIdx.x;
  if (i >= EDGES_ALL) return;
  int b, s;
  if (i < 80000)       { b = td_d[i];                  s = td_s[i]; }
  else if (i < 330000) { b = 32000 + wd_d[i - 80000];  s = wd_s[i - 80000]; }
  else if (i < 350000) { b = 64000 + tt_d[i - 330000]; s = tt_s[i - 330000]; }
  else if (i < 450000) { b = 64800 + wt_d[i - 350000]; s = wt_s[i - 350000]; }
  else                 { b = 65600 + ww_d[i - 450000]; s = ww_s[i - 450000]; }
  csrc[offs[b] + rank[i]] = s;
}

__global__ __launch_bounds__(256) void scanA_kernel(const int* __restrict__ cnt, int* __restrict__ bsum) {
  const int tid = threadIdx.x, lane = tid & 63, wv = tid >> 6;
  const int i4 = blockIdx.x * 256 + tid;
  int4 v = make_int4(0, 0, 0, 0);
  if (i4 < N4_SCAN) v = reinterpret_cast<const int4*>(cnt)[i4];
  int s = v.x + v.y + v.z + v.w;
  #pragma unroll
  for (int d = 1; d < 64; d <<= 1) s += __shfl_xor(s, d);
  __shared__ int ws[4];
  if (lane == 0) ws[wv] = s;
  __syncthreads();
  if (tid == 0) bsum[blockIdx.x] = ws[0] + ws[1] + ws[2] + ws[3];
}

__global__ __launch_bounds__(256) void scanB_kernel(const int* __restrict__ bsum,
                                                    int* __restrict__ bpre, int* __restrict__ offs,
                                                    unsigned* __restrict__ g) {
  const int tid = threadIdx.x, lane = tid & 63, wv = tid >> 6;
  int v = (tid < NBLK_SCAN) ? bsum[tid] : 0;
  int incl = wave_iscan(v, lane);
  __shared__ int ws[4];
  if (lane == 63) ws[wv] = incl;
  __syncthreads();
  int pre = 0;
  for (int j = 0; j < 4; ++j) if (j < wv) pre += ws[j];
  incl += pre;
  if (tid < NBLK_SCAN) bpre[tid] = incl - v;
  if (tid == NBLK_SCAN - 1) offs[NODES_ALL] = incl;
  for (int i = tid; i < BATCH * H_DIM; i += 256) g[i] = 0x007FFFFFu;
}

__global__ __launch_bounds__(256) void scanC_kernel(const int* __restrict__ cnt,
                                                    const int* __restrict__ bpre,
                                                    int* __restrict__ offs) {
  const int tid = threadIdx.x, lane = tid & 63, wv = tid >> 6;
  const int i4 = blockIdx.x * 256 + tid;
  int4 v = make_int4(0, 0, 0, 0);
  if (i4 < N4_SCAN) v = reinterpret_cast<const int4*>(cnt)[i4];
  const int tsum = v.x + v.y + v.z + v.w;
  int incl = wave_iscan(tsum, lane);
  __shared__ int ws[4];
  if (lane == 63) ws[wv] = incl;
  __syncthreads();
  int pre = bpre[blockIdx.x];
  for (int j = 0; j < 4; ++j) if (j < wv) pre += ws[j];
  int o0 = pre + incl - tsum;
  if (i4 < N4_SCAN) {
    int4 ov = make_int4(o0, o0 + v.x, o0 + v.x + v.y, o0 + v.x + v.y + v.z);
    reinterpret_cast<int4*>(offs)[i4] = ov;
  }
}

// ======================= aggregation =======================
struct AggArgs {
  const u16 *q_td, *q_wd, *q_tt, *q_wt, *q_ww;
  const u8 *kv_t, *kv_w, *vp_t, *vp_w;
  const float *uf_t, *uf_w;
  const int *csrc, *offs;
  const float *pri;
  u16 *t2_d, *t2_t, *t_w;
};

static __device__ __forceinline__ void butterfly4(
    f32x2 acc0, f32x2 acc1, f32x2 acc2, f32x2 acc3, float ss,
    int lane, f32x2& red, float& ss_out)
{
  ss += __shfl_xor(ss, 16); ss += __shfl_xor(ss, 32);
  const bool h16 = (lane & 16) != 0, h32 = (lane & 32) != 0;
  f32x2 k0 = h16 ? acc2 : acc0;
  f32x2 k1 = h16 ? acc3 : acc1;
  f32x2 s0 = h16 ? acc0 : acc2;
  f32x2 s1 = h16 ? acc1 : acc3;
  k0[0] += __shfl_xor(s0[0], 16); k0[1] += __shfl_xor(s0[1], 16);
  k1[0] += __shfl_xor(s1[0], 16); k1[1] += __shfl_xor(s1[1], 16);
  f32x2 kk = h32 ? k1 : k0;
  f32x2 sd = h32 ? k0 : k1;
  kk[0] += __shfl_xor(sd[0], 32); kk[1] += __shfl_xor(sd[1], 32);
  red = kk; ss_out = ss;
}

static __device__ __forceinline__ void agg_core(
    const u16* __restrict__ q, const u8* __restrict__ kv,
    const int* __restrict__ offs, const int* __restrict__ csrc,
    const float* __restrict__ pri,
    int node, int grp, int stride, int sl, int lane,
    f32x2& red, float& ss_out)
{
  const int e0 = offs[node], e1 = offs[node + 1];
  f32x2 acc0 = (f32x2)0.f, acc1 = (f32x2)0.f, acc2 = (f32x2)0.f, acc3 = (f32x2)0.f;
  float ss = 0.f;
  if (e1 > e0) {
    const float prih = pri[sl >> 2] * 0.17677669529663687f;
    const bf16x8 qv = *reinterpret_cast<const bf16x8*>(q + (size_t)node * 128 + sl * 8);
    f32x2 q2[4];
    #pragma unroll
    for (int p = 0; p < 4; ++p) {
      f32x2 t; t[0] = b2f((u16)qv[2 * p]); t[1] = b2f((u16)qv[2 * p + 1]); q2[p] = t;
    }
    const int last = e1 - 1;
    for (int base = e0; base < e1; base += 2 * stride) {
      const int eA = base + grp, eB = base + stride + grp;
      const bool vA = eA < e1, vB = eB < e1;
      const int sA = csrc[vA ? eA : last];
      const int sB = csrc[vB ? eB : last];
      const uint4 cA = *reinterpret_cast<const uint4*>(kv + (size_t)sA * 256 + sl * 16);
      const uint4 cB = *reinterpret_cast<const uint4*>(kv + (size_t)sB * 256 + sl * 16);
      f32x2 dA = q2[0] * cvt8<false>((int)cA.x);
      dA += q2[1] * cvt8<true>((int)cA.x);
      dA += q2[2] * cvt8<false>((int)cA.y);
      dA += q2[3] * cvt8<true>((int)cA.y);
      f32x2 dB = q2[0] * cvt8<false>((int)cB.x);
      dB += q2[1] * cvt8<true>((int)cB.x);
      dB += q2[2] * cvt8<false>((int)cB.y);
      dB += q2[3] * cvt8<true>((int)cB.y);
      float dotA = dA[0] + dA[1];
      float dotB = dB[0] + dB[1];
      dotA += __shfl_xor(dotA, 1); dotA += __shfl_xor(dotA, 2);
      dotB += __shfl_xor(dotB, 1); dotB += __shfl_xor(dotB, 2);
      const float wA = vA ? __expf(dotA * prih) : 0.f;
      const float wB = vB ? __expf(dotB * prih) : 0.f;
      ss += wA + wB;
      f32x2 wA2; wA2[0] = wA; wA2[1] = wA;
      f32x2 wB2; wB2[0] = wB; wB2[1] = wB;
      acc0 += wA2 * cvt8<false>((int)cA.z);
      acc1 += wA2 * cvt8<true>((int)cA.z);
      acc2 += wA2 * cvt8<false>((int)cA.w);
      acc3 += wA2 * cvt8<true>((int)cA.w);
      acc0 += wB2 * cvt8<false>((int)cB.z);
      acc1 += wB2 * cvt8<true>((int)cB.z);
      acc2 += wB2 * cvt8<false>((int)cB.w);
      acc3 += wB2 * cvt8<true>((int)cB.w);
    }
  }
  butterfly4(acc0, acc1, acc2, acc3, ss, lane, red, ss_out);
}

static __device__ __forceinline__ void agg_docu(
    const u8* __restrict__ vp, const float* __restrict__ uf,
    const int* __restrict__ offs, const int* __restrict__ csrc,
    int node, int sub, int sl, int lane,
    f32x2& red, float& ss_out)
{
  const int e0 = offs[node], e1 = offs[node + 1];
  f32x2 acc0 = (f32x2)0.f, acc1 = (f32x2)0.f, acc2 = (f32x2)0.f, acc3 = (f32x2)0.f;
  float ss = 0.f;
  if (e1 > e0) {
    const int h = sl >> 2;
    const int last = e1 - 1;
    for (int base = e0; base < e1; base += 8) {
      const int eA = base + sub, eB = base + 4 + sub;
      const bool vA = eA < e1, vB = eB < e1;
      const int sA = csrc[vA ? eA : last];
      const int sB = csrc[vB ? eB : last];
      uint2 cA = *reinterpret_cast<const uint2*>(vp + (size_t)sA * 128 + sl * 8);
      uint2 cB = *reinterpret_cast<const uint2*>(vp + (size_t)sB * 128 + sl * 8);
      float uA = uf[sA * 4 + h];
      float uB = uf[sB * 4 + h];
      if (!vA) { cA = make_uint2(0u, 0u); uA = 0.f; }
      if (!vB) { cB = make_uint2(0u, 0u); uB = 0.f; }
      ss += uA + uB;
      acc0 += cvt8<false>((int)cA.x); acc1 += cvt8<true>((int)cA.x);
      acc2 += cvt8<false>((int)cA.y); acc3 += cvt8<true>((int)cA.y);
      acc0 += cvt8<false>((int)cB.x); acc1 += cvt8<true>((int)cB.x);
      acc2 += cvt8<false>((int)cB.y); acc3 += cvt8<true>((int)cB.y);
    }
  }
  butterfly4(acc0, acc1, acc2, acc3, ss, lane, red, ss_out);
}

static __device__ __forceinline__ int chbase_of(int lane) {
  return (lane & 15) * 8 + ((lane >> 4) & 1) * 4 + ((lane >> 5) & 1) * 2;
}

template<int DOCU>
__global__ __launch_bounds__(256) void agg_all_kernel(AggArgs A, int topic_n)
{
  __shared__ float lacc[4][128];
  __shared__ float lssA[4];
  const int tid = threadIdx.x, lane = tid & 63, wv = tid >> 6;
  const int sub = lane >> 4, sl = lane & 15;
  const int bid = blockIdx.x;
  const int chb = chbase_of(lane);
  f32x2 red; float ss;

  if (bid < topic_n) {
    const int node = bid;
    for (int r = 0; r < 2; ++r) {
      agg_core(r ? A.q_wt : A.q_tt, r ? A.kv_w : A.kv_t,
               A.offs + (r ? 64800 : 64000), A.csrc, A.pri + (r ? 12 : 4),
               node, wv * 4 + sub, 16, sl, lane, red, ss);
      lacc[wv][chb] = red[0]; lacc[wv][chb + 1] = red[1];
      if (lane == 0) lssA[wv] = ss;
      __syncthreads();
      if (tid < 128) {
        float a = lacc[0][tid] + lacc[1][tid] + lacc[2][tid] + lacc[3][tid];
        float st = lssA[0] + lssA[1] + lssA[2] + lssA[3];
        float inv = (st > 0.f) ? 1.f / st : 0.f;
        A.t2_t[(size_t)node * 256 + r * 128 + tid] = f2bf(a * inv);
      }
      __syncthreads();
    }
  } else if (bid < topic_n + 8000) {
    const int node = (bid - topic_n) * 4 + wv;
    if (DOCU) {
      agg_docu(A.vp_t, A.uf_t, A.offs + 0, A.csrc, node, sub, sl, lane, red, ss);
    } else {
      agg_core(A.q_td, A.kv_t, A.offs + 0, A.csrc, A.pri + 0, node, sub, 4, sl, lane, red, ss);
    }
    {
      float inv = (ss > 0.f) ? 1.f / ss : 0.f;
      unsigned pk = (unsigned)f2bf(red[0] * inv) | ((unsigned)f2bf(red[1] * inv) << 16);
      *reinterpret_cast<unsigned*>(A.t2_d + (size_t)node * 256 + chb) = pk;
    }
    if (DOCU) {
      agg_docu(A.vp_w, A.uf_w, A.offs + 32000, A.csrc, node, sub, sl, lane, red, ss);
    } else {
      agg_core(A.q_wd, A.kv_w, A.offs + 32000, A.csrc, A.pri + 8, node, sub, 4, sl, lane, red, ss);
    }
    {
      float inv = (ss > 0.f) ? 1.f / ss : 0.f;
      unsigned pk = (unsigned)f2bf(red[0] * inv) | ((unsigned)f2bf(red[1] * inv) << 16);
      *reinterpret_cast<unsigned*>(A.t2_d + (size_t)node * 256 + 128 + chb) = pk;
    }
  } else {
    const int node = (bid - topic_n - 8000) * 4 + wv;
    agg_core(A.q_ww, A.kv_w, A.offs + 65600, A.csrc, A.pri + 16, node, sub, 4, sl, lane, red, ss);
    float inv = (ss > 0.f) ? 1.f / ss : 0.f;
    unsigned pk = (unsigned)f2bf(red[0] * inv) | ((unsigned)f2bf(red[1] * inv) << 16);
    *reinterpret_cast<unsigned*>(A.t_w + (size_t)node * 128 + chb) = pk;
  }
}

// ======================= readout =======================
__global__ void segmax_kernel(const u16* __restrict__ hd, const int* __restrict__ gid,
                              unsigned* g) {
  int c = threadIdx.x;
  int d0 = blockIdx.x * 128;
  int dend = min(d0 + 128, N_DOC);
  int cur = -1; float m = 0.f;
  for (int d = d0; d < dend; ++d) {
    int gg = gid[d];
    float v = b2f(hd[(size_t)d * 128 + c]);
    if (gg != cur) {
      if (cur >= 0) atomicMax(&g[cur * 128 + c], fenc(m));
      cur = gg; m = v;
    } else {
      m = fmaxf(m, v);
    }
  }
  if (cur >= 0) atomicMax(&g[cur * 128 + c], fenc(m));
}

__global__ void final_kernel(const unsigned* __restrict__ g, const float* __restrict__ out_w,
                             const float* __restrict__ out_b, const float* __restrict__ y,
                             float* out) {
  int tid = threadIdx.x;
  int b = tid >> 4, seg = tid & 15;
  float p = 0.f;
  #pragma unroll
  for (int j = 0; j < 8; ++j) {
    int c = seg * 8 + j;
    p += fdec(g[b * 128 + c]) * out_w[c];
  }
  p += __shfl_xor(p, 1);
  p += __shfl_xor(p, 2);
  p += __shfl_xor(p, 4);
  p += __shfl_xor(p, 8);
  __shared__ float logits[BATCH];
  __shared__ float losses[BATCH];
  if (seg == 0) logits[b] = p + out_b[0];
  __syncthreads();
  if (tid < BATCH) {
    float l = logits[tid];
    out[1 + tid] = 1.f / (1.f + expf(-l));
    float ls_pos = (l > 0.f) ? -log1pf(expf(-l)) : l - log1pf(expf(l));
    float ls_neg = (l < 0.f) ? -log1pf(expf(l)) : -l - log1pf(expf(-l));
    losses[tid] = -(y[tid] * ls_pos + (1.f - y[tid]) * ls_neg);
  }
  __syncthreads();
  if (tid == 0) {
    float s = 0.f;
    for (int j = 0; j < BATCH; ++j) s += losses[j];
    out[0] = s / (float)BATCH;
  }
}

// ======================= host =======================
extern "C" void kernel_launch(void* const* d_in, const int* in_sizes, int n_in,
                              void* d_out, int out_size, void* d_ws, size_t ws_size,
                              hipStream_t stream)
{
  const float* word_embeds  = (const float*)d_in[0];
  const float* topic_embeds = (const float*)d_in[1];
  const float* KW  = (const float*)d_in[2];
  const float* Kb  = (const float*)d_in[3];
  const float* QW  = (const float*)d_in[4];
  const float* Qb  = (const float*)d_in[5];
  const float* VW  = (const float*)d_in[6];
  const float* Vb  = (const float*)d_in[7];
  const float* AW  = (const float*)d_in[8];
  const float* Ab  = (const float*)d_in[9];
  const float* rel_att = (const float*)d_in[10];
  const float* rel_msg = (const float*)d_in[11];
  const float* rel_pri = (const float*)d_in[12];
  const float* skip    = (const float*)d_in[13];
  const float* adapt_w = (const float*)d_in[14];
  const float* adapt_b = (const float*)d_in[15];
  const float* out_w   = (const float*)d_in[16];
  const float* out_b   = (const float*)d_in[17];
  const float* y_data  = (const float*)d_in[18];
  const int* word_ids  = (const int*)d_in[19];
  const int* topic_ids = (const int*)d_in[20];
  const int* doc_gid   = (const int*)d_in[21];
  const int* td_src = (const int*)d_in[22];
  const int* td_dst = (const int*)d_in[23];
  const int* tt_src = (const int*)d_in[24];
  const int* tt_dst = (const int*)d_in[25];
  const int* wd_src = (const int*)d_in[26];
  const int* wd_dst = (const int*)d_in[27];
  const int* wt_src = (const int*)d_in[28];
  const int* wt_dst = (const int*)d_in[29];
  const int* ww_src = (const int*)d_in[30];
  const int* ww_dst = (const int*)d_in[31];

  char* base = (char*)d_ws;
  size_t off_b = 0;
  auto alloc = [&](size_t bytes) -> char* {
    char* p = base + off_b;
    off_b = (off_b + bytes + 255) & ~(size_t)255;
    return p;
  };

  u16* wtab = (u16*)alloc((size_t)VOCAB * 320 * 2);
  u16* hw   = (u16*)alloc((size_t)N_WORD * 128 * 2);
  u16* hd   = (u16*)alloc((size_t)N_DOC * 128 * 2);
  u16* ht   = (u16*)alloc((size_t)N_TOPIC * 128 * 2);
  u8*  kv_w = (u8*)alloc((size_t)N_WORD * 256);
  u8*  kv_t = (u8*)alloc((size_t)N_TOPIC * 256);
  u8*  vp_w = (u8*)alloc((size_t)N_WORD * 128);
  u8*  vp_t = (u8*)alloc((size_t)N_TOPIC * 128);
  float* uf_w = (float*)alloc((size_t)N_WORD * 4 * 4);
  float* uf_t = (float*)alloc((size_t)N_TOPIC * 4 * 4);
  u16* q_td = (u16*)alloc((size_t)N_DOC * 128 * 2);
  u16* q_wd = (u16*)alloc((size_t)N_DOC * 128 * 2);
  u16* q_tt = (u16*)alloc((size_t)N_TOPIC * 128 * 2);
  u16* q_wt = (u16*)alloc((size_t)N_TOPIC * 128 * 2);
  u16* q_ww = (u16*)alloc((size_t)N_WORD * 128 * 2);
  u16* t2_d = (u16*)alloc((size_t)N_DOC * 256 * 2);
  u16* t2_t = (u16*)alloc((size_t)N_TOPIC * 256 * 2);
  u16* t_w  = (u16*)alloc((size_t)N_WORD * 128 * 2);
  unsigned* g = (unsigned*)alloc((size_t)BATCH * 128 * 4);

  int* cnt_all  = (int*)alloc((size_t)NODES_ALL * 4);
  int* offs_all = (int*)alloc(((size_t)NODES_ALL + 1) * 4);
  int* csrc_all = (int*)alloc((size_t)EDGES_ALL * 4);
  int* rank_all = (int*)alloc((size_t)EDGES_ALL * 4);
  int* bsum     = (int*)alloc((size_t)NBLK_SCAN * 4);
  int* bpre     = (int*)alloc((size_t)NBLK_SCAN * 4);

  u16* blw        = (u16*)alloc((size_t)(40960 + 28 * 16384) * 2);
  float* bias_are = (float*)alloc((size_t)29 * 128 * 4);

  auto BLp = [&](int wid) -> const u16* {
    return (wid == 0) ? blw : blw + 40960 + (size_t)(wid - 1) * 16384;
  };
  auto BIp = [&](int wid) -> const float* { return bias_are + wid * 128; };
  auto WID = [&](int li, int j) { return 1 + li * 14 + j; };

  // ---- prep ----
  prep_kernel<<<29 * 8, 256, 0, stream>>>(KW, Kb, QW, Qb, VW, Vb, AW, Ab,
                                          rel_att, rel_msg, adapt_w, adapt_b, blw, bias_are);
  conv_wtab_kernel<<<(VOCAB * 320 + 255) / 256, 256, 0, stream>>>(word_embeds, wtab);
  gather_topic_kernel<<<(N_TOPIC * 128 + 255) / 256, 256, 0, stream>>>(topic_embeds, topic_ids, ht);

  hipMemsetAsync(cnt_all, 0, (size_t)NODES_ALL * 4, stream);
  count_rank_kernel<<<(EDGES_ALL + 255) / 256, 256, 0, stream>>>(
      td_dst, wd_dst, tt_dst, wt_dst, ww_dst, cnt_all, rank_all);
  scanA_kernel<<<NBLK_SCAN, 256, 0, stream>>>(cnt_all, bsum);
  scanB_kernel<<<1, 256, 0, stream>>>(bsum, bpre, offs_all, g);
  scanC_kernel<<<NBLK_SCAN, 256, 0, stream>>>(cnt_all, bpre, offs_all);
  fill_rank_kernel<<<(EDGES_ALL + 255) / 256, 256, 0, stream>>>(
      td_src, td_dst, wd_src, wd_dst, tt_src, tt_dst, wt_src, wt_dst, ww_src, ww_dst,
      offs_all, rank_all, csrc_all);

  const int GW = (N_WORD + 63) / 64, GD = (N_DOC + 63) / 64, GT = (N_TOPIC + 63) / 64;

  // ================= layer 0 =================
  adapt_l0w_kernel<<<GW, 256, 0, stream>>>(
      wtab, word_ids,
      BLp(0), BIp(0),
      BLp(WID(0, 1)), BIp(WID(0, 1)),
      BLp(WID(0, 3)), BIp(WID(0, 3)),
      BLp(WID(0, 8)), BIp(WID(0, 8)),
      BIp(WID(0, 6)), rel_pri + 8,
      hw, kv_w, vp_w, uf_w, q_ww, N_WORD);
  gemmN_l0t_kernel<<<GT, 256, 0, stream>>>(
      ht,
      BLp(WID(0, 0)), BIp(WID(0, 0)),
      BLp(WID(0, 2)), BIp(WID(0, 2)),
      BLp(WID(0, 5)), BIp(WID(0, 5)),
      BLp(WID(0, 7)), BIp(WID(0, 7)),
      BIp(WID(0, 4)), rel_pri + 0,
      kv_t, vp_t, uf_t, q_tt, q_wt, N_TOPIC);

  AggArgs A0;
  A0.q_td = q_td; A0.q_wd = q_wd; A0.q_tt = q_tt; A0.q_wt = q_wt; A0.q_ww = q_ww;
  A0.kv_t = kv_t; A0.kv_w = kv_w; A0.vp_t = vp_t; A0.vp_w = vp_w;
  A0.uf_t = uf_t; A0.uf_w = uf_w;
  A0.csrc = csrc_all; A0.offs = offs_all;
  A0.pri = rel_pri;
  A0.t2_d = t2_d; A0.t2_t = t2_t; A0.t_w = t_w;
  agg_all_kernel<1><<<28800, 256, 0, stream>>>(A0, 800);

  comb_dq_kernel<<<GD, 256, 0, stream>>>(
      t2_d, BLp(WID(0, 9)), BLp(WID(0, 11)), BIp(WID(0, 9)), skip + 0,
      BLp(WID(1, 4)), BIp(WID(1, 4)), BLp(WID(1, 6)), BIp(WID(1, 6)),
      hd, q_td, q_wd, N_DOC);
  gemm2_kernel<4><<<GT, 256, 0, stream>>>(t2_t, BLp(WID(0, 10)), BLp(WID(0, 12)),
                                          BIp(WID(0, 10)), ht, skip + 1, N_TOPIC);
  comb_kv_kernel<<<GW, 256, 0, stream>>>(
      t_w, hw, BLp(WID(0, 13)), BIp(WID(0, 13)),
      BLp(WID(1, 1)), BIp(WID(1, 1)), BLp(WID(1, 3)), BIp(WID(1, 3)),
      skip + 2, kv_w, N_WORD);

  // ================= layer 1 =================
  gemm_kv_kernel<<<GT, 256, 0, stream>>>(
      ht, BLp(WID(1, 0)), BIp(WID(1, 0)), BLp(WID(1, 2)), BIp(WID(1, 2)), kv_t, N_TOPIC);

  AggArgs A1 = A0;
  A1.pri = rel_pri + 20;
  agg_all_kernel<0><<<8000, 256, 0, stream>>>(A1, 0);

  gemm2_kernel<4><<<GD, 256, 0, stream>>>(t2_d, BLp(WID(1, 9)), BLp(WID(1, 11)),
                                          BIp(WID(1, 9)), hd, skip + 3, N_DOC);

  // ---- readout ----
  segmax_kernel<<<(N_DOC + 127) / 128, 128, 0, stream>>>(hd, doc_gid, g);
  final_kernel<<<1, 256, 0, stream>>>(g, out_w, out_b, y_data, (float*)d_out);
}

// Round 11
// 372.808 us; speedup vs baseline: 12.4335x; 1.0127x over previous
//
#include <hip/hip_runtime.h>
#include <cstdint>
#include <cstddef>

#define H_DIM 128
#define N_DOC 32000
#define N_TOPIC 800
#define N_WORD 80000
#define BATCH 16
#define VOCAB 15000
#define NODES_ALL 145600
#define EDGES_ALL 850000
#define NBLK_SCAN 143
#define N4_SCAN 36400
#define LDSW 136   // u16 row stride: 272 B, 16B-aligned

typedef short bf16x8 __attribute__((ext_vector_type(8)));
typedef float f32x4 __attribute__((ext_vector_type(4)));
typedef float f32x2 __attribute__((ext_vector_type(2)));
typedef unsigned short u16;
typedef unsigned char u8;

static __device__ __forceinline__ u16 f2bf(float x) {
  unsigned u = __float_as_uint(x);
  u += 0x7fffu + ((u >> 16) & 1u);
  return (u16)(u >> 16);
}
static __device__ __forceinline__ float b2f(unsigned h) {
  return __uint_as_float(h << 16);
}
static __device__ __forceinline__ unsigned fenc(float f) {
  unsigned u = __float_as_uint(f);
  return (u & 0x80000000u) ? ~u : (u | 0x80000000u);
}
static __device__ __forceinline__ float fdec(unsigned k) {
  return (k & 0x80000000u) ? __uint_as_float(k ^ 0x80000000u) : __uint_as_float(~k);
}
static __device__ __forceinline__ int wave_iscan(int v, int lane) {
  #pragma unroll
  for (int d = 1; d < 64; d <<= 1) {
    int t = __shfl_up(v, d);
    if (lane >= d) v += t;
  }
  return v;
}
static __device__ __forceinline__ unsigned blend2(unsigned pr, unsigned bl, float aa) {
  float v0 = b2f(pr & 0xffffu) * aa + b2f(bl & 0xffffu) * (1.f - aa);
  float v1 = b2f(pr >> 16) * aa + b2f(bl >> 16) * (1.f - aa);
  return (unsigned)f2bf(v0) | ((unsigned)f2bf(v1) << 16);
}
template<bool HI>
static __device__ __forceinline__ f32x2 cvt8(int w) {
  return __builtin_amdgcn_cvt_pk_f32_fp8(w, HI);
}

// ======================= weight prep =======================
__global__ __launch_bounds__(256) void prep_kernel(
    const float* __restrict__ KW, const float* __restrict__ Kb,
    const float* __restrict__ QW, const float* __restrict__ Qb,
    const float* __restrict__ VW, const float* __restrict__ Vb,
    const float* __restrict__ AW, const float* __restrict__ Ab,
    const float* __restrict__ rel_att, const float* __restrict__ rel_msg,
    const float* __restrict__ adapt_w, const float* __restrict__ adapt_b,
    u16* __restrict__ bl_arena, float* __restrict__ bias_arena)
{
  const int wid = blockIdx.x >> 3, t = blockIdx.x & 7;
  int KS, Kreal, fold;
  const float *W, *b, *R = nullptr;
  float scale = 1.f;
  if (wid == 0) { KS = 10; Kreal = 300; fold = 0; W = adapt_w; b = adapt_b; }
  else {
    KS = 4; Kreal = 128;
    const int wl = wid - 1, li = wl / 14, j = wl % 14;
    const int dstnid[5] = {0, 1, 0, 1, 2};
    if (j < 4) {
      fold = 0;
      const float* Wb = (j < 2) ? KW : VW;
      const float* bb = (j < 2) ? Kb : Vb;
      const int nid = (j & 1) ? 2 : 1;
      W = Wb + ((size_t)li * 3 + nid) * 16384; b = bb + ((size_t)li * 3 + nid) * 128;
    } else if (j < 9) {
      fold = 1; const int r = j - 4; const int nid = dstnid[r];
      W = QW + ((size_t)li * 3 + nid) * 16384; b = Qb + ((size_t)li * 3 + nid) * 128;
      R = rel_att + ((size_t)li * 5 + r) * 4096;
    } else {
      fold = 3; const int r = j - 9; const int nid = dstnid[r];
      W = AW + ((size_t)li * 3 + nid) * 16384; b = Ab + ((size_t)li * 3 + nid) * 128;
      R = rel_msg + ((size_t)li * 5 + r) * 4096;
      scale = (r == 4) ? 1.f : 0.5f;
    }
  }
  u16* obl = (wid == 0) ? bl_arena : bl_arena + 40960 + (size_t)(wid - 1) * 16384;
  float* obias = bias_arena + wid * 128;

  const int nelem = KS * 512;
  for (int e = threadIdx.x; e < nelem; e += 256) {
    const int s = e >> 9, rem = e & 511, l = rem >> 3, jj = rem & 7;
    const int k = s * 32 + ((l >> 4) << 3) + jj;
    const int nn = t * 16 + (l & 15);
    float v = 0.f;
    if (k < Kreal) {
      if (fold == 0) v = W[(size_t)k * 128 + nn];
      else if (fold == 1) {
        const int h = nn >> 5, d = nn & 31;
        const float* Wr = W + (size_t)k * 128 + h * 32;
        const float* Rh = R + h * 1024;
        for (int f = 0; f < 32; ++f) v += Wr[f] * Rh[d * 32 + f];
      } else {
        const int h = k >> 5, dd = k & 31;
        const float* Rh = R + h * 1024 + dd * 32;
        const float* Wc = W + (size_t)h * 32 * 128 + nn;
        float sa = 0.f;
        for (int f = 0; f < 32; ++f) sa += Rh[f] * Wc[(size_t)f * 128];
        v = sa * scale;
      }
    }
    obl[(size_t)(t * KS + s) * 512 + rem] = f2bf(v);
  }
  if (t == 0 && threadIdx.x < 128) {
    const int nn = threadIdx.x;
    float v = 0.f;
    if (fold != 1) v = b[nn];
    else {
      const int h = nn >> 5, d = nn & 31;
      const float* Rh = R + h * 1024;
      for (int f = 0; f < 32; ++f) v += b[h * 32 + f] * Rh[d * 32 + f];
    }
    obias[nn] = v;
  }
}

// ======================= GEMM helpers (wave-local tiles, no barriers) =======================
static __device__ __forceinline__ void kv_write_half(
    const u16* lds16, int rr, int cs, u8* kv, size_t m, int vhalf)
{
  u8* Cp = kv + m * 256 + (cs >> 3) * 16 + (vhalf ? 8 : 0);
  #pragma unroll
  for (int q2 = 0; q2 < 4; ++q2) {
    uint4 ld = *reinterpret_cast<const uint4*>(&lds16[rr * LDSW + cs + q2 * 8]);
    int t0 = __builtin_amdgcn_cvt_pk_fp8_f32(b2f(ld.x & 0xffffu), b2f(ld.x >> 16), 0, false);
    unsigned w0 = (unsigned)__builtin_amdgcn_cvt_pk_fp8_f32(b2f(ld.y & 0xffffu), b2f(ld.y >> 16), t0, true);
    int t1 = __builtin_amdgcn_cvt_pk_fp8_f32(b2f(ld.z & 0xffffu), b2f(ld.z >> 16), 0, false);
    unsigned w1 = (unsigned)__builtin_amdgcn_cvt_pk_fp8_f32(b2f(ld.w & 0xffffu), b2f(ld.w >> 16), t1, true);
    *reinterpret_cast<uint2*>(Cp + q2 * 16) = make_uint2(w0, w1);
  }
}

static __device__ __forceinline__ void bf16_write_row(
    const u16* lds16, int rr, int cs, u16* C, size_t m)
{
  u16* Cp = C + m * 128 + cs;
  #pragma unroll
  for (int q2 = 0; q2 < 4; ++q2)
    *reinterpret_cast<uint4*>(Cp + q2 * 8) =
        *reinterpret_cast<const uint4*>(&lds16[rr * LDSW + cs + q2 * 8]);
}

#define GEMM_ACC(AV, BLP)                                                        \
  {                                                                              \
    const u16* Bp = (BLP) + (size_t)lane * 8;                                    \
    _Pragma("unroll")                                                            \
    for (int s = 0; s < 4; ++s) {                                                \
      _Pragma("unroll")                                                          \
      for (int t = 0; t < 8; ++t) {                                              \
        bf16x8 bfr = *reinterpret_cast<const bf16x8*>(Bp + (size_t)(t * 4 + s) * 512); \
        acc[t] = __builtin_amdgcn_mfma_f32_16x16x32_bf16(AV[s], bfr, acc[t], 0, 0, 0); \
      }                                                                          \
    }                                                                            \
  }

// wave-local: wave w writes rows w*16+g*4+j  (g = lane>>4)
#define ACC_TO_LDS(BIAS)                                                         \
  {                                                                              \
    _Pragma("unroll")                                                            \
    for (int t = 0; t < 8; ++t) {                                                \
      const int col = t * 16 + (lane & 15);                                      \
      const float bb = (BIAS)[col];                                              \
      const int mr = w * 16 + g * 4;                                             \
      _Pragma("unroll")                                                          \
      for (int j = 0; j < 4; ++j)                                                \
        lds16[(mr + j) * LDSW + col] = f2bf(acc[t][j] + bb);                     \
    }                                                                            \
  }

static __device__ __forceinline__ float lds_qc_dot(
    const u16* lds16, int rr, int cs, const float* __restrict__ qc)
{
  float dot = 0.f;
  #pragma unroll
  for (int q2 = 0; q2 < 4; ++q2) {
    uint4 ld = *reinterpret_cast<const uint4*>(&lds16[rr * LDSW + cs + q2 * 8]);
    float4 qa = *reinterpret_cast<const float4*>(&qc[cs + q2 * 8]);
    float4 qb = *reinterpret_cast<const float4*>(&qc[cs + q2 * 8 + 4]);
    dot += b2f(ld.x & 0xffffu) * qa.x + b2f(ld.x >> 16) * qa.y
         + b2f(ld.y & 0xffffu) * qa.z + b2f(ld.y >> 16) * qa.w
         + b2f(ld.z & 0xffffu) * qb.x + b2f(ld.z >> 16) * qb.y
         + b2f(ld.w & 0xffffu) * qb.z + b2f(ld.w >> 16) * qb.w;
  }
  return dot;
}

static __device__ __forceinline__ void vp_write(
    const u16* lds16, int rr, int cs, float u_keep, u8* vp, size_t m)
{
  unsigned wpk[8];
  #pragma unroll
  for (int q2 = 0; q2 < 4; ++q2) {
    uint4 ld = *reinterpret_cast<const uint4*>(&lds16[rr * LDSW + cs + q2 * 8]);
    int t0 = __builtin_amdgcn_cvt_pk_fp8_f32(u_keep * b2f(ld.x & 0xffffu), u_keep * b2f(ld.x >> 16), 0, false);
    wpk[2 * q2] = (unsigned)__builtin_amdgcn_cvt_pk_fp8_f32(u_keep * b2f(ld.y & 0xffffu), u_keep * b2f(ld.y >> 16), t0, true);
    int t1 = __builtin_amdgcn_cvt_pk_fp8_f32(u_keep * b2f(ld.z & 0xffffu), u_keep * b2f(ld.z >> 16), 0, false);
    wpk[2 * q2 + 1] = (unsigned)__builtin_amdgcn_cvt_pk_fp8_f32(u_keep * b2f(ld.w & 0xffffu), u_keep * b2f(ld.w >> 16), t1, true);
  }
  *reinterpret_cast<uint4*>(vp + m * 128 + cs)      = make_uint4(wpk[0], wpk[1], wpk[2], wpk[3]);
  *reinterpret_cast<uint4*>(vp + m * 128 + cs + 16) = make_uint4(wpk[4], wpk[5], wpk[6], wpk[7]);
}

// ======================= fused adapt + L0 word projections (barrier-free) =======================
__global__ __launch_bounds__(256) void adapt_l0w_kernel(
    const u16* __restrict__ wtab, const int* __restrict__ word_ids,
    const u16* __restrict__ BLa, const float* __restrict__ ba,
    const u16* __restrict__ BLk, const float* __restrict__ bk,
    const u16* __restrict__ BLv, const float* __restrict__ bv,
    const u16* __restrict__ BLq, const float* __restrict__ bq,
    const float* __restrict__ qc, const float* __restrict__ priw,
    u16* __restrict__ hw, u8* __restrict__ kv, u8* __restrict__ vp,
    float* __restrict__ uf, u16* __restrict__ qout, int n)
{
  __shared__ u16 lds16[64 * LDSW];
  const int tid = threadIdx.x, lane = tid & 63, w = tid >> 6;
  int rl = blockIdx.x * 64 + w * 16 + (lane & 15);
  if (rl >= n) rl = n - 1;
  const int row = word_ids[rl];
  const int g = lane >> 4;

  bf16x8 a10[10];
  const u16* Ap = wtab + (size_t)row * 320 + g * 8;
  #pragma unroll
  for (int s = 0; s < 10; ++s) a10[s] = *reinterpret_cast<const bf16x8*>(Ap + s * 32);

  // wave-local epilogue mapping
  const int rr = w * 16 + (lane >> 2), cs = (lane & 3) * 32;
  const int m = blockIdx.x * 64 + rr;

  f32x4 acc[8];
  #pragma unroll
  for (int t = 0; t < 8; ++t) acc[t] = (f32x4)0.f;
  {
    const u16* Bp = BLa + (size_t)lane * 8;
    #pragma unroll
    for (int s = 0; s < 10; ++s) {
      #pragma unroll
      for (int t = 0; t < 8; ++t) {
        bf16x8 bfr = *reinterpret_cast<const bf16x8*>(Bp + (size_t)(t * 10 + s) * 512);
        acc[t] = __builtin_amdgcn_mfma_f32_16x16x32_bf16(a10[s], bfr, acc[t], 0, 0, 0);
      }
    }
  }
  #pragma unroll
  for (int t = 0; t < 8; ++t) {
    const int col = t * 16 + (lane & 15);
    const float bb = ba[col];
    const int mr = w * 16 + g * 4;
    #pragma unroll
    for (int j = 0; j < 4; ++j)
      lds16[(mr + j) * LDSW + col] = f2bf(tanhf(acc[t][j] + bb));
  }
  if (m < n) bf16_write_row(lds16, rr, cs, hw, m);
  bf16x8 an[4];
  {
    const int rloc = w * 16 + (lane & 15);
    #pragma unroll
    for (int s = 0; s < 4; ++s)
      an[s] = *reinterpret_cast<const bf16x8*>(&lds16[rloc * LDSW + s * 32 + g * 8]);
  }

  // k (+u)
  #pragma unroll
  for (int t = 0; t < 8; ++t) acc[t] = (f32x4)0.f;
  GEMM_ACC(an, BLk)
  ACC_TO_LDS(bk)
  float u_keep = 0.f;
  if (m < n) {
    kv_write_half(lds16, rr, cs, kv, m, 0);
    float dot = lds_qc_dot(lds16, rr, cs, qc);
    u_keep = __expf(dot * (priw[cs >> 5] * 0.17677669529663687f));
    uf[m * 4 + (cs >> 5)] = u_keep;
  }
  // v (+vp)
  #pragma unroll
  for (int t = 0; t < 8; ++t) acc[t] = (f32x4)0.f;
  GEMM_ACC(an, BLv)
  ACC_TO_LDS(bv)
  if (m < n) {
    kv_write_half(lds16, rr, cs, kv, m, 1);
    vp_write(lds16, rr, cs, u_keep, vp, m);
  }
  // q_ww
  #pragma unroll
  for (int t = 0; t < 8; ++t) acc[t] = (f32x4)0.f;
  GEMM_ACC(an, BLq)
  ACC_TO_LDS(bq)
  if (m < n) bf16_write_row(lds16, rr, cs, qout, m);
}

// ======================= L1 topic k/v GEMM =======================
__global__ __launch_bounds__(256) void gemm_kv_kernel(
    const u16* __restrict__ A,
    const u16* __restrict__ BLk, const float* __restrict__ bk,
    const u16* __restrict__ BLv, const float* __restrict__ bv,
    u8* __restrict__ kv, int n)
{
  __shared__ u16 lds16[64 * LDSW];
  const int tid = threadIdx.x, lane = tid & 63, w = tid >> 6;
  int rl = blockIdx.x * 64 + w * 16 + (lane & 15);
  if (rl >= n) rl = n - 1;
  const int g = lane >> 4;
  bf16x8 a[4];
  const u16* Ap = A + (size_t)rl * 128 + g * 8;
  #pragma unroll
  for (int s = 0; s < 4; ++s) a[s] = *reinterpret_cast<const bf16x8*>(Ap + s * 32);
  const int rr = w * 16 + (lane >> 2), cs = (lane & 3) * 32;
  const int m = blockIdx.x * 64 + rr;

  f32x4 acc[8];
  #pragma unroll
  for (int t = 0; t < 8; ++t) acc[t] = (f32x4)0.f;
  GEMM_ACC(a, BLk)
  ACC_TO_LDS(bk)
  if (m < n) kv_write_half(lds16, rr, cs, kv, m, 0);

  #pragma unroll
  for (int t = 0; t < 8; ++t) acc[t] = (f32x4)0.f;
  GEMM_ACC(a, BLv)
  ACC_TO_LDS(bv)
  if (m < n) kv_write_half(lds16, rr, cs, kv, m, 1);
}

// ======================= L0 topic projections =======================
__global__ __launch_bounds__(256) void gemmN_l0t_kernel(
    const u16* __restrict__ A,
    const u16* __restrict__ BLk, const float* __restrict__ bk,
    const u16* __restrict__ BLv, const float* __restrict__ bv,
    const u16* __restrict__ BLq0, const float* __restrict__ bq0,
    const u16* __restrict__ BLq1, const float* __restrict__ bq1,
    const float* __restrict__ qc, const float* __restrict__ prit,
    u8* __restrict__ kv, u8* __restrict__ vp, float* __restrict__ uf,
    u16* __restrict__ q0, u16* __restrict__ q1, int n)
{
  __shared__ u16 lds16[64 * LDSW];
  const int tid = threadIdx.x, lane = tid & 63, w = tid >> 6;
  int rl = blockIdx.x * 64 + w * 16 + (lane & 15);
  if (rl >= n) rl = n - 1;
  const int g = lane >> 4;
  bf16x8 a[4];
  const u16* Ap = A + (size_t)rl * 128 + g * 8;
  #pragma unroll
  for (int s = 0; s < 4; ++s) a[s] = *reinterpret_cast<const bf16x8*>(Ap + s * 32);
  const int rr = w * 16 + (lane >> 2), cs = (lane & 3) * 32;
  const int m = blockIdx.x * 64 + rr;

  f32x4 acc[8];
  #pragma unroll
  for (int t = 0; t < 8; ++t) acc[t] = (f32x4)0.f;
  GEMM_ACC(a, BLk)
  ACC_TO_LDS(bk)
  float u_keep = 0.f;
  if (m < n) {
    kv_write_half(lds16, rr, cs, kv, m, 0);
    float dot = lds_qc_dot(lds16, rr, cs, qc);
    u_keep = __expf(dot * (prit[cs >> 5] * 0.17677669529663687f));
    uf[m * 4 + (cs >> 5)] = u_keep;
  }
  #pragma unroll
  for (int t = 0; t < 8; ++t) acc[t] = (f32x4)0.f;
  GEMM_ACC(a, BLv)
  ACC_TO_LDS(bv)
  if (m < n) {
    kv_write_half(lds16, rr, cs, kv, m, 1);
    vp_write(lds16, rr, cs, u_keep, vp, m);
  }
  #pragma unroll
  for (int t = 0; t < 8; ++t) acc[t] = (f32x4)0.f;
  GEMM_ACC(a, BLq0)
  ACC_TO_LDS(bq0)
  if (m < n) bf16_write_row(lds16, rr, cs, q0, m);

  #pragma unroll
  for (int t = 0; t < 8; ++t) acc[t] = (f32x4)0.f;
  GEMM_ACC(a, BLq1)
  ACC_TO_LDS(bq1)
  if (m < n) bf16_write_row(lds16, rr, cs, q1, m);
}

// ======================= dual-A comb GEMM =======================
template<int KS>
__global__ __launch_bounds__(256) void gemm2_kernel(
    const u16* __restrict__ A2, const u16* __restrict__ BL0, const u16* __restrict__ BL1,
    const float* __restrict__ bias, u16* __restrict__ C,
    const float* __restrict__ skipp, int n)
{
  __shared__ u16 lds16[64 * LDSW];
  const int tid = threadIdx.x, lane = tid & 63, w = tid >> 6;
  int rl = blockIdx.x * 64 + w * 16 + (lane & 15);
  if (rl >= n) rl = n - 1;
  const int g = lane >> 4;

  bf16x8 a0[KS], a1[KS];
  const u16* Ap = A2 + (size_t)rl * 256 + g * 8;
  #pragma unroll
  for (int s = 0; s < KS; ++s) {
    a0[s] = *reinterpret_cast<const bf16x8*>(Ap + s * 32);
    a1[s] = *reinterpret_cast<const bf16x8*>(Ap + 128 + s * 32);
  }
  f32x4 acc[8];
  #pragma unroll
  for (int t = 0; t < 8; ++t) acc[t] = (f32x4)0.f;
  const u16* Bp0 = BL0 + (size_t)lane * 8;
  const u16* Bp1 = BL1 + (size_t)lane * 8;
  #pragma unroll
  for (int s = 0; s < KS; ++s) {
    #pragma unroll
    for (int t = 0; t < 8; ++t) {
      bf16x8 b0 = *reinterpret_cast<const bf16x8*>(Bp0 + (size_t)(t * KS + s) * 512);
      acc[t] = __builtin_amdgcn_mfma_f32_16x16x32_bf16(a0[s], b0, acc[t], 0, 0, 0);
      bf16x8 b1 = *reinterpret_cast<const bf16x8*>(Bp1 + (size_t)(t * KS + s) * 512);
      acc[t] = __builtin_amdgcn_mfma_f32_16x16x32_bf16(a1[s], b1, acc[t], 0, 0, 0);
    }
  }
  ACC_TO_LDS(bias)
  const int rr = w * 16 + (lane >> 2), cs = (lane & 3) * 32;
  const int m = blockIdx.x * 64 + rr;
  if (m < n) {
    const float aa = 1.f / (1.f + __expf(-skipp[0]));
    #pragma unroll
    for (int q2 = 0; q2 < 4; ++q2) {
      uint4 pr = *reinterpret_cast<const uint4*>(&lds16[rr * LDSW + cs + q2 * 8]);
      uint4 blv = *reinterpret_cast<const uint4*>(C + (size_t)m * 128 + cs + q2 * 8);
      uint4 st;
      st.x = blend2(pr.x, blv.x, aa);
      st.y = blend2(pr.y, blv.y, aa);
      st.z = blend2(pr.z, blv.z, aa);
      st.w = blend2(pr.w, blv.w, aa);
      *reinterpret_cast<uint4*>(C + (size_t)m * 128 + cs + q2 * 8) = st;
    }
  }
}

// ======================= fused comb_d(L0, blend=0) + L1 doc q projections =======================
__global__ __launch_bounds__(256) void comb_dq_kernel(
    const u16* __restrict__ A2, const u16* __restrict__ BL0, const u16* __restrict__ BL1,
    const float* __restrict__ bias, const float* __restrict__ skipp,
    const u16* __restrict__ BLq0, const float* __restrict__ bq0,
    const u16* __restrict__ BLq1, const float* __restrict__ bq1,
    u16* __restrict__ hd, u16* __restrict__ q0, u16* __restrict__ q1, int n)
{
  __shared__ u16 lds16[64 * LDSW];
  const int tid = threadIdx.x, lane = tid & 63, w = tid >> 6;
  int rl = blockIdx.x * 64 + w * 16 + (lane & 15);
  if (rl >= n) rl = n - 1;
  const int g = lane >> 4;

  bf16x8 a0[4], a1[4];
  const u16* Ap = A2 + (size_t)rl * 256 + g * 8;
  #pragma unroll
  for (int s = 0; s < 4; ++s) {
    a0[s] = *reinterpret_cast<const bf16x8*>(Ap + s * 32);
    a1[s] = *reinterpret_cast<const bf16x8*>(Ap + 128 + s * 32);
  }
  f32x4 acc[8];
  #pragma unroll
  for (int t = 0; t < 8; ++t) acc[t] = (f32x4)0.f;
  {
    const u16* Bp0 = BL0 + (size_t)lane * 8;
    const u16* Bp1 = BL1 + (size_t)lane * 8;
    #pragma unroll
    for (int s = 0; s < 4; ++s) {
      #pragma unroll
      for (int t = 0; t < 8; ++t) {
        bf16x8 b0 = *reinterpret_cast<const bf16x8*>(Bp0 + (size_t)(t * 4 + s) * 512);
        acc[t] = __builtin_amdgcn_mfma_f32_16x16x32_bf16(a0[s], b0, acc[t], 0, 0, 0);
        bf16x8 b1 = *reinterpret_cast<const bf16x8*>(Bp1 + (size_t)(t * 4 + s) * 512);
        acc[t] = __builtin_amdgcn_mfma_f32_16x16x32_bf16(a1[s], b1, acc[t], 0, 0, 0);
      }
    }
  }
  const float aa = 1.f / (1.f + __expf(-skipp[0]));
  #pragma unroll
  for (int t = 0; t < 8; ++t) {
    const int col = t * 16 + (lane & 15);
    const float bb = bias[col];
    const int mr = w * 16 + g * 4;
    #pragma unroll
    for (int j = 0; j < 4; ++j)
      lds16[(mr + j) * LDSW + col] = f2bf((acc[t][j] + bb) * aa);
  }
  const int rr = w * 16 + (lane >> 2), cs = (lane & 3) * 32;
  const int m = blockIdx.x * 64 + rr;
  if (m < n) bf16_write_row(lds16, rr, cs, hd, m);
  bf16x8 an[4];
  {
    const int rloc = w * 16 + (lane & 15);
    #pragma unroll
    for (int s = 0; s < 4; ++s)
      an[s] = *reinterpret_cast<const bf16x8*>(&lds16[rloc * LDSW + s * 32 + g * 8]);
  }
  #pragma unroll
  for (int t = 0; t < 8; ++t) acc[t] = (f32x4)0.f;
  GEMM_ACC(an, BLq0)
  ACC_TO_LDS(bq0)
  if (m < n) bf16_write_row(lds16, rr, cs, q0, m);
  #pragma unroll
  for (int t = 0; t < 8; ++t) acc[t] = (f32x4)0.f;
  GEMM_ACC(an, BLq1)
  ACC_TO_LDS(bq1)
  if (m < n) bf16_write_row(lds16, rr, cs, q1, m);
}

// ======================= fused comb_w(L0) + L1 word k/v =======================
__global__ __launch_bounds__(256) void comb_kv_kernel(
    const u16* __restrict__ Aw, const u16* __restrict__ hwold,
    const u16* __restrict__ BLc, const float* __restrict__ bc,
    const u16* __restrict__ BLk, const float* __restrict__ bk,
    const u16* __restrict__ BLv, const float* __restrict__ bv,
    const float* __restrict__ skipp, u8* __restrict__ kv, int n)
{
  __shared__ u16 lds16[64 * LDSW];
  const int tid = threadIdx.x, lane = tid & 63, w = tid >> 6;
  int rl = blockIdx.x * 64 + w * 16 + (lane & 15);
  if (rl >= n) rl = n - 1;
  const int g = lane >> 4;

  bf16x8 a[4];
  const u16* Ap = Aw + (size_t)rl * 128 + g * 8;
  #pragma unroll
  for (int s = 0; s < 4; ++s) a[s] = *reinterpret_cast<const bf16x8*>(Ap + s * 32);

  f32x4 acc[8];
  #pragma unroll
  for (int t = 0; t < 8; ++t) acc[t] = (f32x4)0.f;
  GEMM_ACC(a, BLc)
  ACC_TO_LDS(bc)
  const int rr = w * 16 + (lane >> 2), cs = (lane & 3) * 32;
  const int m = blockIdx.x * 64 + rr;
  if (m < n) {
    const float aa = 1.f / (1.f + __expf(-skipp[0]));
    #pragma unroll
    for (int q2 = 0; q2 < 4; ++q2) {
      uint4 pr = *reinterpret_cast<const uint4*>(&lds16[rr * LDSW + cs + q2 * 8]);
      uint4 blv = *reinterpret_cast<const uint4*>(hwold + (size_t)m * 128 + cs + q2 * 8);
      uint4 st;
      st.x = blend2(pr.x, blv.x, aa);
      st.y = blend2(pr.y, blv.y, aa);
      st.z = blend2(pr.z, blv.z, aa);
      st.w = blend2(pr.w, blv.w, aa);
      *reinterpret_cast<uint4*>(&lds16[rr * LDSW + cs + q2 * 8]) = st;
    }
  }
  bf16x8 an[4];
  {
    const int rloc = w * 16 + (lane & 15);
    #pragma unroll
    for (int s = 0; s < 4; ++s)
      an[s] = *reinterpret_cast<const bf16x8*>(&lds16[rloc * LDSW + s * 32 + g * 8]);
  }
  #pragma unroll
  for (int t = 0; t < 8; ++t) acc[t] = (f32x4)0.f;
  GEMM_ACC(an, BLk)
  ACC_TO_LDS(bk)
  if (m < n) kv_write_half(lds16, rr, cs, kv, m, 0);
  #pragma unroll
  for (int t = 0; t < 8; ++t) acc[t] = (f32x4)0.f;
  GEMM_ACC(an, BLv)
  ACC_TO_LDS(bv)
  if (m < n) kv_write_half(lds16, rr, cs, kv, m, 1);
}

// ======================= misc small kernels =======================
__global__ void conv_wtab_kernel(const float* __restrict__ we, u16* __restrict__ wt) {
  int i = blockIdx.x * 256 + threadIdx.x;
  if (i < VOCAB * 320) {
    int r = i / 320, c = i - r * 320;
    wt[i] = (c < 300) ? f2bf(we[(size_t)r * 300 + c]) : (u16)0;
  }
}

__global__ void gather_topic_kernel(const float* __restrict__ emb, const int* __restrict__ ids,
                                    u16* __restrict__ out) {
  int i = blockIdx.x * 256 + threadIdx.x;
  if (i < N_TOPIC * 128) {
    int node = i >> 7, c = i & 127;
    out[i] = f2bf(emb[(size_t)ids[node] * 128 + c]);
  }
}

// ======================= CSR build =======================
__global__ void count_rank_kernel(const int* __restrict__ td, const int* __restrict__ wd,
                                  const int* __restrict__ tt, const int* __restrict__ wt,
                                  const int* __restrict__ ww, int* cnt, int* __restrict__ rank) {
  int i = blockIdx.x * 256 + threadIdx.x;
  if (i >= EDGES_ALL) return;
  int b;
  if (i < 80000)       b = td[i];
  else if (i < 330000) b = 32000 + wd[i - 80000];
  else if (i < 350000) b = 64000 + tt[i - 330000];
  else if (i < 450000) b = 64800 + wt[i - 350000];
  else                 b = 65600 + ww[i - 450000];
  rank[i] = atomicAdd(&cnt[b], 1);
}

__global__ void fill_rank_kernel(const int* __restrict__ td_s, const int* __restrict__ td_d,
                                 const int* __restrict__ wd_s, const int* __restrict__ wd_d,
                                 const int* __restrict__ tt_s, const int* __restrict__ tt_d,
                                 const int* __restrict__ wt_s, const int* __restrict__ wt_d,
                                 const int* __restrict__ ww_s, const int* __restrict__ ww_d,
                                 const int* __restrict__ offs, const int* __restrict__ rank,
                                 int* __restrict__ csrc) {
  int i = blockIdx.x * 256 + threadIdx.x;
  if (i >= EDGES_ALL) return;
  int b, s;
  if (i < 80000)       { b = td_d[i];                  s = td_s[i]; }
  else if (i < 330000) { b = 32000 + wd_d[i - 80000];  s = wd_s[i - 80000]; }
  else if (i < 350000) { b = 64000 + tt_d[i - 330000]; s = tt_s[i - 330000]; }
  else if (i < 450000) { b = 64800 + wt_d[i - 350000]; s = wt_s[i - 350000]; }
  else                 { b = 65600 + ww_d[i - 450000]; s = ww_s[i - 450000]; }
  csrc[offs[b] + rank[i]] = s;
}

__global__ __launch_bounds__(256) void scanA_kernel(const int* __restrict__ cnt, int* __restrict__ bsum) {
  const int tid = threadIdx.x, lane = tid & 63, wv = tid >> 6;
  const int i4 = blockIdx.x * 256 + tid;
  int4 v = make_int4(0, 0, 0, 0);
  if (i4 < N4_SCAN) v = reinterpret_cast<const int4*>(cnt)[i4];
  int s = v.x + v.y + v.z + v.w;
  #pragma unroll
  for (int d = 1; d < 64; d <<= 1) s += __shfl_xor(s, d);
  __shared__ int ws[4];
  if (lane == 0) ws[wv] = s;
  __syncthreads();
  if (tid == 0) bsum[blockIdx.x] = ws[0] + ws[1] + ws[2] + ws[3];
}

__global__ __launch_bounds__(256) void scanB_kernel(const int* __restrict__ bsum,
                                                    int* __restrict__ bpre, int* __restrict__ offs,
                                                    unsigned* __restrict__ g) {
  const int tid = threadIdx.x, lane = tid & 63, wv = tid >> 6;
  int v = (tid < NBLK_SCAN) ? bsum[tid] : 0;
  int incl = wave_iscan(v, lane);
  __shared__ int ws[4];
  if (lane == 63) ws[wv] = incl;
  __syncthreads();
  int pre = 0;
  for (int j = 0; j < 4; ++j) if (j < wv) pre += ws[j];
  incl += pre;
  if (tid < NBLK_SCAN) bpre[tid] = incl - v;
  if (tid == NBLK_SCAN - 1) offs[NODES_ALL] = incl;
  for (int i = tid; i < BATCH * H_DIM; i += 256) g[i] = 0x007FFFFFu;
}

__global__ __launch_bounds__(256) void scanC_kernel(const int* __restrict__ cnt,
                                                    const int* __restrict__ bpre,
                                                    int* __restrict__ offs) {
  const int tid = threadIdx.x, lane = tid & 63, wv = tid >> 6;
  const int i4 = blockIdx.x * 256 + tid;
  int4 v = make_int4(0, 0, 0, 0);
  if (i4 < N4_SCAN) v = reinterpret_cast<const int4*>(cnt)[i4];
  const int tsum = v.x + v.y + v.z + v.w;
  int incl = wave_iscan(tsum, lane);
  __shared__ int ws[4];
  if (lane == 63) ws[wv] = incl;
  __syncthreads();
  int pre = bpre[blockIdx.x];
  for (int j = 0; j < 4; ++j) if (j < wv) pre += ws[j];
  int o0 = pre + incl - tsum;
  if (i4 < N4_SCAN) {
    int4 ov = make_int4(o0, o0 + v.x, o0 + v.x + v.y, o0 + v.x + v.y + v.z);
    reinterpret_cast<int4*>(offs)[i4] = ov;
  }
}

// ======================= aggregation =======================
struct AggArgs {
  const u16 *q_td, *q_wd, *q_tt, *q_wt, *q_ww;
  const u8 *kv_t, *kv_w, *vp_t, *vp_w;
  const float *uf_t, *uf_w;
  const int *csrc, *offs;
  const float *pri;
  u16 *t2_d, *t2_t, *t_w;
};

static __device__ __forceinline__ void butterfly4(
    f32x2 acc0, f32x2 acc1, f32x2 acc2, f32x2 acc3, float ss,
    int lane, f32x2& red, float& ss_out)
{
  ss += __shfl_xor(ss, 16); ss += __shfl_xor(ss, 32);
  const bool h16 = (lane & 16) != 0, h32 = (lane & 32) != 0;
  f32x2 k0 = h16 ? acc2 : acc0;
  f32x2 k1 = h16 ? acc3 : acc1;
  f32x2 s0 = h16 ? acc0 : acc2;
  f32x2 s1 = h16 ? acc1 : acc3;
  k0[0] += __shfl_xor(s0[0], 16); k0[1] += __shfl_xor(s0[1], 16);
  k1[0] += __shfl_xor(s1[0], 16); k1[1] += __shfl_xor(s1[1], 16);
  f32x2 kk = h32 ? k1 : k0;
  f32x2 sd = h32 ? k0 : k1;
  kk[0] += __shfl_xor(sd[0], 32); kk[1] += __shfl_xor(sd[1], 32);
  red = kk; ss_out = ss;
}

static __device__ __forceinline__ void agg_core(
    const u16* __restrict__ q, const u8* __restrict__ kv,
    const int* __restrict__ offs, const int* __restrict__ csrc,
    const float* __restrict__ pri,
    int node, int grp, int stride, int sl, int lane,
    f32x2& red, float& ss_out)
{
  const int e0 = offs[node], e1 = offs[node + 1];
  f32x2 acc0 = (f32x2)0.f, acc1 = (f32x2)0.f, acc2 = (f32x2)0.f, acc3 = (f32x2)0.f;
  float ss = 0.f;
  if (e1 > e0) {
    const float prih = pri[sl >> 2] * 0.17677669529663687f;
    const bf16x8 qv = *reinterpret_cast<const bf16x8*>(q + (size_t)node * 128 + sl * 8);
    f32x2 q2[4];
    #pragma unroll
    for (int p = 0; p < 4; ++p) {
      f32x2 t; t[0] = b2f((u16)qv[2 * p]); t[1] = b2f((u16)qv[2 * p + 1]); q2[p] = t;
    }
    const int last = e1 - 1;
    for (int base = e0; base < e1; base += 2 * stride) {
      const int eA = base + grp, eB = base + stride + grp;
      const bool vA = eA < e1, vB = eB < e1;
      const int sA = csrc[vA ? eA : last];
      const int sB = csrc[vB ? eB : last];
      const uint4 cA = *reinterpret_cast<const uint4*>(kv + (size_t)sA * 256 + sl * 16);
      const uint4 cB = *reinterpret_cast<const uint4*>(kv + (size_t)sB * 256 + sl * 16);
      f32x2 dA = q2[0] * cvt8<false>((int)cA.x);
      dA += q2[1] * cvt8<true>((int)cA.x);
      dA += q2[2] * cvt8<false>((int)cA.y);
      dA += q2[3] * cvt8<true>((int)cA.y);
      f32x2 dB = q2[0] * cvt8<false>((int)cB.x);
      dB += q2[1] * cvt8<true>((int)cB.x);
      dB += q2[2] * cvt8<false>((int)cB.y);
      dB += q2[3] * cvt8<true>((int)cB.y);
      float dotA = dA[0] + dA[1];
      float dotB = dB[0] + dB[1];
      dotA += __shfl_xor(dotA, 1); dotA += __shfl_xor(dotA, 2);
      dotB += __shfl_xor(dotB, 1); dotB += __shfl_xor(dotB, 2);
      const float wA = vA ? __expf(dotA * prih) : 0.f;
      const float wB = vB ? __expf(dotB * prih) : 0.f;
      ss += wA + wB;
      f32x2 wA2; wA2[0] = wA; wA2[1] = wA;
      f32x2 wB2; wB2[0] = wB; wB2[1] = wB;
      acc0 += wA2 * cvt8<false>((int)cA.z);
      acc1 += wA2 * cvt8<true>((int)cA.z);
      acc2 += wA2 * cvt8<false>((int)cA.w);
      acc3 += wA2 * cvt8<true>((int)cA.w);
      acc0 += wB2 * cvt8<false>((int)cB.z);
      acc1 += wB2 * cvt8<true>((int)cB.z);
      acc2 += wB2 * cvt8<false>((int)cB.w);
      acc3 += wB2 * cvt8<true>((int)cB.w);
    }
  }
  butterfly4(acc0, acc1, acc2, acc3, ss, lane, red, ss_out);
}

static __device__ __forceinline__ void agg_docu(
    const u8* __restrict__ vp, const float* __restrict__ uf,
    const int* __restrict__ offs, const int* __restrict__ csrc,
    int node, int sub, int sl, int lane,
    f32x2& red, float& ss_out)
{
  const int e0 = offs[node], e1 = offs[node + 1];
  f32x2 acc0 = (f32x2)0.f, acc1 = (f32x2)0.f, acc2 = (f32x2)0.f, acc3 = (f32x2)0.f;
  float ss = 0.f;
  if (e1 > e0) {
    const int h = sl >> 2;
    const int last = e1 - 1;
    for (int base = e0; base < e1; base += 8) {
      const int eA = base + sub, eB = base + 4 + sub;
      const bool vA = eA < e1, vB = eB < e1;
      const int sA = csrc[vA ? eA : last];
      const int sB = csrc[vB ? eB : last];
      uint2 cA = *reinterpret_cast<const uint2*>(vp + (size_t)sA * 128 + sl * 8);
      uint2 cB = *reinterpret_cast<const uint2*>(vp + (size_t)sB * 128 + sl * 8);
      float uA = uf[sA * 4 + h];
      float uB = uf[sB * 4 + h];
      if (!vA) { cA = make_uint2(0u, 0u); uA = 0.f; }
      if (!vB) { cB = make_uint2(0u, 0u); uB = 0.f; }
      ss += uA + uB;
      acc0 += cvt8<false>((int)cA.x); acc1 += cvt8<true>((int)cA.x);
      acc2 += cvt8<false>((int)cA.y); acc3 += cvt8<true>((int)cA.y);
      acc0 += cvt8<false>((int)cB.x); acc1 += cvt8<true>((int)cB.x);
      acc2 += cvt8<false>((int)cB.y); acc3 += cvt8<true>((int)cB.y);
    }
  }
  butterfly4(acc0, acc1, acc2, acc3, ss, lane, red, ss_out);
}

static __device__ __forceinline__ int chbase_of(int lane) {
  return (lane & 15) * 8 + ((lane >> 4) & 1) * 4 + ((lane >> 5) & 1) * 2;
}

template<int DOCU>
__global__ __launch_bounds__(256) void agg_all_kernel(AggArgs A, int topic_n)
{
  __shared__ float lacc[4][128];
  __shared__ float lssA[4];
  const int tid = threadIdx.x, lane = tid & 63, wv = tid >> 6;
  const int sub = lane >> 4, sl = lane & 15;
  const int bid = blockIdx.x;
  const int chb = chbase_of(lane);
  f32x2 red; float ss;

  if (bid < topic_n) {
    const int node = bid;
    for (int r = 0; r < 2; ++r) {
      agg_core(r ? A.q_wt : A.q_tt, r ? A.kv_w : A.kv_t,
               A.offs + (r ? 64800 : 64000), A.csrc, A.pri + (r ? 12 : 4),
               node, wv * 4 + sub, 16, sl, lane, red, ss);
      lacc[wv][chb] = red[0]; lacc[wv][chb + 1] = red[1];
      if (lane == 0) lssA[wv] = ss;
      __syncthreads();
      if (tid < 128) {
        float a = lacc[0][tid] + lacc[1][tid] + lacc[2][tid] + lacc[3][tid];
        float st = lssA[0] + lssA[1] + lssA[2] + lssA[3];
        float inv = (st > 0.f) ? 1.f / st : 0.f;
        A.t2_t[(size_t)node * 256 + r * 128 + tid] = f2bf(a * inv);
      }
      __syncthreads();
    }
  } else if (bid < topic_n + 8000) {
    const int node = (bid - topic_n) * 4 + wv;
    if (DOCU) {
      agg_docu(A.vp_t, A.uf_t, A.offs + 0, A.csrc, node, sub, sl, lane, red, ss);
    } else {
      agg_core(A.q_td, A.kv_t, A.offs + 0, A.csrc, A.pri + 0, node, sub, 4, sl, lane, red, ss);
    }
    {
      float inv = (ss > 0.f) ? 1.f / ss : 0.f;
      unsigned pk = (unsigned)f2bf(red[0] * inv) | ((unsigned)f2bf(red[1] * inv) << 16);
      *reinterpret_cast<unsigned*>(A.t2_d + (size_t)node * 256 + chb) = pk;
    }
    if (DOCU) {
      agg_docu(A.vp_w, A.uf_w, A.offs + 32000, A.csrc, node, sub, sl, lane, red, ss);
    } else {
      agg_core(A.q_wd, A.kv_w, A.offs + 32000, A.csrc, A.pri + 8, node, sub, 4, sl, lane, red, ss);
    }
    {
      float inv = (ss > 0.f) ? 1.f / ss : 0.f;
      unsigned pk = (unsigned)f2bf(red[0] * inv) | ((unsigned)f2bf(red[1] * inv) << 16);
      *reinterpret_cast<unsigned*>(A.t2_d + (size_t)node * 256 + 128 + chb) = pk;
    }
  } else {
    const int node = (bid - topic_n - 8000) * 4 + wv;
    agg_core(A.q_ww, A.kv_w, A.offs + 65600, A.csrc, A.pri + 16, node, sub, 4, sl, lane, red, ss);
    float inv = (ss > 0.f) ? 1.f / ss : 0.f;
    unsigned pk = (unsigned)f2bf(red[0] * inv) | ((unsigned)f2bf(red[1] * inv) << 16);
    *reinterpret_cast<unsigned*>(A.t_w + (size_t)node * 128 + chb) = pk;
  }
}

// ======================= readout =======================
__global__ void segmax_kernel(const u16* __restrict__ hd, const int* __restrict__ gid,
                              unsigned* g) {
  int c = threadIdx.x;
  int d0 = blockIdx.x * 128;
  int dend = min(d0 + 128, N_DOC);
  int cur = -1; float m = 0.f;
  for (int d = d0; d < dend; ++d) {
    int gg = gid[d];
    float v = b2f(hd[(size_t)d * 128 + c]);
    if (gg != cur) {
      if (cur >= 0) atomicMax(&g[cur * 128 + c], fenc(m));
      cur = gg; m = v;
    } else {
      m = fmaxf(m, v);
    }
  }
  if (cur >= 0) atomicMax(&g[cur * 128 + c], fenc(m));
}

__global__ void final_kernel(const unsigned* __restrict__ g, const float* __restrict__ out_w,
                             const float* __restrict__ out_b, const float* __restrict__ y,
                             float* out) {
  int tid = threadIdx.x;
  int b = tid >> 4, seg = tid & 15;
  float p = 0.f;
  #pragma unroll
  for (int j = 0; j < 8; ++j) {
    int c = seg * 8 + j;
    p += fdec(g[b * 128 + c]) * out_w[c];
  }
  p += __shfl_xor(p, 1);
  p += __shfl_xor(p, 2);
  p += __shfl_xor(p, 4);
  p += __shfl_xor(p, 8);
  __shared__ float logits[BATCH];
  __shared__ float losses[BATCH];
  if (seg == 0) logits[b] = p + out_b[0];
  __syncthreads();
  if (tid < BATCH) {
    float l = logits[tid];
    out[1 + tid] = 1.f / (1.f + expf(-l));
    float ls_pos = (l > 0.f) ? -log1pf(expf(-l)) : l - log1pf(expf(l));
    float ls_neg = (l < 0.f) ? -log1pf(expf(l)) : -l - log1pf(expf(-l));
    losses[tid] = -(y[tid] * ls_pos + (1.f - y[tid]) * ls_neg);
  }
  __syncthreads();
  if (tid == 0) {
    float s = 0.f;
    for (int j = 0; j < BATCH; ++j) s += losses[j];
    out[0] = s / (float)BATCH;
  }
}

// ======================= host =======================
extern "C" void kernel_launch(void* const* d_in, const int* in_sizes, int n_in,
                              void* d_out, int out_size, void* d_ws, size_t ws_size,
                              hipStream_t stream)
{
  const float* word_embeds  = (const float*)d_in[0];
  const float* topic_embeds = (const float*)d_in[1];
  const float* KW  = (const float*)d_in[2];
  const float* Kb  = (const float*)d_in[3];
  const float* QW  = (const float*)d_in[4];
  const float* Qb  = (const float*)d_in[5];
  const float* VW  = (const float*)d_in[6];
  const float* Vb  = (const float*)d_in[7];
  const float* AW  = (const float*)d_in[8];
  const float* Ab  = (const float*)d_in[9];
  const float* rel_att = (const float*)d_in[10];
  const float* rel_msg = (const float*)d_in[11];
  const float* rel_pri = (const float*)d_in[12];
  const float* skip    = (const float*)d_in[13];
  const float* adapt_w = (const float*)d_in[14];
  const float* adapt_b = (const float*)d_in[15];
  const float* out_w   = (const float*)d_in[16];
  const float* out_b   = (const float*)d_in[17];
  const float* y_data  = (const float*)d_in[18];
  const int* word_ids  = (const int*)d_in[19];
  const int* topic_ids = (const int*)d_in[20];
  const int* doc_gid   = (const int*)d_in[21];
  const int* td_src = (const int*)d_in[22];
  const int* td_dst = (const int*)d_in[23];
  const int* tt_src = (const int*)d_in[24];
  const int* tt_dst = (const int*)d_in[25];
  const int* wd_src = (const int*)d_in[26];
  const int* wd_dst = (const int*)d_in[27];
  const int* wt_src = (const int*)d_in[28];
  const int* wt_dst = (const int*)d_in[29];
  const int* ww_src = (const int*)d_in[30];
  const int* ww_dst = (const int*)d_in[31];

  char* base = (char*)d_ws;
  size_t off_b = 0;
  auto alloc = [&](size_t bytes) -> char* {
    char* p = base + off_b;
    off_b = (off_b + bytes + 255) & ~(size_t)255;
    return p;
  };

  u16* wtab = (u16*)alloc((size_t)VOCAB * 320 * 2);
  u16* hw   = (u16*)alloc((size_t)N_WORD * 128 * 2);
  u16* hd   = (u16*)alloc((size_t)N_DOC * 128 * 2);
  u16* ht   = (u16*)alloc((size_t)N_TOPIC * 128 * 2);
  u8*  kv_w = (u8*)alloc((size_t)N_WORD * 256);
  u8*  kv_t = (u8*)alloc((size_t)N_TOPIC * 256);
  u8*  vp_w = (u8*)alloc((size_t)N_WORD * 128);
  u8*  vp_t = (u8*)alloc((size_t)N_TOPIC * 128);
  float* uf_w = (float*)alloc((size_t)N_WORD * 4 * 4);
  float* uf_t = (float*)alloc((size_t)N_TOPIC * 4 * 4);
  u16* q_td = (u16*)alloc((size_t)N_DOC * 128 * 2);
  u16* q_wd = (u16*)alloc((size_t)N_DOC * 128 * 2);
  u16* q_tt = (u16*)alloc((size_t)N_TOPIC * 128 * 2);
  u16* q_wt = (u16*)alloc((size_t)N_TOPIC * 128 * 2);
  u16* q_ww = (u16*)alloc((size_t)N_WORD * 128 * 2);
  u16* t2_d = (u16*)alloc((size_t)N_DOC * 256 * 2);
  u16* t2_t = (u16*)alloc((size_t)N_TOPIC * 256 * 2);
  u16* t_w  = (u16*)alloc((size_t)N_WORD * 128 * 2);
  unsigned* g = (unsigned*)alloc((size_t)BATCH * 128 * 4);

  int* cnt_all  = (int*)alloc((size_t)NODES_ALL * 4);
  int* offs_all = (int*)alloc(((size_t)NODES_ALL + 1) * 4);
  int* csrc_all = (int*)alloc((size_t)EDGES_ALL * 4);
  int* rank_all = (int*)alloc((size_t)EDGES_ALL * 4);
  int* bsum     = (int*)alloc((size_t)NBLK_SCAN * 4);
  int* bpre     = (int*)alloc((size_t)NBLK_SCAN * 4);

  u16* blw        = (u16*)alloc((size_t)(40960 + 28 * 16384) * 2);
  float* bias_are = (float*)alloc((size_t)29 * 128 * 4);

  auto BLp = [&](int wid) -> const u16* {
    return (wid == 0) ? blw : blw + 40960 + (size_t)(wid - 1) * 16384;
  };
  auto BIp = [&](int wid) -> const float* { return bias_are + wid * 128; };
  auto WID = [&](int li, int j) { return 1 + li * 14 + j; };

  // ---- prep ----
  prep_kernel<<<29 * 8, 256, 0, stream>>>(KW, Kb, QW, Qb, VW, Vb, AW, Ab,
                                          rel_att, rel_msg, adapt_w, adapt_b, blw, bias_are);
  conv_wtab_kernel<<<(VOCAB * 320 + 255) / 256, 256, 0, stream>>>(word_embeds, wtab);
  gather_topic_kernel<<<(N_TOPIC * 128 + 255) / 256, 256, 0, stream>>>(topic_embeds, topic_ids, ht);

  hipMemsetAsync(cnt_all, 0, (size_t)NODES_ALL * 4, stream);
  count_rank_kernel<<<(EDGES_ALL + 255) / 256, 256, 0, stream>>>(
      td_dst, wd_dst, tt_dst, wt_dst, ww_dst, cnt_all, rank_all);
  scanA_kernel<<<NBLK_SCAN, 256, 0, stream>>>(cnt_all, bsum);
  scanB_kernel<<<1, 256, 0, stream>>>(bsum, bpre, offs_all, g);
  scanC_kernel<<<NBLK_SCAN, 256, 0, stream>>>(cnt_all, bpre, offs_all);
  fill_rank_kernel<<<(EDGES_ALL + 255) / 256, 256, 0, stream>>>(
      td_src, td_dst, wd_src, wd_dst, tt_src, tt_dst, wt_src, wt_dst, ww_src, ww_dst,
      offs_all, rank_all, csrc_all);

  const int GW = (N_WORD + 63) / 64, GD = (N_DOC + 63) / 64, GT = (N_TOPIC + 63) / 64;

  // ================= layer 0 =================
  adapt_l0w_kernel<<<GW, 256, 0, stream>>>(
      wtab, word_ids,
      BLp(0), BIp(0),
      BLp(WID(0, 1)), BIp(WID(0, 1)),
      BLp(WID(0, 3)), BIp(WID(0, 3)),
      BLp(WID(0, 8)), BIp(WID(0, 8)),
      BIp(WID(0, 6)), rel_pri + 8,
      hw, kv_w, vp_w, uf_w, q_ww, N_WORD);
  gemmN_l0t_kernel<<<GT, 256, 0, stream>>>(
      ht,
      BLp(WID(0, 0)), BIp(WID(0, 0)),
      BLp(WID(0, 2)), BIp(WID(0, 2)),
      BLp(WID(0, 5)), BIp(WID(0, 5)),
      BLp(WID(0, 7)), BIp(WID(0, 7)),
      BIp(WID(0, 4)), rel_pri + 0,
      kv_t, vp_t, uf_t, q_tt, q_wt, N_TOPIC);

  AggArgs A0;
  A0.q_td = q_td; A0.q_wd = q_wd; A0.q_tt = q_tt; A0.q_wt = q_wt; A0.q_ww = q_ww;
  A0.kv_t = kv_t; A0.kv_w = kv_w; A0.vp_t = vp_t; A0.vp_w = vp_w;
  A0.uf_t = uf_t; A0.uf_w = uf_w;
  A0.csrc = csrc_all; A0.offs = offs_all;
  A0.pri = rel_pri;
  A0.t2_d = t2_d; A0.t2_t = t2_t; A0.t_w = t_w;
  agg_all_kernel<1><<<28800, 256, 0, stream>>>(A0, 800);

  comb_dq_kernel<<<GD, 256, 0, stream>>>(
      t2_d, BLp(WID(0, 9)), BLp(WID(0, 11)), BIp(WID(0, 9)), skip + 0,
      BLp(WID(1, 4)), BIp(WID(1, 4)), BLp(WID(1, 6)), BIp(WID(1, 6)),
      hd, q_td, q_wd, N_DOC);
  gemm2_kernel<4><<<GT, 256, 0, stream>>>(t2_t, BLp(WID(0, 10)), BLp(WID(0, 12)),
                                          BIp(WID(0, 10)), ht, skip + 1, N_TOPIC);
  comb_kv_kernel<<<GW, 256, 0, stream>>>(
      t_w, hw, BLp(WID(0, 13)), BIp(WID(0, 13)),
      BLp(WID(1, 1)), BIp(WID(1, 1)), BLp(WID(1, 3)), BIp(WID(1, 3)),
      skip + 2, kv_w, N_WORD);

  // ================= layer 1 =================
  gemm_kv_kernel<<<GT, 256, 0, stream>>>(
      ht, BLp(WID(1, 0)), BIp(WID(1, 0)), BLp(WID(1, 2)), BIp(WID(1, 2)), kv_t, N_TOPIC);

  AggArgs A1 = A0;
  A1.pri = rel_pri + 20;
  agg_all_kernel<0><<<8000, 256, 0, stream>>>(A1, 0);

  gemm2_kernel<4><<<GD, 256, 0, stream>>>(t2_d, BLp(WID(1, 9)), BLp(WID(1, 11)),
                                          BIp(WID(1, 9)), hd, skip + 3, N_DOC);

  // ---- readout ----
  segmax_kernel<<<(N_DOC + 127) / 128, 128, 0, stream>>>(hd, doc_gid, g);
  final_kernel<<<1, 256, 0, stream>>>(g, out_w, out_b, y_data, (float*)d_out);
}